// Round 1
// baseline (2344.137 us; speedup 1.0000x reference)
//
#include <hip/hip_runtime.h>
#include <math.h>

constexpr int N_    = 30000;
constexpr int E_    = 200000;
constexpr int EALL_ = 400000;
constexpr int R_    = 500;
constexpr int EH_   = 300;
constexpr int RH_   = 100;
constexpr int X2D_  = EH_ + 2*RH_;   // 500
constexpr int OUTD_ = 2*X2D_;        // 1000

__device__ __forceinline__ float lrelu_(float v){ return v > 0.f ? v : 0.01f*v; }

// ---------------- CSR build ----------------
__global__ void k_count(const int* __restrict__ ids, int* __restrict__ cnt, int n){
  int e = blockIdx.x*blockDim.x + threadIdx.x;
  if (e < n) atomicAdd(&cnt[ids[e]], 1);
}

__global__ void k_exscan(const int* __restrict__ cnt, int* __restrict__ off, int L){
  __shared__ int buf[1024];
  __shared__ int carry;
  int t = threadIdx.x;
  if (t == 0) carry = 0;
  __syncthreads();
  for (int b = 0; b < L; b += 1024) {
    int v = (b + t < L) ? cnt[b + t] : 0;
    buf[t] = v;
    __syncthreads();
    for (int o = 1; o < 1024; o <<= 1) {
      int add = (t >= o) ? buf[t - o] : 0;
      __syncthreads();
      buf[t] += add;
      __syncthreads();
    }
    if (b + t < L) off[b + t] = carry + buf[t] - v;  // exclusive
    int total = buf[1023];
    __syncthreads();
    if (t == 0) carry += total;
    __syncthreads();
  }
  if (t == 0) off[L] = carry;
}

__global__ void k_dis(const int* __restrict__ cnt, float* __restrict__ dis, int n){
  int i = blockIdx.x*blockDim.x + threadIdx.x;
  if (i < n){ int c = cnt[i]; dis[i] = (c > 0) ? rsqrtf((float)c) : 0.f; }
}

__global__ void k_scatter(const int* __restrict__ ids, const int* __restrict__ off,
                          int* __restrict__ cur, int* __restrict__ el, int n){
  int e = blockIdx.x*blockDim.x + threadIdx.x;
  if (e < n){ int s = ids[e]; int p = off[s] + atomicAdd(&cur[s], 1); el[p] = e; }
}

// ---------------- generic GEMM: C[M,Nn] = A[M,K](lda) * W[Nn,K]^T ----------------
__global__ void k_gemm(const float* __restrict__ A, int lda,
                       const float* __restrict__ W,
                       float* __restrict__ C, int ldc,
                       int M, int Nn, int K){
  __shared__ float As[16][65];
  __shared__ float Bs[16][65];
  int tid = threadIdx.x;
  int tx = tid & 15, ty = tid >> 4;
  int m0 = blockIdx.x * 64, n0 = blockIdx.y * 64;
  float acc[4][4] = {{0.f}};
  for (int k0 = 0; k0 < K; k0 += 16) {
    for (int i = tid; i < 64*16; i += 256) {
      int m = i >> 4, k = i & 15;
      float v = 0.f;
      if (m0 + m < M && k0 + k < K) v = A[(size_t)(m0+m)*lda + k0 + k];
      As[k][m] = v;
    }
    for (int i = tid; i < 64*16; i += 256) {
      int n = i >> 4, k = i & 15;
      float v = 0.f;
      if (n0 + n < Nn && k0 + k < K) v = W[(size_t)(n0+n)*K + k0 + k];
      Bs[k][n] = v;
    }
    __syncthreads();
    #pragma unroll
    for (int kk = 0; kk < 16; ++kk) {
      float a[4], b[4];
      #pragma unroll
      for (int p=0;p<4;++p) a[p] = As[kk][ty*4+p];
      #pragma unroll
      for (int q=0;q<4;++q) b[q] = Bs[kk][tx*4+q];
      #pragma unroll
      for (int p=0;p<4;++p)
        #pragma unroll
        for (int q=0;q<4;++q) acc[p][q] += a[p]*b[q];
    }
    __syncthreads();
  }
  for (int p=0;p<4;++p){
    int m = m0 + ty*4 + p;
    if (m < M) for (int q=0;q<4;++q){
      int n = n0 + tx*4 + q;
      if (n < Nn) C[(size_t)m*ldc + n] = acc[p][q];
    }
  }
}

// ---------------- GCN gather: Y[i] = relu(dis[i] * sum_e dis[j]*X[j]) ----------------
__global__ void k_gcn(const int* __restrict__ off, const int* __restrict__ el,
                      const int* __restrict__ src, const float* __restrict__ dis,
                      const float* __restrict__ X, int ldx, float* __restrict__ Y){
  int n = blockIdx.x;
  int f = threadIdx.x;  // 320 threads, f < 300 active
  int s = off[n], t = off[n+1];
  float acc = 0.f;
  for (int p = s; p < t; ++p) {
    int j = src[el[p]];
    float w = dis[j];
    if (f < EH_) acc += w * X[(size_t)j*ldx + f];
  }
  if (f < EH_) {
    float v = dis[n] * acc;
    Y[(size_t)n*EH_ + f] = fmaxf(v, 0.f);
  }
}

// ---------------- highway combine ----------------
__global__ void k_highway(const float* __restrict__ Xold, int ldo,
                          const float* __restrict__ Y, const float* __restrict__ G,
                          const float* __restrict__ b,
                          float* __restrict__ Xn, int ldn){
  int idx = blockIdx.x*blockDim.x + threadIdx.x;
  if (idx >= N_*EH_) return;
  int n = idx / EH_, f = idx - n*EH_;
  float z = G[idx] + b[f];
  float gate = 1.f/(1.f + expf(-z));
  float xo = Xold[(size_t)n*ldo + f];
  Xn[(size_t)n*ldn + f] = gate*Y[idx] + (1.f-gate)*xo;
}

// ---------------- E2R small projections p1..p4 [N,2] ----------------
__global__ void k_pproj(const float* __restrict__ xh, const float* __restrict__ xt,
                        const float* __restrict__ ah, const float* __restrict__ at,
                        float* __restrict__ p1, float* __restrict__ p2,
                        float* __restrict__ p3, float* __restrict__ p4){
  int n = blockIdx.x*blockDim.x + threadIdx.x;
  if (n >= N_) return;
  float a0=0,a1=0,b0=0,b1=0,c0=0,c1=0,d0=0,d1=0;
  for (int f=0; f<RH_; ++f) {
    float vh = xh[(size_t)n*RH_+f], vt = xt[(size_t)n*RH_+f];
    float w0 = ah[f], w1 = ah[RH_+f], u0 = at[f], u1 = at[RH_+f];
    a0 += vh*w0; a1 += vh*w1;   // p1 = xh@ah^T
    b0 += vt*u0; b1 += vt*u1;   // p2 = xt@at^T
    c0 += vt*w0; c1 += vt*w1;   // p3 = xt@ah^T
    d0 += vh*u0; d1 += vh*u1;   // p4 = xh@at^T
  }
  p1[n*2]=a0; p1[n*2+1]=a1; p2[n*2]=b0; p2[n*2+1]=b1;
  p3[n*2]=c0; p3[n*2+1]=c1; p4[n*2]=d0; p4[n*2+1]=d1;
}

__global__ void k_e2r_logits(const int* __restrict__ hi, const int* __restrict__ ti,
                             const float* __restrict__ p1, const float* __restrict__ p2,
                             const float* __restrict__ p3, const float* __restrict__ p4,
                             float* __restrict__ e1, float* __restrict__ e2){
  int e = blockIdx.x*blockDim.x + threadIdx.x;
  if (e >= E_) return;
  int h = hi[e], t = ti[e];
  #pragma unroll
  for (int k=0;k<2;++k){
    e1[e*2+k] = lrelu_(p1[h*2+k] + p2[t*2+k]);
    e2[e*2+k] = lrelu_(p3[h*2+k] + p4[t*2+k]);
  }
}

// ---------------- segment softmax stats (wave per segment) ----------------
template<int K>
__global__ void k_segstats(const int* __restrict__ off, const int* __restrict__ el,
                           const float* __restrict__ l,
                           float* __restrict__ mo, float* __restrict__ so){
  int seg = blockIdx.x;
  int t = threadIdx.x;           // 64
  int k = t & (K - 1);
  int g = t / K;
  const int GS = 64 / K;
  int s = off[seg], e = off[seg + 1];
  float m = -1e30f;
  for (int p = s + g; p < e; p += GS) m = fmaxf(m, l[(size_t)el[p]*K + k]);
  #pragma unroll
  for (int o = K; o < 64; o <<= 1) m = fmaxf(m, __shfl_xor(m, o));
  float sum = 0.f;
  for (int p = s + g; p < e; p += GS) sum += expf(l[(size_t)el[p]*K + k] - m);
  #pragma unroll
  for (int o = K; o < 64; o <<= 1) sum += __shfl_xor(sum, o);
  if (t < K) { mo[(size_t)seg*K + t] = m; so[(size_t)seg*K + t] = sum; }
}

// per-edge sum over heads of softmax alpha
template<int K>
__global__ void k_alsum(const float* __restrict__ l, const int* __restrict__ seg,
                        const float* __restrict__ m, const float* __restrict__ s,
                        float* __restrict__ out, int n){
  int e = blockIdx.x*blockDim.x + threadIdx.x;
  if (e >= n) return;
  int sg = seg[e];
  float acc = 0.f;
  #pragma unroll
  for (int k = 0; k < K; ++k)
    acc += expf(l[(size_t)e*K + k] - m[(size_t)sg*K + k]) / (s[(size_t)sg*K + k] + 1e-16f);
  out[e] = acc;
}

// ---------------- E2R aggregate into x_r [R,100] ----------------
__global__ void k_e2r_agg(const int* __restrict__ off, const int* __restrict__ el,
                          const int* __restrict__ hi, const int* __restrict__ ti,
                          const float* __restrict__ s1, const float* __restrict__ s2,
                          const float* __restrict__ xh, const float* __restrict__ xt,
                          float* __restrict__ xr){
  int r = blockIdx.x;
  int f = threadIdx.x;           // 128, f < 100 active
  int s = off[r], e = off[r+1];
  float aH = 0.f, aT = 0.f;
  for (int p = s; p < e; ++p) {
    int ed = el[p];
    if (f < RH_) {
      aH += s1[ed] * xh[(size_t)hi[ed]*RH_ + f];
      aT += s2[ed] * xt[(size_t)ti[ed]*RH_ + f];
    }
  }
  if (f < RH_) xr[(size_t)r*RH_ + f] = (aH + aT) * 0.25f;
}

// ---------------- R2E ----------------
__global__ void k_r2e_logits(const int* __restrict__ hi, const int* __restrict__ ti,
                             const int* __restrict__ rl,
                             const float* __restrict__ seh, const float* __restrict__ set_,
                             const float* __restrict__ sr,
                             float* __restrict__ lh, float* __restrict__ lt){
  int e = blockIdx.x*blockDim.x + threadIdx.x;
  if (e >= E_) return;
  int h = hi[e], t = ti[e], r = rl[e];
  #pragma unroll
  for (int k=0;k<8;++k){
    lh[(size_t)e*8+k] = lrelu_(seh[(size_t)h*8+k] + sr[(size_t)r*8+k]);
    lt[(size_t)e*8+k] = lrelu_(set_[(size_t)t*8+k] + sr[(size_t)r*8+k]);
  }
}

__global__ void k_r2e_agg(const int* __restrict__ off, const int* __restrict__ el,
                          const int* __restrict__ rl, const float* __restrict__ sE,
                          const float* __restrict__ xr, float* __restrict__ out, int col){
  int n = blockIdx.x;
  int f = threadIdx.x;           // 128, f < 100 active
  int s = off[n], e = off[n+1];
  float a = 0.f;
  for (int p = s; p < e; ++p) {
    int ed = el[p];
    if (f < RH_) a += sE[ed] * xr[(size_t)rl[ed]*RH_ + f];
  }
  if (f < RH_) out[(size_t)n*OUTD_ + col + f] = a * 0.125f;
}

// ---------------- GAT ----------------
__global__ void k_gat_logits(const int* __restrict__ ja, const int* __restrict__ ia,
                             const float* __restrict__ gi, const float* __restrict__ gj,
                             float* __restrict__ lg){
  int e = blockIdx.x*blockDim.x + threadIdx.x;
  if (e >= EALL_) return;
  int i = ia[e], j = ja[e];
  #pragma unroll
  for (int k=0;k<8;++k)
    lg[(size_t)e*8+k] = lrelu_(gi[(size_t)i*8+k] + gj[(size_t)j*8+k]);
}

__global__ void k_gat_agg(const int* __restrict__ off, const int* __restrict__ el,
                          const int* __restrict__ ja, const float* __restrict__ ag,
                          const float* __restrict__ X2, float* __restrict__ out){
  int n = blockIdx.x;
  int f = threadIdx.x;           // 512, f < 500 active
  int s = off[n], e = off[n+1];
  float a = 0.f;
  for (int p = s; p < e; ++p) {
    int ed = el[p];
    int j = ja[ed];
    if (f < X2D_) a += ag[ed] * X2[(size_t)j*OUTD_ + f];
  }
  if (f < X2D_) out[(size_t)n*OUTD_ + X2D_ + f] = a * 0.125f;
}

// ---------------- host ----------------
static inline void gemm(const float* A, int lda, const float* W, float* C, int ldc,
                        int M, int Nn, int K, hipStream_t st){
  dim3 g((M+63)/64, (Nn+63)/64);
  k_gemm<<<g, 256, 0, st>>>(A, lda, W, C, ldc, M, Nn, K);
}

extern "C" void kernel_launch(void* const* d_in, const int* in_sizes, int n_in,
                              void* d_out, int out_size, void* d_ws, size_t ws_size,
                              hipStream_t stream) {
  const float* x_e   = (const float*)d_in[0];
  const int*   ei    = (const int*)d_in[1];
  const int*   rel   = (const int*)d_in[2];
  const int*   eia   = (const int*)d_in[3];
  const float* hw1_w = (const float*)d_in[5];
  const float* hw1_b = (const float*)d_in[6];
  const float* hw2_w = (const float*)d_in[7];
  const float* hw2_b = (const float*)d_in[8];
  const float* e2r_wh= (const float*)d_in[9];
  const float* e2r_wt= (const float*)d_in[10];
  const float* e2r_ah= (const float*)d_in[11];
  const float* e2r_at= (const float*)d_in[12];
  const float* r2e_ah= (const float*)d_in[13];
  const float* r2e_at= (const float*)d_in[14];
  const float* r2e_ar= (const float*)d_in[15];
  const float* gat_ai= (const float*)d_in[16];
  const float* gat_aj= (const float*)d_in[17];
  float* out = (float*)d_out;

  const int* hi = ei;            // edge_index[0] (head)
  const int* ti = ei + E_;       // edge_index[1] (tail)
  const int* ja = eia;           // edge_index_all[0] (source j)
  const int* ia = eia + EALL_;   // edge_index_all[1] (dest i)

  char* base = (char*)d_ws;
  size_t off = 0;
  auto alloc = [&](size_t bytes)->void*{
    void* p = base + off;
    off = (off + bytes + 255) & ~(size_t)255;
    return p;
  };

  // --- zeroed int region (counts + cursors) ---
  size_t z0 = off;
  int* cnt_dest = (int*)alloc(N_*4);
  int* cur_dest = (int*)alloc(N_*4);
  int* cnt_h    = (int*)alloc(N_*4);
  int* cur_h    = (int*)alloc(N_*4);
  int* cnt_t    = (int*)alloc(N_*4);
  int* cur_t    = (int*)alloc(N_*4);
  int* cnt_rel  = (int*)alloc(R_*4);
  int* cur_rel  = (int*)alloc(R_*4);
  size_t z1 = off;

  int* off_dest = (int*)alloc((N_+1)*4);
  int* off_rel  = (int*)alloc((R_+1)*4);
  int* off_h    = (int*)alloc((N_+1)*4);
  int* off_t    = (int*)alloc((N_+1)*4);
  int* el_dest  = (int*)alloc((size_t)EALL_*4);
  int* el_rel   = (int*)alloc((size_t)E_*4);
  int* el_h     = (int*)alloc((size_t)E_*4);
  int* el_t     = (int*)alloc((size_t)E_*4);

  float* dis  = (float*)alloc(N_*4);
  float* y    = (float*)alloc((size_t)N_*EH_*4);   // 36 MB (GCN out; later re-used for lh/lt)
  float* g    = (float*)alloc((size_t)N_*EH_*4);   // 36 MB (gate pre-act; later re-used for lg)
  float* xh   = (float*)alloc((size_t)N_*RH_*4);
  float* xt   = (float*)alloc((size_t)N_*RH_*4);
  float* p1   = (float*)alloc((size_t)N_*2*4);
  float* p2   = (float*)alloc((size_t)N_*2*4);
  float* p3   = (float*)alloc((size_t)N_*2*4);
  float* p4   = (float*)alloc((size_t)N_*2*4);
  float* e1   = (float*)alloc((size_t)E_*2*4);
  float* e2   = (float*)alloc((size_t)E_*2*4);
  float* m1   = (float*)alloc((size_t)R_*2*4);
  float* s1s  = (float*)alloc((size_t)R_*2*4);
  float* m2   = (float*)alloc((size_t)R_*2*4);
  float* s2s  = (float*)alloc((size_t)R_*2*4);
  float* s1   = (float*)alloc((size_t)E_*4);
  float* s2   = (float*)alloc((size_t)E_*4);
  float* xr   = (float*)alloc((size_t)R_*RH_*4);
  float* seh  = (float*)alloc((size_t)N_*8*4);
  float* set_ = (float*)alloc((size_t)N_*8*4);
  float* sr   = (float*)alloc((size_t)R_*8*4);
  float* mh   = (float*)alloc((size_t)N_*8*4);
  float* shs  = (float*)alloc((size_t)N_*8*4);
  float* mt   = (float*)alloc((size_t)N_*8*4);
  float* sts  = (float*)alloc((size_t)N_*8*4);
  float* sh   = (float*)alloc((size_t)E_*4);
  float* st   = (float*)alloc((size_t)E_*4);
  float* gi   = (float*)alloc((size_t)N_*8*4);
  float* gj   = (float*)alloc((size_t)N_*8*4);
  float* mg   = (float*)alloc((size_t)N_*8*4);
  float* sgs  = (float*)alloc((size_t)N_*8*4);
  float* ag   = (float*)alloc((size_t)EALL_*4);

  // aliases into dead buffers (y,g free after highway2)
  float* lh = y;                 // [E,8] = 6.4 MB
  float* lt = y + (size_t)E_*8;  // fits in 36 MB
  float* lg = g;                 // [E_ALL,8] = 12.8 MB

  hipMemsetAsync(base + z0, 0, z1 - z0, stream);

  const int TB = 256;
  int gE    = (E_ + TB - 1)/TB;
  int gEall = (EALL_ + TB - 1)/TB;
  int gN    = (N_ + TB - 1)/TB;

  // ---- CSR builds ----
  k_count<<<gEall, TB, 0, stream>>>(ia,  cnt_dest, EALL_);
  k_count<<<gE,    TB, 0, stream>>>(rel, cnt_rel,  E_);
  k_count<<<gE,    TB, 0, stream>>>(hi,  cnt_h,    E_);
  k_count<<<gE,    TB, 0, stream>>>(ti,  cnt_t,    E_);
  k_exscan<<<1, 1024, 0, stream>>>(cnt_dest, off_dest, N_);
  k_exscan<<<1, 1024, 0, stream>>>(cnt_rel,  off_rel,  R_);
  k_exscan<<<1, 1024, 0, stream>>>(cnt_h,    off_h,    N_);
  k_exscan<<<1, 1024, 0, stream>>>(cnt_t,    off_t,    N_);
  k_dis<<<gN, TB, 0, stream>>>(cnt_dest, dis, N_);
  k_scatter<<<gEall, TB, 0, stream>>>(ia,  off_dest, cur_dest, el_dest, EALL_);
  k_scatter<<<gE,    TB, 0, stream>>>(rel, off_rel,  cur_rel,  el_rel,  E_);
  k_scatter<<<gE,    TB, 0, stream>>>(hi,  off_h,    cur_h,    el_h,    E_);
  k_scatter<<<gE,    TB, 0, stream>>>(ti,  off_t,    cur_t,    el_t,    E_);

  // ---- GCN + Highway block 1 (x lives in out cols 0..299, stride 1000) ----
  gemm(x_e, EH_, hw1_w, g, EH_, N_, EH_, EH_, stream);
  k_gcn<<<N_, 320, 0, stream>>>(off_dest, el_dest, ja, dis, x_e, EH_, y);
  k_highway<<<(N_*EH_ + TB - 1)/TB, TB, 0, stream>>>(x_e, EH_, y, g, hw1_b, out, OUTD_);

  // ---- block 2 ----
  gemm(out, OUTD_, hw2_w, g, EH_, N_, EH_, EH_, stream);
  k_gcn<<<N_, 320, 0, stream>>>(off_dest, el_dest, ja, dis, out, OUTD_, y);
  k_highway<<<(N_*EH_ + TB - 1)/TB, TB, 0, stream>>>(out, OUTD_, y, g, hw2_b, out, OUTD_);

  // ---- E2R ----
  gemm(out, OUTD_, e2r_wh, xh, RH_, N_, RH_, EH_, stream);
  gemm(out, OUTD_, e2r_wt, xt, RH_, N_, RH_, EH_, stream);
  k_pproj<<<gN, TB, 0, stream>>>(xh, xt, e2r_ah, e2r_at, p1, p2, p3, p4);
  k_e2r_logits<<<gE, TB, 0, stream>>>(hi, ti, p1, p2, p3, p4, e1, e2);
  k_segstats<2><<<R_, 64, 0, stream>>>(off_rel, el_rel, e1, m1, s1s);
  k_segstats<2><<<R_, 64, 0, stream>>>(off_rel, el_rel, e2, m2, s2s);
  k_alsum<2><<<gE, TB, 0, stream>>>(e1, rel, m1, s1s, s1, E_);
  k_alsum<2><<<gE, TB, 0, stream>>>(e2, rel, m2, s2s, s2, E_);
  k_e2r_agg<<<R_, 128, 0, stream>>>(off_rel, el_rel, hi, ti, s1, s2, xh, xt, xr);

  // ---- R2E ----
  gemm(out, OUTD_, r2e_ah, seh,  8, N_, 8, EH_, stream);
  gemm(out, OUTD_, r2e_at, set_, 8, N_, 8, EH_, stream);
  gemm(xr,  RH_,   r2e_ar, sr,   8, R_, 8, RH_, stream);
  k_r2e_logits<<<gE, TB, 0, stream>>>(hi, ti, rel, seh, set_, sr, lh, lt);
  k_segstats<8><<<N_, 64, 0, stream>>>(off_h, el_h, lh, mh, shs);
  k_segstats<8><<<N_, 64, 0, stream>>>(off_t, el_t, lt, mt, sts);
  k_alsum<8><<<gE, TB, 0, stream>>>(lh, hi, mh, shs, sh, E_);
  k_alsum<8><<<gE, TB, 0, stream>>>(lt, ti, mt, sts, st, E_);
  k_r2e_agg<<<N_, 128, 0, stream>>>(off_h, el_h, rel, sh, xr, out, EH_);        // cols 300..399
  k_r2e_agg<<<N_, 128, 0, stream>>>(off_t, el_t, rel, st, xr, out, EH_ + RH_);  // cols 400..499

  // ---- GAT ----
  gemm(out, OUTD_, gat_ai, gi, 8, N_, 8, X2D_, stream);
  gemm(out, OUTD_, gat_aj, gj, 8, N_, 8, X2D_, stream);
  k_gat_logits<<<gEall, TB, 0, stream>>>(ja, ia, gi, gj, lg);
  k_segstats<8><<<N_, 64, 0, stream>>>(off_dest, el_dest, lg, mg, sgs);
  k_alsum<8><<<gEall, TB, 0, stream>>>(lg, ia, mg, sgs, ag, EALL_);
  k_gat_agg<<<N_, 512, 0, stream>>>(off_dest, el_dest, ja, ag, out, out);       // cols 500..999
}

// Round 2
// 1243.305 us; speedup vs baseline: 1.8854x; 1.8854x over previous
//
#include <hip/hip_runtime.h>
#include <math.h>

constexpr int N_    = 30000;
constexpr int E_    = 200000;
constexpr int EALL_ = 400000;
constexpr int R_    = 500;
constexpr int EH_   = 300;
constexpr int RH_   = 100;
constexpr int X2D_  = 500;
constexpr int OUTD_ = 1000;
constexpr int LD4   = OUTD_/4;  // 250
constexpr int EH4   = EH_/4;    // 75
constexpr int RH4   = RH_/4;    // 25

__device__ __forceinline__ float lrelu_(float v){ return v > 0.f ? v : 0.01f*v; }
__device__ __forceinline__ float sig_(float z){ return 1.f/(1.f + expf(-z)); }

// ---------------- CSR build (fused) ----------------
__global__ void k_count4(const int* __restrict__ ia, const int* __restrict__ rel,
                         const int* __restrict__ hi, const int* __restrict__ ti,
                         int* cd, int* cr, int* ch, int* ct){
  int idx = blockIdx.x*blockDim.x + threadIdx.x;
  if (idx < EALL_) { atomicAdd(&cd[ia[idx]], 1); return; }
  idx -= EALL_;
  if (idx < E_) { atomicAdd(&cr[rel[idx]], 1); return; }
  idx -= E_;
  if (idx < E_) { atomicAdd(&ch[hi[idx]], 1); return; }
  idx -= E_;
  if (idx < E_) { atomicAdd(&ct[ti[idx]], 1); return; }
}

// 4 arrays scanned by 4 blocks
__global__ void k_scan4(const int* c0, int* o0, int L0,
                        const int* c1, int* o1, int L1,
                        const int* c2, int* o2, int L2,
                        const int* c3, int* o3, int L3){
  const int* c; int* o; int L;
  switch (blockIdx.x){
    case 0: c=c0; o=o0; L=L0; break;
    case 1: c=c1; o=o1; L=L1; break;
    case 2: c=c2; o=o2; L=L2; break;
    default: c=c3; o=o3; L=L3; break;
  }
  __shared__ int sums[256];
  int t = threadIdx.x;
  int chunk = (L + 255) / 256;
  int s = min(t*chunk, L), e = min(s + chunk, L);
  int acc = 0;
  for (int i = s; i < e; ++i) acc += c[i];
  sums[t] = acc;
  __syncthreads();
  for (int off = 1; off < 256; off <<= 1) {
    int v = (t >= off) ? sums[t - off] : 0;
    __syncthreads();
    sums[t] += v;
    __syncthreads();
  }
  int run = t ? sums[t-1] : 0;
  for (int i = s; i < e; ++i) { o[i] = run; run += c[i]; }
  if (t == 255) o[L] = sums[255];
}

__global__ void k_dis(const int* __restrict__ cnt, float* __restrict__ dis){
  int i = blockIdx.x*blockDim.x + threadIdx.x;
  if (i < N_){ int c = cnt[i]; dis[i] = (c > 0) ? rsqrtf((float)c) : 0.f; }
}

__global__ void k_scatter4(const int* __restrict__ ja, const int* __restrict__ ia,
                           const int* __restrict__ rel, const int* __restrict__ hi,
                           const int* __restrict__ ti,
                           const int* od, const int* orl, const int* oh, const int* ot,
                           int* curd, int* curr, int* curh, int* curt,
                           int* j_dest, int* pos_dest,
                           int* hr, int* tr, int* pos_rel,
                           int* relh, int* pos_h,
                           int* relt, int* pos_t){
  int idx = blockIdx.x*blockDim.x + threadIdx.x;
  if (idx < EALL_){
    int e = idx, s = ia[e];
    int p = od[s] + atomicAdd(&curd[s], 1);
    j_dest[p] = ja[e]; pos_dest[e] = p; return;
  }
  idx -= EALL_;
  if (idx < E_){
    int e = idx, s = rel[e];
    int p = orl[s] + atomicAdd(&curr[s], 1);
    hr[p] = hi[e]; tr[p] = ti[e]; pos_rel[e] = p; return;
  }
  idx -= E_;
  if (idx < E_){
    int e = idx, s = hi[e];
    int p = oh[s] + atomicAdd(&curh[s], 1);
    relh[p] = rel[e]; pos_h[e] = p; return;
  }
  idx -= E_;
  if (idx < E_){
    int e = idx, s = ti[e];
    int p = ot[s] + atomicAdd(&curt[s], 1);
    relt[p] = rel[e]; pos_t[e] = p; return;
  }
}

__global__ void k_wj(const int* __restrict__ jd, const float* __restrict__ dis,
                     float* __restrict__ wj){
  int p = blockIdx.x*blockDim.x + threadIdx.x;
  if (p < EALL_) wj[p] = dis[jd[p]];
}

// ---------------- GEMM: C[M,Nn] = A[M,K](lda) * W[Nn,K]^T ----------------
__global__ void k_gemm(const float* __restrict__ A, int lda,
                       const float* __restrict__ W,
                       float* __restrict__ C, int ldc,
                       int M, int Nn, int K){
  __shared__ float As[16][68];
  __shared__ float Bs[16][68];
  int tid = threadIdx.x;
  int tx = tid & 15, ty = tid >> 4;
  int m0 = blockIdx.x * 64, n0 = blockIdx.y * 64;
  float acc[4][4] = {{0.f}};
  for (int k0 = 0; k0 < K; k0 += 16) {
    #pragma unroll
    for (int i = 0; i < 4; ++i) {
      int idx = tid + i*256;
      int m = idx >> 4, k = idx & 15;
      float v = 0.f, w = 0.f;
      if (m0 + m < M && k0 + k < K) v = A[(size_t)(m0+m)*lda + k0 + k];
      if (n0 + m < Nn && k0 + k < K) w = W[(size_t)(n0+m)*K + k0 + k];
      As[k][m] = v;
      Bs[k][m] = w;
    }
    __syncthreads();
    #pragma unroll
    for (int kk = 0; kk < 16; ++kk) {
      float4 a = *reinterpret_cast<const float4*>(&As[kk][ty*4]);
      float4 b = *reinterpret_cast<const float4*>(&Bs[kk][tx*4]);
      acc[0][0]+=a.x*b.x; acc[0][1]+=a.x*b.y; acc[0][2]+=a.x*b.z; acc[0][3]+=a.x*b.w;
      acc[1][0]+=a.y*b.x; acc[1][1]+=a.y*b.y; acc[1][2]+=a.y*b.z; acc[1][3]+=a.y*b.w;
      acc[2][0]+=a.z*b.x; acc[2][1]+=a.z*b.y; acc[2][2]+=a.z*b.z; acc[2][3]+=a.z*b.w;
      acc[3][0]+=a.w*b.x; acc[3][1]+=a.w*b.y; acc[3][2]+=a.w*b.z; acc[3][3]+=a.w*b.w;
    }
    __syncthreads();
  }
  for (int p = 0; p < 4; ++p){
    int m = m0 + ty*4 + p;
    if (m < M) for (int q = 0; q < 4; ++q){
      int n = n0 + tx*4 + q;
      if (n < Nn) C[(size_t)m*ldc + n] = acc[p][q];
    }
  }
}

// ---------------- GCN gather ----------------
__global__ void k_gcn2(const int* __restrict__ off, const int* __restrict__ jd,
                       const float* __restrict__ wj, const float* __restrict__ dis,
                       const float4* __restrict__ X, int ldx4, float4* __restrict__ Y){
  __shared__ int js[128];
  __shared__ float ws[128];
  int n = blockIdx.x, tid = threadIdx.x;
  int s = off[n], t = off[n+1];
  float4 acc = make_float4(0.f,0.f,0.f,0.f);
  for (int base = s; base < t; base += 128){
    int m = min(128, t - base);
    __syncthreads();
    if (tid < m){ js[tid] = jd[base+tid]; ws[tid] = wj[base+tid]; }
    __syncthreads();
    if (tid < EH4){
      for (int q = 0; q < m; ++q){
        float w = ws[q];
        float4 v = X[(size_t)js[q]*ldx4 + tid];
        acc.x += w*v.x; acc.y += w*v.y; acc.z += w*v.z; acc.w += w*v.w;
      }
    }
  }
  if (tid < EH4){
    float dn = dis[n];
    float4 r;
    r.x = fmaxf(dn*acc.x, 0.f); r.y = fmaxf(dn*acc.y, 0.f);
    r.z = fmaxf(dn*acc.z, 0.f); r.w = fmaxf(dn*acc.w, 0.f);
    Y[(size_t)n*EH4 + tid] = r;
  }
}

// ---------------- highway (float4) ----------------
__global__ void k_highway2(const float4* __restrict__ Xold, int ldo4,
                           const float4* __restrict__ Y, const float4* __restrict__ G,
                           const float* __restrict__ b,
                           float4* __restrict__ Xn, int ldn4){
  int idx = blockIdx.x*blockDim.x + threadIdx.x;
  if (idx >= N_*EH4) return;
  int n = idx / EH4, f = idx - n*EH4;
  float4 g4 = G[idx];
  float4 b4 = reinterpret_cast<const float4*>(b)[f];
  float4 y4 = Y[idx];
  float4 xo = Xold[(size_t)n*ldo4 + f];
  float4 r;
  float gx;
  gx = sig_(g4.x + b4.x); r.x = gx*y4.x + (1.f-gx)*xo.x;
  gx = sig_(g4.y + b4.y); r.y = gx*y4.y + (1.f-gx)*xo.y;
  gx = sig_(g4.z + b4.z); r.z = gx*y4.z + (1.f-gx)*xo.z;
  gx = sig_(g4.w + b4.w); r.w = gx*y4.w + (1.f-gx)*xo.w;
  Xn[(size_t)n*ldn4 + f] = r;
}

// ---------------- E2R projections p1..p4 [N,2] (from fused xhxt [N,200]) ----------------
__global__ void k_pproj(const float* __restrict__ xhxt,
                        const float* __restrict__ ah, const float* __restrict__ at,
                        float* __restrict__ p1, float* __restrict__ p2,
                        float* __restrict__ p3, float* __restrict__ p4){
  int n = blockIdx.x*blockDim.x + threadIdx.x;
  if (n >= N_) return;
  float a0=0,a1=0,b0=0,b1=0,c0=0,c1=0,d0=0,d1=0;
  const float* xh = xhxt + (size_t)n*200;
  const float* xt = xh + 100;
  for (int f = 0; f < RH_; ++f) {
    float vh = xh[f], vt = xt[f];
    float w0 = ah[f], w1 = ah[RH_+f], u0 = at[f], u1 = at[RH_+f];
    a0 += vh*w0; a1 += vh*w1;
    b0 += vt*u0; b1 += vt*u1;
    c0 += vt*w0; c1 += vt*w1;
    d0 += vh*u0; d1 += vh*u1;
  }
  p1[n*2]=a0; p1[n*2+1]=a1; p2[n*2]=b0; p2[n*2+1]=b1;
  p3[n*2]=c0; p3[n*2+1]=c1; p4[n*2]=d0; p4[n*2+1]=d1;
}

__global__ void k_e2r_logits2(const int* __restrict__ hi, const int* __restrict__ ti,
                              const int* __restrict__ pos_rel,
                              const float* __restrict__ p1, const float* __restrict__ p2,
                              const float* __restrict__ p3, const float* __restrict__ p4,
                              float* __restrict__ e1p, float* __restrict__ e2p){
  int e = blockIdx.x*blockDim.x + threadIdx.x;
  if (e >= E_) return;
  int h = hi[e], t = ti[e];
  size_t pp = (size_t)pos_rel[e]*2;
  e1p[pp]   = lrelu_(p1[h*2]   + p2[t*2]);
  e1p[pp+1] = lrelu_(p1[h*2+1] + p2[t*2+1]);
  e2p[pp]   = lrelu_(p3[h*2]   + p4[t*2]);
  e2p[pp+1] = lrelu_(p3[h*2+1] + p4[t*2+1]);
}

// ---------------- segment softmax (stats + fold, permuted logits) ----------------
template<int K>
__device__ __forceinline__ void softmax_fold(const int* __restrict__ off,
                                             const float* __restrict__ lp,
                                             float* __restrict__ op, int seg){
  int lane = threadIdx.x & 63;
  int k = lane & (K - 1);
  int g = lane / K;
  const int GS = 64 / K;
  int s = off[seg], e = off[seg + 1];
  float m = -1e30f;
  for (int p = s + g; p < e; p += GS) m = fmaxf(m, lp[(size_t)p*K + k]);
  #pragma unroll
  for (int o = K; o < 64; o <<= 1) m = fmaxf(m, __shfl_xor(m, o));
  float sum = 0.f;
  for (int p = s + g; p < e; p += GS) sum += expf(lp[(size_t)p*K + k] - m);
  #pragma unroll
  for (int o = K; o < 64; o <<= 1) sum += __shfl_xor(sum, o);
  float inv = 1.f / (sum + 1e-16f);
  for (int p = s + g; p < e; p += GS){
    float t = expf(lp[(size_t)p*K + k] - m) * inv;
    #pragma unroll
    for (int o = 1; o < K; o <<= 1) t += __shfl_xor(t, o);
    if (k == 0) op[p] = t;
  }
}

__global__ void k_fold_rel(const int* __restrict__ off,
                           const float* __restrict__ e1p, const float* __restrict__ e2p,
                           float* __restrict__ s1p, float* __restrict__ s2p){
  int w = threadIdx.x >> 6;
  if (w == 0) softmax_fold<2>(off, e1p, s1p, blockIdx.x);
  else        softmax_fold<2>(off, e2p, s2p, blockIdx.x);
}

__global__ void k_fold_ht(const int* __restrict__ offh, const int* __restrict__ offt,
                          const float* __restrict__ lhp, const float* __restrict__ ltp,
                          float* __restrict__ shp, float* __restrict__ stp){
  int w = threadIdx.x >> 6;
  int n = blockIdx.x*2 + (w >> 1);
  if (n >= N_) return;
  if (w & 1) softmax_fold<8>(offt, ltp, stp, n);
  else       softmax_fold<8>(offh, lhp, shp, n);
}

__global__ void k_fold_gat(const int* __restrict__ off, const float* __restrict__ lgp,
                           float* __restrict__ agp){
  int w = threadIdx.x >> 6;
  int n = blockIdx.x*4 + w;
  if (n >= N_) return;
  softmax_fold<8>(off, lgp, agp, n);
}

// ---------------- E2R aggregate -> xr [R,100] ----------------
__global__ void k_e2r_agg2(const int* __restrict__ off,
                           const int* __restrict__ hr, const int* __restrict__ tr,
                           const float* __restrict__ s1p, const float* __restrict__ s2p,
                           const float4* __restrict__ xhxt4, float4* __restrict__ xr4){
  int r = blockIdx.x, lane = threadIdx.x;
  int s = off[r], e = off[r+1];
  if (lane >= RH4) return;
  float4 aH = make_float4(0.f,0.f,0.f,0.f);
  float4 aT = make_float4(0.f,0.f,0.f,0.f);
  for (int p = s; p < e; ++p){
    float w1 = s1p[p], w2 = s2p[p];
    float4 vh = xhxt4[(size_t)hr[p]*50 + lane];
    float4 vt = xhxt4[(size_t)tr[p]*50 + 25 + lane];
    aH.x += w1*vh.x; aH.y += w1*vh.y; aH.z += w1*vh.z; aH.w += w1*vh.w;
    aT.x += w2*vt.x; aT.y += w2*vt.y; aT.z += w2*vt.z; aT.w += w2*vt.w;
  }
  float4 o = make_float4((aH.x+aT.x)*0.25f, (aH.y+aT.y)*0.25f,
                         (aH.z+aT.z)*0.25f, (aH.w+aT.w)*0.25f);
  xr4[(size_t)r*RH4 + lane] = o;
}

// ---------------- 16-head row dots: out16[n,16] = [X@wA.T | X@wB.T] ----------------
__global__ void k_dots16(const float* __restrict__ X, int ldx, int K,
                         const float* __restrict__ wA, const float* __restrict__ wB,
                         float* __restrict__ out16, int M){
  __shared__ float xs[16][65];
  __shared__ float ws[16][65];
  int tid = threadIdx.x;
  int tx = tid & 15, ty = tid >> 4;
  int r0 = blockIdx.x*16;
  float acc = 0.f;
  for (int c0 = 0; c0 < K; c0 += 64){
    int cl = min(64, K - c0);
    #pragma unroll
    for (int i = 0; i < 4; ++i){
      int idx = tid + i*256;
      int r = idx >> 6, k = idx & 63;
      float xv = 0.f, wv = 0.f;
      if (k < cl && r0 + r < M) xv = X[(size_t)(r0+r)*ldx + c0 + k];
      if (k < cl) wv = (r < 8) ? wA[(size_t)r*K + c0 + k] : wB[(size_t)(r-8)*K + c0 + k];
      xs[r][k] = xv;
      ws[r][k] = wv;
    }
    __syncthreads();
    #pragma unroll
    for (int k = 0; k < 64; ++k) acc += xs[ty][k]*ws[tx][k];
    __syncthreads();
  }
  if (r0 + ty < M) out16[(size_t)(r0+ty)*16 + tx] = acc;
}

// ---------------- sr [R,8] ----------------
__global__ void k_sr(const float* __restrict__ xr, const float* __restrict__ ar,
                     float* __restrict__ sr8){
  int idx = blockIdx.x*blockDim.x + threadIdx.x;
  if (idx >= R_*8) return;
  int r = idx >> 3, h = idx & 7;
  float acc = 0.f;
  for (int k = 0; k < RH_; ++k) acc += xr[(size_t)r*RH_ + k]*ar[(size_t)h*RH_ + k];
  sr8[idx] = acc;
}

// ---------------- R2E logits (permuted writes) ----------------
__global__ void k_r2e_logits2(const int* __restrict__ hi, const int* __restrict__ ti,
                              const int* __restrict__ rl,
                              const float* __restrict__ st16, const float* __restrict__ sr8,
                              const int* __restrict__ pos_h, const int* __restrict__ pos_t,
                              float* __restrict__ lhp, float* __restrict__ ltp){
  int e = blockIdx.x*blockDim.x + threadIdx.x;
  if (e >= E_) return;
  int h = hi[e], t = ti[e], r = rl[e];
  const float4* sh4 = reinterpret_cast<const float4*>(st16 + (size_t)h*16);
  const float4* st4 = reinterpret_cast<const float4*>(st16 + (size_t)t*16 + 8);
  const float4* sr4 = reinterpret_cast<const float4*>(sr8 + (size_t)r*8);
  float4 a0 = sh4[0], a1 = sh4[1], b0 = st4[0], b1 = st4[1], c0 = sr4[0], c1 = sr4[1];
  float4 o0, o1;
  o0.x = lrelu_(a0.x+c0.x); o0.y = lrelu_(a0.y+c0.y); o0.z = lrelu_(a0.z+c0.z); o0.w = lrelu_(a0.w+c0.w);
  o1.x = lrelu_(a1.x+c1.x); o1.y = lrelu_(a1.y+c1.y); o1.z = lrelu_(a1.z+c1.z); o1.w = lrelu_(a1.w+c1.w);
  float4* dh = reinterpret_cast<float4*>(lhp + (size_t)pos_h[e]*8);
  dh[0] = o0; dh[1] = o1;
  o0.x = lrelu_(b0.x+c0.x); o0.y = lrelu_(b0.y+c0.y); o0.z = lrelu_(b0.z+c0.z); o0.w = lrelu_(b0.w+c0.w);
  o1.x = lrelu_(b1.x+c1.x); o1.y = lrelu_(b1.y+c1.y); o1.z = lrelu_(b1.z+c1.z); o1.w = lrelu_(b1.w+c1.w);
  float4* dt = reinterpret_cast<float4*>(ltp + (size_t)pos_t[e]*8);
  dt[0] = o0; dt[1] = o1;
}

// ---------------- R2E aggregate (h & t sides in one kernel) ----------------
__global__ void k_r2e_agg2(const int* __restrict__ offh, const int* __restrict__ offt,
                           const int* __restrict__ relh, const int* __restrict__ relt,
                           const float* __restrict__ shp, const float* __restrict__ stp,
                           const float4* __restrict__ xr4, float4* __restrict__ out){
  int n = blockIdx.x;
  int side = threadIdx.x >> 6, lane = threadIdx.x & 63;
  const int* off = side ? offt : offh;
  const int* rr  = side ? relt : relh;
  const float* sp = side ? stp : shp;
  int s = off[n], e = off[n+1];
  if (lane >= RH4) return;
  float4 acc = make_float4(0.f,0.f,0.f,0.f);
  for (int p = s; p < e; ++p){
    float a = sp[p];
    float4 v = xr4[(size_t)rr[p]*RH4 + lane];
    acc.x += a*v.x; acc.y += a*v.y; acc.z += a*v.z; acc.w += a*v.w;
  }
  float4 o = make_float4(acc.x*0.125f, acc.y*0.125f, acc.z*0.125f, acc.w*0.125f);
  out[(size_t)n*LD4 + (side ? 100 : 75) + lane] = o;
}

// ---------------- GAT logits ----------------
__global__ void k_gat_logits2(const int* __restrict__ ja, const int* __restrict__ ia,
                              const int* __restrict__ pos_dest,
                              const float* __restrict__ gg16, float* __restrict__ lgp){
  int e = blockIdx.x*blockDim.x + threadIdx.x;
  if (e >= EALL_) return;
  int i = ia[e], j = ja[e];
  const float4* gi4 = reinterpret_cast<const float4*>(gg16 + (size_t)i*16);
  const float4* gj4 = reinterpret_cast<const float4*>(gg16 + (size_t)j*16 + 8);
  float4 a0 = gi4[0], a1 = gi4[1], b0 = gj4[0], b1 = gj4[1];
  float4 o0, o1;
  o0.x = lrelu_(a0.x+b0.x); o0.y = lrelu_(a0.y+b0.y); o0.z = lrelu_(a0.z+b0.z); o0.w = lrelu_(a0.w+b0.w);
  o1.x = lrelu_(a1.x+b1.x); o1.y = lrelu_(a1.y+b1.y); o1.z = lrelu_(a1.z+b1.z); o1.w = lrelu_(a1.w+b1.w);
  float4* d = reinterpret_cast<float4*>(lgp + (size_t)pos_dest[e]*8);
  d[0] = o0; d[1] = o1;
}

// ---------------- GAT aggregate ----------------
__global__ void k_gat_agg2(const int* __restrict__ off, const int* __restrict__ jd,
                           const float* __restrict__ agp,
                           const float4* __restrict__ X2, float4* __restrict__ out){
  __shared__ int js[128];
  __shared__ float as_[128];
  int n = blockIdx.x, tid = threadIdx.x;
  int s = off[n], t = off[n+1];
  float4 acc = make_float4(0.f,0.f,0.f,0.f);
  for (int base = s; base < t; base += 128){
    int m = min(128, t - base);
    __syncthreads();
    if (tid < m){ js[tid] = jd[base+tid]; as_[tid] = agp[base+tid]; }
    __syncthreads();
    if (tid < 125){
      for (int q = 0; q < m; ++q){
        float a = as_[q];
        float4 v = X2[(size_t)js[q]*LD4 + tid];
        acc.x += a*v.x; acc.y += a*v.y; acc.z += a*v.z; acc.w += a*v.w;
      }
    }
  }
  if (tid < 125){
    float4 r = make_float4(acc.x*0.125f, acc.y*0.125f, acc.z*0.125f, acc.w*0.125f);
    out[(size_t)n*LD4 + 125 + tid] = r;
  }
}

// ---------------- host ----------------
static inline void gemm(const float* A, int lda, const float* W, float* C, int ldc,
                        int M, int Nn, int K, hipStream_t st){
  dim3 g((M+63)/64, (Nn+63)/64);
  k_gemm<<<g, 256, 0, st>>>(A, lda, W, C, ldc, M, Nn, K);
}

extern "C" void kernel_launch(void* const* d_in, const int* in_sizes, int n_in,
                              void* d_out, int out_size, void* d_ws, size_t ws_size,
                              hipStream_t stream) {
  const float* x_e   = (const float*)d_in[0];
  const int*   ei    = (const int*)d_in[1];
  const int*   rel   = (const int*)d_in[2];
  const int*   eia   = (const int*)d_in[3];
  const float* hw1_w = (const float*)d_in[5];
  const float* hw1_b = (const float*)d_in[6];
  const float* hw2_w = (const float*)d_in[7];
  const float* hw2_b = (const float*)d_in[8];
  const float* e2r_wh= (const float*)d_in[9];
  const float* e2r_wt= (const float*)d_in[10];
  const float* e2r_ah= (const float*)d_in[11];
  const float* e2r_at= (const float*)d_in[12];
  const float* r2e_ah= (const float*)d_in[13];
  const float* r2e_at= (const float*)d_in[14];
  const float* r2e_ar= (const float*)d_in[15];
  const float* gat_ai= (const float*)d_in[16];
  const float* gat_aj= (const float*)d_in[17];
  float* out = (float*)d_out;

  const int* hi = ei;
  const int* ti = ei + E_;
  const int* ja = eia;
  const int* ia = eia + EALL_;

  char* base = (char*)d_ws;
  size_t off = 0;
  auto alloc = [&](size_t bytes)->void*{
    void* p = base + off;
    off = (off + bytes + 255) & ~(size_t)255;
    return p;
  };

  // zeroed region: counts + cursors
  size_t z0 = off;
  int* cnt_dest = (int*)alloc(N_*4);
  int* cur_dest = (int*)alloc(N_*4);
  int* cnt_h    = (int*)alloc(N_*4);
  int* cur_h    = (int*)alloc(N_*4);
  int* cnt_t    = (int*)alloc(N_*4);
  int* cur_t    = (int*)alloc(N_*4);
  int* cnt_rel  = (int*)alloc(R_*4);
  int* cur_rel  = (int*)alloc(R_*4);
  size_t z1 = off;

  int* off_dest = (int*)alloc((N_+1)*4);
  int* off_rel  = (int*)alloc((R_+1)*4);
  int* off_h    = (int*)alloc((N_+1)*4);
  int* off_t    = (int*)alloc((N_+1)*4);
  int* j_dest   = (int*)alloc((size_t)EALL_*4);
  int* pos_dest = (int*)alloc((size_t)EALL_*4);
  int* hr       = (int*)alloc((size_t)E_*4);
  int* tr       = (int*)alloc((size_t)E_*4);
  int* pos_rel  = (int*)alloc((size_t)E_*4);
  int* relh     = (int*)alloc((size_t)E_*4);
  int* pos_h    = (int*)alloc((size_t)E_*4);
  int* relt     = (int*)alloc((size_t)E_*4);
  int* pos_t    = (int*)alloc((size_t)E_*4);

  float* dis   = (float*)alloc(N_*4);
  float* wj    = (float*)alloc((size_t)EALL_*4);
  float* y     = (float*)alloc((size_t)N_*EH_*4);   // 36 MB; later aliased by lhp/ltp
  float* g     = (float*)alloc((size_t)N_*EH_*4);   // 36 MB; later aliased by lgp
  float* w_cat = (float*)alloc((size_t)200*EH_*4);
  float* xhxt  = (float*)alloc((size_t)N_*200*4);
  float* p1    = (float*)alloc((size_t)N_*2*4);
  float* p2    = (float*)alloc((size_t)N_*2*4);
  float* p3    = (float*)alloc((size_t)N_*2*4);
  float* p4    = (float*)alloc((size_t)N_*2*4);
  float* e1p   = (float*)alloc((size_t)E_*2*4);
  float* e2p   = (float*)alloc((size_t)E_*2*4);
  float* s1p   = (float*)alloc((size_t)E_*4);
  float* s2p   = (float*)alloc((size_t)E_*4);
  float* xr    = (float*)alloc((size_t)R_*RH_*4);
  float* st16  = (float*)alloc((size_t)N_*16*4);
  float* sr8   = (float*)alloc((size_t)R_*8*4);
  float* shp   = (float*)alloc((size_t)E_*4);
  float* stp   = (float*)alloc((size_t)E_*4);
  float* gg16  = (float*)alloc((size_t)N_*16*4);
  float* agp   = (float*)alloc((size_t)EALL_*4);

  // aliases into dead buffers
  float* lhp = y;                   // [E,8]  6.4 MB (y dead after highway2)
  float* ltp = y + (size_t)E_*8;    // [E,8]  6.4 MB
  float* lgp = g;                   // [EALL,8] 12.8 MB (g dead after highway2)

  hipMemsetAsync(base + z0, 0, z1 - z0, stream);
  hipMemcpyAsync(w_cat, e2r_wh, (size_t)RH_*EH_*4, hipMemcpyDeviceToDevice, stream);
  hipMemcpyAsync(w_cat + (size_t)RH_*EH_, e2r_wt, (size_t)RH_*EH_*4, hipMemcpyDeviceToDevice, stream);

  const int TB = 256;
  const int TOT = EALL_ + 3*E_;
  int gTOT  = (TOT + TB - 1)/TB;
  int gE    = (E_ + TB - 1)/TB;
  int gEall = (EALL_ + TB - 1)/TB;
  int gN    = (N_ + TB - 1)/TB;

  // CSR build
  k_count4<<<gTOT, TB, 0, stream>>>(ia, rel, hi, ti, cnt_dest, cnt_rel, cnt_h, cnt_t);
  k_scan4<<<4, 256, 0, stream>>>(cnt_dest, off_dest, N_, cnt_rel, off_rel, R_,
                                 cnt_h, off_h, N_, cnt_t, off_t, N_);
  k_dis<<<gN, TB, 0, stream>>>(cnt_dest, dis);
  k_scatter4<<<gTOT, TB, 0, stream>>>(ja, ia, rel, hi, ti,
                                      off_dest, off_rel, off_h, off_t,
                                      cur_dest, cur_rel, cur_h, cur_t,
                                      j_dest, pos_dest, hr, tr, pos_rel,
                                      relh, pos_h, relt, pos_t);
  k_wj<<<gEall, TB, 0, stream>>>(j_dest, dis, wj);

  // GCN + highway block 1 (x -> out cols 0..299)
  gemm(x_e, EH_, hw1_w, g, EH_, N_, EH_, EH_, stream);
  k_gcn2<<<N_, 128, 0, stream>>>(off_dest, j_dest, wj, dis, (const float4*)x_e, EH4, (float4*)y);
  k_highway2<<<(N_*EH4 + TB - 1)/TB, TB, 0, stream>>>((const float4*)x_e, EH4, (const float4*)y,
                                                      (const float4*)g, hw1_b, (float4*)out, LD4);
  // block 2
  gemm(out, OUTD_, hw2_w, g, EH_, N_, EH_, EH_, stream);
  k_gcn2<<<N_, 128, 0, stream>>>(off_dest, j_dest, wj, dis, (const float4*)out, LD4, (float4*)y);
  k_highway2<<<(N_*EH4 + TB - 1)/TB, TB, 0, stream>>>((const float4*)out, LD4, (const float4*)y,
                                                      (const float4*)g, hw2_b, (float4*)out, LD4);

  // E2R
  gemm(out, OUTD_, w_cat, xhxt, 200, N_, 200, EH_, stream);
  k_pproj<<<gN, TB, 0, stream>>>(xhxt, e2r_ah, e2r_at, p1, p2, p3, p4);
  k_e2r_logits2<<<gE, TB, 0, stream>>>(hi, ti, pos_rel, p1, p2, p3, p4, e1p, e2p);
  k_fold_rel<<<R_, 128, 0, stream>>>(off_rel, e1p, e2p, s1p, s2p);
  k_e2r_agg2<<<R_, 64, 0, stream>>>(off_rel, hr, tr, s1p, s2p, (const float4*)xhxt, (float4*)xr);

  // R2E
  k_dots16<<<(N_+15)/16, 256, 0, stream>>>(out, OUTD_, EH_, r2e_ah, r2e_at, st16, N_);
  k_sr<<<(R_*8 + TB - 1)/TB, TB, 0, stream>>>(xr, r2e_ar, sr8);
  k_r2e_logits2<<<gE, TB, 0, stream>>>(hi, ti, rel, st16, sr8, pos_h, pos_t, lhp, ltp);
  k_fold_ht<<<(N_+1)/2, 256, 0, stream>>>(off_h, off_t, lhp, ltp, shp, stp);
  k_r2e_agg2<<<N_, 128, 0, stream>>>(off_h, off_t, relh, relt, shp, stp,
                                     (const float4*)xr, (float4*)out);

  // GAT
  k_dots16<<<(N_+15)/16, 256, 0, stream>>>(out, OUTD_, X2D_, gat_ai, gat_aj, gg16, N_);
  k_gat_logits2<<<gEall, TB, 0, stream>>>(ja, ia, pos_dest, gg16, lgp);
  k_fold_gat<<<(N_+3)/4, 256, 0, stream>>>(off_dest, lgp, agp);
  k_gat_agg2<<<N_, 128, 0, stream>>>(off_dest, j_dest, agp, (const float4*)out, (float4*)out);
}

// Round 3
// 1104.049 us; speedup vs baseline: 2.1232x; 1.1261x over previous
//
#include <hip/hip_runtime.h>
#include <math.h>

constexpr int N_    = 30000;
constexpr int E_    = 200000;
constexpr int EALL_ = 400000;
constexpr int R_    = 500;
constexpr int EH_   = 300;
constexpr int RH_   = 100;
constexpr int X2D_  = 500;
constexpr int OUTD_ = 1000;
constexpr int LD4   = OUTD_/4;  // 250
constexpr int EH4   = EH_/4;    // 75
constexpr int RH4   = RH_/4;    // 25
constexpr int NC_   = 16;       // chunks per relation for e2r agg

__device__ __forceinline__ float lrelu_(float v){ return v > 0.f ? v : 0.01f*v; }
__device__ __forceinline__ float sig_(float z){ return 1.f/(1.f + expf(-z)); }

// ---------------- CSR build (fused) ----------------
__global__ void k_count4(const int* __restrict__ ia, const int* __restrict__ rel,
                         const int* __restrict__ hi, const int* __restrict__ ti,
                         int* cd, int* cr, int* ch, int* ct){
  int idx = blockIdx.x*blockDim.x + threadIdx.x;
  if (idx < EALL_) { atomicAdd(&cd[ia[idx]], 1); return; }
  idx -= EALL_;
  if (idx < E_) { atomicAdd(&cr[rel[idx]], 1); return; }
  idx -= E_;
  if (idx < E_) { atomicAdd(&ch[hi[idx]], 1); return; }
  idx -= E_;
  if (idx < E_) { atomicAdd(&ct[ti[idx]], 1); return; }
}

__global__ void k_scan4(const int* c0, int* o0, int L0,
                        const int* c1, int* o1, int L1,
                        const int* c2, int* o2, int L2,
                        const int* c3, int* o3, int L3){
  const int* c; int* o; int L;
  switch (blockIdx.x){
    case 0: c=c0; o=o0; L=L0; break;
    case 1: c=c1; o=o1; L=L1; break;
    case 2: c=c2; o=o2; L=L2; break;
    default: c=c3; o=o3; L=L3; break;
  }
  __shared__ int sums[256];
  int t = threadIdx.x;
  int chunk = (L + 255) / 256;
  int s = min(t*chunk, L), e = min(s + chunk, L);
  int acc = 0;
  for (int i = s; i < e; ++i) acc += c[i];
  sums[t] = acc;
  __syncthreads();
  for (int off = 1; off < 256; off <<= 1) {
    int v = (t >= off) ? sums[t - off] : 0;
    __syncthreads();
    sums[t] += v;
    __syncthreads();
  }
  int run = t ? sums[t-1] : 0;
  for (int i = s; i < e; ++i) { o[i] = run; run += c[i]; }
  if (t == 255) o[L] = sums[255];
}

__global__ void k_dis(const int* __restrict__ cnt, float* __restrict__ dis){
  int i = blockIdx.x*blockDim.x + threadIdx.x;
  if (i < N_){ int c = cnt[i]; dis[i] = (c > 0) ? rsqrtf((float)c) : 0.f; }
}

__global__ void k_scatter4(const int* __restrict__ ja, const int* __restrict__ ia,
                           const int* __restrict__ rel, const int* __restrict__ hi,
                           const int* __restrict__ ti,
                           const int* od, const int* orl, const int* oh, const int* ot,
                           int* curd, int* curr, int* curh, int* curt,
                           int* j_dest, int* pos_dest,
                           int* hr, int* tr, int* pos_rel,
                           int* relh, int* pos_h,
                           int* relt, int* pos_t){
  int idx = blockIdx.x*blockDim.x + threadIdx.x;
  if (idx < EALL_){
    int e = idx, s = ia[e];
    int p = od[s] + atomicAdd(&curd[s], 1);
    j_dest[p] = ja[e]; pos_dest[e] = p; return;
  }
  idx -= EALL_;
  if (idx < E_){
    int e = idx, s = rel[e];
    int p = orl[s] + atomicAdd(&curr[s], 1);
    hr[p] = hi[e]; tr[p] = ti[e]; pos_rel[e] = p; return;
  }
  idx -= E_;
  if (idx < E_){
    int e = idx, s = hi[e];
    int p = oh[s] + atomicAdd(&curh[s], 1);
    relh[p] = rel[e]; pos_h[e] = p; return;
  }
  idx -= E_;
  if (idx < E_){
    int e = idx, s = ti[e];
    int p = ot[s] + atomicAdd(&curt[s], 1);
    relt[p] = rel[e]; pos_t[e] = p; return;
  }
}

__global__ void k_wj(const int* __restrict__ jd, const float* __restrict__ dis,
                     float* __restrict__ wj){
  int p = blockIdx.x*blockDim.x + threadIdx.x;
  if (p < EALL_) wj[p] = dis[jd[p]];
}

// ---------------- GEMM: C[M,Nn] = A[M,K](lda) * W[Nn,K]^T ----------------
__global__ void k_gemm(const float* __restrict__ A, int lda,
                       const float* __restrict__ W,
                       float* __restrict__ C, int ldc,
                       int M, int Nn, int K){
  __shared__ float As[16][68];
  __shared__ float Bs[16][68];
  int tid = threadIdx.x;
  int tx = tid & 15, ty = tid >> 4;
  int m0 = blockIdx.x * 64, n0 = blockIdx.y * 64;
  float acc[4][4] = {{0.f}};
  for (int k0 = 0; k0 < K; k0 += 16) {
    #pragma unroll
    for (int i = 0; i < 4; ++i) {
      int idx = tid + i*256;
      int m = idx >> 4, k = idx & 15;
      float v = 0.f, w = 0.f;
      if (m0 + m < M && k0 + k < K) v = A[(size_t)(m0+m)*lda + k0 + k];
      if (n0 + m < Nn && k0 + k < K) w = W[(size_t)(n0+m)*K + k0 + k];
      As[k][m] = v;
      Bs[k][m] = w;
    }
    __syncthreads();
    #pragma unroll
    for (int kk = 0; kk < 16; ++kk) {
      float4 a = *reinterpret_cast<const float4*>(&As[kk][ty*4]);
      float4 b = *reinterpret_cast<const float4*>(&Bs[kk][tx*4]);
      acc[0][0]+=a.x*b.x; acc[0][1]+=a.x*b.y; acc[0][2]+=a.x*b.z; acc[0][3]+=a.x*b.w;
      acc[1][0]+=a.y*b.x; acc[1][1]+=a.y*b.y; acc[1][2]+=a.y*b.z; acc[1][3]+=a.y*b.w;
      acc[2][0]+=a.z*b.x; acc[2][1]+=a.z*b.y; acc[2][2]+=a.z*b.z; acc[2][3]+=a.z*b.w;
      acc[3][0]+=a.w*b.x; acc[3][1]+=a.w*b.y; acc[3][2]+=a.w*b.z; acc[3][3]+=a.w*b.w;
    }
    __syncthreads();
  }
  for (int p = 0; p < 4; ++p){
    int m = m0 + ty*4 + p;
    if (m < M) for (int q = 0; q < 4; ++q){
      int n = n0 + tx*4 + q;
      if (n < Nn) C[(size_t)m*ldc + n] = acc[p][q];
    }
  }
}

// ---------------- GCN gather (unroll-2) ----------------
__global__ void k_gcn2(const int* __restrict__ off, const int* __restrict__ jd,
                       const float* __restrict__ wj, const float* __restrict__ dis,
                       const float4* __restrict__ X, int ldx4, float4* __restrict__ Y){
  __shared__ int js[128];
  __shared__ float ws[128];
  int n = blockIdx.x, tid = threadIdx.x;
  int s = off[n], t = off[n+1];
  float4 acc = make_float4(0.f,0.f,0.f,0.f);
  for (int base = s; base < t; base += 128){
    int m = min(128, t - base);
    __syncthreads();
    if (tid < m){ js[tid] = jd[base+tid]; ws[tid] = wj[base+tid]; }
    __syncthreads();
    if (tid < EH4){
      int q = 0;
      for (; q + 1 < m; q += 2){
        float w0 = ws[q], w1 = ws[q+1];
        float4 v0 = X[(size_t)js[q]*ldx4 + tid];
        float4 v1 = X[(size_t)js[q+1]*ldx4 + tid];
        acc.x += w0*v0.x + w1*v1.x; acc.y += w0*v0.y + w1*v1.y;
        acc.z += w0*v0.z + w1*v1.z; acc.w += w0*v0.w + w1*v1.w;
      }
      if (q < m){
        float w0 = ws[q];
        float4 v0 = X[(size_t)js[q]*ldx4 + tid];
        acc.x += w0*v0.x; acc.y += w0*v0.y; acc.z += w0*v0.z; acc.w += w0*v0.w;
      }
    }
  }
  if (tid < EH4){
    float dn = dis[n];
    float4 r;
    r.x = fmaxf(dn*acc.x, 0.f); r.y = fmaxf(dn*acc.y, 0.f);
    r.z = fmaxf(dn*acc.z, 0.f); r.w = fmaxf(dn*acc.w, 0.f);
    Y[(size_t)n*EH4 + tid] = r;
  }
}

// ---------------- highway (float4) ----------------
__global__ void k_highway2(const float4* __restrict__ Xold, int ldo4,
                           const float4* __restrict__ Y, const float4* __restrict__ G,
                           const float* __restrict__ b,
                           float4* __restrict__ Xn, int ldn4){
  int idx = blockIdx.x*blockDim.x + threadIdx.x;
  if (idx >= N_*EH4) return;
  int n = idx / EH4, f = idx - n*EH4;
  float4 g4 = G[idx];
  float4 b4 = reinterpret_cast<const float4*>(b)[f];
  float4 y4 = Y[idx];
  float4 xo = Xold[(size_t)n*ldo4 + f];
  float4 r;
  float gx;
  gx = sig_(g4.x + b4.x); r.x = gx*y4.x + (1.f-gx)*xo.x;
  gx = sig_(g4.y + b4.y); r.y = gx*y4.y + (1.f-gx)*xo.y;
  gx = sig_(g4.z + b4.z); r.z = gx*y4.z + (1.f-gx)*xo.z;
  gx = sig_(g4.w + b4.w); r.w = gx*y4.w + (1.f-gx)*xo.w;
  Xn[(size_t)n*ldn4 + f] = r;
}

// ---------------- E2R projections p1..p4 [N,2] ----------------
__global__ void k_pproj(const float* __restrict__ xhxt,
                        const float* __restrict__ ah, const float* __restrict__ at,
                        float* __restrict__ p1, float* __restrict__ p2,
                        float* __restrict__ p3, float* __restrict__ p4){
  int n = blockIdx.x*blockDim.x + threadIdx.x;
  if (n >= N_) return;
  float a0=0,a1=0,b0=0,b1=0,c0=0,c1=0,d0=0,d1=0;
  const float* xh = xhxt + (size_t)n*200;
  const float* xt = xh + 100;
  for (int f = 0; f < RH_; ++f) {
    float vh = xh[f], vt = xt[f];
    float w0 = ah[f], w1 = ah[RH_+f], u0 = at[f], u1 = at[RH_+f];
    a0 += vh*w0; a1 += vh*w1;
    b0 += vt*u0; b1 += vt*u1;
    c0 += vt*w0; c1 += vt*w1;
    d0 += vh*u0; d1 += vh*u1;
  }
  p1[n*2]=a0; p1[n*2+1]=a1; p2[n*2]=b0; p2[n*2+1]=b1;
  p3[n*2]=c0; p3[n*2+1]=c1; p4[n*2]=d0; p4[n*2+1]=d1;
}

__global__ void k_e2r_logits2(const int* __restrict__ hi, const int* __restrict__ ti,
                              const int* __restrict__ pos_rel,
                              const float* __restrict__ p1, const float* __restrict__ p2,
                              const float* __restrict__ p3, const float* __restrict__ p4,
                              float* __restrict__ e1p, float* __restrict__ e2p){
  int e = blockIdx.x*blockDim.x + threadIdx.x;
  if (e >= E_) return;
  int h = hi[e], t = ti[e];
  size_t pp = (size_t)pos_rel[e]*2;
  e1p[pp]   = lrelu_(p1[h*2]   + p2[t*2]);
  e1p[pp+1] = lrelu_(p1[h*2+1] + p2[t*2+1]);
  e2p[pp]   = lrelu_(p3[h*2]   + p4[t*2]);
  e2p[pp+1] = lrelu_(p3[h*2+1] + p4[t*2+1]);
}

// ---------------- segment softmax fold (single wave; used where blocks are many) ----------------
template<int K>
__device__ __forceinline__ void softmax_fold(const int* __restrict__ off,
                                             const float* __restrict__ lp,
                                             float* __restrict__ op, int seg){
  int lane = threadIdx.x & 63;
  int k = lane & (K - 1);
  int g = lane / K;
  const int GS = 64 / K;
  int s = off[seg], e = off[seg + 1];
  float m = -1e30f;
  for (int p = s + g; p < e; p += GS) m = fmaxf(m, lp[(size_t)p*K + k]);
  #pragma unroll
  for (int o = K; o < 64; o <<= 1) m = fmaxf(m, __shfl_xor(m, o));
  float sum = 0.f;
  for (int p = s + g; p < e; p += GS) sum += expf(lp[(size_t)p*K + k] - m);
  #pragma unroll
  for (int o = K; o < 64; o <<= 1) sum += __shfl_xor(sum, o);
  float inv = 1.f / (sum + 1e-16f);
  for (int p = s + g; p < e; p += GS){
    float t = expf(lp[(size_t)p*K + k] - m) * inv;
    #pragma unroll
    for (int o = 1; o < K; o <<= 1) t += __shfl_xor(t, o);
    if (k == 0) op[p] = t;
  }
}

// rel-segment fold: 4 waves per relation (2 per logit array, LDS combine)
__global__ void k_fold_rel(const int* __restrict__ off,
                           const float* __restrict__ e1p, const float* __restrict__ e2p,
                           float* __restrict__ s1p, float* __restrict__ s2p){
  __shared__ float lm[4][2];
  __shared__ float lsum[4][2];
  int r = blockIdx.x;
  int w = threadIdx.x >> 6;      // 0..3
  int lane = threadIdx.x & 63;
  const float* lp = (w < 2) ? e1p : e2p;
  float* op = (w < 2) ? s1p : s2p;
  int half = w & 1;
  int k = lane & 1, g = lane >> 1;
  int gg = half*32 + g;          // 64 groups across the wave pair
  int s = off[r], e = off[r+1];
  float m = -1e30f;
  for (int p = s + gg; p < e; p += 64) m = fmaxf(m, lp[(size_t)p*2 + k]);
  #pragma unroll
  for (int o = 2; o < 64; o <<= 1) m = fmaxf(m, __shfl_xor(m, o));
  if (lane < 2) lm[w][lane] = m;
  __syncthreads();
  m = fmaxf(lm[w][k], lm[w^1][k]);
  float sum = 0.f;
  for (int p = s + gg; p < e; p += 64) sum += expf(lp[(size_t)p*2 + k] - m);
  #pragma unroll
  for (int o = 2; o < 64; o <<= 1) sum += __shfl_xor(sum, o);
  if (lane < 2) lsum[w][lane] = sum;
  __syncthreads();
  sum = lsum[w][k] + lsum[w^1][k];
  float inv = 1.f / (sum + 1e-16f);
  for (int p = s + gg; p < e; p += 64){
    float t = expf(lp[(size_t)p*2 + k] - m) * inv;
    t += __shfl_xor(t, 1);
    if (k == 0) op[p] = t;
  }
}

__global__ void k_fold_ht(const int* __restrict__ offh, const int* __restrict__ offt,
                          const float* __restrict__ lhp, const float* __restrict__ ltp,
                          float* __restrict__ shp, float* __restrict__ stp){
  int w = threadIdx.x >> 6;
  int n = blockIdx.x*2 + (w >> 1);
  if (n >= N_) return;
  if (w & 1) softmax_fold<8>(offt, ltp, stp, n);
  else       softmax_fold<8>(offh, lhp, shp, n);
}

__global__ void k_fold_gat(const int* __restrict__ off, const float* __restrict__ lgp,
                           float* __restrict__ agp){
  int w = threadIdx.x >> 6;
  int n = blockIdx.x*4 + w;
  if (n >= N_) return;
  softmax_fold<8>(off, lgp, agp, n);
}

// ---------------- E2R aggregate: chunked partials + deterministic reduce ----------------
__global__ void k_e2r_agg3(const int* __restrict__ off,
                           const int* __restrict__ hr, const int* __restrict__ tr,
                           const float* __restrict__ s1p, const float* __restrict__ s2p,
                           const float4* __restrict__ xhxt4, float4* __restrict__ xr_part){
  int r = blockIdx.x, c = blockIdx.y;
  int lane = threadIdx.x;           // 64
  int side = lane >> 5, fl = lane & 31;
  int s = off[r], e = off[r+1];
  int len = e - s;
  int per = (len + NC_ - 1)/NC_;
  int cs = s + c*per, ce = min(cs + per, e);
  float4 acc = make_float4(0.f,0.f,0.f,0.f);
  if (fl < RH4){
    const int* idx = side ? tr : hr;
    const float* wv = side ? s2p : s1p;
    int fofs = side ? 25 + fl : fl;
    int p = cs;
    for (; p + 1 < ce; p += 2){
      float a0 = wv[p], a1 = wv[p+1];
      float4 v0 = xhxt4[(size_t)idx[p]*50 + fofs];
      float4 v1 = xhxt4[(size_t)idx[p+1]*50 + fofs];
      acc.x += a0*v0.x + a1*v1.x; acc.y += a0*v0.y + a1*v1.y;
      acc.z += a0*v0.z + a1*v1.z; acc.w += a0*v0.w + a1*v1.w;
    }
    if (p < ce){
      float a0 = wv[p];
      float4 v0 = xhxt4[(size_t)idx[p]*50 + fofs];
      acc.x += a0*v0.x; acc.y += a0*v0.y; acc.z += a0*v0.z; acc.w += a0*v0.w;
    }
  }
  float4 oth;
  oth.x = __shfl_xor(acc.x, 32); oth.y = __shfl_xor(acc.y, 32);
  oth.z = __shfl_xor(acc.z, 32); oth.w = __shfl_xor(acc.w, 32);
  if (side == 0 && fl < RH4){
    float4 o = make_float4(acc.x+oth.x, acc.y+oth.y, acc.z+oth.z, acc.w+oth.w);
    xr_part[((size_t)c*R_ + r)*RH4 + fl] = o;
  }
}

__global__ void k_e2r_red(const float4* __restrict__ xr_part, float4* __restrict__ xr4){
  int idx = blockIdx.x*blockDim.x + threadIdx.x;   // R_*RH4 = 12500
  if (idx >= R_*RH4) return;
  float4 a = make_float4(0.f,0.f,0.f,0.f);
  #pragma unroll
  for (int c = 0; c < NC_; ++c){
    float4 v = xr_part[(size_t)c*R_*RH4 + idx];
    a.x += v.x; a.y += v.y; a.z += v.z; a.w += v.w;
  }
  xr4[idx] = make_float4(a.x*0.25f, a.y*0.25f, a.z*0.25f, a.w*0.25f);
}

// ---------------- 16-head row dots ----------------
__global__ void k_dots16(const float* __restrict__ X, int ldx, int K,
                         const float* __restrict__ wA, const float* __restrict__ wB,
                         float* __restrict__ out16, int M){
  __shared__ float xs[16][65];
  __shared__ float ws[16][65];
  int tid = threadIdx.x;
  int tx = tid & 15, ty = tid >> 4;
  int r0 = blockIdx.x*16;
  float acc = 0.f;
  for (int c0 = 0; c0 < K; c0 += 64){
    int cl = min(64, K - c0);
    #pragma unroll
    for (int i = 0; i < 4; ++i){
      int idx = tid + i*256;
      int r = idx >> 6, k = idx & 63;
      float xv = 0.f, wv = 0.f;
      if (k < cl && r0 + r < M) xv = X[(size_t)(r0+r)*ldx + c0 + k];
      if (k < cl) wv = (r < 8) ? wA[(size_t)r*K + c0 + k] : wB[(size_t)(r-8)*K + c0 + k];
      xs[r][k] = xv;
      ws[r][k] = wv;
    }
    __syncthreads();
    #pragma unroll
    for (int k = 0; k < 64; ++k) acc += xs[ty][k]*ws[tx][k];
    __syncthreads();
  }
  if (r0 + ty < M) out16[(size_t)(r0+ty)*16 + tx] = acc;
}

// ---------------- sr [R,8] ----------------
__global__ void k_sr(const float* __restrict__ xr, const float* __restrict__ ar,
                     float* __restrict__ sr8){
  int idx = blockIdx.x*blockDim.x + threadIdx.x;
  if (idx >= R_*8) return;
  int r = idx >> 3, h = idx & 7;
  float acc = 0.f;
  for (int k = 0; k < RH_; ++k) acc += xr[(size_t)r*RH_ + k]*ar[(size_t)h*RH_ + k];
  sr8[idx] = acc;
}

// ---------------- R2E logits (permuted writes) ----------------
__global__ void k_r2e_logits2(const int* __restrict__ hi, const int* __restrict__ ti,
                              const int* __restrict__ rl,
                              const float* __restrict__ st16, const float* __restrict__ sr8,
                              const int* __restrict__ pos_h, const int* __restrict__ pos_t,
                              float* __restrict__ lhp, float* __restrict__ ltp){
  int e = blockIdx.x*blockDim.x + threadIdx.x;
  if (e >= E_) return;
  int h = hi[e], t = ti[e], r = rl[e];
  const float4* sh4 = reinterpret_cast<const float4*>(st16 + (size_t)h*16);
  const float4* st4 = reinterpret_cast<const float4*>(st16 + (size_t)t*16 + 8);
  const float4* sr4 = reinterpret_cast<const float4*>(sr8 + (size_t)r*8);
  float4 a0 = sh4[0], a1 = sh4[1], b0 = st4[0], b1 = st4[1], c0 = sr4[0], c1 = sr4[1];
  float4 o0, o1;
  o0.x = lrelu_(a0.x+c0.x); o0.y = lrelu_(a0.y+c0.y); o0.z = lrelu_(a0.z+c0.z); o0.w = lrelu_(a0.w+c0.w);
  o1.x = lrelu_(a1.x+c1.x); o1.y = lrelu_(a1.y+c1.y); o1.z = lrelu_(a1.z+c1.z); o1.w = lrelu_(a1.w+c1.w);
  float4* dh = reinterpret_cast<float4*>(lhp + (size_t)pos_h[e]*8);
  dh[0] = o0; dh[1] = o1;
  o0.x = lrelu_(b0.x+c0.x); o0.y = lrelu_(b0.y+c0.y); o0.z = lrelu_(b0.z+c0.z); o0.w = lrelu_(b0.w+c0.w);
  o1.x = lrelu_(b1.x+c1.x); o1.y = lrelu_(b1.y+c1.y); o1.z = lrelu_(b1.z+c1.z); o1.w = lrelu_(b1.w+c1.w);
  float4* dt = reinterpret_cast<float4*>(ltp + (size_t)pos_t[e]*8);
  dt[0] = o0; dt[1] = o1;
}

// ---------------- R2E aggregate ----------------
__global__ void k_r2e_agg2(const int* __restrict__ offh, const int* __restrict__ offt,
                           const int* __restrict__ relh, const int* __restrict__ relt,
                           const float* __restrict__ shp, const float* __restrict__ stp,
                           const float4* __restrict__ xr4, float4* __restrict__ out){
  int n = blockIdx.x;
  int side = threadIdx.x >> 6, lane = threadIdx.x & 63;
  const int* off = side ? offt : offh;
  const int* rr  = side ? relt : relh;
  const float* sp = side ? stp : shp;
  int s = off[n], e = off[n+1];
  if (lane >= RH4) return;
  float4 acc = make_float4(0.f,0.f,0.f,0.f);
  int p = s;
  for (; p + 1 < e; p += 2){
    float a0 = sp[p], a1 = sp[p+1];
    float4 v0 = xr4[(size_t)rr[p]*RH4 + lane];
    float4 v1 = xr4[(size_t)rr[p+1]*RH4 + lane];
    acc.x += a0*v0.x + a1*v1.x; acc.y += a0*v0.y + a1*v1.y;
    acc.z += a0*v0.z + a1*v1.z; acc.w += a0*v0.w + a1*v1.w;
  }
  if (p < e){
    float a0 = sp[p];
    float4 v0 = xr4[(size_t)rr[p]*RH4 + lane];
    acc.x += a0*v0.x; acc.y += a0*v0.y; acc.z += a0*v0.z; acc.w += a0*v0.w;
  }
  float4 o = make_float4(acc.x*0.125f, acc.y*0.125f, acc.z*0.125f, acc.w*0.125f);
  out[(size_t)n*LD4 + (side ? 100 : 75) + lane] = o;
}

// ---------------- GAT logits ----------------
__global__ void k_gat_logits2(const int* __restrict__ ja, const int* __restrict__ ia,
                              const int* __restrict__ pos_dest,
                              const float* __restrict__ gg16, float* __restrict__ lgp){
  int e = blockIdx.x*blockDim.x + threadIdx.x;
  if (e >= EALL_) return;
  int i = ia[e], j = ja[e];
  const float4* gi4 = reinterpret_cast<const float4*>(gg16 + (size_t)i*16);
  const float4* gj4 = reinterpret_cast<const float4*>(gg16 + (size_t)j*16 + 8);
  float4 a0 = gi4[0], a1 = gi4[1], b0 = gj4[0], b1 = gj4[1];
  float4 o0, o1;
  o0.x = lrelu_(a0.x+b0.x); o0.y = lrelu_(a0.y+b0.y); o0.z = lrelu_(a0.z+b0.z); o0.w = lrelu_(a0.w+b0.w);
  o1.x = lrelu_(a1.x+b1.x); o1.y = lrelu_(a1.y+b1.y); o1.z = lrelu_(a1.z+b1.z); o1.w = lrelu_(a1.w+b1.w);
  float4* d = reinterpret_cast<float4*>(lgp + (size_t)pos_dest[e]*8);
  d[0] = o0; d[1] = o1;
}

// ---------------- GAT aggregate (unroll-2) ----------------
__global__ void k_gat_agg2(const int* __restrict__ off, const int* __restrict__ jd,
                           const float* __restrict__ agp,
                           const float4* __restrict__ X2, float4* __restrict__ out){
  __shared__ int js[128];
  __shared__ float as_[128];
  int n = blockIdx.x, tid = threadIdx.x;
  int s = off[n], t = off[n+1];
  float4 acc = make_float4(0.f,0.f,0.f,0.f);
  for (int base = s; base < t; base += 128){
    int m = min(128, t - base);
    __syncthreads();
    if (tid < m){ js[tid] = jd[base+tid]; as_[tid] = agp[base+tid]; }
    __syncthreads();
    if (tid < 125){
      int q = 0;
      for (; q + 1 < m; q += 2){
        float a0 = as_[q], a1 = as_[q+1];
        float4 v0 = X2[(size_t)js[q]*LD4 + tid];
        float4 v1 = X2[(size_t)js[q+1]*LD4 + tid];
        acc.x += a0*v0.x + a1*v1.x; acc.y += a0*v0.y + a1*v1.y;
        acc.z += a0*v0.z + a1*v1.z; acc.w += a0*v0.w + a1*v1.w;
      }
      if (q < m){
        float a0 = as_[q];
        float4 v0 = X2[(size_t)js[q]*LD4 + tid];
        acc.x += a0*v0.x; acc.y += a0*v0.y; acc.z += a0*v0.z; acc.w += a0*v0.w;
      }
    }
  }
  if (tid < 125){
    float4 r = make_float4(acc.x*0.125f, acc.y*0.125f, acc.z*0.125f, acc.w*0.125f);
    out[(size_t)n*LD4 + 125 + tid] = r;
  }
}

// ---------------- host ----------------
static inline void gemm(const float* A, int lda, const float* W, float* C, int ldc,
                        int M, int Nn, int K, hipStream_t st){
  dim3 g((M+63)/64, (Nn+63)/64);
  k_gemm<<<g, 256, 0, st>>>(A, lda, W, C, ldc, M, Nn, K);
}

extern "C" void kernel_launch(void* const* d_in, const int* in_sizes, int n_in,
                              void* d_out, int out_size, void* d_ws, size_t ws_size,
                              hipStream_t stream) {
  const float* x_e   = (const float*)d_in[0];
  const int*   ei    = (const int*)d_in[1];
  const int*   rel   = (const int*)d_in[2];
  const int*   eia   = (const int*)d_in[3];
  const float* hw1_w = (const float*)d_in[5];
  const float* hw1_b = (const float*)d_in[6];
  const float* hw2_w = (const float*)d_in[7];
  const float* hw2_b = (const float*)d_in[8];
  const float* e2r_wh= (const float*)d_in[9];
  const float* e2r_wt= (const float*)d_in[10];
  const float* e2r_ah= (const float*)d_in[11];
  const float* e2r_at= (const float*)d_in[12];
  const float* r2e_ah= (const float*)d_in[13];
  const float* r2e_at= (const float*)d_in[14];
  const float* r2e_ar= (const float*)d_in[15];
  const float* gat_ai= (const float*)d_in[16];
  const float* gat_aj= (const float*)d_in[17];
  float* out = (float*)d_out;

  const int* hi = ei;
  const int* ti = ei + E_;
  const int* ja = eia;
  const int* ia = eia + EALL_;

  char* base = (char*)d_ws;
  size_t off = 0;
  auto alloc = [&](size_t bytes)->void*{
    void* p = base + off;
    off = (off + bytes + 255) & ~(size_t)255;
    return p;
  };

  // zeroed region: counts + cursors
  size_t z0 = off;
  int* cnt_dest = (int*)alloc(N_*4);
  int* cur_dest = (int*)alloc(N_*4);
  int* cnt_h    = (int*)alloc(N_*4);
  int* cur_h    = (int*)alloc(N_*4);
  int* cnt_t    = (int*)alloc(N_*4);
  int* cur_t    = (int*)alloc(N_*4);
  int* cnt_rel  = (int*)alloc(R_*4);
  int* cur_rel  = (int*)alloc(R_*4);
  size_t z1 = off;

  int* off_dest = (int*)alloc((N_+1)*4);
  int* off_rel  = (int*)alloc((R_+1)*4);
  int* off_h    = (int*)alloc((N_+1)*4);
  int* off_t    = (int*)alloc((N_+1)*4);
  int* j_dest   = (int*)alloc((size_t)EALL_*4);
  int* pos_dest = (int*)alloc((size_t)EALL_*4);
  int* hr       = (int*)alloc((size_t)E_*4);
  int* tr       = (int*)alloc((size_t)E_*4);
  int* pos_rel  = (int*)alloc((size_t)E_*4);
  int* relh     = (int*)alloc((size_t)E_*4);
  int* pos_h    = (int*)alloc((size_t)E_*4);
  int* relt     = (int*)alloc((size_t)E_*4);
  int* pos_t    = (int*)alloc((size_t)E_*4);

  float* dis   = (float*)alloc(N_*4);
  float* wj    = (float*)alloc((size_t)EALL_*4);
  float* y     = (float*)alloc((size_t)N_*EH_*4);   // 36 MB; later aliased by lhp/ltp
  float* g     = (float*)alloc((size_t)N_*EH_*4);   // 36 MB; later aliased by lgp
  float* w_cat = (float*)alloc((size_t)200*EH_*4);
  float* xhxt  = (float*)alloc((size_t)N_*200*4);
  float* p1    = (float*)alloc((size_t)N_*2*4);
  float* p2    = (float*)alloc((size_t)N_*2*4);
  float* p3    = (float*)alloc((size_t)N_*2*4);
  float* p4    = (float*)alloc((size_t)N_*2*4);
  float* e1p   = (float*)alloc((size_t)E_*2*4);
  float* e2p   = (float*)alloc((size_t)E_*2*4);
  float* s1p   = (float*)alloc((size_t)E_*4);
  float* s2p   = (float*)alloc((size_t)E_*4);
  float* xr    = (float*)alloc((size_t)R_*RH_*4);
  float* xr_part=(float*)alloc((size_t)NC_*R_*RH_*4);  // 3.2 MB
  float* st16  = (float*)alloc((size_t)N_*16*4);
  float* sr8   = (float*)alloc((size_t)R_*8*4);
  float* shp   = (float*)alloc((size_t)E_*4);
  float* stp   = (float*)alloc((size_t)E_*4);
  float* gg16  = (float*)alloc((size_t)N_*16*4);
  float* agp   = (float*)alloc((size_t)EALL_*4);

  // aliases into dead buffers
  float* lhp = y;                   // [E,8]  (y dead after highway2)
  float* ltp = y + (size_t)E_*8;
  float* lgp = g;                   // [EALL,8] (g dead after highway2)

  hipMemsetAsync(base + z0, 0, z1 - z0, stream);
  hipMemcpyAsync(w_cat, e2r_wh, (size_t)RH_*EH_*4, hipMemcpyDeviceToDevice, stream);
  hipMemcpyAsync(w_cat + (size_t)RH_*EH_, e2r_wt, (size_t)RH_*EH_*4, hipMemcpyDeviceToDevice, stream);

  const int TB = 256;
  const int TOT = EALL_ + 3*E_;
  int gTOT  = (TOT + TB - 1)/TB;
  int gE    = (E_ + TB - 1)/TB;
  int gEall = (EALL_ + TB - 1)/TB;
  int gN    = (N_ + TB - 1)/TB;

  // CSR build
  k_count4<<<gTOT, TB, 0, stream>>>(ia, rel, hi, ti, cnt_dest, cnt_rel, cnt_h, cnt_t);
  k_scan4<<<4, 256, 0, stream>>>(cnt_dest, off_dest, N_, cnt_rel, off_rel, R_,
                                 cnt_h, off_h, N_, cnt_t, off_t, N_);
  k_dis<<<gN, TB, 0, stream>>>(cnt_dest, dis);
  k_scatter4<<<gTOT, TB, 0, stream>>>(ja, ia, rel, hi, ti,
                                      off_dest, off_rel, off_h, off_t,
                                      cur_dest, cur_rel, cur_h, cur_t,
                                      j_dest, pos_dest, hr, tr, pos_rel,
                                      relh, pos_h, relt, pos_t);
  k_wj<<<gEall, TB, 0, stream>>>(j_dest, dis, wj);

  // GCN + highway block 1 (x -> out cols 0..299)
  gemm(x_e, EH_, hw1_w, g, EH_, N_, EH_, EH_, stream);
  k_gcn2<<<N_, 128, 0, stream>>>(off_dest, j_dest, wj, dis, (const float4*)x_e, EH4, (float4*)y);
  k_highway2<<<(N_*EH4 + TB - 1)/TB, TB, 0, stream>>>((const float4*)x_e, EH4, (const float4*)y,
                                                      (const float4*)g, hw1_b, (float4*)out, LD4);
  // block 2
  gemm(out, OUTD_, hw2_w, g, EH_, N_, EH_, EH_, stream);
  k_gcn2<<<N_, 128, 0, stream>>>(off_dest, j_dest, wj, dis, (const float4*)out, LD4, (float4*)y);
  k_highway2<<<(N_*EH4 + TB - 1)/TB, TB, 0, stream>>>((const float4*)out, LD4, (const float4*)y,
                                                      (const float4*)g, hw2_b, (float4*)out, LD4);

  // E2R
  gemm(out, OUTD_, w_cat, xhxt, 200, N_, 200, EH_, stream);
  k_pproj<<<gN, TB, 0, stream>>>(xhxt, e2r_ah, e2r_at, p1, p2, p3, p4);
  k_e2r_logits2<<<gE, TB, 0, stream>>>(hi, ti, pos_rel, p1, p2, p3, p4, e1p, e2p);
  k_fold_rel<<<R_, 256, 0, stream>>>(off_rel, e1p, e2p, s1p, s2p);
  k_e2r_agg3<<<dim3(R_, NC_), 64, 0, stream>>>(off_rel, hr, tr, s1p, s2p,
                                               (const float4*)xhxt, (float4*)xr_part);
  k_e2r_red<<<(R_*RH4 + TB - 1)/TB, TB, 0, stream>>>((const float4*)xr_part, (float4*)xr);

  // R2E
  k_dots16<<<(N_+15)/16, 256, 0, stream>>>(out, OUTD_, EH_, r2e_ah, r2e_at, st16, N_);
  k_sr<<<(R_*8 + TB - 1)/TB, TB, 0, stream>>>(xr, r2e_ar, sr8);
  k_r2e_logits2<<<gE, TB, 0, stream>>>(hi, ti, rel, st16, sr8, pos_h, pos_t, lhp, ltp);
  k_fold_ht<<<(N_+1)/2, 256, 0, stream>>>(off_h, off_t, lhp, ltp, shp, stp);
  k_r2e_agg2<<<N_, 128, 0, stream>>>(off_h, off_t, relh, relt, shp, stp,
                                     (const float4*)xr, (float4*)out);

  // GAT
  k_dots16<<<(N_+15)/16, 256, 0, stream>>>(out, OUTD_, X2D_, gat_ai, gat_aj, gg16, N_);
  k_gat_logits2<<<gEall, TB, 0, stream>>>(ja, ia, pos_dest, gg16, lgp);
  k_fold_gat<<<(N_+3)/4, 256, 0, stream>>>(off_dest, lgp, agp);
  k_gat_agg2<<<N_, 128, 0, stream>>>(off_dest, j_dest, agp, (const float4*)out, (float4*)out);
}

// Round 4
// 1018.474 us; speedup vs baseline: 2.3016x; 1.0840x over previous
//
#include <hip/hip_runtime.h>
#include <math.h>

constexpr int N_    = 30000;
constexpr int E_    = 200000;
constexpr int EALL_ = 400000;
constexpr int R_    = 500;
constexpr int EH_   = 300;
constexpr int RH_   = 100;
constexpr int X2D_  = 500;
constexpr int OUTD_ = 1000;
constexpr int LD4   = OUTD_/4;  // 250
constexpr int EH4   = EH_/4;    // 75
constexpr int RH4   = RH_/4;    // 25
constexpr int NC_   = 16;       // chunks per relation for e2r agg
constexpr int XBS_  = 304;      // bf16 row stride for x tables (608 B, 8B-aligned rows)
constexpr int X2BS_ = 504;      // bf16 row stride for x2 table (1008 B)

__device__ __forceinline__ float lrelu_(float v){ return v > 0.f ? v : 0.01f*v; }
__device__ __forceinline__ float sig_(float z){ return 1.f/(1.f + expf(-z)); }
__device__ __forceinline__ unsigned short f2bf_(float f){
  unsigned int u = __float_as_uint(f);
  unsigned int r = (u + 0x7FFFu + ((u >> 16) & 1u)) >> 16;
  return (unsigned short)r;
}
__device__ __forceinline__ float bf2f_(unsigned short h){
  return __uint_as_float(((unsigned int)h) << 16);
}

// ---------------- CSR build (fused) ----------------
__global__ void k_count4(const int* __restrict__ ia, const int* __restrict__ rel,
                         const int* __restrict__ hi, const int* __restrict__ ti,
                         int* cd, int* cr, int* ch, int* ct){
  int idx = blockIdx.x*blockDim.x + threadIdx.x;
  if (idx < EALL_) { atomicAdd(&cd[ia[idx]], 1); return; }
  idx -= EALL_;
  if (idx < E_) { atomicAdd(&cr[rel[idx]], 1); return; }
  idx -= E_;
  if (idx < E_) { atomicAdd(&ch[hi[idx]], 1); return; }
  idx -= E_;
  if (idx < E_) { atomicAdd(&ct[ti[idx]], 1); return; }
}

__global__ void k_scan4(const int* c0, int* o0, int L0,
                        const int* c1, int* o1, int L1,
                        const int* c2, int* o2, int L2,
                        const int* c3, int* o3, int L3){
  const int* c; int* o; int L;
  switch (blockIdx.x){
    case 0: c=c0; o=o0; L=L0; break;
    case 1: c=c1; o=o1; L=L1; break;
    case 2: c=c2; o=o2; L=L2; break;
    default: c=c3; o=o3; L=L3; break;
  }
  __shared__ int sums[256];
  int t = threadIdx.x;
  int chunk = (L + 255) / 256;
  int s = min(t*chunk, L), e = min(s + chunk, L);
  int acc = 0;
  for (int i = s; i < e; ++i) acc += c[i];
  sums[t] = acc;
  __syncthreads();
  for (int off = 1; off < 256; off <<= 1) {
    int v = (t >= off) ? sums[t - off] : 0;
    __syncthreads();
    sums[t] += v;
    __syncthreads();
  }
  int run = t ? sums[t-1] : 0;
  for (int i = s; i < e; ++i) { o[i] = run; run += c[i]; }
  if (t == 255) o[L] = sums[255];
}

__global__ void k_dis(const int* __restrict__ cnt, float* __restrict__ dis){
  int i = blockIdx.x*blockDim.x + threadIdx.x;
  if (i < N_){ int c = cnt[i]; dis[i] = (c > 0) ? rsqrtf((float)c) : 0.f; }
}

__global__ void k_scatter4(const int* __restrict__ ja, const int* __restrict__ ia,
                           const int* __restrict__ rel, const int* __restrict__ hi,
                           const int* __restrict__ ti,
                           const int* od, const int* orl, const int* oh, const int* ot,
                           int* curd, int* curr, int* curh, int* curt,
                           int* j_dest, int* pos_dest,
                           int* hr, int* tr, int* pos_rel,
                           int* relh, int* pos_h,
                           int* relt, int* pos_t){
  int idx = blockIdx.x*blockDim.x + threadIdx.x;
  if (idx < EALL_){
    int e = idx, s = ia[e];
    int p = od[s] + atomicAdd(&curd[s], 1);
    j_dest[p] = ja[e]; pos_dest[e] = p; return;
  }
  idx -= EALL_;
  if (idx < E_){
    int e = idx, s = rel[e];
    int p = orl[s] + atomicAdd(&curr[s], 1);
    hr[p] = hi[e]; tr[p] = ti[e]; pos_rel[e] = p; return;
  }
  idx -= E_;
  if (idx < E_){
    int e = idx, s = hi[e];
    int p = oh[s] + atomicAdd(&curh[s], 1);
    relh[p] = rel[e]; pos_h[e] = p; return;
  }
  idx -= E_;
  if (idx < E_){
    int e = idx, s = ti[e];
    int p = ot[s] + atomicAdd(&curt[s], 1);
    relt[p] = rel[e]; pos_t[e] = p; return;
  }
}

__global__ void k_wj(const int* __restrict__ jd, const float* __restrict__ dis,
                     float* __restrict__ wj){
  int p = blockIdx.x*blockDim.x + threadIdx.x;
  if (p < EALL_) wj[p] = dis[jd[p]];
}

// ---------------- bf16 pack kernels ----------------
// pack X[M rows, 300 cols f32 @ ldx4 float4] -> xb[M][XBS_] bf16
__global__ void k_pack_x(const float4* __restrict__ X, int ldx4,
                         unsigned short* __restrict__ xb){
  int idx = blockIdx.x*blockDim.x + threadIdx.x;
  if (idx >= N_*EH4) return;
  int n = idx / EH4, c = idx - n*EH4;
  float4 v = X[(size_t)n*ldx4 + c];
  ushort4 o;
  o.x = f2bf_(v.x); o.y = f2bf_(v.y); o.z = f2bf_(v.z); o.w = f2bf_(v.w);
  *reinterpret_cast<ushort4*>(&xb[(size_t)n*XBS_ + c*4]) = o;
}

// pack out cols 0..499 -> x2b[N][X2BS_] bf16
__global__ void k_pack_x2(const float4* __restrict__ X, unsigned short* __restrict__ x2b){
  int idx = blockIdx.x*blockDim.x + threadIdx.x;
  if (idx >= N_*125) return;
  int n = idx / 125, c = idx - n*125;
  float4 v = X[(size_t)n*LD4 + c];
  ushort4 o;
  o.x = f2bf_(v.x); o.y = f2bf_(v.y); o.z = f2bf_(v.z); o.w = f2bf_(v.w);
  *reinterpret_cast<ushort4*>(&x2b[(size_t)n*X2BS_ + c*4]) = o;
}

// ---------------- GEMM: C[M,Nn] = A[M,K](lda) * W[Nn,K]^T ----------------
__global__ void k_gemm(const float* __restrict__ A, int lda,
                       const float* __restrict__ W,
                       float* __restrict__ C, int ldc,
                       int M, int Nn, int K){
  __shared__ float As[16][68];
  __shared__ float Bs[16][68];
  int tid = threadIdx.x;
  int tx = tid & 15, ty = tid >> 4;
  int m0 = blockIdx.x * 64, n0 = blockIdx.y * 64;
  float acc[4][4] = {{0.f}};
  for (int k0 = 0; k0 < K; k0 += 16) {
    #pragma unroll
    for (int i = 0; i < 4; ++i) {
      int idx = tid + i*256;
      int m = idx >> 4, k = idx & 15;
      float v = 0.f, w = 0.f;
      if (m0 + m < M && k0 + k < K) v = A[(size_t)(m0+m)*lda + k0 + k];
      if (n0 + m < Nn && k0 + k < K) w = W[(size_t)(n0+m)*K + k0 + k];
      As[k][m] = v;
      Bs[k][m] = w;
    }
    __syncthreads();
    #pragma unroll
    for (int kk = 0; kk < 16; ++kk) {
      float4 a = *reinterpret_cast<const float4*>(&As[kk][ty*4]);
      float4 b = *reinterpret_cast<const float4*>(&Bs[kk][tx*4]);
      acc[0][0]+=a.x*b.x; acc[0][1]+=a.x*b.y; acc[0][2]+=a.x*b.z; acc[0][3]+=a.x*b.w;
      acc[1][0]+=a.y*b.x; acc[1][1]+=a.y*b.y; acc[1][2]+=a.y*b.z; acc[1][3]+=a.y*b.w;
      acc[2][0]+=a.z*b.x; acc[2][1]+=a.z*b.y; acc[2][2]+=a.z*b.z; acc[2][3]+=a.z*b.w;
      acc[3][0]+=a.w*b.x; acc[3][1]+=a.w*b.y; acc[3][2]+=a.w*b.z; acc[3][3]+=a.w*b.w;
    }
    __syncthreads();
  }
  for (int p = 0; p < 4; ++p){
    int m = m0 + ty*4 + p;
    if (m < M) for (int q = 0; q < 4; ++q){
      int n = n0 + tx*4 + q;
      if (n < Nn) C[(size_t)m*ldc + n] = acc[p][q];
    }
  }
}

// ---------------- GCN gather (bf16 table, unroll-2) ----------------
__global__ void k_gcn3(const int* __restrict__ off, const int* __restrict__ jd,
                       const float* __restrict__ wj, const float* __restrict__ dis,
                       const unsigned short* __restrict__ xb, float4* __restrict__ Y){
  __shared__ int js[128];
  __shared__ float ws[128];
  int n = blockIdx.x, tid = threadIdx.x;
  int s = off[n], t = off[n+1];
  float4 acc = make_float4(0.f,0.f,0.f,0.f);
  for (int base = s; base < t; base += 128){
    int m = min(128, t - base);
    __syncthreads();
    if (tid < m){ js[tid] = jd[base+tid]; ws[tid] = wj[base+tid]; }
    __syncthreads();
    if (tid < EH4){
      int q = 0;
      for (; q + 1 < m; q += 2){
        float w0 = ws[q], w1 = ws[q+1];
        ushort4 u0 = *reinterpret_cast<const ushort4*>(&xb[(size_t)js[q]*XBS_ + tid*4]);
        ushort4 u1 = *reinterpret_cast<const ushort4*>(&xb[(size_t)js[q+1]*XBS_ + tid*4]);
        acc.x += w0*bf2f_(u0.x) + w1*bf2f_(u1.x);
        acc.y += w0*bf2f_(u0.y) + w1*bf2f_(u1.y);
        acc.z += w0*bf2f_(u0.z) + w1*bf2f_(u1.z);
        acc.w += w0*bf2f_(u0.w) + w1*bf2f_(u1.w);
      }
      if (q < m){
        float w0 = ws[q];
        ushort4 u0 = *reinterpret_cast<const ushort4*>(&xb[(size_t)js[q]*XBS_ + tid*4]);
        acc.x += w0*bf2f_(u0.x); acc.y += w0*bf2f_(u0.y);
        acc.z += w0*bf2f_(u0.z); acc.w += w0*bf2f_(u0.w);
      }
    }
  }
  if (tid < EH4){
    float dn = dis[n];
    float4 r;
    r.x = fmaxf(dn*acc.x, 0.f); r.y = fmaxf(dn*acc.y, 0.f);
    r.z = fmaxf(dn*acc.z, 0.f); r.w = fmaxf(dn*acc.w, 0.f);
    Y[(size_t)n*EH4 + tid] = r;
  }
}

// ---------------- highway (float4) ----------------
__global__ void k_highway2(const float4* __restrict__ Xold, int ldo4,
                           const float4* __restrict__ Y, const float4* __restrict__ G,
                           const float* __restrict__ b,
                           float4* __restrict__ Xn, int ldn4){
  int idx = blockIdx.x*blockDim.x + threadIdx.x;
  if (idx >= N_*EH4) return;
  int n = idx / EH4, f = idx - n*EH4;
  float4 g4 = G[idx];
  float4 b4 = reinterpret_cast<const float4*>(b)[f];
  float4 y4 = Y[idx];
  float4 xo = Xold[(size_t)n*ldo4 + f];
  float4 r;
  float gx;
  gx = sig_(g4.x + b4.x); r.x = gx*y4.x + (1.f-gx)*xo.x;
  gx = sig_(g4.y + b4.y); r.y = gx*y4.y + (1.f-gx)*xo.y;
  gx = sig_(g4.z + b4.z); r.z = gx*y4.z + (1.f-gx)*xo.z;
  gx = sig_(g4.w + b4.w); r.w = gx*y4.w + (1.f-gx)*xo.w;
  Xn[(size_t)n*ldn4 + f] = r;
}

// ---------------- E2R projections p1..p4 [N,2] ----------------
__global__ void k_pproj(const float* __restrict__ xhxt,
                        const float* __restrict__ ah, const float* __restrict__ at,
                        float* __restrict__ p1, float* __restrict__ p2,
                        float* __restrict__ p3, float* __restrict__ p4){
  int n = blockIdx.x*blockDim.x + threadIdx.x;
  if (n >= N_) return;
  float a0=0,a1=0,b0=0,b1=0,c0=0,c1=0,d0=0,d1=0;
  const float* xh = xhxt + (size_t)n*200;
  const float* xt = xh + 100;
  for (int f = 0; f < RH_; ++f) {
    float vh = xh[f], vt = xt[f];
    float w0 = ah[f], w1 = ah[RH_+f], u0 = at[f], u1 = at[RH_+f];
    a0 += vh*w0; a1 += vh*w1;
    b0 += vt*u0; b1 += vt*u1;
    c0 += vt*w0; c1 += vt*w1;
    d0 += vh*u0; d1 += vh*u1;
  }
  p1[n*2]=a0; p1[n*2+1]=a1; p2[n*2]=b0; p2[n*2+1]=b1;
  p3[n*2]=c0; p3[n*2+1]=c1; p4[n*2]=d0; p4[n*2+1]=d1;
}

__global__ void k_e2r_logits2(const int* __restrict__ hi, const int* __restrict__ ti,
                              const int* __restrict__ pos_rel,
                              const float* __restrict__ p1, const float* __restrict__ p2,
                              const float* __restrict__ p3, const float* __restrict__ p4,
                              float* __restrict__ e1p, float* __restrict__ e2p){
  int e = blockIdx.x*blockDim.x + threadIdx.x;
  if (e >= E_) return;
  int h = hi[e], t = ti[e];
  size_t pp = (size_t)pos_rel[e]*2;
  e1p[pp]   = lrelu_(p1[h*2]   + p2[t*2]);
  e1p[pp+1] = lrelu_(p1[h*2+1] + p2[t*2+1]);
  e2p[pp]   = lrelu_(p3[h*2]   + p4[t*2]);
  e2p[pp+1] = lrelu_(p3[h*2+1] + p4[t*2+1]);
}

// ---------------- segment softmax fold ----------------
template<int K>
__device__ __forceinline__ void softmax_fold(const int* __restrict__ off,
                                             const float* __restrict__ lp,
                                             float* __restrict__ op, int seg){
  int lane = threadIdx.x & 63;
  int k = lane & (K - 1);
  int g = lane / K;
  const int GS = 64 / K;
  int s = off[seg], e = off[seg + 1];
  float m = -1e30f;
  for (int p = s + g; p < e; p += GS) m = fmaxf(m, lp[(size_t)p*K + k]);
  #pragma unroll
  for (int o = K; o < 64; o <<= 1) m = fmaxf(m, __shfl_xor(m, o));
  float sum = 0.f;
  for (int p = s + g; p < e; p += GS) sum += expf(lp[(size_t)p*K + k] - m);
  #pragma unroll
  for (int o = K; o < 64; o <<= 1) sum += __shfl_xor(sum, o);
  float inv = 1.f / (sum + 1e-16f);
  for (int p = s + g; p < e; p += GS){
    float t = expf(lp[(size_t)p*K + k] - m) * inv;
    #pragma unroll
    for (int o = 1; o < K; o <<= 1) t += __shfl_xor(t, o);
    if (k == 0) op[p] = t;
  }
}

// rel-segment fold: 4 waves per relation (2 per logit array, LDS combine)
__global__ void k_fold_rel(const int* __restrict__ off,
                           const float* __restrict__ e1p, const float* __restrict__ e2p,
                           float* __restrict__ s1p, float* __restrict__ s2p){
  __shared__ float lm[4][2];
  __shared__ float lsum[4][2];
  int r = blockIdx.x;
  int w = threadIdx.x >> 6;      // 0..3
  int lane = threadIdx.x & 63;
  const float* lp = (w < 2) ? e1p : e2p;
  float* op = (w < 2) ? s1p : s2p;
  int half = w & 1;
  int k = lane & 1, g = lane >> 1;
  int gg = half*32 + g;
  int s = off[r], e = off[r+1];
  float m = -1e30f;
  for (int p = s + gg; p < e; p += 64) m = fmaxf(m, lp[(size_t)p*2 + k]);
  #pragma unroll
  for (int o = 2; o < 64; o <<= 1) m = fmaxf(m, __shfl_xor(m, o));
  if (lane < 2) lm[w][lane] = m;
  __syncthreads();
  m = fmaxf(lm[w][k], lm[w^1][k]);
  float sum = 0.f;
  for (int p = s + gg; p < e; p += 64) sum += expf(lp[(size_t)p*2 + k] - m);
  #pragma unroll
  for (int o = 2; o < 64; o <<= 1) sum += __shfl_xor(sum, o);
  if (lane < 2) lsum[w][lane] = sum;
  __syncthreads();
  sum = lsum[w][k] + lsum[w^1][k];
  float inv = 1.f / (sum + 1e-16f);
  for (int p = s + gg; p < e; p += 64){
    float t = expf(lp[(size_t)p*2 + k] - m) * inv;
    t += __shfl_xor(t, 1);
    if (k == 0) op[p] = t;
  }
}

__global__ void k_fold_ht(const int* __restrict__ offh, const int* __restrict__ offt,
                          const float* __restrict__ lhp, const float* __restrict__ ltp,
                          float* __restrict__ shp, float* __restrict__ stp){
  int w = threadIdx.x >> 6;
  int n = blockIdx.x*2 + (w >> 1);
  if (n >= N_) return;
  if (w & 1) softmax_fold<8>(offt, ltp, stp, n);
  else       softmax_fold<8>(offh, lhp, shp, n);
}

__global__ void k_fold_gat(const int* __restrict__ off, const float* __restrict__ lgp,
                           float* __restrict__ agp){
  int w = threadIdx.x >> 6;
  int n = blockIdx.x*4 + w;
  if (n >= N_) return;
  softmax_fold<8>(off, lgp, agp, n);
}

// ---------------- E2R aggregate: chunked partials + deterministic reduce ----------------
__global__ void k_e2r_agg3(const int* __restrict__ off,
                           const int* __restrict__ hr, const int* __restrict__ tr,
                           const float* __restrict__ s1p, const float* __restrict__ s2p,
                           const float4* __restrict__ xhxt4, float4* __restrict__ xr_part){
  int r = blockIdx.x, c = blockIdx.y;
  int lane = threadIdx.x;           // 64
  int side = lane >> 5, fl = lane & 31;
  int s = off[r], e = off[r+1];
  int len = e - s;
  int per = (len + NC_ - 1)/NC_;
  int cs = s + c*per, ce = min(cs + per, e);
  float4 acc = make_float4(0.f,0.f,0.f,0.f);
  if (fl < RH4){
    const int* idx = side ? tr : hr;
    const float* wv = side ? s2p : s1p;
    int fofs = side ? 25 + fl : fl;
    int p = cs;
    for (; p + 1 < ce; p += 2){
      float a0 = wv[p], a1 = wv[p+1];
      float4 v0 = xhxt4[(size_t)idx[p]*50 + fofs];
      float4 v1 = xhxt4[(size_t)idx[p+1]*50 + fofs];
      acc.x += a0*v0.x + a1*v1.x; acc.y += a0*v0.y + a1*v1.y;
      acc.z += a0*v0.z + a1*v1.z; acc.w += a0*v0.w + a1*v1.w;
    }
    if (p < ce){
      float a0 = wv[p];
      float4 v0 = xhxt4[(size_t)idx[p]*50 + fofs];
      acc.x += a0*v0.x; acc.y += a0*v0.y; acc.z += a0*v0.z; acc.w += a0*v0.w;
    }
  }
  float4 oth;
  oth.x = __shfl_xor(acc.x, 32); oth.y = __shfl_xor(acc.y, 32);
  oth.z = __shfl_xor(acc.z, 32); oth.w = __shfl_xor(acc.w, 32);
  if (side == 0 && fl < RH4){
    float4 o = make_float4(acc.x+oth.x, acc.y+oth.y, acc.z+oth.z, acc.w+oth.w);
    xr_part[((size_t)c*R_ + r)*RH4 + fl] = o;
  }
}

__global__ void k_e2r_red(const float4* __restrict__ xr_part, float4* __restrict__ xr4){
  int idx = blockIdx.x*blockDim.x + threadIdx.x;
  if (idx >= R_*RH4) return;
  float4 a = make_float4(0.f,0.f,0.f,0.f);
  #pragma unroll
  for (int c = 0; c < NC_; ++c){
    float4 v = xr_part[(size_t)c*R_*RH4 + idx];
    a.x += v.x; a.y += v.y; a.z += v.z; a.w += v.w;
  }
  xr4[idx] = make_float4(a.x*0.25f, a.y*0.25f, a.z*0.25f, a.w*0.25f);
}

// ---------------- 16-head row dots ----------------
__global__ void k_dots16(const float* __restrict__ X, int ldx, int K,
                         const float* __restrict__ wA, const float* __restrict__ wB,
                         float* __restrict__ out16, int M){
  __shared__ float xs[16][65];
  __shared__ float ws[16][65];
  int tid = threadIdx.x;
  int tx = tid & 15, ty = tid >> 4;
  int r0 = blockIdx.x*16;
  float acc = 0.f;
  for (int c0 = 0; c0 < K; c0 += 64){
    int cl = min(64, K - c0);
    #pragma unroll
    for (int i = 0; i < 4; ++i){
      int idx = tid + i*256;
      int r = idx >> 6, k = idx & 63;
      float xv = 0.f, wv = 0.f;
      if (k < cl && r0 + r < M) xv = X[(size_t)(r0+r)*ldx + c0 + k];
      if (k < cl) wv = (r < 8) ? wA[(size_t)r*K + c0 + k] : wB[(size_t)(r-8)*K + c0 + k];
      xs[r][k] = xv;
      ws[r][k] = wv;
    }
    __syncthreads();
    #pragma unroll
    for (int k = 0; k < 64; ++k) acc += xs[ty][k]*ws[tx][k];
    __syncthreads();
  }
  if (r0 + ty < M) out16[(size_t)(r0+ty)*16 + tx] = acc;
}

// ---------------- sr [R,8] ----------------
__global__ void k_sr(const float* __restrict__ xr, const float* __restrict__ ar,
                     float* __restrict__ sr8){
  int idx = blockIdx.x*blockDim.x + threadIdx.x;
  if (idx >= R_*8) return;
  int r = idx >> 3, h = idx & 7;
  float acc = 0.f;
  for (int k = 0; k < RH_; ++k) acc += xr[(size_t)r*RH_ + k]*ar[(size_t)h*RH_ + k];
  sr8[idx] = acc;
}

// ---------------- R2E logits (permuted writes) ----------------
__global__ void k_r2e_logits2(const int* __restrict__ hi, const int* __restrict__ ti,
                              const int* __restrict__ rl,
                              const float* __restrict__ st16, const float* __restrict__ sr8,
                              const int* __restrict__ pos_h, const int* __restrict__ pos_t,
                              float* __restrict__ lhp, float* __restrict__ ltp){
  int e = blockIdx.x*blockDim.x + threadIdx.x;
  if (e >= E_) return;
  int h = hi[e], t = ti[e], r = rl[e];
  const float4* sh4 = reinterpret_cast<const float4*>(st16 + (size_t)h*16);
  const float4* st4 = reinterpret_cast<const float4*>(st16 + (size_t)t*16 + 8);
  const float4* sr4 = reinterpret_cast<const float4*>(sr8 + (size_t)r*8);
  float4 a0 = sh4[0], a1 = sh4[1], b0 = st4[0], b1 = st4[1], c0 = sr4[0], c1 = sr4[1];
  float4 o0, o1;
  o0.x = lrelu_(a0.x+c0.x); o0.y = lrelu_(a0.y+c0.y); o0.z = lrelu_(a0.z+c0.z); o0.w = lrelu_(a0.w+c0.w);
  o1.x = lrelu_(a1.x+c1.x); o1.y = lrelu_(a1.y+c1.y); o1.z = lrelu_(a1.z+c1.z); o1.w = lrelu_(a1.w+c1.w);
  float4* dh = reinterpret_cast<float4*>(lhp + (size_t)pos_h[e]*8);
  dh[0] = o0; dh[1] = o1;
  o0.x = lrelu_(b0.x+c0.x); o0.y = lrelu_(b0.y+c0.y); o0.z = lrelu_(b0.z+c0.z); o0.w = lrelu_(b0.w+c0.w);
  o1.x = lrelu_(b1.x+c1.x); o1.y = lrelu_(b1.y+c1.y); o1.z = lrelu_(b1.z+c1.z); o1.w = lrelu_(b1.w+c1.w);
  float4* dt = reinterpret_cast<float4*>(ltp + (size_t)pos_t[e]*8);
  dt[0] = o0; dt[1] = o1;
}

// ---------------- R2E aggregate ----------------
__global__ void k_r2e_agg2(const int* __restrict__ offh, const int* __restrict__ offt,
                           const int* __restrict__ relh, const int* __restrict__ relt,
                           const float* __restrict__ shp, const float* __restrict__ stp,
                           const float4* __restrict__ xr4, float4* __restrict__ out){
  int n = blockIdx.x;
  int side = threadIdx.x >> 6, lane = threadIdx.x & 63;
  const int* off = side ? offt : offh;
  const int* rr  = side ? relt : relh;
  const float* sp = side ? stp : shp;
  int s = off[n], e = off[n+1];
  if (lane >= RH4) return;
  float4 acc = make_float4(0.f,0.f,0.f,0.f);
  int p = s;
  for (; p + 1 < e; p += 2){
    float a0 = sp[p], a1 = sp[p+1];
    float4 v0 = xr4[(size_t)rr[p]*RH4 + lane];
    float4 v1 = xr4[(size_t)rr[p+1]*RH4 + lane];
    acc.x += a0*v0.x + a1*v1.x; acc.y += a0*v0.y + a1*v1.y;
    acc.z += a0*v0.z + a1*v1.z; acc.w += a0*v0.w + a1*v1.w;
  }
  if (p < e){
    float a0 = sp[p];
    float4 v0 = xr4[(size_t)rr[p]*RH4 + lane];
    acc.x += a0*v0.x; acc.y += a0*v0.y; acc.z += a0*v0.z; acc.w += a0*v0.w;
  }
  float4 o = make_float4(acc.x*0.125f, acc.y*0.125f, acc.z*0.125f, acc.w*0.125f);
  out[(size_t)n*LD4 + (side ? 100 : 75) + lane] = o;
}

// ---------------- GAT logits ----------------
__global__ void k_gat_logits2(const int* __restrict__ ja, const int* __restrict__ ia,
                              const int* __restrict__ pos_dest,
                              const float* __restrict__ gg16, float* __restrict__ lgp){
  int e = blockIdx.x*blockDim.x + threadIdx.x;
  if (e >= EALL_) return;
  int i = ia[e], j = ja[e];
  const float4* gi4 = reinterpret_cast<const float4*>(gg16 + (size_t)i*16);
  const float4* gj4 = reinterpret_cast<const float4*>(gg16 + (size_t)j*16 + 8);
  float4 a0 = gi4[0], a1 = gi4[1], b0 = gj4[0], b1 = gj4[1];
  float4 o0, o1;
  o0.x = lrelu_(a0.x+b0.x); o0.y = lrelu_(a0.y+b0.y); o0.z = lrelu_(a0.z+b0.z); o0.w = lrelu_(a0.w+b0.w);
  o1.x = lrelu_(a1.x+b1.x); o1.y = lrelu_(a1.y+b1.y); o1.z = lrelu_(a1.z+b1.z); o1.w = lrelu_(a1.w+b1.w);
  float4* d = reinterpret_cast<float4*>(lgp + (size_t)pos_dest[e]*8);
  d[0] = o0; d[1] = o1;
}

// ---------------- GAT aggregate (bf16 table, unroll-2) ----------------
__global__ void k_gat_agg3(const int* __restrict__ off, const int* __restrict__ jd,
                           const float* __restrict__ agp,
                           const unsigned short* __restrict__ x2b, float4* __restrict__ out){
  __shared__ int js[128];
  __shared__ float as_[128];
  int n = blockIdx.x, tid = threadIdx.x;
  int s = off[n], t = off[n+1];
  float4 acc = make_float4(0.f,0.f,0.f,0.f);
  for (int base = s; base < t; base += 128){
    int m = min(128, t - base);
    __syncthreads();
    if (tid < m){ js[tid] = jd[base+tid]; as_[tid] = agp[base+tid]; }
    __syncthreads();
    if (tid < 125){
      int q = 0;
      for (; q + 1 < m; q += 2){
        float a0 = as_[q], a1 = as_[q+1];
        ushort4 u0 = *reinterpret_cast<const ushort4*>(&x2b[(size_t)js[q]*X2BS_ + tid*4]);
        ushort4 u1 = *reinterpret_cast<const ushort4*>(&x2b[(size_t)js[q+1]*X2BS_ + tid*4]);
        acc.x += a0*bf2f_(u0.x) + a1*bf2f_(u1.x);
        acc.y += a0*bf2f_(u0.y) + a1*bf2f_(u1.y);
        acc.z += a0*bf2f_(u0.z) + a1*bf2f_(u1.z);
        acc.w += a0*bf2f_(u0.w) + a1*bf2f_(u1.w);
      }
      if (q < m){
        float a0 = as_[q];
        ushort4 u0 = *reinterpret_cast<const ushort4*>(&x2b[(size_t)js[q]*X2BS_ + tid*4]);
        acc.x += a0*bf2f_(u0.x); acc.y += a0*bf2f_(u0.y);
        acc.z += a0*bf2f_(u0.z); acc.w += a0*bf2f_(u0.w);
      }
    }
  }
  if (tid < 125){
    float4 r = make_float4(acc.x*0.125f, acc.y*0.125f, acc.z*0.125f, acc.w*0.125f);
    out[(size_t)n*LD4 + 125 + tid] = r;
  }
}

// ---------------- host ----------------
static inline void gemm(const float* A, int lda, const float* W, float* C, int ldc,
                        int M, int Nn, int K, hipStream_t st){
  dim3 g((M+63)/64, (Nn+63)/64);
  k_gemm<<<g, 256, 0, st>>>(A, lda, W, C, ldc, M, Nn, K);
}

extern "C" void kernel_launch(void* const* d_in, const int* in_sizes, int n_in,
                              void* d_out, int out_size, void* d_ws, size_t ws_size,
                              hipStream_t stream) {
  const float* x_e   = (const float*)d_in[0];
  const int*   ei    = (const int*)d_in[1];
  const int*   rel   = (const int*)d_in[2];
  const int*   eia   = (const int*)d_in[3];
  const float* hw1_w = (const float*)d_in[5];
  const float* hw1_b = (const float*)d_in[6];
  const float* hw2_w = (const float*)d_in[7];
  const float* hw2_b = (const float*)d_in[8];
  const float* e2r_wh= (const float*)d_in[9];
  const float* e2r_wt= (const float*)d_in[10];
  const float* e2r_ah= (const float*)d_in[11];
  const float* e2r_at= (const float*)d_in[12];
  const float* r2e_ah= (const float*)d_in[13];
  const float* r2e_at= (const float*)d_in[14];
  const float* r2e_ar= (const float*)d_in[15];
  const float* gat_ai= (const float*)d_in[16];
  const float* gat_aj= (const float*)d_in[17];
  float* out = (float*)d_out;

  const int* hi = ei;
  const int* ti = ei + E_;
  const int* ja = eia;
  const int* ia = eia + EALL_;

  char* base = (char*)d_ws;
  size_t off = 0;
  auto alloc = [&](size_t bytes)->void*{
    void* p = base + off;
    off = (off + bytes + 255) & ~(size_t)255;
    return p;
  };

  // zeroed region: counts + cursors
  size_t z0 = off;
  int* cnt_dest = (int*)alloc(N_*4);
  int* cur_dest = (int*)alloc(N_*4);
  int* cnt_h    = (int*)alloc(N_*4);
  int* cur_h    = (int*)alloc(N_*4);
  int* cnt_t    = (int*)alloc(N_*4);
  int* cur_t    = (int*)alloc(N_*4);
  int* cnt_rel  = (int*)alloc(R_*4);
  int* cur_rel  = (int*)alloc(R_*4);
  size_t z1 = off;

  int* off_dest = (int*)alloc((N_+1)*4);
  int* off_rel  = (int*)alloc((R_+1)*4);
  int* off_h    = (int*)alloc((N_+1)*4);
  int* off_t    = (int*)alloc((N_+1)*4);
  int* j_dest   = (int*)alloc((size_t)EALL_*4);
  int* pos_dest = (int*)alloc((size_t)EALL_*4);
  int* hr       = (int*)alloc((size_t)E_*4);
  int* tr       = (int*)alloc((size_t)E_*4);
  int* pos_rel  = (int*)alloc((size_t)E_*4);
  int* relh     = (int*)alloc((size_t)E_*4);
  int* pos_h    = (int*)alloc((size_t)E_*4);
  int* relt     = (int*)alloc((size_t)E_*4);
  int* pos_t    = (int*)alloc((size_t)E_*4);

  float* dis   = (float*)alloc(N_*4);
  float* wj    = (float*)alloc((size_t)EALL_*4);
  float* y     = (float*)alloc((size_t)N_*EH_*4);   // 36 MB; later aliased by lhp/ltp
  float* g     = (float*)alloc((size_t)N_*EH_*4);   // 36 MB; later aliased by lgp
  float* w_cat = (float*)alloc((size_t)200*EH_*4);
  float* xhxt  = (float*)alloc((size_t)N_*200*4);
  float* p1    = (float*)alloc((size_t)N_*2*4);
  float* p2    = (float*)alloc((size_t)N_*2*4);
  float* p3    = (float*)alloc((size_t)N_*2*4);
  float* p4    = (float*)alloc((size_t)N_*2*4);
  float* e1p   = (float*)alloc((size_t)E_*2*4);
  float* e2p   = (float*)alloc((size_t)E_*2*4);
  float* s1p   = (float*)alloc((size_t)E_*4);
  float* s2p   = (float*)alloc((size_t)E_*4);
  float* xr    = (float*)alloc((size_t)R_*RH_*4);
  float* xr_part=(float*)alloc((size_t)NC_*R_*RH_*4);
  float* st16  = (float*)alloc((size_t)N_*16*4);
  float* sr8   = (float*)alloc((size_t)R_*8*4);
  float* shp   = (float*)alloc((size_t)E_*4);
  float* stp   = (float*)alloc((size_t)E_*4);
  float* gg16  = (float*)alloc((size_t)N_*16*4);
  float* agp   = (float*)alloc((size_t)EALL_*4);
  unsigned short* xb  = (unsigned short*)alloc((size_t)N_*XBS_*2);   // 18.2 MB
  unsigned short* x2b = (unsigned short*)alloc((size_t)N_*X2BS_*2);  // 30.2 MB

  // aliases into dead buffers
  float* lhp = y;                   // [E,8]  (y dead after highway2)
  float* ltp = y + (size_t)E_*8;
  float* lgp = g;                   // [EALL,8] (g dead after highway2)

  hipMemsetAsync(base + z0, 0, z1 - z0, stream);
  hipMemcpyAsync(w_cat, e2r_wh, (size_t)RH_*EH_*4, hipMemcpyDeviceToDevice, stream);
  hipMemcpyAsync(w_cat + (size_t)RH_*EH_, e2r_wt, (size_t)RH_*EH_*4, hipMemcpyDeviceToDevice, stream);

  const int TB = 256;
  const int TOT = EALL_ + 3*E_;
  int gTOT  = (TOT + TB - 1)/TB;
  int gE    = (E_ + TB - 1)/TB;
  int gEall = (EALL_ + TB - 1)/TB;
  int gN    = (N_ + TB - 1)/TB;
  int gPKX  = (N_*EH4 + TB - 1)/TB;
  int gPK2  = (N_*125 + TB - 1)/TB;

  // CSR build
  k_count4<<<gTOT, TB, 0, stream>>>(ia, rel, hi, ti, cnt_dest, cnt_rel, cnt_h, cnt_t);
  k_scan4<<<4, 256, 0, stream>>>(cnt_dest, off_dest, N_, cnt_rel, off_rel, R_,
                                 cnt_h, off_h, N_, cnt_t, off_t, N_);
  k_dis<<<gN, TB, 0, stream>>>(cnt_dest, dis);
  k_scatter4<<<gTOT, TB, 0, stream>>>(ja, ia, rel, hi, ti,
                                      off_dest, off_rel, off_h, off_t,
                                      cur_dest, cur_rel, cur_h, cur_t,
                                      j_dest, pos_dest, hr, tr, pos_rel,
                                      relh, pos_h, relt, pos_t);
  k_wj<<<gEall, TB, 0, stream>>>(j_dest, dis, wj);

  // GCN + highway block 1 (x -> out cols 0..299)
  k_pack_x<<<gPKX, TB, 0, stream>>>((const float4*)x_e, EH4, xb);
  gemm(x_e, EH_, hw1_w, g, EH_, N_, EH_, EH_, stream);
  k_gcn3<<<N_, 128, 0, stream>>>(off_dest, j_dest, wj, dis, xb, (float4*)y);
  k_highway2<<<(N_*EH4 + TB - 1)/TB, TB, 0, stream>>>((const float4*)x_e, EH4, (const float4*)y,
                                                      (const float4*)g, hw1_b, (float4*)out, LD4);
  // block 2
  k_pack_x<<<gPKX, TB, 0, stream>>>((const float4*)out, LD4, xb);
  gemm(out, OUTD_, hw2_w, g, EH_, N_, EH_, EH_, stream);
  k_gcn3<<<N_, 128, 0, stream>>>(off_dest, j_dest, wj, dis, xb, (float4*)y);
  k_highway2<<<(N_*EH4 + TB - 1)/TB, TB, 0, stream>>>((const float4*)out, LD4, (const float4*)y,
                                                      (const float4*)g, hw2_b, (float4*)out, LD4);

  // E2R
  gemm(out, OUTD_, w_cat, xhxt, 200, N_, 200, EH_, stream);
  k_pproj<<<gN, TB, 0, stream>>>(xhxt, e2r_ah, e2r_at, p1, p2, p3, p4);
  k_e2r_logits2<<<gE, TB, 0, stream>>>(hi, ti, pos_rel, p1, p2, p3, p4, e1p, e2p);
  k_fold_rel<<<R_, 256, 0, stream>>>(off_rel, e1p, e2p, s1p, s2p);
  k_e2r_agg3<<<dim3(R_, NC_), 64, 0, stream>>>(off_rel, hr, tr, s1p, s2p,
                                               (const float4*)xhxt, (float4*)xr_part);
  k_e2r_red<<<(R_*RH4 + TB - 1)/TB, TB, 0, stream>>>((const float4*)xr_part, (float4*)xr);

  // R2E
  k_dots16<<<(N_+15)/16, 256, 0, stream>>>(out, OUTD_, EH_, r2e_ah, r2e_at, st16, N_);
  k_sr<<<(R_*8 + TB - 1)/TB, TB, 0, stream>>>(xr, r2e_ar, sr8);
  k_r2e_logits2<<<gE, TB, 0, stream>>>(hi, ti, rel, st16, sr8, pos_h, pos_t, lhp, ltp);
  k_fold_ht<<<(N_+1)/2, 256, 0, stream>>>(off_h, off_t, lhp, ltp, shp, stp);
  k_r2e_agg2<<<N_, 128, 0, stream>>>(off_h, off_t, relh, relt, shp, stp,
                                     (const float4*)xr, (float4*)out);

  // GAT
  k_dots16<<<(N_+15)/16, 256, 0, stream>>>(out, OUTD_, X2D_, gat_ai, gat_aj, gg16, N_);
  k_pack_x2<<<gPK2, TB, 0, stream>>>((const float4*)out, x2b);
  k_gat_logits2<<<gEall, TB, 0, stream>>>(ja, ia, pos_dest, gg16, lgp);
  k_fold_gat<<<(N_+3)/4, 256, 0, stream>>>(off_dest, lgp, agp);
  k_gat_agg3<<<N_, 128, 0, stream>>>(off_dest, j_dest, agp, x2b, (float4*)out);
}

// Round 5
// 834.181 us; speedup vs baseline: 2.8101x; 1.2209x over previous
//
#include <hip/hip_runtime.h>
#include <math.h>

constexpr int N_    = 30000;
constexpr int E_    = 200000;
constexpr int EALL_ = 400000;
constexpr int R_    = 500;
constexpr int EH_   = 300;
constexpr int RH_   = 100;
constexpr int X2D_  = 500;
constexpr int OUTD_ = 1000;
constexpr int LD4   = OUTD_/4;  // 250
constexpr int EH4   = EH_/4;    // 75
constexpr int RH4   = RH_/4;    // 25
constexpr int NC_   = 16;       // chunks per relation for e2r agg
constexpr int XBS_  = 320;      // bf16 row stride for x tables (zero-padded K for MFMA)
constexpr int X2BS_ = 504;      // bf16 row stride for x2 table
constexpr int KP_   = 320;      // padded K for MFMA weights

typedef __attribute__((ext_vector_type(4))) float f32x4;
typedef __attribute__((ext_vector_type(8))) short s16x8;

__device__ __forceinline__ float lrelu_(float v){ return v > 0.f ? v : 0.01f*v; }
__device__ __forceinline__ float sig_(float z){ return 1.f/(1.f + expf(-z)); }
__device__ __forceinline__ unsigned short f2bf_(float f){
  unsigned int u = __float_as_uint(f);
  unsigned int r = (u + 0x7FFFu + ((u >> 16) & 1u)) >> 16;
  return (unsigned short)r;
}
__device__ __forceinline__ float bf2f_(unsigned short h){
  return __uint_as_float(((unsigned int)h) << 16);
}

// ---------------- CSR build (fused) ----------------
__global__ void k_count4(const int* __restrict__ ia, const int* __restrict__ rel,
                         const int* __restrict__ hi, const int* __restrict__ ti,
                         int* cd, int* cr, int* ch, int* ct){
  int idx = blockIdx.x*blockDim.x + threadIdx.x;
  if (idx < EALL_) { atomicAdd(&cd[ia[idx]], 1); return; }
  idx -= EALL_;
  if (idx < E_) { atomicAdd(&cr[rel[idx]], 1); return; }
  idx -= E_;
  if (idx < E_) { atomicAdd(&ch[hi[idx]], 1); return; }
  idx -= E_;
  if (idx < E_) { atomicAdd(&ct[ti[idx]], 1); return; }
}

__global__ void k_scan4(const int* c0, int* o0, int L0,
                        const int* c1, int* o1, int L1,
                        const int* c2, int* o2, int L2,
                        const int* c3, int* o3, int L3){
  const int* c; int* o; int L;
  switch (blockIdx.x){
    case 0: c=c0; o=o0; L=L0; break;
    case 1: c=c1; o=o1; L=L1; break;
    case 2: c=c2; o=o2; L=L2; break;
    default: c=c3; o=o3; L=L3; break;
  }
  __shared__ int sums[256];
  int t = threadIdx.x;
  int chunk = (L + 255) / 256;
  int s = min(t*chunk, L), e = min(s + chunk, L);
  int acc = 0;
  for (int i = s; i < e; ++i) acc += c[i];
  sums[t] = acc;
  __syncthreads();
  for (int off = 1; off < 256; off <<= 1) {
    int v = (t >= off) ? sums[t - off] : 0;
    __syncthreads();
    sums[t] += v;
    __syncthreads();
  }
  int run = t ? sums[t-1] : 0;
  for (int i = s; i < e; ++i) { o[i] = run; run += c[i]; }
  if (t == 255) o[L] = sums[255];
}

__global__ void k_dis(const int* __restrict__ cnt, float* __restrict__ dis){
  int i = blockIdx.x*blockDim.x + threadIdx.x;
  if (i < N_){ int c = cnt[i]; dis[i] = (c > 0) ? rsqrtf((float)c) : 0.f; }
}

__global__ void k_scatter4(const int* __restrict__ ja, const int* __restrict__ ia,
                           const int* __restrict__ rel, const int* __restrict__ hi,
                           const int* __restrict__ ti,
                           const int* od, const int* orl, const int* oh, const int* ot,
                           int* curd, int* curr, int* curh, int* curt,
                           int* j_dest, int* pos_dest,
                           int* hr, int* tr, int* pos_rel,
                           int* relh, int* pos_h,
                           int* relt, int* pos_t){
  int idx = blockIdx.x*blockDim.x + threadIdx.x;
  if (idx < EALL_){
    int e = idx, s = ia[e];
    int p = od[s] + atomicAdd(&curd[s], 1);
    j_dest[p] = ja[e]; pos_dest[e] = p; return;
  }
  idx -= EALL_;
  if (idx < E_){
    int e = idx, s = rel[e];
    int p = orl[s] + atomicAdd(&curr[s], 1);
    hr[p] = hi[e]; tr[p] = ti[e]; pos_rel[e] = p; return;
  }
  idx -= E_;
  if (idx < E_){
    int e = idx, s = hi[e];
    int p = oh[s] + atomicAdd(&curh[s], 1);
    relh[p] = rel[e]; pos_h[e] = p; return;
  }
  idx -= E_;
  if (idx < E_){
    int e = idx, s = ti[e];
    int p = ot[s] + atomicAdd(&curt[s], 1);
    relt[p] = rel[e]; pos_t[e] = p; return;
  }
}

__global__ void k_wj(const int* __restrict__ jd, const float* __restrict__ dis,
                     float* __restrict__ wj){
  int p = blockIdx.x*blockDim.x + threadIdx.x;
  if (p < EALL_) wj[p] = dis[jd[p]];
}

// ---------------- bf16 pack kernels ----------------
// pack X[M rows, 300 cols f32 @ ldx4 float4] -> xb[M][XBS_=320] bf16, zero-padded
__global__ void k_pack_x(const float4* __restrict__ X, int ldx4,
                         unsigned short* __restrict__ xb){
  int idx = blockIdx.x*blockDim.x + threadIdx.x;   // N_*80 ushort4 chunks
  if (idx >= N_*80) return;
  int n = idx / 80, c = idx - n*80;
  ushort4 o = make_ushort4(0,0,0,0);
  if (c < EH4){
    float4 v = X[(size_t)n*ldx4 + c];
    o.x = f2bf_(v.x); o.y = f2bf_(v.y); o.z = f2bf_(v.z); o.w = f2bf_(v.w);
  }
  *reinterpret_cast<ushort4*>(&xb[(size_t)n*XBS_ + c*4]) = o;
}

// pack out cols 0..499 -> x2b[N][X2BS_] bf16
__global__ void k_pack_x2(const float4* __restrict__ X, unsigned short* __restrict__ x2b){
  int idx = blockIdx.x*blockDim.x + threadIdx.x;
  if (idx >= N_*125) return;
  int n = idx / 125, c = idx - n*125;
  float4 v = X[(size_t)n*LD4 + c];
  ushort4 o;
  o.x = f2bf_(v.x); o.y = f2bf_(v.y); o.z = f2bf_(v.z); o.w = f2bf_(v.w);
  *reinterpret_cast<ushort4*>(&x2b[(size_t)n*X2BS_ + c*4]) = o;
}

// pack weight W[Nn][300] f32 -> [Nn][KP_] bf16 zero-padded
__global__ void k_pack_w(const float* __restrict__ W, int Nn,
                         unsigned short* __restrict__ out){
  int idx = blockIdx.x*blockDim.x + threadIdx.x;
  if (idx >= Nn*KP_) return;
  int n = idx / KP_, k = idx - n*KP_;
  out[idx] = (k < EH_) ? f2bf_(W[(size_t)n*EH_ + k]) : (unsigned short)0;
}

// pack [e2r_wh ; e2r_wt] (each [100][300]) -> [200][KP_] bf16
__global__ void k_pack_wcat(const float* __restrict__ wh, const float* __restrict__ wt,
                            unsigned short* __restrict__ out){
  int idx = blockIdx.x*blockDim.x + threadIdx.x;
  if (idx >= 200*KP_) return;
  int n = idx / KP_, k = idx - n*KP_;
  unsigned short v = 0;
  if (k < EH_) v = f2bf_((n < 100) ? wh[(size_t)n*EH_ + k] : wt[(size_t)(n-100)*EH_ + k]);
  out[idx] = v;
}

// ---------------- MFMA GEMM: C[M,Nn] = Ab[M,320]bf16 * Wb[Nn,320]bf16^T ----------------
// block: 256 thr = 4 waves; tile 128(m) x 64(n); wave tile 64x32 (4x2 frags 16x16)
__global__ __launch_bounds__(256) void k_gemm_mfma(
    const unsigned short* __restrict__ Ab,
    const unsigned short* __restrict__ Wb,
    float* __restrict__ C, int ldc, int M, int Nn){
  constexpr int WS = 328;  // Ws LDS stride (shorts)
  constexpr int AS = 40;   // As LDS stride (shorts)
  __shared__ unsigned short Ws[64*WS];
  __shared__ unsigned short As[128*AS];
  int tid = threadIdx.x;
  int lane = tid & 63, wave = tid >> 6;
  int wm = wave & 1, wn = wave >> 1;
  int m0 = blockIdx.x*128, n0 = blockIdx.y*64;

  // load 64-row W strip (full K) into LDS
  for (int c = tid; c < 64*(KP_/8); c += 256){
    int n = c / (KP_/8), k8 = (c % (KP_/8))*8;
    s16x8 v = {0,0,0,0,0,0,0,0};
    if (n0 + n < Nn)
      v = *reinterpret_cast<const s16x8*>(&Wb[(size_t)(n0+n)*KP_ + k8]);
    *reinterpret_cast<s16x8*>(&Ws[n*WS + k8]) = v;
  }

  f32x4 acc[4][2] = {};
  int kf = (lane >> 4)*8;
  int rA = lane & 15;
  for (int k0 = 0; k0 < KP_; k0 += 32){
    __syncthreads();   // protect As reuse + (iter0) Ws visibility
    for (int c = tid; c < 128*4; c += 256){
      int r = c >> 2, k8 = (c & 3)*8;
      s16x8 v = {0,0,0,0,0,0,0,0};
      if (m0 + r < M)
        v = *reinterpret_cast<const s16x8*>(&Ab[(size_t)(m0+r)*XBS_ + k0 + k8]);
      *reinterpret_cast<s16x8*>(&As[r*AS + k8]) = v;
    }
    __syncthreads();
    s16x8 afr[4], bfr[2];
    #pragma unroll
    for (int mf = 0; mf < 4; ++mf)
      afr[mf] = *reinterpret_cast<const s16x8*>(&As[(wm*64 + mf*16 + rA)*AS + kf]);
    #pragma unroll
    for (int nf = 0; nf < 2; ++nf)
      bfr[nf] = *reinterpret_cast<const s16x8*>(&Ws[(wn*32 + nf*16 + rA)*WS + k0 + kf]);
    #pragma unroll
    for (int mf = 0; mf < 4; ++mf)
      #pragma unroll
      for (int nf = 0; nf < 2; ++nf)
        acc[mf][nf] = __builtin_amdgcn_mfma_f32_16x16x32_bf16(afr[mf], bfr[nf], acc[mf][nf], 0, 0, 0);
  }
  // C write: col = lane&15, row = (lane>>4)*4 + reg
  int col0 = n0 + wn*32 + (lane & 15);
  int rbase = m0 + wm*64 + (lane >> 4)*4;
  #pragma unroll
  for (int mf = 0; mf < 4; ++mf){
    #pragma unroll
    for (int nf = 0; nf < 2; ++nf){
      int col = col0 + nf*16;
      if (col < Nn){
        #pragma unroll
        for (int r = 0; r < 4; ++r){
          int row = rbase + mf*16 + r;
          if (row < M) C[(size_t)row*ldc + col] = acc[mf][nf][r];
        }
      }
    }
  }
}

// ---------------- GCN gather (bf16 table, unroll-2) ----------------
__global__ void k_gcn3(const int* __restrict__ off, const int* __restrict__ jd,
                       const float* __restrict__ wj, const float* __restrict__ dis,
                       const unsigned short* __restrict__ xb, float4* __restrict__ Y){
  __shared__ int js[128];
  __shared__ float ws[128];
  int n = blockIdx.x, tid = threadIdx.x;
  int s = off[n], t = off[n+1];
  float4 acc = make_float4(0.f,0.f,0.f,0.f);
  for (int base = s; base < t; base += 128){
    int m = min(128, t - base);
    __syncthreads();
    if (tid < m){ js[tid] = jd[base+tid]; ws[tid] = wj[base+tid]; }
    __syncthreads();
    if (tid < EH4){
      int q = 0;
      for (; q + 1 < m; q += 2){
        float w0 = ws[q], w1 = ws[q+1];
        ushort4 u0 = *reinterpret_cast<const ushort4*>(&xb[(size_t)js[q]*XBS_ + tid*4]);
        ushort4 u1 = *reinterpret_cast<const ushort4*>(&xb[(size_t)js[q+1]*XBS_ + tid*4]);
        acc.x += w0*bf2f_(u0.x) + w1*bf2f_(u1.x);
        acc.y += w0*bf2f_(u0.y) + w1*bf2f_(u1.y);
        acc.z += w0*bf2f_(u0.z) + w1*bf2f_(u1.z);
        acc.w += w0*bf2f_(u0.w) + w1*bf2f_(u1.w);
      }
      if (q < m){
        float w0 = ws[q];
        ushort4 u0 = *reinterpret_cast<const ushort4*>(&xb[(size_t)js[q]*XBS_ + tid*4]);
        acc.x += w0*bf2f_(u0.x); acc.y += w0*bf2f_(u0.y);
        acc.z += w0*bf2f_(u0.z); acc.w += w0*bf2f_(u0.w);
      }
    }
  }
  if (tid < EH4){
    float dn = dis[n];
    float4 r;
    r.x = fmaxf(dn*acc.x, 0.f); r.y = fmaxf(dn*acc.y, 0.f);
    r.z = fmaxf(dn*acc.z, 0.f); r.w = fmaxf(dn*acc.w, 0.f);
    Y[(size_t)n*EH4 + tid] = r;
  }
}

// ---------------- highway (float4) ----------------
__global__ void k_highway2(const float4* __restrict__ Xold, int ldo4,
                           const float4* __restrict__ Y, const float4* __restrict__ G,
                           const float* __restrict__ b,
                           float4* __restrict__ Xn, int ldn4){
  int idx = blockIdx.x*blockDim.x + threadIdx.x;
  if (idx >= N_*EH4) return;
  int n = idx / EH4, f = idx - n*EH4;
  float4 g4 = G[idx];
  float4 b4 = reinterpret_cast<const float4*>(b)[f];
  float4 y4 = Y[idx];
  float4 xo = Xold[(size_t)n*ldo4 + f];
  float4 r;
  float gx;
  gx = sig_(g4.x + b4.x); r.x = gx*y4.x + (1.f-gx)*xo.x;
  gx = sig_(g4.y + b4.y); r.y = gx*y4.y + (1.f-gx)*xo.y;
  gx = sig_(g4.z + b4.z); r.z = gx*y4.z + (1.f-gx)*xo.z;
  gx = sig_(g4.w + b4.w); r.w = gx*y4.w + (1.f-gx)*xo.w;
  Xn[(size_t)n*ldn4 + f] = r;
}

// ---------------- E2R projections p1..p4 [N,2] ----------------
__global__ void k_pproj(const float* __restrict__ xhxt,
                        const float* __restrict__ ah, const float* __restrict__ at,
                        float* __restrict__ p1, float* __restrict__ p2,
                        float* __restrict__ p3, float* __restrict__ p4){
  int n = blockIdx.x*blockDim.x + threadIdx.x;
  if (n >= N_) return;
  float a0=0,a1=0,b0=0,b1=0,c0=0,c1=0,d0=0,d1=0;
  const float* xh = xhxt + (size_t)n*200;
  const float* xt = xh + 100;
  for (int f = 0; f < RH_; ++f) {
    float vh = xh[f], vt = xt[f];
    float w0 = ah[f], w1 = ah[RH_+f], u0 = at[f], u1 = at[RH_+f];
    a0 += vh*w0; a1 += vh*w1;
    b0 += vt*u0; b1 += vt*u1;
    c0 += vt*w0; c1 += vt*w1;
    d0 += vh*u0; d1 += vh*u1;
  }
  p1[n*2]=a0; p1[n*2+1]=a1; p2[n*2]=b0; p2[n*2+1]=b1;
  p3[n*2]=c0; p3[n*2+1]=c1; p4[n*2]=d0; p4[n*2+1]=d1;
}

__global__ void k_e2r_logits2(const int* __restrict__ hi, const int* __restrict__ ti,
                              const int* __restrict__ pos_rel,
                              const float* __restrict__ p1, const float* __restrict__ p2,
                              const float* __restrict__ p3, const float* __restrict__ p4,
                              float* __restrict__ e1p, float* __restrict__ e2p){
  int e = blockIdx.x*blockDim.x + threadIdx.x;
  if (e >= E_) return;
  int h = hi[e], t = ti[e];
  size_t pp = (size_t)pos_rel[e]*2;
  e1p[pp]   = lrelu_(p1[h*2]   + p2[t*2]);
  e1p[pp+1] = lrelu_(p1[h*2+1] + p2[t*2+1]);
  e2p[pp]   = lrelu_(p3[h*2]   + p4[t*2]);
  e2p[pp+1] = lrelu_(p3[h*2+1] + p4[t*2+1]);
}

// ---------------- segment softmax fold ----------------
template<int K>
__device__ __forceinline__ void softmax_fold(const int* __restrict__ off,
                                             const float* __restrict__ lp,
                                             float* __restrict__ op, int seg){
  int lane = threadIdx.x & 63;
  int k = lane & (K - 1);
  int g = lane / K;
  const int GS = 64 / K;
  int s = off[seg], e = off[seg + 1];
  float m = -1e30f;
  for (int p = s + g; p < e; p += GS) m = fmaxf(m, lp[(size_t)p*K + k]);
  #pragma unroll
  for (int o = K; o < 64; o <<= 1) m = fmaxf(m, __shfl_xor(m, o));
  float sum = 0.f;
  for (int p = s + g; p < e; p += GS) sum += expf(lp[(size_t)p*K + k] - m);
  #pragma unroll
  for (int o = K; o < 64; o <<= 1) sum += __shfl_xor(sum, o);
  float inv = 1.f / (sum + 1e-16f);
  for (int p = s + g; p < e; p += GS){
    float t = expf(lp[(size_t)p*K + k] - m) * inv;
    #pragma unroll
    for (int o = 1; o < K; o <<= 1) t += __shfl_xor(t, o);
    if (k == 0) op[p] = t;
  }
}

// rel-segment fold: 4 waves per relation (2 per logit array, LDS combine)
__global__ void k_fold_rel(const int* __restrict__ off,
                           const float* __restrict__ e1p, const float* __restrict__ e2p,
                           float* __restrict__ s1p, float* __restrict__ s2p){
  __shared__ float lm[4][2];
  __shared__ float lsum[4][2];
  int r = blockIdx.x;
  int w = threadIdx.x >> 6;      // 0..3
  int lane = threadIdx.x & 63;
  const float* lp = (w < 2) ? e1p : e2p;
  float* op = (w < 2) ? s1p : s2p;
  int half = w & 1;
  int k = lane & 1, g = lane >> 1;
  int gg = half*32 + g;
  int s = off[r], e = off[r+1];
  float m = -1e30f;
  for (int p = s + gg; p < e; p += 64) m = fmaxf(m, lp[(size_t)p*2 + k]);
  #pragma unroll
  for (int o = 2; o < 64; o <<= 1) m = fmaxf(m, __shfl_xor(m, o));
  if (lane < 2) lm[w][lane] = m;
  __syncthreads();
  m = fmaxf(lm[w][k], lm[w^1][k]);
  float sum = 0.f;
  for (int p = s + gg; p < e; p += 64) sum += expf(lp[(size_t)p*2 + k] - m);
  #pragma unroll
  for (int o = 2; o < 64; o <<= 1) sum += __shfl_xor(sum, o);
  if (lane < 2) lsum[w][lane] = sum;
  __syncthreads();
  sum = lsum[w][k] + lsum[w^1][k];
  float inv = 1.f / (sum + 1e-16f);
  for (int p = s + gg; p < e; p += 64){
    float t = expf(lp[(size_t)p*2 + k] - m) * inv;
    t += __shfl_xor(t, 1);
    if (k == 0) op[p] = t;
  }
}

__global__ void k_fold_ht(const int* __restrict__ offh, const int* __restrict__ offt,
                          const float* __restrict__ lhp, const float* __restrict__ ltp,
                          float* __restrict__ shp, float* __restrict__ stp){
  int w = threadIdx.x >> 6;
  int n = blockIdx.x*2 + (w >> 1);
  if (n >= N_) return;
  if (w & 1) softmax_fold<8>(offt, ltp, stp, n);
  else       softmax_fold<8>(offh, lhp, shp, n);
}

__global__ void k_fold_gat(const int* __restrict__ off, const float* __restrict__ lgp,
                           float* __restrict__ agp){
  int w = threadIdx.x >> 6;
  int n = blockIdx.x*4 + w;
  if (n >= N_) return;
  softmax_fold<8>(off, lgp, agp, n);
}

// ---------------- E2R aggregate: chunked partials + deterministic reduce ----------------
__global__ void k_e2r_agg3(const int* __restrict__ off,
                           const int* __restrict__ hr, const int* __restrict__ tr,
                           const float* __restrict__ s1p, const float* __restrict__ s2p,
                           const float4* __restrict__ xhxt4, float4* __restrict__ xr_part){
  int r = blockIdx.x, c = blockIdx.y;
  int lane = threadIdx.x;           // 64
  int side = lane >> 5, fl = lane & 31;
  int s = off[r], e = off[r+1];
  int len = e - s;
  int per = (len + NC_ - 1)/NC_;
  int cs = s + c*per, ce = min(cs + per, e);
  float4 acc = make_float4(0.f,0.f,0.f,0.f);
  if (fl < RH4){
    const int* idx = side ? tr : hr;
    const float* wv = side ? s2p : s1p;
    int fofs = side ? 25 + fl : fl;
    int p = cs;
    for (; p + 1 < ce; p += 2){
      float a0 = wv[p], a1 = wv[p+1];
      float4 v0 = xhxt4[(size_t)idx[p]*50 + fofs];
      float4 v1 = xhxt4[(size_t)idx[p+1]*50 + fofs];
      acc.x += a0*v0.x + a1*v1.x; acc.y += a0*v0.y + a1*v1.y;
      acc.z += a0*v0.z + a1*v1.z; acc.w += a0*v0.w + a1*v1.w;
    }
    if (p < ce){
      float a0 = wv[p];
      float4 v0 = xhxt4[(size_t)idx[p]*50 + fofs];
      acc.x += a0*v0.x; acc.y += a0*v0.y; acc.z += a0*v0.z; acc.w += a0*v0.w;
    }
  }
  float4 oth;
  oth.x = __shfl_xor(acc.x, 32); oth.y = __shfl_xor(acc.y, 32);
  oth.z = __shfl_xor(acc.z, 32); oth.w = __shfl_xor(acc.w, 32);
  if (side == 0 && fl < RH4){
    float4 o = make_float4(acc.x+oth.x, acc.y+oth.y, acc.z+oth.z, acc.w+oth.w);
    xr_part[((size_t)c*R_ + r)*RH4 + fl] = o;
  }
}

__global__ void k_e2r_red(const float4* __restrict__ xr_part, float4* __restrict__ xr4){
  int idx = blockIdx.x*blockDim.x + threadIdx.x;
  if (idx >= R_*RH4) return;
  float4 a = make_float4(0.f,0.f,0.f,0.f);
  #pragma unroll
  for (int c = 0; c < NC_; ++c){
    float4 v = xr_part[(size_t)c*R_*RH4 + idx];
    a.x += v.x; a.y += v.y; a.z += v.z; a.w += v.w;
  }
  xr4[idx] = make_float4(a.x*0.25f, a.y*0.25f, a.z*0.25f, a.w*0.25f);
}

// ---------------- 16-head row dots ----------------
__global__ void k_dots16(const float* __restrict__ X, int ldx, int K,
                         const float* __restrict__ wA, const float* __restrict__ wB,
                         float* __restrict__ out16, int M){
  __shared__ float xs[16][65];
  __shared__ float ws[16][65];
  int tid = threadIdx.x;
  int tx = tid & 15, ty = tid >> 4;
  int r0 = blockIdx.x*16;
  float acc = 0.f;
  for (int c0 = 0; c0 < K; c0 += 64){
    int cl = min(64, K - c0);
    #pragma unroll
    for (int i = 0; i < 4; ++i){
      int idx = tid + i*256;
      int r = idx >> 6, k = idx & 63;
      float xv = 0.f, wv = 0.f;
      if (k < cl && r0 + r < M) xv = X[(size_t)(r0+r)*ldx + c0 + k];
      if (k < cl) wv = (r < 8) ? wA[(size_t)r*K + c0 + k] : wB[(size_t)(r-8)*K + c0 + k];
      xs[r][k] = xv;
      ws[r][k] = wv;
    }
    __syncthreads();
    #pragma unroll
    for (int k = 0; k < 64; ++k) acc += xs[ty][k]*ws[tx][k];
    __syncthreads();
  }
  if (r0 + ty < M) out16[(size_t)(r0+ty)*16 + tx] = acc;
}

// ---------------- sr [R,8] ----------------
__global__ void k_sr(const float* __restrict__ xr, const float* __restrict__ ar,
                     float* __restrict__ sr8){
  int idx = blockIdx.x*blockDim.x + threadIdx.x;
  if (idx >= R_*8) return;
  int r = idx >> 3, h = idx & 7;
  float acc = 0.f;
  for (int k = 0; k < RH_; ++k) acc += xr[(size_t)r*RH_ + k]*ar[(size_t)h*RH_ + k];
  sr8[idx] = acc;
}

// ---------------- R2E logits (permuted writes) ----------------
__global__ void k_r2e_logits2(const int* __restrict__ hi, const int* __restrict__ ti,
                              const int* __restrict__ rl,
                              const float* __restrict__ st16, const float* __restrict__ sr8,
                              const int* __restrict__ pos_h, const int* __restrict__ pos_t,
                              float* __restrict__ lhp, float* __restrict__ ltp){
  int e = blockIdx.x*blockDim.x + threadIdx.x;
  if (e >= E_) return;
  int h = hi[e], t = ti[e], r = rl[e];
  const float4* sh4 = reinterpret_cast<const float4*>(st16 + (size_t)h*16);
  const float4* st4 = reinterpret_cast<const float4*>(st16 + (size_t)t*16 + 8);
  const float4* sr4 = reinterpret_cast<const float4*>(sr8 + (size_t)r*8);
  float4 a0 = sh4[0], a1 = sh4[1], b0 = st4[0], b1 = st4[1], c0 = sr4[0], c1 = sr4[1];
  float4 o0, o1;
  o0.x = lrelu_(a0.x+c0.x); o0.y = lrelu_(a0.y+c0.y); o0.z = lrelu_(a0.z+c0.z); o0.w = lrelu_(a0.w+c0.w);
  o1.x = lrelu_(a1.x+c1.x); o1.y = lrelu_(a1.y+c1.y); o1.z = lrelu_(a1.z+c1.z); o1.w = lrelu_(a1.w+c1.w);
  float4* dh = reinterpret_cast<float4*>(lhp + (size_t)pos_h[e]*8);
  dh[0] = o0; dh[1] = o1;
  o0.x = lrelu_(b0.x+c0.x); o0.y = lrelu_(b0.y+c0.y); o0.z = lrelu_(b0.z+c0.z); o0.w = lrelu_(b0.w+c0.w);
  o1.x = lrelu_(b1.x+c1.x); o1.y = lrelu_(b1.y+c1.y); o1.z = lrelu_(b1.z+c1.z); o1.w = lrelu_(b1.w+c1.w);
  float4* dt = reinterpret_cast<float4*>(ltp + (size_t)pos_t[e]*8);
  dt[0] = o0; dt[1] = o1;
}

// ---------------- R2E aggregate ----------------
__global__ void k_r2e_agg2(const int* __restrict__ offh, const int* __restrict__ offt,
                           const int* __restrict__ relh, const int* __restrict__ relt,
                           const float* __restrict__ shp, const float* __restrict__ stp,
                           const float4* __restrict__ xr4, float4* __restrict__ out){
  int n = blockIdx.x;
  int side = threadIdx.x >> 6, lane = threadIdx.x & 63;
  const int* off = side ? offt : offh;
  const int* rr  = side ? relt : relh;
  const float* sp = side ? stp : shp;
  int s = off[n], e = off[n+1];
  if (lane >= RH4) return;
  float4 acc = make_float4(0.f,0.f,0.f,0.f);
  int p = s;
  for (; p + 1 < e; p += 2){
    float a0 = sp[p], a1 = sp[p+1];
    float4 v0 = xr4[(size_t)rr[p]*RH4 + lane];
    float4 v1 = xr4[(size_t)rr[p+1]*RH4 + lane];
    acc.x += a0*v0.x + a1*v1.x; acc.y += a0*v0.y + a1*v1.y;
    acc.z += a0*v0.z + a1*v1.z; acc.w += a0*v0.w + a1*v1.w;
  }
  if (p < e){
    float a0 = sp[p];
    float4 v0 = xr4[(size_t)rr[p]*RH4 + lane];
    acc.x += a0*v0.x; acc.y += a0*v0.y; acc.z += a0*v0.z; acc.w += a0*v0.w;
  }
  float4 o = make_float4(acc.x*0.125f, acc.y*0.125f, acc.z*0.125f, acc.w*0.125f);
  out[(size_t)n*LD4 + (side ? 100 : 75) + lane] = o;
}

// ---------------- GAT logits ----------------
__global__ void k_gat_logits2(const int* __restrict__ ja, const int* __restrict__ ia,
                              const int* __restrict__ pos_dest,
                              const float* __restrict__ gg16, float* __restrict__ lgp){
  int e = blockIdx.x*blockDim.x + threadIdx.x;
  if (e >= EALL_) return;
  int i = ia[e], j = ja[e];
  const float4* gi4 = reinterpret_cast<const float4*>(gg16 + (size_t)i*16);
  const float4* gj4 = reinterpret_cast<const float4*>(gg16 + (size_t)j*16 + 8);
  float4 a0 = gi4[0], a1 = gi4[1], b0 = gj4[0], b1 = gj4[1];
  float4 o0, o1;
  o0.x = lrelu_(a0.x+b0.x); o0.y = lrelu_(a0.y+b0.y); o0.z = lrelu_(a0.z+b0.z); o0.w = lrelu_(a0.w+b0.w);
  o1.x = lrelu_(a1.x+b1.x); o1.y = lrelu_(a1.y+b1.y); o1.z = lrelu_(a1.z+b1.z); o1.w = lrelu_(a1.w+b1.w);
  float4* d = reinterpret_cast<float4*>(lgp + (size_t)pos_dest[e]*8);
  d[0] = o0; d[1] = o1;
}

// ---------------- GAT aggregate (bf16 table, unroll-2) ----------------
__global__ void k_gat_agg3(const int* __restrict__ off, const int* __restrict__ jd,
                           const float* __restrict__ agp,
                           const unsigned short* __restrict__ x2b, float4* __restrict__ out){
  __shared__ int js[128];
  __shared__ float as_[128];
  int n = blockIdx.x, tid = threadIdx.x;
  int s = off[n], t = off[n+1];
  float4 acc = make_float4(0.f,0.f,0.f,0.f);
  for (int base = s; base < t; base += 128){
    int m = min(128, t - base);
    __syncthreads();
    if (tid < m){ js[tid] = jd[base+tid]; as_[tid] = agp[base+tid]; }
    __syncthreads();
    if (tid < 125){
      int q = 0;
      for (; q + 1 < m; q += 2){
        float a0 = as_[q], a1 = as_[q+1];
        ushort4 u0 = *reinterpret_cast<const ushort4*>(&x2b[(size_t)js[q]*X2BS_ + tid*4]);
        ushort4 u1 = *reinterpret_cast<const ushort4*>(&x2b[(size_t)js[q+1]*X2BS_ + tid*4]);
        acc.x += a0*bf2f_(u0.x) + a1*bf2f_(u1.x);
        acc.y += a0*bf2f_(u0.y) + a1*bf2f_(u1.y);
        acc.z += a0*bf2f_(u0.z) + a1*bf2f_(u1.z);
        acc.w += a0*bf2f_(u0.w) + a1*bf2f_(u1.w);
      }
      if (q < m){
        float a0 = as_[q];
        ushort4 u0 = *reinterpret_cast<const ushort4*>(&x2b[(size_t)js[q]*X2BS_ + tid*4]);
        acc.x += a0*bf2f_(u0.x); acc.y += a0*bf2f_(u0.y);
        acc.z += a0*bf2f_(u0.z); acc.w += a0*bf2f_(u0.w);
      }
    }
  }
  if (tid < 125){
    float4 r = make_float4(acc.x*0.125f, acc.y*0.125f, acc.z*0.125f, acc.w*0.125f);
    out[(size_t)n*LD4 + 125 + tid] = r;
  }
}

// ---------------- host ----------------
static inline void gemm_mfma(const unsigned short* Ab, const unsigned short* Wb,
                             float* C, int ldc, int M, int Nn, hipStream_t st){
  dim3 g((M + 127)/128, (Nn + 63)/64);
  k_gemm_mfma<<<g, 256, 0, st>>>(Ab, Wb, C, ldc, M, Nn);
}

extern "C" void kernel_launch(void* const* d_in, const int* in_sizes, int n_in,
                              void* d_out, int out_size, void* d_ws, size_t ws_size,
                              hipStream_t stream) {
  const float* x_e   = (const float*)d_in[0];
  const int*   ei    = (const int*)d_in[1];
  const int*   rel   = (const int*)d_in[2];
  const int*   eia   = (const int*)d_in[3];
  const float* hw1_w = (const float*)d_in[5];
  const float* hw1_b = (const float*)d_in[6];
  const float* hw2_w = (const float*)d_in[7];
  const float* hw2_b = (const float*)d_in[8];
  const float* e2r_wh= (const float*)d_in[9];
  const float* e2r_wt= (const float*)d_in[10];
  const float* e2r_ah= (const float*)d_in[11];
  const float* e2r_at= (const float*)d_in[12];
  const float* r2e_ah= (const float*)d_in[13];
  const float* r2e_at= (const float*)d_in[14];
  const float* r2e_ar= (const float*)d_in[15];
  const float* gat_ai= (const float*)d_in[16];
  const float* gat_aj= (const float*)d_in[17];
  float* out = (float*)d_out;

  const int* hi = ei;
  const int* ti = ei + E_;
  const int* ja = eia;
  const int* ia = eia + EALL_;

  char* base = (char*)d_ws;
  size_t off = 0;
  auto alloc = [&](size_t bytes)->void*{
    void* p = base + off;
    off = (off + bytes + 255) & ~(size_t)255;
    return p;
  };

  // zeroed region: counts + cursors
  size_t z0 = off;
  int* cnt_dest = (int*)alloc(N_*4);
  int* cur_dest = (int*)alloc(N_*4);
  int* cnt_h    = (int*)alloc(N_*4);
  int* cur_h    = (int*)alloc(N_*4);
  int* cnt_t    = (int*)alloc(N_*4);
  int* cur_t    = (int*)alloc(N_*4);
  int* cnt_rel  = (int*)alloc(R_*4);
  int* cur_rel  = (int*)alloc(R_*4);
  size_t z1 = off;

  int* off_dest = (int*)alloc((N_+1)*4);
  int* off_rel  = (int*)alloc((R_+1)*4);
  int* off_h    = (int*)alloc((N_+1)*4);
  int* off_t    = (int*)alloc((N_+1)*4);
  int* j_dest   = (int*)alloc((size_t)EALL_*4);
  int* pos_dest = (int*)alloc((size_t)EALL_*4);
  int* hr       = (int*)alloc((size_t)E_*4);
  int* tr       = (int*)alloc((size_t)E_*4);
  int* pos_rel  = (int*)alloc((size_t)E_*4);
  int* relh     = (int*)alloc((size_t)E_*4);
  int* pos_h    = (int*)alloc((size_t)E_*4);
  int* relt     = (int*)alloc((size_t)E_*4);
  int* pos_t    = (int*)alloc((size_t)E_*4);

  float* dis   = (float*)alloc(N_*4);
  float* wj    = (float*)alloc((size_t)EALL_*4);
  float* y     = (float*)alloc((size_t)N_*EH_*4);   // 36 MB; later aliased by lhp/ltp
  float* g     = (float*)alloc((size_t)N_*EH_*4);   // 36 MB; later aliased by lgp
  float* xhxt  = (float*)alloc((size_t)N_*200*4);
  float* p1    = (float*)alloc((size_t)N_*2*4);
  float* p2    = (float*)alloc((size_t)N_*2*4);
  float* p3    = (float*)alloc((size_t)N_*2*4);
  float* p4    = (float*)alloc((size_t)N_*2*4);
  float* e1p   = (float*)alloc((size_t)E_*2*4);
  float* e2p   = (float*)alloc((size_t)E_*2*4);
  float* s1p   = (float*)alloc((size_t)E_*4);
  float* s2p   = (float*)alloc((size_t)E_*4);
  float* xr    = (float*)alloc((size_t)R_*RH_*4);
  float* xr_part=(float*)alloc((size_t)NC_*R_*RH_*4);
  float* st16  = (float*)alloc((size_t)N_*16*4);
  float* sr8   = (float*)alloc((size_t)R_*8*4);
  float* shp   = (float*)alloc((size_t)E_*4);
  float* stp   = (float*)alloc((size_t)E_*4);
  float* gg16  = (float*)alloc((size_t)N_*16*4);
  float* agp   = (float*)alloc((size_t)EALL_*4);
  unsigned short* xb  = (unsigned short*)alloc((size_t)N_*XBS_*2);   // 19.2 MB
  unsigned short* x2b = (unsigned short*)alloc((size_t)N_*X2BS_*2);  // 30.2 MB
  unsigned short* w1b = (unsigned short*)alloc((size_t)EH_*KP_*2);   // 192 KB
  unsigned short* w2b = (unsigned short*)alloc((size_t)EH_*KP_*2);
  unsigned short* wcb = (unsigned short*)alloc((size_t)200*KP_*2);   // 128 KB

  // aliases into dead buffers
  float* lhp = y;                   // [E,8]  (y dead after highway2)
  float* ltp = y + (size_t)E_*8;
  float* lgp = g;                   // [EALL,8] (g dead after highway2)

  hipMemsetAsync(base + z0, 0, z1 - z0, stream);

  const int TB = 256;
  const int TOT = EALL_ + 3*E_;
  int gTOT  = (TOT + TB - 1)/TB;
  int gE    = (E_ + TB - 1)/TB;
  int gEall = (EALL_ + TB - 1)/TB;
  int gN    = (N_ + TB - 1)/TB;
  int gPKX  = (N_*80 + TB - 1)/TB;
  int gPK2  = (N_*125 + TB - 1)/TB;

  // weight packs (independent of everything else)
  k_pack_w<<<(EH_*KP_ + TB - 1)/TB, TB, 0, stream>>>(hw1_w, EH_, w1b);
  k_pack_w<<<(EH_*KP_ + TB - 1)/TB, TB, 0, stream>>>(hw2_w, EH_, w2b);
  k_pack_wcat<<<(200*KP_ + TB - 1)/TB, TB, 0, stream>>>(e2r_wh, e2r_wt, wcb);

  // CSR build
  k_count4<<<gTOT, TB, 0, stream>>>(ia, rel, hi, ti, cnt_dest, cnt_rel, cnt_h, cnt_t);
  k_scan4<<<4, 256, 0, stream>>>(cnt_dest, off_dest, N_, cnt_rel, off_rel, R_,
                                 cnt_h, off_h, N_, cnt_t, off_t, N_);
  k_dis<<<gN, TB, 0, stream>>>(cnt_dest, dis);
  k_scatter4<<<gTOT, TB, 0, stream>>>(ja, ia, rel, hi, ti,
                                      off_dest, off_rel, off_h, off_t,
                                      cur_dest, cur_rel, cur_h, cur_t,
                                      j_dest, pos_dest, hr, tr, pos_rel,
                                      relh, pos_h, relt, pos_t);
  k_wj<<<gEall, TB, 0, stream>>>(j_dest, dis, wj);

  // GCN + highway block 1 (x -> out cols 0..299)
  k_pack_x<<<gPKX, TB, 0, stream>>>((const float4*)x_e, EH4, xb);
  gemm_mfma(xb, w1b, g, EH_, N_, EH_, stream);
  k_gcn3<<<N_, 128, 0, stream>>>(off_dest, j_dest, wj, dis, xb, (float4*)y);
  k_highway2<<<(N_*EH4 + TB - 1)/TB, TB, 0, stream>>>((const float4*)x_e, EH4, (const float4*)y,
                                                      (const float4*)g, hw1_b, (float4*)out, LD4);
  // block 2
  k_pack_x<<<gPKX, TB, 0, stream>>>((const float4*)out, LD4, xb);
  gemm_mfma(xb, w2b, g, EH_, N_, EH_, stream);
  k_gcn3<<<N_, 128, 0, stream>>>(off_dest, j_dest, wj, dis, xb, (float4*)y);
  k_highway2<<<(N_*EH4 + TB - 1)/TB, TB, 0, stream>>>((const float4*)out, LD4, (const float4*)y,
                                                      (const float4*)g, hw2_b, (float4*)out, LD4);

  // E2R (pack final x, reuse xb as MFMA A-operand)
  k_pack_x<<<gPKX, TB, 0, stream>>>((const float4*)out, LD4, xb);
  gemm_mfma(xb, wcb, xhxt, 200, N_, 200, stream);
  k_pproj<<<gN, TB, 0, stream>>>(xhxt, e2r_ah, e2r_at, p1, p2, p3, p4);
  k_e2r_logits2<<<gE, TB, 0, stream>>>(hi, ti, pos_rel, p1, p2, p3, p4, e1p, e2p);
  k_fold_rel<<<R_, 256, 0, stream>>>(off_rel, e1p, e2p, s1p, s2p);
  k_e2r_agg3<<<dim3(R_, NC_), 64, 0, stream>>>(off_rel, hr, tr, s1p, s2p,
                                               (const float4*)xhxt, (float4*)xr_part);
  k_e2r_red<<<(R_*RH4 + TB - 1)/TB, TB, 0, stream>>>((const float4*)xr_part, (float4*)xr);

  // R2E
  k_dots16<<<(N_+15)/16, 256, 0, stream>>>(out, OUTD_, EH_, r2e_ah, r2e_at, st16, N_);
  k_sr<<<(R_*8 + TB - 1)/TB, TB, 0, stream>>>(xr, r2e_ar, sr8);
  k_r2e_logits2<<<gE, TB, 0, stream>>>(hi, ti, rel, st16, sr8, pos_h, pos_t, lhp, ltp);
  k_fold_ht<<<(N_+1)/2, 256, 0, stream>>>(off_h, off_t, lhp, ltp, shp, stp);
  k_r2e_agg2<<<N_, 128, 0, stream>>>(off_h, off_t, relh, relt, shp, stp,
                                     (const float4*)xr, (float4*)out);

  // GAT
  k_dots16<<<(N_+15)/16, 256, 0, stream>>>(out, OUTD_, X2D_, gat_ai, gat_aj, gg16, N_);
  k_pack_x2<<<gPK2, TB, 0, stream>>>((const float4*)out, x2b);
  k_gat_logits2<<<gEall, TB, 0, stream>>>(ja, ia, pos_dest, gg16, lgp);
  k_fold_gat<<<(N_+3)/4, 256, 0, stream>>>(off_dest, lgp, agp);
  k_gat_agg3<<<N_, 128, 0, stream>>>(off_dest, j_dest, agp, x2b, (float4*)out);
}

// Round 6
// 749.124 us; speedup vs baseline: 3.1292x; 1.1135x over previous
//
#include <hip/hip_runtime.h>
#include <math.h>

constexpr int N_    = 30000;
constexpr int E_    = 200000;
constexpr int EALL_ = 400000;
constexpr int R_    = 500;
constexpr int EH_   = 300;
constexpr int RH_   = 100;
constexpr int X2D_  = 500;
constexpr int OUTD_ = 1000;
constexpr int LD4   = OUTD_/4;  // 250
constexpr int EH4   = EH_/4;    // 75
constexpr int RH4   = RH_/4;    // 25
constexpr int NC_   = 16;       // chunks per relation for e2r agg
constexpr int XBS_  = 320;      // bf16 row stride for x tables (zero-padded K for MFMA)
constexpr int X2BS_ = 504;      // bf16 row stride for x2 table
constexpr int KP_   = 320;      // padded K for MFMA weights
constexpr int NBR_  = 64;       // blocks for rel counting sort
constexpr int PERB_ = (E_ + NBR_ - 1)/NBR_;  // 3125 edges per block

typedef __attribute__((ext_vector_type(4))) float f32x4;
typedef __attribute__((ext_vector_type(8))) short s16x8;

__device__ __forceinline__ float lrelu_(float v){ return v > 0.f ? v : 0.01f*v; }
__device__ __forceinline__ float sig_(float z){ return 1.f/(1.f + expf(-z)); }
__device__ __forceinline__ unsigned short f2bf_(float f){
  unsigned int u = __float_as_uint(f);
  unsigned int r = (u + 0x7FFFu + ((u >> 16) & 1u)) >> 16;
  return (unsigned short)r;
}
__device__ __forceinline__ float bf2f_(unsigned short h){
  return __uint_as_float(((unsigned int)h) << 16);
}

// ---------------- CSR build: dest/h/t via atomics (low contention) ----------------
__global__ void k_count3(const int* __restrict__ ia,
                         const int* __restrict__ hi, const int* __restrict__ ti,
                         int* cd, int* ch, int* ct){
  int idx = blockIdx.x*blockDim.x + threadIdx.x;
  if (idx < EALL_) { atomicAdd(&cd[ia[idx]], 1); return; }
  idx -= EALL_;
  if (idx < E_) { atomicAdd(&ch[hi[idx]], 1); return; }
  idx -= E_;
  if (idx < E_) { atomicAdd(&ct[ti[idx]], 1); return; }
}

__global__ void k_scan3(const int* c0, int* o0, int L0,
                        const int* c1, int* o1, int L1,
                        const int* c2, int* o2, int L2){
  const int* c; int* o; int L;
  switch (blockIdx.x){
    case 0: c=c0; o=o0; L=L0; break;
    case 1: c=c1; o=o1; L=L1; break;
    default: c=c2; o=o2; L=L2; break;
  }
  __shared__ int sums[256];
  int t = threadIdx.x;
  int chunk = (L + 255) / 256;
  int s = min(t*chunk, L), e = min(s + chunk, L);
  int acc = 0;
  for (int i = s; i < e; ++i) acc += c[i];
  sums[t] = acc;
  __syncthreads();
  for (int off = 1; off < 256; off <<= 1) {
    int v = (t >= off) ? sums[t - off] : 0;
    __syncthreads();
    sums[t] += v;
    __syncthreads();
  }
  int run = t ? sums[t-1] : 0;
  for (int i = s; i < e; ++i) { o[i] = run; run += c[i]; }
  if (t == 255) o[L] = sums[255];
}

__global__ void k_dis(const int* __restrict__ cnt, float* __restrict__ dis){
  int i = blockIdx.x*blockDim.x + threadIdx.x;
  if (i < N_){ int c = cnt[i]; dis[i] = (c > 0) ? rsqrtf((float)c) : 0.f; }
}

__global__ void k_scatter3(const int* __restrict__ ja, const int* __restrict__ ia,
                           const int* __restrict__ rel, const int* __restrict__ hi,
                           const int* __restrict__ ti,
                           const int* od, const int* oh, const int* ot,
                           int* curd, int* curh, int* curt,
                           int* j_dest, int* pos_dest,
                           int* relh, int* pos_h,
                           int* relt, int* pos_t){
  int idx = blockIdx.x*blockDim.x + threadIdx.x;
  if (idx < EALL_){
    int e = idx, s = ia[e];
    int p = od[s] + atomicAdd(&curd[s], 1);
    j_dest[p] = ja[e]; pos_dest[e] = p; return;
  }
  idx -= EALL_;
  if (idx < E_){
    int e = idx, s = hi[e];
    int p = oh[s] + atomicAdd(&curh[s], 1);
    relh[p] = rel[e]; pos_h[e] = p; return;
  }
  idx -= E_;
  if (idx < E_){
    int e = idx, s = ti[e];
    int p = ot[s] + atomicAdd(&curt[s], 1);
    relt[p] = rel[e]; pos_t[e] = p; return;
  }
}

// ---------------- rel CSR: block counting sort, no global atomics ----------------
__global__ void k_relhist(const int* __restrict__ rel, int* __restrict__ H){
  __shared__ int h[R_];
  int b = blockIdx.x, tid = threadIdx.x;
  for (int i = tid; i < R_; i += 256) h[i] = 0;
  __syncthreads();
  int s = b*PERB_, e = min(s + PERB_, E_);
  for (int i = s + tid; i < e; i += 256) atomicAdd(&h[rel[i]], 1);
  __syncthreads();
  for (int i = tid; i < R_; i += 256) H[b*R_ + i] = h[i];
}

__global__ void k_relscan(int* __restrict__ H, int* __restrict__ off_rel){
  __shared__ int tot[R_];
  int tid = threadIdx.x;
  for (int r = tid; r < R_; r += 256){
    int acc = 0;
    for (int b = 0; b < NBR_; ++b){ int v = H[b*R_ + r]; H[b*R_ + r] = acc; acc += v; }
    tot[r] = acc;
  }
  __syncthreads();
  if (tid == 0){
    int run = 0;
    for (int r = 0; r < R_; ++r){ off_rel[r] = run; run += tot[r]; }
    off_rel[R_] = run;
  }
  __syncthreads();
  for (int r = tid; r < R_; r += 256){
    int o = off_rel[r];
    for (int b = 0; b < NBR_; ++b) H[b*R_ + r] += o;
  }
}

__global__ void k_relscatter(const int* __restrict__ rel, const int* __restrict__ hi,
                             const int* __restrict__ ti, const int* __restrict__ H,
                             int* __restrict__ hr, int* __restrict__ tr,
                             int* __restrict__ pos_rel){
  __shared__ int cur[R_];
  int b = blockIdx.x, tid = threadIdx.x;
  for (int i = tid; i < R_; i += 256) cur[i] = H[b*R_ + i];
  __syncthreads();
  int s = b*PERB_, e = min(s + PERB_, E_);
  for (int i = s + tid; i < e; i += 256){
    int r = rel[i];
    int p = atomicAdd(&cur[r], 1);
    hr[p] = hi[i]; tr[p] = ti[i]; pos_rel[i] = p;
  }
}

__global__ void k_wj(const int* __restrict__ jd, const float* __restrict__ dis,
                     float* __restrict__ wj){
  int p = blockIdx.x*blockDim.x + threadIdx.x;
  if (p < EALL_) wj[p] = dis[jd[p]];
}

// ---------------- bf16 pack kernels ----------------
__global__ void k_pack_x(const float4* __restrict__ X, int ldx4,
                         unsigned short* __restrict__ xb){
  int idx = blockIdx.x*blockDim.x + threadIdx.x;   // N_*80 ushort4 chunks
  if (idx >= N_*80) return;
  int n = idx / 80, c = idx - n*80;
  ushort4 o = make_ushort4(0,0,0,0);
  if (c < EH4){
    float4 v = X[(size_t)n*ldx4 + c];
    o.x = f2bf_(v.x); o.y = f2bf_(v.y); o.z = f2bf_(v.z); o.w = f2bf_(v.w);
  }
  *reinterpret_cast<ushort4*>(&xb[(size_t)n*XBS_ + c*4]) = o;
}

__global__ void k_pack_x2(const float4* __restrict__ X, unsigned short* __restrict__ x2b){
  int idx = blockIdx.x*blockDim.x + threadIdx.x;
  if (idx >= N_*125) return;
  int n = idx / 125, c = idx - n*125;
  float4 v = X[(size_t)n*LD4 + c];
  ushort4 o;
  o.x = f2bf_(v.x); o.y = f2bf_(v.y); o.z = f2bf_(v.z); o.w = f2bf_(v.w);
  *reinterpret_cast<ushort4*>(&x2b[(size_t)n*X2BS_ + c*4]) = o;
}

__global__ void k_pack_w(const float* __restrict__ W, int Nn,
                         unsigned short* __restrict__ out){
  int idx = blockIdx.x*blockDim.x + threadIdx.x;
  if (idx >= Nn*KP_) return;
  int n = idx / KP_, k = idx - n*KP_;
  out[idx] = (k < EH_) ? f2bf_(W[(size_t)n*EH_ + k]) : (unsigned short)0;
}

__global__ void k_pack_wcat(const float* __restrict__ wh, const float* __restrict__ wt,
                            unsigned short* __restrict__ out){
  int idx = blockIdx.x*blockDim.x + threadIdx.x;
  if (idx >= 200*KP_) return;
  int n = idx / KP_, k = idx - n*KP_;
  unsigned short v = 0;
  if (k < EH_) v = f2bf_((n < 100) ? wh[(size_t)n*EH_ + k] : wt[(size_t)(n-100)*EH_ + k]);
  out[idx] = v;
}

// ---------------- MFMA GEMM ----------------
__global__ __launch_bounds__(256) void k_gemm_mfma(
    const unsigned short* __restrict__ Ab,
    const unsigned short* __restrict__ Wb,
    float* __restrict__ C, int ldc, int M, int Nn){
  constexpr int WS = 328;
  constexpr int AS = 40;
  __shared__ unsigned short Ws[64*WS];
  __shared__ unsigned short As[128*AS];
  int tid = threadIdx.x;
  int lane = tid & 63, wave = tid >> 6;
  int wm = wave & 1, wn = wave >> 1;
  int m0 = blockIdx.x*128, n0 = blockIdx.y*64;

  for (int c = tid; c < 64*(KP_/8); c += 256){
    int n = c / (KP_/8), k8 = (c % (KP_/8))*8;
    s16x8 v = {0,0,0,0,0,0,0,0};
    if (n0 + n < Nn)
      v = *reinterpret_cast<const s16x8*>(&Wb[(size_t)(n0+n)*KP_ + k8]);
    *reinterpret_cast<s16x8*>(&Ws[n*WS + k8]) = v;
  }

  f32x4 acc[4][2] = {};
  int kf = (lane >> 4)*8;
  int rA = lane & 15;
  for (int k0 = 0; k0 < KP_; k0 += 32){
    __syncthreads();
    for (int c = tid; c < 128*4; c += 256){
      int r = c >> 2, k8 = (c & 3)*8;
      s16x8 v = {0,0,0,0,0,0,0,0};
      if (m0 + r < M)
        v = *reinterpret_cast<const s16x8*>(&Ab[(size_t)(m0+r)*XBS_ + k0 + k8]);
      *reinterpret_cast<s16x8*>(&As[r*AS + k8]) = v;
    }
    __syncthreads();
    s16x8 afr[4], bfr[2];
    #pragma unroll
    for (int mf = 0; mf < 4; ++mf)
      afr[mf] = *reinterpret_cast<const s16x8*>(&As[(wm*64 + mf*16 + rA)*AS + kf]);
    #pragma unroll
    for (int nf = 0; nf < 2; ++nf)
      bfr[nf] = *reinterpret_cast<const s16x8*>(&Ws[(wn*32 + nf*16 + rA)*WS + k0 + kf]);
    #pragma unroll
    for (int mf = 0; mf < 4; ++mf)
      #pragma unroll
      for (int nf = 0; nf < 2; ++nf)
        acc[mf][nf] = __builtin_amdgcn_mfma_f32_16x16x32_bf16(afr[mf], bfr[nf], acc[mf][nf], 0, 0, 0);
  }
  int col0 = n0 + wn*32 + (lane & 15);
  int rbase = m0 + wm*64 + (lane >> 4)*4;
  #pragma unroll
  for (int mf = 0; mf < 4; ++mf){
    #pragma unroll
    for (int nf = 0; nf < 2; ++nf){
      int col = col0 + nf*16;
      if (col < Nn){
        #pragma unroll
        for (int r = 0; r < 4; ++r){
          int row = rbase + mf*16 + r;
          if (row < M) C[(size_t)row*ldc + col] = acc[mf][nf][r];
        }
      }
    }
  }
}

// ---------------- GCN gather (bf16 table, unroll-2) ----------------
__global__ void k_gcn3(const int* __restrict__ off, const int* __restrict__ jd,
                       const float* __restrict__ wj, const float* __restrict__ dis,
                       const unsigned short* __restrict__ xb, float4* __restrict__ Y){
  __shared__ int js[128];
  __shared__ float ws[128];
  int n = blockIdx.x, tid = threadIdx.x;
  int s = off[n], t = off[n+1];
  float4 acc = make_float4(0.f,0.f,0.f,0.f);
  for (int base = s; base < t; base += 128){
    int m = min(128, t - base);
    __syncthreads();
    if (tid < m){ js[tid] = jd[base+tid]; ws[tid] = wj[base+tid]; }
    __syncthreads();
    if (tid < EH4){
      int q = 0;
      for (; q + 1 < m; q += 2){
        float w0 = ws[q], w1 = ws[q+1];
        ushort4 u0 = *reinterpret_cast<const ushort4*>(&xb[(size_t)js[q]*XBS_ + tid*4]);
        ushort4 u1 = *reinterpret_cast<const ushort4*>(&xb[(size_t)js[q+1]*XBS_ + tid*4]);
        acc.x += w0*bf2f_(u0.x) + w1*bf2f_(u1.x);
        acc.y += w0*bf2f_(u0.y) + w1*bf2f_(u1.y);
        acc.z += w0*bf2f_(u0.z) + w1*bf2f_(u1.z);
        acc.w += w0*bf2f_(u0.w) + w1*bf2f_(u1.w);
      }
      if (q < m){
        float w0 = ws[q];
        ushort4 u0 = *reinterpret_cast<const ushort4*>(&xb[(size_t)js[q]*XBS_ + tid*4]);
        acc.x += w0*bf2f_(u0.x); acc.y += w0*bf2f_(u0.y);
        acc.z += w0*bf2f_(u0.z); acc.w += w0*bf2f_(u0.w);
      }
    }
  }
  if (tid < EH4){
    float dn = dis[n];
    float4 r;
    r.x = fmaxf(dn*acc.x, 0.f); r.y = fmaxf(dn*acc.y, 0.f);
    r.z = fmaxf(dn*acc.z, 0.f); r.w = fmaxf(dn*acc.w, 0.f);
    Y[(size_t)n*EH4 + tid] = r;
  }
}

// ---------------- highway (float4) ----------------
__global__ void k_highway2(const float4* __restrict__ Xold, int ldo4,
                           const float4* __restrict__ Y, const float4* __restrict__ G,
                           const float* __restrict__ b,
                           float4* __restrict__ Xn, int ldn4){
  int idx = blockIdx.x*blockDim.x + threadIdx.x;
  if (idx >= N_*EH4) return;
  int n = idx / EH4, f = idx - n*EH4;
  float4 g4 = G[idx];
  float4 b4 = reinterpret_cast<const float4*>(b)[f];
  float4 y4 = Y[idx];
  float4 xo = Xold[(size_t)n*ldo4 + f];
  float4 r;
  float gx;
  gx = sig_(g4.x + b4.x); r.x = gx*y4.x + (1.f-gx)*xo.x;
  gx = sig_(g4.y + b4.y); r.y = gx*y4.y + (1.f-gx)*xo.y;
  gx = sig_(g4.z + b4.z); r.z = gx*y4.z + (1.f-gx)*xo.z;
  gx = sig_(g4.w + b4.w); r.w = gx*y4.w + (1.f-gx)*xo.w;
  Xn[(size_t)n*ldn4 + f] = r;
}

// ---------------- E2R projections p1..p4 [N,2] ----------------
__global__ void k_pproj(const float* __restrict__ xhxt,
                        const float* __restrict__ ah, const float* __restrict__ at,
                        float* __restrict__ p1, float* __restrict__ p2,
                        float* __restrict__ p3, float* __restrict__ p4){
  int n = blockIdx.x*blockDim.x + threadIdx.x;
  if (n >= N_) return;
  float a0=0,a1=0,b0=0,b1=0,c0=0,c1=0,d0=0,d1=0;
  const float* xh = xhxt + (size_t)n*200;
  const float* xt = xh + 100;
  for (int f = 0; f < RH_; ++f) {
    float vh = xh[f], vt = xt[f];
    float w0 = ah[f], w1 = ah[RH_+f], u0 = at[f], u1 = at[RH_+f];
    a0 += vh*w0; a1 += vh*w1;
    b0 += vt*u0; b1 += vt*u1;
    c0 += vt*w0; c1 += vt*w1;
    d0 += vh*u0; d1 += vh*u1;
  }
  p1[n*2]=a0; p1[n*2+1]=a1; p2[n*2]=b0; p2[n*2+1]=b1;
  p3[n*2]=c0; p3[n*2+1]=c1; p4[n*2]=d0; p4[n*2+1]=d1;
}

__global__ void k_e2r_logits2(const int* __restrict__ hi, const int* __restrict__ ti,
                              const int* __restrict__ pos_rel,
                              const float* __restrict__ p1, const float* __restrict__ p2,
                              const float* __restrict__ p3, const float* __restrict__ p4,
                              float* __restrict__ e1p, float* __restrict__ e2p){
  int e = blockIdx.x*blockDim.x + threadIdx.x;
  if (e >= E_) return;
  int h = hi[e], t = ti[e];
  size_t pp = (size_t)pos_rel[e]*2;
  e1p[pp]   = lrelu_(p1[h*2]   + p2[t*2]);
  e1p[pp+1] = lrelu_(p1[h*2+1] + p2[t*2+1]);
  e2p[pp]   = lrelu_(p3[h*2]   + p4[t*2]);
  e2p[pp+1] = lrelu_(p3[h*2+1] + p4[t*2+1]);
}

// ---------------- segment softmax fold ----------------
template<int K>
__device__ __forceinline__ void softmax_fold(const int* __restrict__ off,
                                             const float* __restrict__ lp,
                                             float* __restrict__ op, int seg){
  int lane = threadIdx.x & 63;
  int k = lane & (K - 1);
  int g = lane / K;
  const int GS = 64 / K;
  int s = off[seg], e = off[seg + 1];
  float m = -1e30f;
  for (int p = s + g; p < e; p += GS) m = fmaxf(m, lp[(size_t)p*K + k]);
  #pragma unroll
  for (int o = K; o < 64; o <<= 1) m = fmaxf(m, __shfl_xor(m, o));
  float sum = 0.f;
  for (int p = s + g; p < e; p += GS) sum += expf(lp[(size_t)p*K + k] - m);
  #pragma unroll
  for (int o = K; o < 64; o <<= 1) sum += __shfl_xor(sum, o);
  float inv = 1.f / (sum + 1e-16f);
  for (int p = s + g; p < e; p += GS){
    float t = expf(lp[(size_t)p*K + k] - m) * inv;
    #pragma unroll
    for (int o = 1; o < K; o <<= 1) t += __shfl_xor(t, o);
    if (k == 0) op[p] = t;
  }
}

// rel-segment fold: 4 waves per relation (2 per logit array, LDS combine)
__global__ void k_fold_rel(const int* __restrict__ off,
                           const float* __restrict__ e1p, const float* __restrict__ e2p,
                           float* __restrict__ s1p, float* __restrict__ s2p){
  __shared__ float lm[4][2];
  __shared__ float lsum[4][2];
  int r = blockIdx.x;
  int w = threadIdx.x >> 6;      // 0..3
  int lane = threadIdx.x & 63;
  const float* lp = (w < 2) ? e1p : e2p;
  float* op = (w < 2) ? s1p : s2p;
  int half = w & 1;
  int k = lane & 1, g = lane >> 1;
  int gg = half*32 + g;
  int s = off[r], e = off[r+1];
  float m = -1e30f;
  for (int p = s + gg; p < e; p += 64) m = fmaxf(m, lp[(size_t)p*2 + k]);
  #pragma unroll
  for (int o = 2; o < 64; o <<= 1) m = fmaxf(m, __shfl_xor(m, o));
  if (lane < 2) lm[w][lane] = m;
  __syncthreads();
  m = fmaxf(lm[w][k], lm[w^1][k]);
  float sum = 0.f;
  for (int p = s + gg; p < e; p += 64) sum += expf(lp[(size_t)p*2 + k] - m);
  #pragma unroll
  for (int o = 2; o < 64; o <<= 1) sum += __shfl_xor(sum, o);
  if (lane < 2) lsum[w][lane] = sum;
  __syncthreads();
  sum = lsum[w][k] + lsum[w^1][k];
  float inv = 1.f / (sum + 1e-16f);
  for (int p = s + gg; p < e; p += 64){
    float t = expf(lp[(size_t)p*2 + k] - m) * inv;
    t += __shfl_xor(t, 1);
    if (k == 0) op[p] = t;
  }
}

__global__ void k_fold_ht(const int* __restrict__ offh, const int* __restrict__ offt,
                          const float* __restrict__ lhp, const float* __restrict__ ltp,
                          float* __restrict__ shp, float* __restrict__ stp){
  int w = threadIdx.x >> 6;
  int n = blockIdx.x*2 + (w >> 1);
  if (n >= N_) return;
  if (w & 1) softmax_fold<8>(offt, ltp, stp, n);
  else       softmax_fold<8>(offh, lhp, shp, n);
}

__global__ void k_fold_gat(const int* __restrict__ off, const float* __restrict__ lgp,
                           float* __restrict__ agp){
  int w = threadIdx.x >> 6;
  int n = blockIdx.x*4 + w;
  if (n >= N_) return;
  softmax_fold<8>(off, lgp, agp, n);
}

// ---------------- E2R aggregate: chunked partials + deterministic reduce ----------------
__global__ void k_e2r_agg3(const int* __restrict__ off,
                           const int* __restrict__ hr, const int* __restrict__ tr,
                           const float* __restrict__ s1p, const float* __restrict__ s2p,
                           const float4* __restrict__ xhxt4, float4* __restrict__ xr_part){
  int r = blockIdx.x, c = blockIdx.y;
  int lane = threadIdx.x;           // 64
  int side = lane >> 5, fl = lane & 31;
  int s = off[r], e = off[r+1];
  int len = e - s;
  int per = (len + NC_ - 1)/NC_;
  int cs = s + c*per, ce = min(cs + per, e);
  float4 acc = make_float4(0.f,0.f,0.f,0.f);
  if (fl < RH4){
    const int* idx = side ? tr : hr;
    const float* wv = side ? s2p : s1p;
    int fofs = side ? 25 + fl : fl;
    int p = cs;
    for (; p + 1 < ce; p += 2){
      float a0 = wv[p], a1 = wv[p+1];
      float4 v0 = xhxt4[(size_t)idx[p]*50 + fofs];
      float4 v1 = xhxt4[(size_t)idx[p+1]*50 + fofs];
      acc.x += a0*v0.x + a1*v1.x; acc.y += a0*v0.y + a1*v1.y;
      acc.z += a0*v0.z + a1*v1.z; acc.w += a0*v0.w + a1*v1.w;
    }
    if (p < ce){
      float a0 = wv[p];
      float4 v0 = xhxt4[(size_t)idx[p]*50 + fofs];
      acc.x += a0*v0.x; acc.y += a0*v0.y; acc.z += a0*v0.z; acc.w += a0*v0.w;
    }
  }
  float4 oth;
  oth.x = __shfl_xor(acc.x, 32); oth.y = __shfl_xor(acc.y, 32);
  oth.z = __shfl_xor(acc.z, 32); oth.w = __shfl_xor(acc.w, 32);
  if (side == 0 && fl < RH4){
    float4 o = make_float4(acc.x+oth.x, acc.y+oth.y, acc.z+oth.z, acc.w+oth.w);
    xr_part[((size_t)c*R_ + r)*RH4 + fl] = o;
  }
}

__global__ void k_e2r_red(const float4* __restrict__ xr_part, float4* __restrict__ xr4){
  int idx = blockIdx.x*blockDim.x + threadIdx.x;
  if (idx >= R_*RH4) return;
  float4 a = make_float4(0.f,0.f,0.f,0.f);
  #pragma unroll
  for (int c = 0; c < NC_; ++c){
    float4 v = xr_part[(size_t)c*R_*RH4 + idx];
    a.x += v.x; a.y += v.y; a.z += v.z; a.w += v.w;
  }
  xr4[idx] = make_float4(a.x*0.25f, a.y*0.25f, a.z*0.25f, a.w*0.25f);
}

// ---------------- 16-head row dots ----------------
__global__ void k_dots16(const float* __restrict__ X, int ldx, int K,
                         const float* __restrict__ wA, const float* __restrict__ wB,
                         float* __restrict__ out16, int M){
  __shared__ float xs[16][65];
  __shared__ float ws[16][65];
  int tid = threadIdx.x;
  int tx = tid & 15, ty = tid >> 4;
  int r0 = blockIdx.x*16;
  float acc = 0.f;
  for (int c0 = 0; c0 < K; c0 += 64){
    int cl = min(64, K - c0);
    #pragma unroll
    for (int i = 0; i < 4; ++i){
      int idx = tid + i*256;
      int r = idx >> 6, k = idx & 63;
      float xv = 0.f, wv = 0.f;
      if (k < cl && r0 + r < M) xv = X[(size_t)(r0+r)*ldx + c0 + k];
      if (k < cl) wv = (r < 8) ? wA[(size_t)r*K + c0 + k] : wB[(size_t)(r-8)*K + c0 + k];
      xs[r][k] = xv;
      ws[r][k] = wv;
    }
    __syncthreads();
    #pragma unroll
    for (int k = 0; k < 64; ++k) acc += xs[ty][k]*ws[tx][k];
    __syncthreads();
  }
  if (r0 + ty < M) out16[(size_t)(r0+ty)*16 + tx] = acc;
}

// ---------------- sr [R,8] ----------------
__global__ void k_sr(const float* __restrict__ xr, const float* __restrict__ ar,
                     float* __restrict__ sr8){
  int idx = blockIdx.x*blockDim.x + threadIdx.x;
  if (idx >= R_*8) return;
  int r = idx >> 3, h = idx & 7;
  float acc = 0.f;
  for (int k = 0; k < RH_; ++k) acc += xr[(size_t)r*RH_ + k]*ar[(size_t)h*RH_ + k];
  sr8[idx] = acc;
}

// ---------------- R2E logits (permuted writes) ----------------
__global__ void k_r2e_logits2(const int* __restrict__ hi, const int* __restrict__ ti,
                              const int* __restrict__ rl,
                              const float* __restrict__ st16, const float* __restrict__ sr8,
                              const int* __restrict__ pos_h, const int* __restrict__ pos_t,
                              float* __restrict__ lhp, float* __restrict__ ltp){
  int e = blockIdx.x*blockDim.x + threadIdx.x;
  if (e >= E_) return;
  int h = hi[e], t = ti[e], r = rl[e];
  const float4* sh4 = reinterpret_cast<const float4*>(st16 + (size_t)h*16);
  const float4* st4 = reinterpret_cast<const float4*>(st16 + (size_t)t*16 + 8);
  const float4* sr4 = reinterpret_cast<const float4*>(sr8 + (size_t)r*8);
  float4 a0 = sh4[0], a1 = sh4[1], b0 = st4[0], b1 = st4[1], c0 = sr4[0], c1 = sr4[1];
  float4 o0, o1;
  o0.x = lrelu_(a0.x+c0.x); o0.y = lrelu_(a0.y+c0.y); o0.z = lrelu_(a0.z+c0.z); o0.w = lrelu_(a0.w+c0.w);
  o1.x = lrelu_(a1.x+c1.x); o1.y = lrelu_(a1.y+c1.y); o1.z = lrelu_(a1.z+c1.z); o1.w = lrelu_(a1.w+c1.w);
  float4* dh = reinterpret_cast<float4*>(lhp + (size_t)pos_h[e]*8);
  dh[0] = o0; dh[1] = o1;
  o0.x = lrelu_(b0.x+c0.x); o0.y = lrelu_(b0.y+c0.y); o0.z = lrelu_(b0.z+c0.z); o0.w = lrelu_(b0.w+c0.w);
  o1.x = lrelu_(b1.x+c1.x); o1.y = lrelu_(b1.y+c1.y); o1.z = lrelu_(b1.z+c1.z); o1.w = lrelu_(b1.w+c1.w);
  float4* dt = reinterpret_cast<float4*>(ltp + (size_t)pos_t[e]*8);
  dt[0] = o0; dt[1] = o1;
}

// ---------------- R2E aggregate ----------------
__global__ void k_r2e_agg2(const int* __restrict__ offh, const int* __restrict__ offt,
                           const int* __restrict__ relh, const int* __restrict__ relt,
                           const float* __restrict__ shp, const float* __restrict__ stp,
                           const float4* __restrict__ xr4, float4* __restrict__ out){
  int n = blockIdx.x;
  int side = threadIdx.x >> 6, lane = threadIdx.x & 63;
  const int* off = side ? offt : offh;
  const int* rr  = side ? relt : relh;
  const float* sp = side ? stp : shp;
  int s = off[n], e = off[n+1];
  if (lane >= RH4) return;
  float4 acc = make_float4(0.f,0.f,0.f,0.f);
  int p = s;
  for (; p + 1 < e; p += 2){
    float a0 = sp[p], a1 = sp[p+1];
    float4 v0 = xr4[(size_t)rr[p]*RH4 + lane];
    float4 v1 = xr4[(size_t)rr[p+1]*RH4 + lane];
    acc.x += a0*v0.x + a1*v1.x; acc.y += a0*v0.y + a1*v1.y;
    acc.z += a0*v0.z + a1*v1.z; acc.w += a0*v0.w + a1*v1.w;
  }
  if (p < e){
    float a0 = sp[p];
    float4 v0 = xr4[(size_t)rr[p]*RH4 + lane];
    acc.x += a0*v0.x; acc.y += a0*v0.y; acc.z += a0*v0.z; acc.w += a0*v0.w;
  }
  float4 o = make_float4(acc.x*0.125f, acc.y*0.125f, acc.z*0.125f, acc.w*0.125f);
  out[(size_t)n*LD4 + (side ? 100 : 75) + lane] = o;
}

// ---------------- GAT logits ----------------
__global__ void k_gat_logits2(const int* __restrict__ ja, const int* __restrict__ ia,
                              const int* __restrict__ pos_dest,
                              const float* __restrict__ gg16, float* __restrict__ lgp){
  int e = blockIdx.x*blockDim.x + threadIdx.x;
  if (e >= EALL_) return;
  int i = ia[e], j = ja[e];
  const float4* gi4 = reinterpret_cast<const float4*>(gg16 + (size_t)i*16);
  const float4* gj4 = reinterpret_cast<const float4*>(gg16 + (size_t)j*16 + 8);
  float4 a0 = gi4[0], a1 = gi4[1], b0 = gj4[0], b1 = gj4[1];
  float4 o0, o1;
  o0.x = lrelu_(a0.x+b0.x); o0.y = lrelu_(a0.y+b0.y); o0.z = lrelu_(a0.z+b0.z); o0.w = lrelu_(a0.w+b0.w);
  o1.x = lrelu_(a1.x+b1.x); o1.y = lrelu_(a1.y+b1.y); o1.z = lrelu_(a1.z+b1.z); o1.w = lrelu_(a1.w+b1.w);
  float4* d = reinterpret_cast<float4*>(lgp + (size_t)pos_dest[e]*8);
  d[0] = o0; d[1] = o1;
}

// ---------------- GAT aggregate (bf16 table, unroll-2) ----------------
__global__ void k_gat_agg3(const int* __restrict__ off, const int* __restrict__ jd,
                           const float* __restrict__ agp,
                           const unsigned short* __restrict__ x2b, float4* __restrict__ out){
  __shared__ int js[128];
  __shared__ float as_[128];
  int n = blockIdx.x, tid = threadIdx.x;
  int s = off[n], t = off[n+1];
  float4 acc = make_float4(0.f,0.f,0.f,0.f);
  for (int base = s; base < t; base += 128){
    int m = min(128, t - base);
    __syncthreads();
    if (tid < m){ js[tid] = jd[base+tid]; as_[tid] = agp[base+tid]; }
    __syncthreads();
    if (tid < 125){
      int q = 0;
      for (; q + 1 < m; q += 2){
        float a0 = as_[q], a1 = as_[q+1];
        ushort4 u0 = *reinterpret_cast<const ushort4*>(&x2b[(size_t)js[q]*X2BS_ + tid*4]);
        ushort4 u1 = *reinterpret_cast<const ushort4*>(&x2b[(size_t)js[q+1]*X2BS_ + tid*4]);
        acc.x += a0*bf2f_(u0.x) + a1*bf2f_(u1.x);
        acc.y += a0*bf2f_(u0.y) + a1*bf2f_(u1.y);
        acc.z += a0*bf2f_(u0.z) + a1*bf2f_(u1.z);
        acc.w += a0*bf2f_(u0.w) + a1*bf2f_(u1.w);
      }
      if (q < m){
        float a0 = as_[q];
        ushort4 u0 = *reinterpret_cast<const ushort4*>(&x2b[(size_t)js[q]*X2BS_ + tid*4]);
        acc.x += a0*bf2f_(u0.x); acc.y += a0*bf2f_(u0.y);
        acc.z += a0*bf2f_(u0.z); acc.w += a0*bf2f_(u0.w);
      }
    }
  }
  if (tid < 125){
    float4 r = make_float4(acc.x*0.125f, acc.y*0.125f, acc.z*0.125f, acc.w*0.125f);
    out[(size_t)n*LD4 + 125 + tid] = r;
  }
}

// ---------------- host ----------------
static inline void gemm_mfma(const unsigned short* Ab, const unsigned short* Wb,
                             float* C, int ldc, int M, int Nn, hipStream_t st){
  dim3 g((M + 127)/128, (Nn + 63)/64);
  k_gemm_mfma<<<g, 256, 0, st>>>(Ab, Wb, C, ldc, M, Nn);
}

extern "C" void kernel_launch(void* const* d_in, const int* in_sizes, int n_in,
                              void* d_out, int out_size, void* d_ws, size_t ws_size,
                              hipStream_t stream) {
  const float* x_e   = (const float*)d_in[0];
  const int*   ei    = (const int*)d_in[1];
  const int*   rel   = (const int*)d_in[2];
  const int*   eia   = (const int*)d_in[3];
  const float* hw1_w = (const float*)d_in[5];
  const float* hw1_b = (const float*)d_in[6];
  const float* hw2_w = (const float*)d_in[7];
  const float* hw2_b = (const float*)d_in[8];
  const float* e2r_wh= (const float*)d_in[9];
  const float* e2r_wt= (const float*)d_in[10];
  const float* e2r_ah= (const float*)d_in[11];
  const float* e2r_at= (const float*)d_in[12];
  const float* r2e_ah= (const float*)d_in[13];
  const float* r2e_at= (const float*)d_in[14];
  const float* r2e_ar= (const float*)d_in[15];
  const float* gat_ai= (const float*)d_in[16];
  const float* gat_aj= (const float*)d_in[17];
  float* out = (float*)d_out;

  const int* hi = ei;
  const int* ti = ei + E_;
  const int* ja = eia;
  const int* ia = eia + EALL_;

  char* base = (char*)d_ws;
  size_t off = 0;
  auto alloc = [&](size_t bytes)->void*{
    void* p = base + off;
    off = (off + bytes + 255) & ~(size_t)255;
    return p;
  };

  // zeroed region: counts + cursors (dest/h/t only)
  size_t z0 = off;
  int* cnt_dest = (int*)alloc(N_*4);
  int* cur_dest = (int*)alloc(N_*4);
  int* cnt_h    = (int*)alloc(N_*4);
  int* cur_h    = (int*)alloc(N_*4);
  int* cnt_t    = (int*)alloc(N_*4);
  int* cur_t    = (int*)alloc(N_*4);
  size_t z1 = off;

  int* off_dest = (int*)alloc((N_+1)*4);
  int* off_rel  = (int*)alloc((R_+1)*4);
  int* off_h    = (int*)alloc((N_+1)*4);
  int* off_t    = (int*)alloc((N_+1)*4);
  int* Hrel     = (int*)alloc((size_t)NBR_*R_*4);   // per-block rel hist/bases
  int* j_dest   = (int*)alloc((size_t)EALL_*4);
  int* pos_dest = (int*)alloc((size_t)EALL_*4);
  int* hr       = (int*)alloc((size_t)E_*4);
  int* tr       = (int*)alloc((size_t)E_*4);
  int* pos_rel  = (int*)alloc((size_t)E_*4);
  int* relh     = (int*)alloc((size_t)E_*4);
  int* pos_h    = (int*)alloc((size_t)E_*4);
  int* relt     = (int*)alloc((size_t)E_*4);
  int* pos_t    = (int*)alloc((size_t)E_*4);

  float* dis   = (float*)alloc(N_*4);
  float* wj    = (float*)alloc((size_t)EALL_*4);
  float* y     = (float*)alloc((size_t)N_*EH_*4);   // 36 MB; later aliased by lhp/ltp
  float* g     = (float*)alloc((size_t)N_*EH_*4);   // 36 MB; later aliased by lgp
  float* xhxt  = (float*)alloc((size_t)N_*200*4);
  float* p1    = (float*)alloc((size_t)N_*2*4);
  float* p2    = (float*)alloc((size_t)N_*2*4);
  float* p3    = (float*)alloc((size_t)N_*2*4);
  float* p4    = (float*)alloc((size_t)N_*2*4);
  float* e1p   = (float*)alloc((size_t)E_*2*4);
  float* e2p   = (float*)alloc((size_t)E_*2*4);
  float* s1p   = (float*)alloc((size_t)E_*4);
  float* s2p   = (float*)alloc((size_t)E_*4);
  float* xr    = (float*)alloc((size_t)R_*RH_*4);
  float* xr_part=(float*)alloc((size_t)NC_*R_*RH_*4);
  float* st16  = (float*)alloc((size_t)N_*16*4);
  float* sr8   = (float*)alloc((size_t)R_*8*4);
  float* shp   = (float*)alloc((size_t)E_*4);
  float* stp   = (float*)alloc((size_t)E_*4);
  float* gg16  = (float*)alloc((size_t)N_*16*4);
  float* agp   = (float*)alloc((size_t)EALL_*4);
  unsigned short* xb  = (unsigned short*)alloc((size_t)N_*XBS_*2);   // 19.2 MB
  unsigned short* x2b = (unsigned short*)alloc((size_t)N_*X2BS_*2);  // 30.2 MB
  unsigned short* w1b = (unsigned short*)alloc((size_t)EH_*KP_*2);
  unsigned short* w2b = (unsigned short*)alloc((size_t)EH_*KP_*2);
  unsigned short* wcb = (unsigned short*)alloc((size_t)200*KP_*2);

  // aliases into dead buffers
  float* lhp = y;                   // [E,8]  (y dead after highway2)
  float* ltp = y + (size_t)E_*8;
  float* lgp = g;                   // [EALL,8] (g dead after highway2)

  hipMemsetAsync(base + z0, 0, z1 - z0, stream);

  const int TB = 256;
  const int TOT = EALL_ + 2*E_;
  int gTOT  = (TOT + TB - 1)/TB;
  int gE    = (E_ + TB - 1)/TB;
  int gEall = (EALL_ + TB - 1)/TB;
  int gN    = (N_ + TB - 1)/TB;
  int gPKX  = (N_*80 + TB - 1)/TB;
  int gPK2  = (N_*125 + TB - 1)/TB;

  // weight packs (independent of everything else)
  k_pack_w<<<(EH_*KP_ + TB - 1)/TB, TB, 0, stream>>>(hw1_w, EH_, w1b);
  k_pack_w<<<(EH_*KP_ + TB - 1)/TB, TB, 0, stream>>>(hw2_w, EH_, w2b);
  k_pack_wcat<<<(200*KP_ + TB - 1)/TB, TB, 0, stream>>>(e2r_wh, e2r_wt, wcb);

  // CSR build: rel via block counting sort (no global atomics)
  k_relhist<<<NBR_, 256, 0, stream>>>(rel, Hrel);
  k_relscan<<<1, 256, 0, stream>>>(Hrel, off_rel);
  k_relscatter<<<NBR_, 256, 0, stream>>>(rel, hi, ti, Hrel, hr, tr, pos_rel);

  // CSR build: dest/h/t via atomics
  k_count3<<<gTOT, TB, 0, stream>>>(ia, hi, ti, cnt_dest, cnt_h, cnt_t);
  k_scan3<<<3, 256, 0, stream>>>(cnt_dest, off_dest, N_, cnt_h, off_h, N_, cnt_t, off_t, N_);
  k_dis<<<gN, TB, 0, stream>>>(cnt_dest, dis);
  k_scatter3<<<gTOT, TB, 0, stream>>>(ja, ia, rel, hi, ti,
                                      off_dest, off_h, off_t,
                                      cur_dest, cur_h, cur_t,
                                      j_dest, pos_dest,
                                      relh, pos_h, relt, pos_t);
  k_wj<<<gEall, TB, 0, stream>>>(j_dest, dis, wj);

  // GCN + highway block 1 (x -> out cols 0..299)
  k_pack_x<<<gPKX, TB, 0, stream>>>((const float4*)x_e, EH4, xb);
  gemm_mfma(xb, w1b, g, EH_, N_, EH_, stream);
  k_gcn3<<<N_, 128, 0, stream>>>(off_dest, j_dest, wj, dis, xb, (float4*)y);
  k_highway2<<<(N_*EH4 + TB - 1)/TB, TB, 0, stream>>>((const float4*)x_e, EH4, (const float4*)y,
                                                      (const float4*)g, hw1_b, (float4*)out, LD4);
  // block 2
  k_pack_x<<<gPKX, TB, 0, stream>>>((const float4*)out, LD4, xb);
  gemm_mfma(xb, w2b, g, EH_, N_, EH_, stream);
  k_gcn3<<<N_, 128, 0, stream>>>(off_dest, j_dest, wj, dis, xb, (float4*)y);
  k_highway2<<<(N_*EH4 + TB - 1)/TB, TB, 0, stream>>>((const float4*)out, LD4, (const float4*)y,
                                                      (const float4*)g, hw2_b, (float4*)out, LD4);

  // E2R (pack final x, reuse xb as MFMA A-operand)
  k_pack_x<<<gPKX, TB, 0, stream>>>((const float4*)out, LD4, xb);
  gemm_mfma(xb, wcb, xhxt, 200, N_, 200, stream);
  k_pproj<<<gN, TB, 0, stream>>>(xhxt, e2r_ah, e2r_at, p1, p2, p3, p4);
  k_e2r_logits2<<<gE, TB, 0, stream>>>(hi, ti, pos_rel, p1, p2, p3, p4, e1p, e2p);
  k_fold_rel<<<R_, 256, 0, stream>>>(off_rel, e1p, e2p, s1p, s2p);
  k_e2r_agg3<<<dim3(R_, NC_), 64, 0, stream>>>(off_rel, hr, tr, s1p, s2p,
                                               (const float4*)xhxt, (float4*)xr_part);
  k_e2r_red<<<(R_*RH4 + TB - 1)/TB, TB, 0, stream>>>((const float4*)xr_part, (float4*)xr);

  // R2E
  k_dots16<<<(N_+15)/16, 256, 0, stream>>>(out, OUTD_, EH_, r2e_ah, r2e_at, st16, N_);
  k_sr<<<(R_*8 + TB - 1)/TB, TB, 0, stream>>>(xr, r2e_ar, sr8);
  k_r2e_logits2<<<gE, TB, 0, stream>>>(hi, ti, rel, st16, sr8, pos_h, pos_t, lhp, ltp);
  k_fold_ht<<<(N_+1)/2, 256, 0, stream>>>(off_h, off_t, lhp, ltp, shp, stp);
  k_r2e_agg2<<<N_, 128, 0, stream>>>(off_h, off_t, relh, relt, shp, stp,
                                     (const float4*)xr, (float4*)out);

  // GAT
  k_dots16<<<(N_+15)/16, 256, 0, stream>>>(out, OUTD_, X2D_, gat_ai, gat_aj, gg16, N_);
  k_pack_x2<<<gPK2, TB, 0, stream>>>((const float4*)out, x2b);
  k_gat_logits2<<<gEall, TB, 0, stream>>>(ja, ia, pos_dest, gg16, lgp);
  k_fold_gat<<<(N_+3)/4, 256, 0, stream>>>(off_dest, lgp, agp);
  k_gat_agg3<<<N_, 128, 0, stream>>>(off_dest, j_dest, agp, x2b, (float4*)out);
}

// Round 7
// 718.225 us; speedup vs baseline: 3.2638x; 1.0430x over previous
//
#include <hip/hip_runtime.h>
#include <math.h>

constexpr int N_    = 30000;
constexpr int E_    = 200000;
constexpr int EALL_ = 400000;
constexpr int R_    = 500;
constexpr int EH_   = 300;
constexpr int RH_   = 100;
constexpr int X2D_  = 500;
constexpr int OUTD_ = 1000;
constexpr int LD4   = OUTD_/4;  // 250
constexpr int EH4   = EH_/4;    // 75
constexpr int RH4   = RH_/4;    // 25
constexpr int NC_   = 16;       // chunks per relation for e2r agg
constexpr int XBS_  = 320;      // bf16 row stride for x table (zero-padded K for MFMA)
constexpr int XEBS_ = 200;      // bf16 row stride for xe table
constexpr int KP_   = 320;      // padded K for MFMA weights
constexpr int NBR_  = 64;       // blocks for rel counting sort
constexpr int PERB_ = (E_ + NBR_ - 1)/NBR_;  // 3125 edges per block

typedef __attribute__((ext_vector_type(4))) float f32x4;
typedef __attribute__((ext_vector_type(8))) short s16x8;

__device__ __forceinline__ float lrelu_(float v){ return v > 0.f ? v : 0.01f*v; }
__device__ __forceinline__ float sig_(float z){ return 1.f/(1.f + expf(-z)); }
__device__ __forceinline__ unsigned short f2bf_(float f){
  unsigned int u = __float_as_uint(f);
  unsigned int r = (u + 0x7FFFu + ((u >> 16) & 1u)) >> 16;
  return (unsigned short)r;
}
__device__ __forceinline__ float bf2f_(unsigned short h){
  return __uint_as_float(((unsigned int)h) << 16);
}

// ---------------- CSR build: dest/h/t via atomics ----------------
__global__ void k_count3(const int* __restrict__ ia,
                         const int* __restrict__ hi, const int* __restrict__ ti,
                         int* cd, int* ch, int* ct){
  int idx = blockIdx.x*blockDim.x + threadIdx.x;
  if (idx < EALL_) { atomicAdd(&cd[ia[idx]], 1); return; }
  idx -= EALL_;
  if (idx < E_) { atomicAdd(&ch[hi[idx]], 1); return; }
  idx -= E_;
  if (idx < E_) { atomicAdd(&ct[ti[idx]], 1); return; }
}

// scan 3 count arrays; block 0 also emits dis = rsqrt(deg)
__global__ void k_scan3(const int* c0, int* o0, int L0,
                        const int* c1, int* o1, int L1,
                        const int* c2, int* o2, int L2,
                        float* __restrict__ dis){
  const int* c; int* o; int L;
  switch (blockIdx.x){
    case 0: c=c0; o=o0; L=L0; break;
    case 1: c=c1; o=o1; L=L1; break;
    default: c=c2; o=o2; L=L2; break;
  }
  __shared__ int sums[256];
  int t = threadIdx.x;
  int chunk = (L + 255) / 256;
  int s = min(t*chunk, L), e = min(s + chunk, L);
  int acc = 0;
  for (int i = s; i < e; ++i) acc += c[i];
  sums[t] = acc;
  __syncthreads();
  for (int off = 1; off < 256; off <<= 1) {
    int v = (t >= off) ? sums[t - off] : 0;
    __syncthreads();
    sums[t] += v;
    __syncthreads();
  }
  int run = t ? sums[t-1] : 0;
  for (int i = s; i < e; ++i) {
    o[i] = run; run += c[i];
    if (blockIdx.x == 0) dis[i] = (c[i] > 0) ? rsqrtf((float)c[i]) : 0.f;
  }
  if (t == 255) o[L] = sums[255];
}

// scatter dest (with fused wj), h, t payloads
__global__ void k_scatter3(const int* __restrict__ ja, const int* __restrict__ ia,
                           const int* __restrict__ rel, const int* __restrict__ hi,
                           const int* __restrict__ ti,
                           const int* od, const int* oh, const int* ot,
                           int* curd, int* curh, int* curt,
                           const float* __restrict__ dis,
                           int* j_dest, float* wj,
                           int* relh, int* relt){
  int idx = blockIdx.x*blockDim.x + threadIdx.x;
  if (idx < EALL_){
    int e = idx, s = ia[e];
    int p = od[s] + atomicAdd(&curd[s], 1);
    int j = ja[e];
    j_dest[p] = j; wj[p] = dis[j]; return;
  }
  idx -= EALL_;
  if (idx < E_){
    int e = idx, s = hi[e];
    int p = oh[s] + atomicAdd(&curh[s], 1);
    relh[p] = rel[e]; return;
  }
  idx -= E_;
  if (idx < E_){
    int e = idx, s = ti[e];
    int p = ot[s] + atomicAdd(&curt[s], 1);
    relt[p] = rel[e]; return;
  }
}

// ---------------- rel CSR: block counting sort, no global atomics ----------------
__global__ void k_relhist(const int* __restrict__ rel, int* __restrict__ H){
  __shared__ int h[R_];
  int b = blockIdx.x, tid = threadIdx.x;
  for (int i = tid; i < R_; i += 256) h[i] = 0;
  __syncthreads();
  int s = b*PERB_, e = min(s + PERB_, E_);
  for (int i = s + tid; i < e; i += 256) atomicAdd(&h[rel[i]], 1);
  __syncthreads();
  for (int i = tid; i < R_; i += 256) H[b*R_ + i] = h[i];
}

__global__ void k_relscan(int* __restrict__ H, int* __restrict__ off_rel){
  __shared__ int tot[R_];
  int tid = threadIdx.x;
  for (int r = tid; r < R_; r += 256){
    int acc = 0;
    for (int b = 0; b < NBR_; ++b){ int v = H[b*R_ + r]; H[b*R_ + r] = acc; acc += v; }
    tot[r] = acc;
  }
  __syncthreads();
  if (tid == 0){
    int run = 0;
    for (int r = 0; r < R_; ++r){ off_rel[r] = run; run += tot[r]; }
    off_rel[R_] = run;
  }
  __syncthreads();
  for (int r = tid; r < R_; r += 256){
    int o = off_rel[r];
    for (int b = 0; b < NBR_; ++b) H[b*R_ + r] += o;
  }
}

__global__ void k_relscatter(const int* __restrict__ rel, const int* __restrict__ hi,
                             const int* __restrict__ ti, const int* __restrict__ H,
                             int* __restrict__ hr, int* __restrict__ tr){
  __shared__ int cur[R_];
  int b = blockIdx.x, tid = threadIdx.x;
  for (int i = tid; i < R_; i += 256) cur[i] = H[b*R_ + i];
  __syncthreads();
  int s = b*PERB_, e = min(s + PERB_, E_);
  for (int i = s + tid; i < e; i += 256){
    int r = rel[i];
    int p = atomicAdd(&cur[r], 1);
    hr[p] = hi[i]; tr[p] = ti[i];
  }
}

// ---------------- bf16 pack kernels ----------------
// pack x_e -> xb[N][320] bf16, zero-padded
__global__ void k_pack_x(const float4* __restrict__ X, int ldx4,
                         unsigned short* __restrict__ xb){
  int idx = blockIdx.x*blockDim.x + threadIdx.x;   // N_*80
  if (idx >= N_*80) return;
  int n = idx / 80, c = idx - n*80;
  ushort4 o = make_ushort4(0,0,0,0);
  if (c < EH4){
    float4 v = X[(size_t)n*ldx4 + c];
    o.x = f2bf_(v.x); o.y = f2bf_(v.y); o.z = f2bf_(v.z); o.w = f2bf_(v.w);
  }
  *reinterpret_cast<ushort4*>(&xb[(size_t)n*XBS_ + c*4]) = o;
}

__global__ void k_pack_w(const float* __restrict__ W, int Nn,
                         unsigned short* __restrict__ out){
  int idx = blockIdx.x*blockDim.x + threadIdx.x;
  if (idx >= Nn*KP_) return;
  int n = idx / KP_, k = idx - n*KP_;
  out[idx] = (k < EH_) ? f2bf_(W[(size_t)n*EH_ + k]) : (unsigned short)0;
}

__global__ void k_pack_wcat(const float* __restrict__ wh, const float* __restrict__ wt,
                            unsigned short* __restrict__ out){
  int idx = blockIdx.x*blockDim.x + threadIdx.x;
  if (idx >= 200*KP_) return;
  int n = idx / KP_, k = idx - n*KP_;
  unsigned short v = 0;
  if (k < EH_) v = f2bf_((n < 100) ? wh[(size_t)n*EH_ + k] : wt[(size_t)(n-100)*EH_ + k]);
  out[idx] = v;
}

// ---------------- MFMA GEMM ----------------
__global__ __launch_bounds__(256) void k_gemm_mfma(
    const unsigned short* __restrict__ Ab,
    const unsigned short* __restrict__ Wb,
    float* __restrict__ C, int ldc, int M, int Nn){
  constexpr int WS = 328;
  constexpr int AS = 40;
  __shared__ unsigned short Ws[64*WS];
  __shared__ unsigned short As[128*AS];
  int tid = threadIdx.x;
  int lane = tid & 63, wave = tid >> 6;
  int wm = wave & 1, wn = wave >> 1;
  int m0 = blockIdx.x*128, n0 = blockIdx.y*64;

  for (int c = tid; c < 64*(KP_/8); c += 256){
    int n = c / (KP_/8), k8 = (c % (KP_/8))*8;
    s16x8 v = {0,0,0,0,0,0,0,0};
    if (n0 + n < Nn)
      v = *reinterpret_cast<const s16x8*>(&Wb[(size_t)(n0+n)*KP_ + k8]);
    *reinterpret_cast<s16x8*>(&Ws[n*WS + k8]) = v;
  }

  f32x4 acc[4][2] = {};
  int kf = (lane >> 4)*8;
  int rA = lane & 15;
  for (int k0 = 0; k0 < KP_; k0 += 32){
    __syncthreads();
    for (int c = tid; c < 128*4; c += 256){
      int r = c >> 2, k8 = (c & 3)*8;
      s16x8 v = {0,0,0,0,0,0,0,0};
      if (m0 + r < M)
        v = *reinterpret_cast<const s16x8*>(&Ab[(size_t)(m0+r)*XBS_ + k0 + k8]);
      *reinterpret_cast<s16x8*>(&As[r*AS + k8]) = v;
    }
    __syncthreads();
    s16x8 afr[4], bfr[2];
    #pragma unroll
    for (int mf = 0; mf < 4; ++mf)
      afr[mf] = *reinterpret_cast<const s16x8*>(&As[(wm*64 + mf*16 + rA)*AS + kf]);
    #pragma unroll
    for (int nf = 0; nf < 2; ++nf)
      bfr[nf] = *reinterpret_cast<const s16x8*>(&Ws[(wn*32 + nf*16 + rA)*WS + k0 + kf]);
    #pragma unroll
    for (int mf = 0; mf < 4; ++mf)
      #pragma unroll
      for (int nf = 0; nf < 2; ++nf)
        acc[mf][nf] = __builtin_amdgcn_mfma_f32_16x16x32_bf16(afr[mf], bfr[nf], acc[mf][nf], 0, 0, 0);
  }
  int col0 = n0 + wn*32 + (lane & 15);
  int rbase = m0 + wm*64 + (lane >> 4)*4;
  #pragma unroll
  for (int mf = 0; mf < 4; ++mf){
    #pragma unroll
    for (int nf = 0; nf < 2; ++nf){
      int col = col0 + nf*16;
      if (col < Nn){
        #pragma unroll
        for (int r = 0; r < 4; ++r){
          int row = rbase + mf*16 + r;
          if (row < M) C[(size_t)row*ldc + col] = acc[mf][nf][r];
        }
      }
    }
  }
}

// ---------------- GCN gather: 1 wave per node, full lane utilization ----------------
__global__ void k_gcn4(const int* __restrict__ off, const int* __restrict__ jd,
                       const float* __restrict__ wj, const float* __restrict__ dis,
                       const unsigned short* __restrict__ xb, float4* __restrict__ Y){
  __shared__ int js[64];
  __shared__ float ws[64];
  int n = blockIdx.x, lane = threadIdx.x;   // 64
  int s = off[n], t = off[n+1];
  bool two = lane < (EH4 - 64);             // lanes 0..10 also own chunk 64+lane
  float4 a0 = make_float4(0.f,0.f,0.f,0.f);
  float4 a1 = make_float4(0.f,0.f,0.f,0.f);
  for (int base = s; base < t; base += 64){
    int m = min(64, t - base);
    __syncthreads();
    if (lane < m){ js[lane] = jd[base+lane]; ws[lane] = wj[base+lane]; }
    __syncthreads();
    int q = 0;
    for (; q + 1 < m; q += 2){
      size_t r0 = (size_t)js[q]*XBS_, r1 = (size_t)js[q+1]*XBS_;
      float w0 = ws[q], w1 = ws[q+1];
      ushort4 u0 = *reinterpret_cast<const ushort4*>(&xb[r0 + lane*4]);
      ushort4 u1 = *reinterpret_cast<const ushort4*>(&xb[r1 + lane*4]);
      a0.x += w0*bf2f_(u0.x) + w1*bf2f_(u1.x);
      a0.y += w0*bf2f_(u0.y) + w1*bf2f_(u1.y);
      a0.z += w0*bf2f_(u0.z) + w1*bf2f_(u1.z);
      a0.w += w0*bf2f_(u0.w) + w1*bf2f_(u1.w);
      if (two){
        ushort4 v0 = *reinterpret_cast<const ushort4*>(&xb[r0 + 256 + lane*4]);
        ushort4 v1 = *reinterpret_cast<const ushort4*>(&xb[r1 + 256 + lane*4]);
        a1.x += w0*bf2f_(v0.x) + w1*bf2f_(v1.x);
        a1.y += w0*bf2f_(v0.y) + w1*bf2f_(v1.y);
        a1.z += w0*bf2f_(v0.z) + w1*bf2f_(v1.z);
        a1.w += w0*bf2f_(v0.w) + w1*bf2f_(v1.w);
      }
    }
    if (q < m){
      size_t r0 = (size_t)js[q]*XBS_;
      float w0 = ws[q];
      ushort4 u0 = *reinterpret_cast<const ushort4*>(&xb[r0 + lane*4]);
      a0.x += w0*bf2f_(u0.x); a0.y += w0*bf2f_(u0.y);
      a0.z += w0*bf2f_(u0.z); a0.w += w0*bf2f_(u0.w);
      if (two){
        ushort4 v0 = *reinterpret_cast<const ushort4*>(&xb[r0 + 256 + lane*4]);
        a1.x += w0*bf2f_(v0.x); a1.y += w0*bf2f_(v0.y);
        a1.z += w0*bf2f_(v0.z); a1.w += w0*bf2f_(v0.w);
      }
    }
  }
  float dn = dis[n];
  float4 r;
  r.x = fmaxf(dn*a0.x, 0.f); r.y = fmaxf(dn*a0.y, 0.f);
  r.z = fmaxf(dn*a0.z, 0.f); r.w = fmaxf(dn*a0.w, 0.f);
  Y[(size_t)n*EH4 + lane] = r;
  if (two){
    r.x = fmaxf(dn*a1.x, 0.f); r.y = fmaxf(dn*a1.y, 0.f);
    r.z = fmaxf(dn*a1.z, 0.f); r.w = fmaxf(dn*a1.w, 0.f);
    Y[(size_t)n*EH4 + 64 + lane] = r;
  }
}

// ---------------- highway + fused bf16 pack ----------------
__global__ void k_highway3(const float4* __restrict__ Xold, int ldo4,
                           const float4* __restrict__ Y, const float4* __restrict__ G,
                           const float* __restrict__ b,
                           float4* __restrict__ Xn, unsigned short* __restrict__ xbb){
  int idx = blockIdx.x*blockDim.x + threadIdx.x;
  if (idx >= N_*EH4) return;
  int n = idx / EH4, f = idx - n*EH4;
  float4 g4 = G[idx];
  float4 b4 = reinterpret_cast<const float4*>(b)[f];
  float4 y4 = Y[idx];
  float4 xo = Xold[(size_t)n*ldo4 + f];
  float4 r;
  float gx;
  gx = sig_(g4.x + b4.x); r.x = gx*y4.x + (1.f-gx)*xo.x;
  gx = sig_(g4.y + b4.y); r.y = gx*y4.y + (1.f-gx)*xo.y;
  gx = sig_(g4.z + b4.z); r.z = gx*y4.z + (1.f-gx)*xo.z;
  gx = sig_(g4.w + b4.w); r.w = gx*y4.w + (1.f-gx)*xo.w;
  Xn[(size_t)n*LD4 + f] = r;
  ushort4 o;
  o.x = f2bf_(r.x); o.y = f2bf_(r.y); o.z = f2bf_(r.z); o.w = f2bf_(r.w);
  *reinterpret_cast<ushort4*>(&xbb[(size_t)n*XBS_ + f*4]) = o;
}

// ---------------- E2R projections -> pht[N][8]: {p1_0,p1_1,p3_0,p3_1 | p2_0,p2_1,p4_0,p4_1}
__global__ void k_pproj(const float* __restrict__ xhxt,
                        const float* __restrict__ ah, const float* __restrict__ at,
                        float4* __restrict__ pht){
  int n = blockIdx.x*blockDim.x + threadIdx.x;
  if (n >= N_) return;
  float a0=0,a1=0,b0=0,b1=0,c0=0,c1=0,d0=0,d1=0;
  const float* xh = xhxt + (size_t)n*200;
  const float* xt = xh + 100;
  for (int f = 0; f < RH_; ++f) {
    float vh = xh[f], vt = xt[f];
    float w0 = ah[f], w1 = ah[RH_+f], u0 = at[f], u1 = at[RH_+f];
    a0 += vh*w0; a1 += vh*w1;   // p1 = xh@ah^T
    b0 += vt*u0; b1 += vt*u1;   // p2 = xt@at^T
    c0 += vt*w0; c1 += vt*w1;   // p3 = xt@ah^T
    d0 += vh*u0; d1 += vh*u1;   // p4 = xh@at^T
  }
  pht[(size_t)n*2]     = make_float4(a0, a1, c0, c1);  // h-side: p1 | p3
  pht[(size_t)n*2 + 1] = make_float4(b0, b1, d0, d1);  // t-side: p2 | p4
}

// ---------------- E2R fold: on-the-fly logits, both arrays at once ----------------
__global__ void k_fold_rel2(const int* __restrict__ off,
                            const int* __restrict__ hr, const int* __restrict__ tr,
                            const float4* __restrict__ pht,
                            float* __restrict__ s1p, float* __restrict__ s2p){
  __shared__ float4 redm[4];
  __shared__ float4 reds[4];
  int r = blockIdx.x;
  int tid = threadIdx.x, lane = tid & 63, w = tid >> 6;
  int s = off[r], e = off[r+1];
  float4 mx = make_float4(-1e30f,-1e30f,-1e30f,-1e30f);
  for (int p = s + tid; p < e; p += 256){
    float4 ph = pht[(size_t)hr[p]*2];
    float4 pt = pht[(size_t)tr[p]*2 + 1];
    mx.x = fmaxf(mx.x, lrelu_(ph.x + pt.x));
    mx.y = fmaxf(mx.y, lrelu_(ph.y + pt.y));
    mx.z = fmaxf(mx.z, lrelu_(ph.z + pt.z));
    mx.w = fmaxf(mx.w, lrelu_(ph.w + pt.w));
  }
  #pragma unroll
  for (int o = 1; o < 64; o <<= 1){
    mx.x = fmaxf(mx.x, __shfl_xor(mx.x, o));
    mx.y = fmaxf(mx.y, __shfl_xor(mx.y, o));
    mx.z = fmaxf(mx.z, __shfl_xor(mx.z, o));
    mx.w = fmaxf(mx.w, __shfl_xor(mx.w, o));
  }
  if (lane == 0) redm[w] = mx;
  __syncthreads();
  float4 m;
  m.x = fmaxf(fmaxf(redm[0].x, redm[1].x), fmaxf(redm[2].x, redm[3].x));
  m.y = fmaxf(fmaxf(redm[0].y, redm[1].y), fmaxf(redm[2].y, redm[3].y));
  m.z = fmaxf(fmaxf(redm[0].z, redm[1].z), fmaxf(redm[2].z, redm[3].z));
  m.w = fmaxf(fmaxf(redm[0].w, redm[1].w), fmaxf(redm[2].w, redm[3].w));
  float4 sm = make_float4(0.f,0.f,0.f,0.f);
  for (int p = s + tid; p < e; p += 256){
    float4 ph = pht[(size_t)hr[p]*2];
    float4 pt = pht[(size_t)tr[p]*2 + 1];
    sm.x += expf(lrelu_(ph.x + pt.x) - m.x);
    sm.y += expf(lrelu_(ph.y + pt.y) - m.y);
    sm.z += expf(lrelu_(ph.z + pt.z) - m.z);
    sm.w += expf(lrelu_(ph.w + pt.w) - m.w);
  }
  #pragma unroll
  for (int o = 1; o < 64; o <<= 1){
    sm.x += __shfl_xor(sm.x, o);
    sm.y += __shfl_xor(sm.y, o);
    sm.z += __shfl_xor(sm.z, o);
    sm.w += __shfl_xor(sm.w, o);
  }
  if (lane == 0) reds[w] = sm;
  __syncthreads();
  float4 sv;
  sv.x = reds[0].x + reds[1].x + reds[2].x + reds[3].x;
  sv.y = reds[0].y + reds[1].y + reds[2].y + reds[3].y;
  sv.z = reds[0].z + reds[1].z + reds[2].z + reds[3].z;
  sv.w = reds[0].w + reds[1].w + reds[2].w + reds[3].w;
  float4 inv;
  inv.x = 1.f/(sv.x + 1e-16f); inv.y = 1.f/(sv.y + 1e-16f);
  inv.z = 1.f/(sv.z + 1e-16f); inv.w = 1.f/(sv.w + 1e-16f);
  for (int p = s + tid; p < e; p += 256){
    float4 ph = pht[(size_t)hr[p]*2];
    float4 pt = pht[(size_t)tr[p]*2 + 1];
    s1p[p] = expf(lrelu_(ph.x + pt.x) - m.x)*inv.x + expf(lrelu_(ph.y + pt.y) - m.y)*inv.y;
    s2p[p] = expf(lrelu_(ph.z + pt.z) - m.z)*inv.z + expf(lrelu_(ph.w + pt.w) - m.w)*inv.w;
  }
}

// ---------------- R2E fold: on-the-fly logits from st16 + sr8 ----------------
__global__ void k_fold_ht2(const int* __restrict__ offh, const int* __restrict__ offt,
                           const int* __restrict__ relh, const int* __restrict__ relt,
                           const float* __restrict__ st16, const float* __restrict__ sr8,
                           float* __restrict__ shp, float* __restrict__ stp){
  int w = threadIdx.x >> 6, lane = threadIdx.x & 63;
  int n = blockIdx.x*2 + (w >> 1);
  if (n >= N_) return;
  int side = w & 1;
  const int* off = side ? offt : offh;
  const int* rl  = side ? relt : relh;
  float* op = side ? stp : shp;
  int k = lane & 7, g = lane >> 3;
  float cst = st16[(size_t)n*16 + side*8 + k];
  int s = off[n], e = off[n+1];
  float m = -1e30f;
  for (int p = s + g; p < e; p += 8)
    m = fmaxf(m, lrelu_(cst + sr8[(size_t)rl[p]*8 + k]));
  #pragma unroll
  for (int o = 8; o < 64; o <<= 1) m = fmaxf(m, __shfl_xor(m, o));
  float sum = 0.f;
  for (int p = s + g; p < e; p += 8)
    sum += expf(lrelu_(cst + sr8[(size_t)rl[p]*8 + k]) - m);
  #pragma unroll
  for (int o = 8; o < 64; o <<= 1) sum += __shfl_xor(sum, o);
  float inv = 1.f / (sum + 1e-16f);
  for (int p = s + g; p < e; p += 8){
    float t = expf(lrelu_(cst + sr8[(size_t)rl[p]*8 + k]) - m) * inv;
    #pragma unroll
    for (int o = 1; o < 8; o <<= 1) t += __shfl_xor(t, o);
    if (k == 0) op[p] = t;
  }
}

// ---------------- GAT fold: on-the-fly logits from gg16 ----------------
__global__ void k_fold_gat2(const int* __restrict__ off, const int* __restrict__ jd,
                            const float* __restrict__ gg16, float* __restrict__ agp){
  int w = threadIdx.x >> 6, lane = threadIdx.x & 63;
  int n = blockIdx.x*4 + w;
  if (n >= N_) return;
  int k = lane & 7, g = lane >> 3;
  float cst = gg16[(size_t)n*16 + k];
  int s = off[n], e = off[n+1];
  float m = -1e30f;
  for (int p = s + g; p < e; p += 8)
    m = fmaxf(m, lrelu_(cst + gg16[(size_t)jd[p]*16 + 8 + k]));
  #pragma unroll
  for (int o = 8; o < 64; o <<= 1) m = fmaxf(m, __shfl_xor(m, o));
  float sum = 0.f;
  for (int p = s + g; p < e; p += 8)
    sum += expf(lrelu_(cst + gg16[(size_t)jd[p]*16 + 8 + k]) - m);
  #pragma unroll
  for (int o = 8; o < 64; o <<= 1) sum += __shfl_xor(sum, o);
  float inv = 1.f / (sum + 1e-16f);
  for (int p = s + g; p < e; p += 8){
    float t = expf(lrelu_(cst + gg16[(size_t)jd[p]*16 + 8 + k]) - m) * inv;
    #pragma unroll
    for (int o = 1; o < 8; o <<= 1) t += __shfl_xor(t, o);
    if (k == 0) agp[p] = t;
  }
}

// ---------------- E2R aggregate: chunked partials + deterministic reduce ----------------
__global__ void k_e2r_agg3(const int* __restrict__ off,
                           const int* __restrict__ hr, const int* __restrict__ tr,
                           const float* __restrict__ s1p, const float* __restrict__ s2p,
                           const float4* __restrict__ xhxt4, float4* __restrict__ xr_part){
  int r = blockIdx.x, c = blockIdx.y;
  int lane = threadIdx.x;           // 64
  int side = lane >> 5, fl = lane & 31;
  int s = off[r], e = off[r+1];
  int len = e - s;
  int per = (len + NC_ - 1)/NC_;
  int cs = s + c*per, ce = min(cs + per, e);
  float4 acc = make_float4(0.f,0.f,0.f,0.f);
  if (fl < RH4){
    const int* idx = side ? tr : hr;
    const float* wv = side ? s2p : s1p;
    int fofs = side ? 25 + fl : fl;
    int p = cs;
    for (; p + 1 < ce; p += 2){
      float a0 = wv[p], a1 = wv[p+1];
      float4 v0 = xhxt4[(size_t)idx[p]*50 + fofs];
      float4 v1 = xhxt4[(size_t)idx[p+1]*50 + fofs];
      acc.x += a0*v0.x + a1*v1.x; acc.y += a0*v0.y + a1*v1.y;
      acc.z += a0*v0.z + a1*v1.z; acc.w += a0*v0.w + a1*v1.w;
    }
    if (p < ce){
      float a0 = wv[p];
      float4 v0 = xhxt4[(size_t)idx[p]*50 + fofs];
      acc.x += a0*v0.x; acc.y += a0*v0.y; acc.z += a0*v0.z; acc.w += a0*v0.w;
    }
  }
  float4 oth;
  oth.x = __shfl_xor(acc.x, 32); oth.y = __shfl_xor(acc.y, 32);
  oth.z = __shfl_xor(acc.z, 32); oth.w = __shfl_xor(acc.w, 32);
  if (side == 0 && fl < RH4){
    float4 o = make_float4(acc.x+oth.x, acc.y+oth.y, acc.z+oth.z, acc.w+oth.w);
    xr_part[((size_t)c*R_ + r)*RH4 + fl] = o;
  }
}

__global__ void k_e2r_red(const float4* __restrict__ xr_part, float4* __restrict__ xr4){
  int idx = blockIdx.x*blockDim.x + threadIdx.x;
  if (idx >= R_*RH4) return;
  float4 a = make_float4(0.f,0.f,0.f,0.f);
  #pragma unroll
  for (int c = 0; c < NC_; ++c){
    float4 v = xr_part[(size_t)c*R_*RH4 + idx];
    a.x += v.x; a.y += v.y; a.z += v.z; a.w += v.w;
  }
  xr4[idx] = make_float4(a.x*0.25f, a.y*0.25f, a.z*0.25f, a.w*0.25f);
}

// ---------------- 16-head row dots ----------------
__global__ void k_dots16(const float* __restrict__ X, int ldx, int K,
                         const float* __restrict__ wA, const float* __restrict__ wB,
                         float* __restrict__ out16, int M){
  __shared__ float xs[16][65];
  __shared__ float ws[16][65];
  int tid = threadIdx.x;
  int tx = tid & 15, ty = tid >> 4;
  int r0 = blockIdx.x*16;
  float acc = 0.f;
  for (int c0 = 0; c0 < K; c0 += 64){
    int cl = min(64, K - c0);
    #pragma unroll
    for (int i = 0; i < 4; ++i){
      int idx = tid + i*256;
      int r = idx >> 6, k = idx & 63;
      float xv = 0.f, wv = 0.f;
      if (k < cl && r0 + r < M) xv = X[(size_t)(r0+r)*ldx + c0 + k];
      if (k < cl) wv = (r < 8) ? wA[(size_t)r*K + c0 + k] : wB[(size_t)(r-8)*K + c0 + k];
      xs[r][k] = xv;
      ws[r][k] = wv;
    }
    __syncthreads();
    #pragma unroll
    for (int k = 0; k < 64; ++k) acc += xs[ty][k]*ws[tx][k];
    __syncthreads();
  }
  if (r0 + ty < M) out16[(size_t)(r0+ty)*16 + tx] = acc;
}

// ---------------- sr [R,8] ----------------
__global__ void k_sr(const float* __restrict__ xr, const float* __restrict__ ar,
                     float* __restrict__ sr8){
  int idx = blockIdx.x*blockDim.x + threadIdx.x;
  if (idx >= R_*8) return;
  int r = idx >> 3, h = idx & 7;
  float acc = 0.f;
  for (int k = 0; k < RH_; ++k) acc += xr[(size_t)r*RH_ + k]*ar[(size_t)h*RH_ + k];
  sr8[idx] = acc;
}

// ---------------- R2E aggregate (f32 out + bf16 xeb) ----------------
__global__ void k_r2e_agg2b(const int* __restrict__ offh, const int* __restrict__ offt,
                            const int* __restrict__ relh, const int* __restrict__ relt,
                            const float* __restrict__ shp, const float* __restrict__ stp,
                            const float4* __restrict__ xr4, float4* __restrict__ out,
                            unsigned short* __restrict__ xeb){
  int n = blockIdx.x;
  int side = threadIdx.x >> 6, lane = threadIdx.x & 63;
  const int* off = side ? offt : offh;
  const int* rr  = side ? relt : relh;
  const float* sp = side ? stp : shp;
  int s = off[n], e = off[n+1];
  if (lane >= RH4) return;
  float4 acc = make_float4(0.f,0.f,0.f,0.f);
  int p = s;
  for (; p + 1 < e; p += 2){
    float a0 = sp[p], a1 = sp[p+1];
    float4 v0 = xr4[(size_t)rr[p]*RH4 + lane];
    float4 v1 = xr4[(size_t)rr[p+1]*RH4 + lane];
    acc.x += a0*v0.x + a1*v1.x; acc.y += a0*v0.y + a1*v1.y;
    acc.z += a0*v0.z + a1*v1.z; acc.w += a0*v0.w + a1*v1.w;
  }
  if (p < e){
    float a0 = sp[p];
    float4 v0 = xr4[(size_t)rr[p]*RH4 + lane];
    acc.x += a0*v0.x; acc.y += a0*v0.y; acc.z += a0*v0.z; acc.w += a0*v0.w;
  }
  float4 o = make_float4(acc.x*0.125f, acc.y*0.125f, acc.z*0.125f, acc.w*0.125f);
  out[(size_t)n*LD4 + (side ? 100 : 75) + lane] = o;
  ushort4 ob;
  ob.x = f2bf_(o.x); ob.y = f2bf_(o.y); ob.z = f2bf_(o.z); ob.w = f2bf_(o.w);
  *reinterpret_cast<ushort4*>(&xeb[(size_t)n*XEBS_ + (side ? 100 : 0) + lane*4]) = ob;
}

// ---------------- GAT aggregate (split bf16 tables xb + xeb) ----------------
__global__ void k_gat_agg4(const int* __restrict__ off, const int* __restrict__ jd,
                           const float* __restrict__ agp,
                           const unsigned short* __restrict__ xb,
                           const unsigned short* __restrict__ xeb,
                           float4* __restrict__ out){
  __shared__ int js[128];
  __shared__ float as_[128];
  int n = blockIdx.x, tid = threadIdx.x;
  int s = off[n], t = off[n+1];
  const unsigned short* tbl;
  size_t stride; int cofs;
  if (tid < 75){ tbl = xb;  stride = XBS_;  cofs = tid*4; }
  else         { tbl = xeb; stride = XEBS_; cofs = (tid-75)*4; }
  float4 acc = make_float4(0.f,0.f,0.f,0.f);
  for (int base = s; base < t; base += 128){
    int m = min(128, t - base);
    __syncthreads();
    if (tid < m){ js[tid] = jd[base+tid]; as_[tid] = agp[base+tid]; }
    __syncthreads();
    if (tid < 125){
      int q = 0;
      for (; q + 1 < m; q += 2){
        float a0 = as_[q], a1 = as_[q+1];
        ushort4 u0 = *reinterpret_cast<const ushort4*>(&tbl[(size_t)js[q]*stride + cofs]);
        ushort4 u1 = *reinterpret_cast<const ushort4*>(&tbl[(size_t)js[q+1]*stride + cofs]);
        acc.x += a0*bf2f_(u0.x) + a1*bf2f_(u1.x);
        acc.y += a0*bf2f_(u0.y) + a1*bf2f_(u1.y);
        acc.z += a0*bf2f_(u0.z) + a1*bf2f_(u1.z);
        acc.w += a0*bf2f_(u0.w) + a1*bf2f_(u1.w);
      }
      if (q < m){
        float a0 = as_[q];
        ushort4 u0 = *reinterpret_cast<const ushort4*>(&tbl[(size_t)js[q]*stride + cofs]);
        acc.x += a0*bf2f_(u0.x); acc.y += a0*bf2f_(u0.y);
        acc.z += a0*bf2f_(u0.z); acc.w += a0*bf2f_(u0.w);
      }
    }
  }
  if (tid < 125){
    float4 r = make_float4(acc.x*0.125f, acc.y*0.125f, acc.z*0.125f, acc.w*0.125f);
    out[(size_t)n*LD4 + 125 + tid] = r;
  }
}

// ---------------- host ----------------
static inline void gemm_mfma(const unsigned short* Ab, const unsigned short* Wb,
                             float* C, int ldc, int M, int Nn, hipStream_t st){
  dim3 g((M + 127)/128, (Nn + 63)/64);
  k_gemm_mfma<<<g, 256, 0, st>>>(Ab, Wb, C, ldc, M, Nn);
}

extern "C" void kernel_launch(void* const* d_in, const int* in_sizes, int n_in,
                              void* d_out, int out_size, void* d_ws, size_t ws_size,
                              hipStream_t stream) {
  const float* x_e   = (const float*)d_in[0];
  const int*   ei    = (const int*)d_in[1];
  const int*   rel   = (const int*)d_in[2];
  const int*   eia   = (const int*)d_in[3];
  const float* hw1_w = (const float*)d_in[5];
  const float* hw1_b = (const float*)d_in[6];
  const float* hw2_w = (const float*)d_in[7];
  const float* hw2_b = (const float*)d_in[8];
  const float* e2r_wh= (const float*)d_in[9];
  const float* e2r_wt= (const float*)d_in[10];
  const float* e2r_ah= (const float*)d_in[11];
  const float* e2r_at= (const float*)d_in[12];
  const float* r2e_ah= (const float*)d_in[13];
  const float* r2e_at= (const float*)d_in[14];
  const float* r2e_ar= (const float*)d_in[15];
  const float* gat_ai= (const float*)d_in[16];
  const float* gat_aj= (const float*)d_in[17];
  float* out = (float*)d_out;

  const int* hi = ei;
  const int* ti = ei + E_;
  const int* ja = eia;
  const int* ia = eia + EALL_;

  char* base = (char*)d_ws;
  size_t off = 0;
  auto alloc = [&](size_t bytes)->void*{
    void* p = base + off;
    off = (off + bytes + 255) & ~(size_t)255;
    return p;
  };

  // zeroed region: counts + cursors (dest/h/t only)
  size_t z0 = off;
  int* cnt_dest = (int*)alloc(N_*4);
  int* cur_dest = (int*)alloc(N_*4);
  int* cnt_h    = (int*)alloc(N_*4);
  int* cur_h    = (int*)alloc(N_*4);
  int* cnt_t    = (int*)alloc(N_*4);
  int* cur_t    = (int*)alloc(N_*4);
  size_t z1 = off;

  int* off_dest = (int*)alloc((N_+1)*4);
  int* off_rel  = (int*)alloc((R_+1)*4);
  int* off_h    = (int*)alloc((N_+1)*4);
  int* off_t    = (int*)alloc((N_+1)*4);
  int* Hrel     = (int*)alloc((size_t)NBR_*R_*4);
  int* j_dest   = (int*)alloc((size_t)EALL_*4);
  int* hr       = (int*)alloc((size_t)E_*4);
  int* tr       = (int*)alloc((size_t)E_*4);
  int* relh     = (int*)alloc((size_t)E_*4);
  int* relt     = (int*)alloc((size_t)E_*4);

  float* dis   = (float*)alloc(N_*4);
  float* wj    = (float*)alloc((size_t)EALL_*4);
  float* y     = (float*)alloc((size_t)N_*EH_*4);     // GCN out
  float* g     = (float*)alloc((size_t)N_*EH_*4);     // gate pre-act
  float* xhxt  = (float*)alloc((size_t)N_*200*4);
  float* pht   = (float*)alloc((size_t)N_*8*4);
  float* s1p   = (float*)alloc((size_t)E_*4);
  float* s2p   = (float*)alloc((size_t)E_*4);
  float* xr    = (float*)alloc((size_t)R_*RH_*4);
  float* xr_part=(float*)alloc((size_t)NC_*R_*RH_*4);
  float* st16  = (float*)alloc((size_t)N_*16*4);
  float* sr8   = (float*)alloc((size_t)R_*8*4);
  float* shp   = (float*)alloc((size_t)E_*4);
  float* stp   = (float*)alloc((size_t)E_*4);
  float* gg16  = (float*)alloc((size_t)N_*16*4);
  float* agp   = (float*)alloc((size_t)EALL_*4);
  unsigned short* xb  = (unsigned short*)alloc((size_t)N_*XBS_*2);    // 19.2 MB
  unsigned short* xeb = (unsigned short*)alloc((size_t)N_*XEBS_*2);   // 12 MB
  unsigned short* w1b = (unsigned short*)alloc((size_t)EH_*KP_*2);
  unsigned short* w2b = (unsigned short*)alloc((size_t)EH_*KP_*2);
  unsigned short* wcb = (unsigned short*)alloc((size_t)200*KP_*2);

  hipMemsetAsync(base + z0, 0, z1 - z0, stream);

  const int TB = 256;
  const int TOT = EALL_ + 2*E_;
  int gTOT  = (TOT + TB - 1)/TB;
  int gN    = (N_ + TB - 1)/TB;
  int gPKX  = (N_*80 + TB - 1)/TB;

  // weight packs
  k_pack_w<<<(EH_*KP_ + TB - 1)/TB, TB, 0, stream>>>(hw1_w, EH_, w1b);
  k_pack_w<<<(EH_*KP_ + TB - 1)/TB, TB, 0, stream>>>(hw2_w, EH_, w2b);
  k_pack_wcat<<<(200*KP_ + TB - 1)/TB, TB, 0, stream>>>(e2r_wh, e2r_wt, wcb);

  // CSR build: rel via block counting sort
  k_relhist<<<NBR_, 256, 0, stream>>>(rel, Hrel);
  k_relscan<<<1, 256, 0, stream>>>(Hrel, off_rel);
  k_relscatter<<<NBR_, 256, 0, stream>>>(rel, hi, ti, Hrel, hr, tr);

  // CSR build: dest/h/t
  k_count3<<<gTOT, TB, 0, stream>>>(ia, hi, ti, cnt_dest, cnt_h, cnt_t);
  k_scan3<<<3, 256, 0, stream>>>(cnt_dest, off_dest, N_, cnt_h, off_h, N_, cnt_t, off_t, N_, dis);
  k_scatter3<<<gTOT, TB, 0, stream>>>(ja, ia, rel, hi, ti,
                                      off_dest, off_h, off_t,
                                      cur_dest, cur_h, cur_t,
                                      dis, j_dest, wj, relh, relt);

  // GCN + highway block 1 (x -> out cols 0..299 f32 + xb bf16)
  k_pack_x<<<gPKX, TB, 0, stream>>>((const float4*)x_e, EH4, xb);
  gemm_mfma(xb, w1b, g, EH_, N_, EH_, stream);
  k_gcn4<<<N_, 64, 0, stream>>>(off_dest, j_dest, wj, dis, xb, (float4*)y);
  k_highway3<<<(N_*EH4 + TB - 1)/TB, TB, 0, stream>>>((const float4*)x_e, EH4, (const float4*)y,
                                                      (const float4*)g, hw1_b, (float4*)out, xb);
  // block 2
  gemm_mfma(xb, w2b, g, EH_, N_, EH_, stream);
  k_gcn4<<<N_, 64, 0, stream>>>(off_dest, j_dest, wj, dis, xb, (float4*)y);
  k_highway3<<<(N_*EH4 + TB - 1)/TB, TB, 0, stream>>>((const float4*)out, LD4, (const float4*)y,
                                                      (const float4*)g, hw2_b, (float4*)out, xb);

  // E2R
  gemm_mfma(xb, wcb, xhxt, 200, N_, 200, stream);
  k_pproj<<<gN, TB, 0, stream>>>(xhxt, e2r_ah, e2r_at, (float4*)pht);
  k_fold_rel2<<<R_, 256, 0, stream>>>(off_rel, hr, tr, (const float4*)pht, s1p, s2p);
  k_e2r_agg3<<<dim3(R_, NC_), 64, 0, stream>>>(off_rel, hr, tr, s1p, s2p,
                                               (const float4*)xhxt, (float4*)xr_part);
  k_e2r_red<<<(R_*RH4 + TB - 1)/TB, TB, 0, stream>>>((const float4*)xr_part, (float4*)xr);

  // R2E
  k_dots16<<<(N_+15)/16, 256, 0, stream>>>(out, OUTD_, EH_, r2e_ah, r2e_at, st16, N_);
  k_sr<<<(R_*8 + TB - 1)/TB, TB, 0, stream>>>(xr, r2e_ar, sr8);
  k_fold_ht2<<<(N_+1)/2, 256, 0, stream>>>(off_h, off_t, relh, relt, st16, sr8, shp, stp);
  k_r2e_agg2b<<<N_, 128, 0, stream>>>(off_h, off_t, relh, relt, shp, stp,
                                      (const float4*)xr, (float4*)out, xeb);

  // GAT
  k_dots16<<<(N_+15)/16, 256, 0, stream>>>(out, OUTD_, X2D_, gat_ai, gat_aj, gg16, N_);
  k_fold_gat2<<<(N_+3)/4, 256, 0, stream>>>(off_dest, j_dest, gg16, agp);
  k_gat_agg4<<<N_, 128, 0, stream>>>(off_dest, j_dest, agp, xb, xeb, (float4*)out);
}

// Round 8
// 651.754 us; speedup vs baseline: 3.5967x; 1.1020x over previous
//
#include <hip/hip_runtime.h>
#include <math.h>

constexpr int N_    = 30000;
constexpr int E_    = 200000;
constexpr int EALL_ = 400000;
constexpr int R_    = 500;
constexpr int EH_   = 300;
constexpr int RH_   = 100;
constexpr int X2D_  = 500;
constexpr int OUTD_ = 1000;
constexpr int LD4   = OUTD_/4;  // 250
constexpr int EH4   = EH_/4;    // 75
constexpr int RH4   = RH_/4;    // 25
constexpr int NC_   = 16;       // chunks per relation for e2r agg
constexpr int XBS_  = 320;      // bf16 row stride for x table (zero-padded K for MFMA)
constexpr int XEBS_ = 200;      // bf16 row stride for xe table
constexpr int KP_   = 320;      // padded K for MFMA weights
constexpr int NBR_  = 64;       // blocks for rel counting sort
constexpr int PERB_ = (E_ + NBR_ - 1)/NBR_;  // 3125 edges per block
constexpr int SCB_  = 2048;     // elements per scan block
constexpr int NSB_  = (N_ + SCB_ - 1)/SCB_;  // 15 scan blocks per array
constexpr int SCNP_ = NSB_*SCB_;             // 30720 padded length

typedef __attribute__((ext_vector_type(4))) float f32x4;
typedef __attribute__((ext_vector_type(8))) short s16x8;

__device__ __forceinline__ float lrelu_(float v){ return v > 0.f ? v : 0.01f*v; }
__device__ __forceinline__ float sig_(float z){ return 1.f/(1.f + expf(-z)); }
__device__ __forceinline__ unsigned short f2bf_(float f){
  unsigned int u = __float_as_uint(f);
  unsigned int r = (u + 0x7FFFu + ((u >> 16) & 1u)) >> 16;
  return (unsigned short)r;
}
__device__ __forceinline__ float bf2f_(unsigned short h){
  return __uint_as_float(((unsigned int)h) << 16);
}

// ---------------- CSR build: dest/h/t via atomics ----------------
__global__ void k_count3(const int* __restrict__ ia,
                         const int* __restrict__ hi, const int* __restrict__ ti,
                         int* cd, int* ch, int* ct){
  int idx = blockIdx.x*blockDim.x + threadIdx.x;
  if (idx < EALL_) { atomicAdd(&cd[ia[idx]], 1); return; }
  idx -= EALL_;
  if (idx < E_) { atomicAdd(&ch[hi[idx]], 1); return; }
  idx -= E_;
  if (idx < E_) { atomicAdd(&ct[ti[idx]], 1); return; }
}

// ---------------- hierarchical exclusive scan (3 arrays, padded to SCNP_) ----------------
// phase A: per-block sums
__global__ void k_scanA(const int* __restrict__ c0, const int* __restrict__ c1,
                        const int* __restrict__ c2, int* __restrict__ bsum){
  int arr = blockIdx.x / NSB_, b = blockIdx.x - arr*NSB_;
  const int* c = arr == 0 ? c0 : (arr == 1 ? c1 : c2);
  int t = threadIdx.x;
  const int4* c4 = reinterpret_cast<const int4*>(c + b*SCB_ + t*8);
  int4 u0 = c4[0], u1 = c4[1];
  int acc = u0.x+u0.y+u0.z+u0.w + u1.x+u1.y+u1.z+u1.w;
  __shared__ int red[256];
  red[t] = acc;
  __syncthreads();
  for (int o = 128; o > 0; o >>= 1){
    if (t < o) red[t] += red[t+o];
    __syncthreads();
  }
  if (t == 0) bsum[arr*NSB_ + b] = red[0];
}

// phase B: scan the 15 block sums per array (serial, trivial) + write o[N]
__global__ void k_scanB(int* __restrict__ bsum, int* o0, int* o1, int* o2){
  int t = threadIdx.x;
  if (t < 3){
    int run = 0;
    for (int b = 0; b < NSB_; ++b){ int v = bsum[t*NSB_ + b]; bsum[t*NSB_ + b] = run; run += v; }
    int* o = t == 0 ? o0 : (t == 1 ? o1 : o2);
    o[N_] = run;
  }
}

// phase C: per-thread 8-chunk + LDS scan; writes exclusive offsets (+ dis for arr 0)
__global__ void k_scanC(const int* __restrict__ c0, const int* __restrict__ c1,
                        const int* __restrict__ c2, const int* __restrict__ bsum,
                        int* o0, int* o1, int* o2, float* __restrict__ dis){
  int arr = blockIdx.x / NSB_, b = blockIdx.x - arr*NSB_;
  const int* c = arr == 0 ? c0 : (arr == 1 ? c1 : c2);
  int* o = arr == 0 ? o0 : (arr == 1 ? o1 : o2);
  int t = threadIdx.x;
  int base = b*SCB_ + t*8;
  const int4* c4 = reinterpret_cast<const int4*>(c + base);
  int4 u0 = c4[0], u1 = c4[1];
  int v[8] = {u0.x,u0.y,u0.z,u0.w,u1.x,u1.y,u1.z,u1.w};
  int tot = v[0]+v[1]+v[2]+v[3]+v[4]+v[5]+v[6]+v[7];
  __shared__ int sc[256];
  sc[t] = tot;
  __syncthreads();
  for (int off = 1; off < 256; off <<= 1){
    int add = (t >= off) ? sc[t-off] : 0;
    __syncthreads();
    sc[t] += add;
    __syncthreads();
  }
  int run = bsum[arr*NSB_ + b] + (t ? sc[t-1] : 0);
  #pragma unroll
  for (int i = 0; i < 8; ++i){
    int idx = base + i;
    o[idx] = run;
    if (arr == 0) dis[idx] = v[i] > 0 ? rsqrtf((float)v[i]) : 0.f;
    run += v[i];
  }
}

// scatter dest (with fused wj), h, t payloads
__global__ void k_scatter3(const int* __restrict__ ja, const int* __restrict__ ia,
                           const int* __restrict__ rel, const int* __restrict__ hi,
                           const int* __restrict__ ti,
                           const int* od, const int* oh, const int* ot,
                           int* curd, int* curh, int* curt,
                           const float* __restrict__ dis,
                           int* j_dest, float* wj,
                           int* relh, int* relt){
  int idx = blockIdx.x*blockDim.x + threadIdx.x;
  if (idx < EALL_){
    int e = idx, s = ia[e];
    int p = od[s] + atomicAdd(&curd[s], 1);
    int j = ja[e];
    j_dest[p] = j; wj[p] = dis[j]; return;
  }
  idx -= EALL_;
  if (idx < E_){
    int e = idx, s = hi[e];
    int p = oh[s] + atomicAdd(&curh[s], 1);
    relh[p] = rel[e]; return;
  }
  idx -= E_;
  if (idx < E_){
    int e = idx, s = ti[e];
    int p = ot[s] + atomicAdd(&curt[s], 1);
    relt[p] = rel[e]; return;
  }
}

// ---------------- rel CSR: block counting sort, no global atomics ----------------
__global__ void k_relhist(const int* __restrict__ rel, int* __restrict__ H){
  __shared__ int h[R_];
  int b = blockIdx.x, tid = threadIdx.x;
  for (int i = tid; i < R_; i += 256) h[i] = 0;
  __syncthreads();
  int s = b*PERB_, e = min(s + PERB_, E_);
  for (int i = s + tid; i < e; i += 256) atomicAdd(&h[rel[i]], 1);
  __syncthreads();
  for (int i = tid; i < R_; i += 256) H[b*R_ + i] = h[i];
}

__global__ void k_relscan(int* __restrict__ H, int* __restrict__ off_rel){
  __shared__ int tot[R_];
  __shared__ int sc[256];
  int tid = threadIdx.x;
  for (int r = tid; r < R_; r += 256){
    int acc = 0;
    for (int b = 0; b < NBR_; ++b){ int v = H[b*R_ + r]; H[b*R_ + r] = acc; acc += v; }
    tot[r] = acc;
  }
  __syncthreads();
  // parallel scan of tot[500], 2 bins per thread
  int r0 = tid*2;
  int a0 = (r0 < R_) ? tot[r0] : 0;
  int a1 = (r0+1 < R_) ? tot[r0+1] : 0;
  sc[tid] = a0 + a1;
  __syncthreads();
  for (int off = 1; off < 256; off <<= 1){
    int add = (tid >= off) ? sc[tid-off] : 0;
    __syncthreads();
    sc[tid] += add;
    __syncthreads();
  }
  int run = tid ? sc[tid-1] : 0;
  if (r0 < R_)   off_rel[r0]   = run;
  if (r0+1 < R_) off_rel[r0+1] = run + a0;
  if (tid == 255) off_rel[R_] = sc[255];
  __syncthreads();
  for (int r = tid; r < R_; r += 256){
    int o = off_rel[r];
    for (int b = 0; b < NBR_; ++b) H[b*R_ + r] += o;
  }
}

__global__ void k_relscatter(const int* __restrict__ rel, const int* __restrict__ hi,
                             const int* __restrict__ ti, const int* __restrict__ H,
                             int* __restrict__ hr, int* __restrict__ tr){
  __shared__ int cur[R_];
  int b = blockIdx.x, tid = threadIdx.x;
  for (int i = tid; i < R_; i += 256) cur[i] = H[b*R_ + i];
  __syncthreads();
  int s = b*PERB_, e = min(s + PERB_, E_);
  for (int i = s + tid; i < e; i += 256){
    int r = rel[i];
    int p = atomicAdd(&cur[r], 1);
    hr[p] = hi[i]; tr[p] = ti[i];
  }
}

// ---------------- bf16 pack kernels ----------------
__global__ void k_pack_x(const float4* __restrict__ X, int ldx4,
                         unsigned short* __restrict__ xb){
  int idx = blockIdx.x*blockDim.x + threadIdx.x;   // N_*80
  if (idx >= N_*80) return;
  int n = idx / 80, c = idx - n*80;
  ushort4 o = make_ushort4(0,0,0,0);
  if (c < EH4){
    float4 v = X[(size_t)n*ldx4 + c];
    o.x = f2bf_(v.x); o.y = f2bf_(v.y); o.z = f2bf_(v.z); o.w = f2bf_(v.w);
  }
  *reinterpret_cast<ushort4*>(&xb[(size_t)n*XBS_ + c*4]) = o;
}

// all three weight packs in one launch
__global__ void k_pack_weights(const float* __restrict__ w1, const float* __restrict__ w2,
                               const float* __restrict__ wh, const float* __restrict__ wt,
                               unsigned short* w1b, unsigned short* w2b,
                               unsigned short* wcb){
  int idx = blockIdx.x*blockDim.x + threadIdx.x;
  if (idx < EH_*KP_){
    int n = idx/KP_, k = idx - n*KP_;
    w1b[idx] = (k < EH_) ? f2bf_(w1[(size_t)n*EH_ + k]) : (unsigned short)0;
    return;
  }
  idx -= EH_*KP_;
  if (idx < EH_*KP_){
    int n = idx/KP_, k = idx - n*KP_;
    w2b[idx] = (k < EH_) ? f2bf_(w2[(size_t)n*EH_ + k]) : (unsigned short)0;
    return;
  }
  idx -= EH_*KP_;
  if (idx < 200*KP_){
    int n = idx/KP_, k = idx - n*KP_;
    wcb[idx] = (k < EH_) ? f2bf_((n < 100) ? wh[(size_t)n*EH_ + k] : wt[(size_t)(n-100)*EH_ + k])
                         : (unsigned short)0;
  }
}

// ---------------- MFMA GEMM ----------------
__global__ __launch_bounds__(256) void k_gemm_mfma(
    const unsigned short* __restrict__ Ab,
    const unsigned short* __restrict__ Wb,
    float* __restrict__ C, int ldc, int M, int Nn){
  constexpr int WS = 328;
  constexpr int AS = 40;
  __shared__ unsigned short Ws[64*WS];
  __shared__ unsigned short As[128*AS];
  int tid = threadIdx.x;
  int lane = tid & 63, wave = tid >> 6;
  int wm = wave & 1, wn = wave >> 1;
  int m0 = blockIdx.x*128, n0 = blockIdx.y*64;

  for (int c = tid; c < 64*(KP_/8); c += 256){
    int n = c / (KP_/8), k8 = (c % (KP_/8))*8;
    s16x8 v = {0,0,0,0,0,0,0,0};
    if (n0 + n < Nn)
      v = *reinterpret_cast<const s16x8*>(&Wb[(size_t)(n0+n)*KP_ + k8]);
    *reinterpret_cast<s16x8*>(&Ws[n*WS + k8]) = v;
  }

  f32x4 acc[4][2] = {};
  int kf = (lane >> 4)*8;
  int rA = lane & 15;
  for (int k0 = 0; k0 < KP_; k0 += 32){
    __syncthreads();
    for (int c = tid; c < 128*4; c += 256){
      int r = c >> 2, k8 = (c & 3)*8;
      s16x8 v = {0,0,0,0,0,0,0,0};
      if (m0 + r < M)
        v = *reinterpret_cast<const s16x8*>(&Ab[(size_t)(m0+r)*XBS_ + k0 + k8]);
      *reinterpret_cast<s16x8*>(&As[r*AS + k8]) = v;
    }
    __syncthreads();
    s16x8 afr[4], bfr[2];
    #pragma unroll
    for (int mf = 0; mf < 4; ++mf)
      afr[mf] = *reinterpret_cast<const s16x8*>(&As[(wm*64 + mf*16 + rA)*AS + kf]);
    #pragma unroll
    for (int nf = 0; nf < 2; ++nf)
      bfr[nf] = *reinterpret_cast<const s16x8*>(&Ws[(wn*32 + nf*16 + rA)*WS + k0 + kf]);
    #pragma unroll
    for (int mf = 0; mf < 4; ++mf)
      #pragma unroll
      for (int nf = 0; nf < 2; ++nf)
        acc[mf][nf] = __builtin_amdgcn_mfma_f32_16x16x32_bf16(afr[mf], bfr[nf], acc[mf][nf], 0, 0, 0);
  }
  int col0 = n0 + wn*32 + (lane & 15);
  int rbase = m0 + wm*64 + (lane >> 4)*4;
  #pragma unroll
  for (int mf = 0; mf < 4; ++mf){
    #pragma unroll
    for (int nf = 0; nf < 2; ++nf){
      int col = col0 + nf*16;
      if (col < Nn){
        #pragma unroll
        for (int r = 0; r < 4; ++r){
          int row = rbase + mf*16 + r;
          if (row < M) C[(size_t)row*ldc + col] = acc[mf][nf][r];
        }
      }
    }
  }
}

// ---------------- GCN gather: 1 wave per node ----------------
__global__ void k_gcn4(const int* __restrict__ off, const int* __restrict__ jd,
                       const float* __restrict__ wj, const float* __restrict__ dis,
                       const unsigned short* __restrict__ xb, float4* __restrict__ Y){
  __shared__ int js[64];
  __shared__ float ws[64];
  int n = blockIdx.x, lane = threadIdx.x;   // 64
  int s = off[n], t = off[n+1];
  bool two = lane < (EH4 - 64);
  float4 a0 = make_float4(0.f,0.f,0.f,0.f);
  float4 a1 = make_float4(0.f,0.f,0.f,0.f);
  for (int base = s; base < t; base += 64){
    int m = min(64, t - base);
    __syncthreads();
    if (lane < m){ js[lane] = jd[base+lane]; ws[lane] = wj[base+lane]; }
    __syncthreads();
    int q = 0;
    for (; q + 1 < m; q += 2){
      size_t r0 = (size_t)js[q]*XBS_, r1 = (size_t)js[q+1]*XBS_;
      float w0 = ws[q], w1 = ws[q+1];
      ushort4 u0 = *reinterpret_cast<const ushort4*>(&xb[r0 + lane*4]);
      ushort4 u1 = *reinterpret_cast<const ushort4*>(&xb[r1 + lane*4]);
      a0.x += w0*bf2f_(u0.x) + w1*bf2f_(u1.x);
      a0.y += w0*bf2f_(u0.y) + w1*bf2f_(u1.y);
      a0.z += w0*bf2f_(u0.z) + w1*bf2f_(u1.z);
      a0.w += w0*bf2f_(u0.w) + w1*bf2f_(u1.w);
      if (two){
        ushort4 v0 = *reinterpret_cast<const ushort4*>(&xb[r0 + 256 + lane*4]);
        ushort4 v1 = *reinterpret_cast<const ushort4*>(&xb[r1 + 256 + lane*4]);
        a1.x += w0*bf2f_(v0.x) + w1*bf2f_(v1.x);
        a1.y += w0*bf2f_(v0.y) + w1*bf2f_(v1.y);
        a1.z += w0*bf2f_(v0.z) + w1*bf2f_(v1.z);
        a1.w += w0*bf2f_(v0.w) + w1*bf2f_(v1.w);
      }
    }
    if (q < m){
      size_t r0 = (size_t)js[q]*XBS_;
      float w0 = ws[q];
      ushort4 u0 = *reinterpret_cast<const ushort4*>(&xb[r0 + lane*4]);
      a0.x += w0*bf2f_(u0.x); a0.y += w0*bf2f_(u0.y);
      a0.z += w0*bf2f_(u0.z); a0.w += w0*bf2f_(u0.w);
      if (two){
        ushort4 v0 = *reinterpret_cast<const ushort4*>(&xb[r0 + 256 + lane*4]);
        a1.x += w0*bf2f_(v0.x); a1.y += w0*bf2f_(v0.y);
        a1.z += w0*bf2f_(v0.z); a1.w += w0*bf2f_(v0.w);
      }
    }
  }
  float dn = dis[n];
  float4 r;
  r.x = fmaxf(dn*a0.x, 0.f); r.y = fmaxf(dn*a0.y, 0.f);
  r.z = fmaxf(dn*a0.z, 0.f); r.w = fmaxf(dn*a0.w, 0.f);
  Y[(size_t)n*EH4 + lane] = r;
  if (two){
    r.x = fmaxf(dn*a1.x, 0.f); r.y = fmaxf(dn*a1.y, 0.f);
    r.z = fmaxf(dn*a1.z, 0.f); r.w = fmaxf(dn*a1.w, 0.f);
    Y[(size_t)n*EH4 + 64 + lane] = r;
  }
}

// ---------------- highway + fused bf16 pack ----------------
__global__ void k_highway3(const float4* __restrict__ Xold, int ldo4,
                           const float4* __restrict__ Y, const float4* __restrict__ G,
                           const float* __restrict__ b,
                           float4* __restrict__ Xn, unsigned short* __restrict__ xbb){
  int idx = blockIdx.x*blockDim.x + threadIdx.x;
  if (idx >= N_*EH4) return;
  int n = idx / EH4, f = idx - n*EH4;
  float4 g4 = G[idx];
  float4 b4 = reinterpret_cast<const float4*>(b)[f];
  float4 y4 = Y[idx];
  float4 xo = Xold[(size_t)n*ldo4 + f];
  float4 r;
  float gx;
  gx = sig_(g4.x + b4.x); r.x = gx*y4.x + (1.f-gx)*xo.x;
  gx = sig_(g4.y + b4.y); r.y = gx*y4.y + (1.f-gx)*xo.y;
  gx = sig_(g4.z + b4.z); r.z = gx*y4.z + (1.f-gx)*xo.z;
  gx = sig_(g4.w + b4.w); r.w = gx*y4.w + (1.f-gx)*xo.w;
  Xn[(size_t)n*LD4 + f] = r;
  ushort4 o;
  o.x = f2bf_(r.x); o.y = f2bf_(r.y); o.z = f2bf_(r.z); o.w = f2bf_(r.w);
  *reinterpret_cast<ushort4*>(&xbb[(size_t)n*XBS_ + f*4]) = o;
}

// ---------------- E2R projections -> pht[N][8] ----------------
__global__ void k_pproj(const float* __restrict__ xhxt,
                        const float* __restrict__ ah, const float* __restrict__ at,
                        float4* __restrict__ pht){
  int n = blockIdx.x*blockDim.x + threadIdx.x;
  if (n >= N_) return;
  float a0=0,a1=0,b0=0,b1=0,c0=0,c1=0,d0=0,d1=0;
  const float* xh = xhxt + (size_t)n*200;
  const float* xt = xh + 100;
  for (int f = 0; f < RH_; ++f) {
    float vh = xh[f], vt = xt[f];
    float w0 = ah[f], w1 = ah[RH_+f], u0 = at[f], u1 = at[RH_+f];
    a0 += vh*w0; a1 += vh*w1;
    b0 += vt*u0; b1 += vt*u1;
    c0 += vt*w0; c1 += vt*w1;
    d0 += vh*u0; d1 += vh*u1;
  }
  pht[(size_t)n*2]     = make_float4(a0, a1, c0, c1);  // h-side: p1 | p3
  pht[(size_t)n*2 + 1] = make_float4(b0, b1, d0, d1);  // t-side: p2 | p4
}

// ---------------- E2R fold: on-the-fly logits ----------------
__global__ void k_fold_rel2(const int* __restrict__ off,
                            const int* __restrict__ hr, const int* __restrict__ tr,
                            const float4* __restrict__ pht,
                            float* __restrict__ s1p, float* __restrict__ s2p){
  __shared__ float4 redm[4];
  __shared__ float4 reds[4];
  int r = blockIdx.x;
  int tid = threadIdx.x, lane = tid & 63, w = tid >> 6;
  int s = off[r], e = off[r+1];
  float4 mx = make_float4(-1e30f,-1e30f,-1e30f,-1e30f);
  for (int p = s + tid; p < e; p += 256){
    float4 ph = pht[(size_t)hr[p]*2];
    float4 pt = pht[(size_t)tr[p]*2 + 1];
    mx.x = fmaxf(mx.x, lrelu_(ph.x + pt.x));
    mx.y = fmaxf(mx.y, lrelu_(ph.y + pt.y));
    mx.z = fmaxf(mx.z, lrelu_(ph.z + pt.z));
    mx.w = fmaxf(mx.w, lrelu_(ph.w + pt.w));
  }
  #pragma unroll
  for (int o = 1; o < 64; o <<= 1){
    mx.x = fmaxf(mx.x, __shfl_xor(mx.x, o));
    mx.y = fmaxf(mx.y, __shfl_xor(mx.y, o));
    mx.z = fmaxf(mx.z, __shfl_xor(mx.z, o));
    mx.w = fmaxf(mx.w, __shfl_xor(mx.w, o));
  }
  if (lane == 0) redm[w] = mx;
  __syncthreads();
  float4 m;
  m.x = fmaxf(fmaxf(redm[0].x, redm[1].x), fmaxf(redm[2].x, redm[3].x));
  m.y = fmaxf(fmaxf(redm[0].y, redm[1].y), fmaxf(redm[2].y, redm[3].y));
  m.z = fmaxf(fmaxf(redm[0].z, redm[1].z), fmaxf(redm[2].z, redm[3].z));
  m.w = fmaxf(fmaxf(redm[0].w, redm[1].w), fmaxf(redm[2].w, redm[3].w));
  float4 sm = make_float4(0.f,0.f,0.f,0.f);
  for (int p = s + tid; p < e; p += 256){
    float4 ph = pht[(size_t)hr[p]*2];
    float4 pt = pht[(size_t)tr[p]*2 + 1];
    sm.x += expf(lrelu_(ph.x + pt.x) - m.x);
    sm.y += expf(lrelu_(ph.y + pt.y) - m.y);
    sm.z += expf(lrelu_(ph.z + pt.z) - m.z);
    sm.w += expf(lrelu_(ph.w + pt.w) - m.w);
  }
  #pragma unroll
  for (int o = 1; o < 64; o <<= 1){
    sm.x += __shfl_xor(sm.x, o);
    sm.y += __shfl_xor(sm.y, o);
    sm.z += __shfl_xor(sm.z, o);
    sm.w += __shfl_xor(sm.w, o);
  }
  if (lane == 0) reds[w] = sm;
  __syncthreads();
  float4 sv;
  sv.x = reds[0].x + reds[1].x + reds[2].x + reds[3].x;
  sv.y = reds[0].y + reds[1].y + reds[2].y + reds[3].y;
  sv.z = reds[0].z + reds[1].z + reds[2].z + reds[3].z;
  sv.w = reds[0].w + reds[1].w + reds[2].w + reds[3].w;
  float4 inv;
  inv.x = 1.f/(sv.x + 1e-16f); inv.y = 1.f/(sv.y + 1e-16f);
  inv.z = 1.f/(sv.z + 1e-16f); inv.w = 1.f/(sv.w + 1e-16f);
  for (int p = s + tid; p < e; p += 256){
    float4 ph = pht[(size_t)hr[p]*2];
    float4 pt = pht[(size_t)tr[p]*2 + 1];
    s1p[p] = expf(lrelu_(ph.x + pt.x) - m.x)*inv.x + expf(lrelu_(ph.y + pt.y) - m.y)*inv.y;
    s2p[p] = expf(lrelu_(ph.z + pt.z) - m.z)*inv.z + expf(lrelu_(ph.w + pt.w) - m.w)*inv.w;
  }
}

// ---------------- R2E fold: on-the-fly logits from st16 + sr8 ----------------
__global__ void k_fold_ht2(const int* __restrict__ offh, const int* __restrict__ offt,
                           const int* __restrict__ relh, const int* __restrict__ relt,
                           const float* __restrict__ st16, const float* __restrict__ sr8,
                           float* __restrict__ shp, float* __restrict__ stp){
  int w = threadIdx.x >> 6, lane = threadIdx.x & 63;
  int n = blockIdx.x*2 + (w >> 1);
  if (n >= N_) return;
  int side = w & 1;
  const int* off = side ? offt : offh;
  const int* rl  = side ? relt : relh;
  float* op = side ? stp : shp;
  int k = lane & 7, g = lane >> 3;
  float cst = st16[(size_t)n*16 + side*8 + k];
  int s = off[n], e = off[n+1];
  float m = -1e30f;
  for (int p = s + g; p < e; p += 8)
    m = fmaxf(m, lrelu_(cst + sr8[(size_t)rl[p]*8 + k]));
  #pragma unroll
  for (int o = 8; o < 64; o <<= 1) m = fmaxf(m, __shfl_xor(m, o));
  float sum = 0.f;
  for (int p = s + g; p < e; p += 8)
    sum += expf(lrelu_(cst + sr8[(size_t)rl[p]*8 + k]) - m);
  #pragma unroll
  for (int o = 8; o < 64; o <<= 1) sum += __shfl_xor(sum, o);
  float inv = 1.f / (sum + 1e-16f);
  for (int p = s + g; p < e; p += 8){
    float t = expf(lrelu_(cst + sr8[(size_t)rl[p]*8 + k]) - m) * inv;
    #pragma unroll
    for (int o = 1; o < 8; o <<= 1) t += __shfl_xor(t, o);
    if (k == 0) op[p] = t;
  }
}

// ---------------- GAT fold: on-the-fly logits from gg16 ----------------
__global__ void k_fold_gat2(const int* __restrict__ off, const int* __restrict__ jd,
                            const float* __restrict__ gg16, float* __restrict__ agp){
  int w = threadIdx.x >> 6, lane = threadIdx.x & 63;
  int n = blockIdx.x*4 + w;
  if (n >= N_) return;
  int k = lane & 7, g = lane >> 3;
  float cst = gg16[(size_t)n*16 + k];
  int s = off[n], e = off[n+1];
  float m = -1e30f;
  for (int p = s + g; p < e; p += 8)
    m = fmaxf(m, lrelu_(cst + gg16[(size_t)jd[p]*16 + 8 + k]));
  #pragma unroll
  for (int o = 8; o < 64; o <<= 1) m = fmaxf(m, __shfl_xor(m, o));
  float sum = 0.f;
  for (int p = s + g; p < e; p += 8)
    sum += expf(lrelu_(cst + gg16[(size_t)jd[p]*16 + 8 + k]) - m);
  #pragma unroll
  for (int o = 8; o < 64; o <<= 1) sum += __shfl_xor(sum, o);
  float inv = 1.f / (sum + 1e-16f);
  for (int p = s + g; p < e; p += 8){
    float t = expf(lrelu_(cst + gg16[(size_t)jd[p]*16 + 8 + k]) - m) * inv;
    #pragma unroll
    for (int o = 1; o < 8; o <<= 1) t += __shfl_xor(t, o);
    if (k == 0) agp[p] = t;
  }
}

// ---------------- E2R aggregate: chunked partials + fused reduce/sr8 ----------------
__global__ void k_e2r_agg3(const int* __restrict__ off,
                           const int* __restrict__ hr, const int* __restrict__ tr,
                           const float* __restrict__ s1p, const float* __restrict__ s2p,
                           const float4* __restrict__ xhxt4, float4* __restrict__ xr_part){
  int r = blockIdx.x, c = blockIdx.y;
  int lane = threadIdx.x;           // 64
  int side = lane >> 5, fl = lane & 31;
  int s = off[r], e = off[r+1];
  int len = e - s;
  int per = (len + NC_ - 1)/NC_;
  int cs = s + c*per, ce = min(cs + per, e);
  float4 acc = make_float4(0.f,0.f,0.f,0.f);
  if (fl < RH4){
    const int* idx = side ? tr : hr;
    const float* wv = side ? s2p : s1p;
    int fofs = side ? 25 + fl : fl;
    int p = cs;
    for (; p + 1 < ce; p += 2){
      float a0 = wv[p], a1 = wv[p+1];
      float4 v0 = xhxt4[(size_t)idx[p]*50 + fofs];
      float4 v1 = xhxt4[(size_t)idx[p+1]*50 + fofs];
      acc.x += a0*v0.x + a1*v1.x; acc.y += a0*v0.y + a1*v1.y;
      acc.z += a0*v0.z + a1*v1.z; acc.w += a0*v0.w + a1*v1.w;
    }
    if (p < ce){
      float a0 = wv[p];
      float4 v0 = xhxt4[(size_t)idx[p]*50 + fofs];
      acc.x += a0*v0.x; acc.y += a0*v0.y; acc.z += a0*v0.z; acc.w += a0*v0.w;
    }
  }
  float4 oth;
  oth.x = __shfl_xor(acc.x, 32); oth.y = __shfl_xor(acc.y, 32);
  oth.z = __shfl_xor(acc.z, 32); oth.w = __shfl_xor(acc.w, 32);
  if (side == 0 && fl < RH4){
    float4 o = make_float4(acc.x+oth.x, acc.y+oth.y, acc.z+oth.z, acc.w+oth.w);
    xr_part[((size_t)c*R_ + r)*RH4 + fl] = o;
  }
}

// reduce xr_part -> xr AND compute sr8[r][0..7] (fused k_sr)
__global__ void k_e2r_red2(const float4* __restrict__ xr_part, float4* __restrict__ xr4,
                           const float* __restrict__ ar, float* __restrict__ sr8){
  __shared__ float row[RH_];
  int r = blockIdx.x, lane = threadIdx.x;   // 64
  if (lane < RH4){
    float4 a = make_float4(0.f,0.f,0.f,0.f);
    #pragma unroll
    for (int c = 0; c < NC_; ++c){
      float4 v = xr_part[((size_t)c*R_ + r)*RH4 + lane];
      a.x += v.x; a.y += v.y; a.z += v.z; a.w += v.w;
    }
    a.x *= 0.25f; a.y *= 0.25f; a.z *= 0.25f; a.w *= 0.25f;
    xr4[(size_t)r*RH4 + lane] = a;
    row[lane*4]   = a.x; row[lane*4+1] = a.y;
    row[lane*4+2] = a.z; row[lane*4+3] = a.w;
  }
  __syncthreads();
  int h = lane & 7, gk = lane >> 3;
  float acc = 0.f;
  for (int k = gk; k < RH_; k += 8) acc += row[k]*ar[(size_t)h*RH_ + k];
  #pragma unroll
  for (int o = 8; o < 64; o <<= 1) acc += __shfl_xor(acc, o);
  if (lane < 8) sr8[(size_t)r*8 + lane] = acc;
}

// ---------------- 16-head row dots ----------------
__global__ void k_dots16(const float* __restrict__ X, int ldx, int K,
                         const float* __restrict__ wA, const float* __restrict__ wB,
                         float* __restrict__ out16, int M){
  __shared__ float xs[16][65];
  __shared__ float ws[16][65];
  int tid = threadIdx.x;
  int tx = tid & 15, ty = tid >> 4;
  int r0 = blockIdx.x*16;
  float acc = 0.f;
  for (int c0 = 0; c0 < K; c0 += 64){
    int cl = min(64, K - c0);
    #pragma unroll
    for (int i = 0; i < 4; ++i){
      int idx = tid + i*256;
      int r = idx >> 6, k = idx & 63;
      float xv = 0.f, wv = 0.f;
      if (k < cl && r0 + r < M) xv = X[(size_t)(r0+r)*ldx + c0 + k];
      if (k < cl) wv = (r < 8) ? wA[(size_t)r*K + c0 + k] : wB[(size_t)(r-8)*K + c0 + k];
      xs[r][k] = xv;
      ws[r][k] = wv;
    }
    __syncthreads();
    #pragma unroll
    for (int k = 0; k < 64; ++k) acc += xs[ty][k]*ws[tx][k];
    __syncthreads();
  }
  if (r0 + ty < M) out16[(size_t)(r0+ty)*16 + tx] = acc;
}

// ---------------- R2E aggregate (f32 out + bf16 xeb) ----------------
__global__ void k_r2e_agg2b(const int* __restrict__ offh, const int* __restrict__ offt,
                            const int* __restrict__ relh, const int* __restrict__ relt,
                            const float* __restrict__ shp, const float* __restrict__ stp,
                            const float4* __restrict__ xr4, float4* __restrict__ out,
                            unsigned short* __restrict__ xeb){
  int n = blockIdx.x;
  int side = threadIdx.x >> 6, lane = threadIdx.x & 63;
  const int* off = side ? offt : offh;
  const int* rr  = side ? relt : relh;
  const float* sp = side ? stp : shp;
  int s = off[n], e = off[n+1];
  if (lane >= RH4) return;
  float4 acc = make_float4(0.f,0.f,0.f,0.f);
  int p = s;
  for (; p + 1 < e; p += 2){
    float a0 = sp[p], a1 = sp[p+1];
    float4 v0 = xr4[(size_t)rr[p]*RH4 + lane];
    float4 v1 = xr4[(size_t)rr[p+1]*RH4 + lane];
    acc.x += a0*v0.x + a1*v1.x; acc.y += a0*v0.y + a1*v1.y;
    acc.z += a0*v0.z + a1*v1.z; acc.w += a0*v0.w + a1*v1.w;
  }
  if (p < e){
    float a0 = sp[p];
    float4 v0 = xr4[(size_t)rr[p]*RH4 + lane];
    acc.x += a0*v0.x; acc.y += a0*v0.y; acc.z += a0*v0.z; acc.w += a0*v0.w;
  }
  float4 o = make_float4(acc.x*0.125f, acc.y*0.125f, acc.z*0.125f, acc.w*0.125f);
  out[(size_t)n*LD4 + (side ? 100 : 75) + lane] = o;
  ushort4 ob;
  ob.x = f2bf_(o.x); ob.y = f2bf_(o.y); ob.z = f2bf_(o.z); ob.w = f2bf_(o.w);
  *reinterpret_cast<ushort4*>(&xeb[(size_t)n*XEBS_ + (side ? 100 : 0) + lane*4]) = ob;
}

// ---------------- GAT aggregate (split bf16 tables xb + xeb) ----------------
__global__ void k_gat_agg4(const int* __restrict__ off, const int* __restrict__ jd,
                           const float* __restrict__ agp,
                           const unsigned short* __restrict__ xb,
                           const unsigned short* __restrict__ xeb,
                           float4* __restrict__ out){
  __shared__ int js[128];
  __shared__ float as_[128];
  int n = blockIdx.x, tid = threadIdx.x;
  int s = off[n], t = off[n+1];
  const unsigned short* tbl;
  size_t stride; int cofs;
  if (tid < 75){ tbl = xb;  stride = XBS_;  cofs = tid*4; }
  else         { tbl = xeb; stride = XEBS_; cofs = (tid-75)*4; }
  float4 acc = make_float4(0.f,0.f,0.f,0.f);
  for (int base = s; base < t; base += 128){
    int m = min(128, t - base);
    __syncthreads();
    if (tid < m){ js[tid] = jd[base+tid]; as_[tid] = agp[base+tid]; }
    __syncthreads();
    if (tid < 125){
      int q = 0;
      for (; q + 1 < m; q += 2){
        float a0 = as_[q], a1 = as_[q+1];
        ushort4 u0 = *reinterpret_cast<const ushort4*>(&tbl[(size_t)js[q]*stride + cofs]);
        ushort4 u1 = *reinterpret_cast<const ushort4*>(&tbl[(size_t)js[q+1]*stride + cofs]);
        acc.x += a0*bf2f_(u0.x) + a1*bf2f_(u1.x);
        acc.y += a0*bf2f_(u0.y) + a1*bf2f_(u1.y);
        acc.z += a0*bf2f_(u0.z) + a1*bf2f_(u1.z);
        acc.w += a0*bf2f_(u0.w) + a1*bf2f_(u1.w);
      }
      if (q < m){
        float a0 = as_[q];
        ushort4 u0 = *reinterpret_cast<const ushort4*>(&tbl[(size_t)js[q]*stride + cofs]);
        acc.x += a0*bf2f_(u0.x); acc.y += a0*bf2f_(u0.y);
        acc.z += a0*bf2f_(u0.z); acc.w += a0*bf2f_(u0.w);
      }
    }
  }
  if (tid < 125){
    float4 r = make_float4(acc.x*0.125f, acc.y*0.125f, acc.z*0.125f, acc.w*0.125f);
    out[(size_t)n*LD4 + 125 + tid] = r;
  }
}

// ---------------- host ----------------
static inline void gemm_mfma(const unsigned short* Ab, const unsigned short* Wb,
                             float* C, int ldc, int M, int Nn, hipStream_t st){
  dim3 g((M + 127)/128, (Nn + 63)/64);
  k_gemm_mfma<<<g, 256, 0, st>>>(Ab, Wb, C, ldc, M, Nn);
}

extern "C" void kernel_launch(void* const* d_in, const int* in_sizes, int n_in,
                              void* d_out, int out_size, void* d_ws, size_t ws_size,
                              hipStream_t stream) {
  const float* x_e   = (const float*)d_in[0];
  const int*   ei    = (const int*)d_in[1];
  const int*   rel   = (const int*)d_in[2];
  const int*   eia   = (const int*)d_in[3];
  const float* hw1_w = (const float*)d_in[5];
  const float* hw1_b = (const float*)d_in[6];
  const float* hw2_w = (const float*)d_in[7];
  const float* hw2_b = (const float*)d_in[8];
  const float* e2r_wh= (const float*)d_in[9];
  const float* e2r_wt= (const float*)d_in[10];
  const float* e2r_ah= (const float*)d_in[11];
  const float* e2r_at= (const float*)d_in[12];
  const float* r2e_ah= (const float*)d_in[13];
  const float* r2e_at= (const float*)d_in[14];
  const float* r2e_ar= (const float*)d_in[15];
  const float* gat_ai= (const float*)d_in[16];
  const float* gat_aj= (const float*)d_in[17];
  float* out = (float*)d_out;

  const int* hi = ei;
  const int* ti = ei + E_;
  const int* ja = eia;
  const int* ia = eia + EALL_;

  char* base = (char*)d_ws;
  size_t off = 0;
  auto alloc = [&](size_t bytes)->void*{
    void* p = base + off;
    off = (off + bytes + 255) & ~(size_t)255;
    return p;
  };

  // zeroed region: padded counts + cursors (dest/h/t)
  size_t z0 = off;
  int* cnt_dest = (int*)alloc(SCNP_*4);
  int* cnt_h    = (int*)alloc(SCNP_*4);
  int* cnt_t    = (int*)alloc(SCNP_*4);
  int* cur_dest = (int*)alloc(N_*4);
  int* cur_h    = (int*)alloc(N_*4);
  int* cur_t    = (int*)alloc(N_*4);
  size_t z1 = off;

  int* off_dest = (int*)alloc(SCNP_*4);   // needs N_+1; padded
  int* off_h    = (int*)alloc(SCNP_*4);
  int* off_t    = (int*)alloc(SCNP_*4);
  int* off_rel  = (int*)alloc((R_+1)*4);
  int* bsum     = (int*)alloc(3*NSB_*4);
  int* Hrel     = (int*)alloc((size_t)NBR_*R_*4);
  int* j_dest   = (int*)alloc((size_t)EALL_*4);
  int* hr       = (int*)alloc((size_t)E_*4);
  int* tr       = (int*)alloc((size_t)E_*4);
  int* relh     = (int*)alloc((size_t)E_*4);
  int* relt     = (int*)alloc((size_t)E_*4);

  float* dis   = (float*)alloc(SCNP_*4);
  float* wj    = (float*)alloc((size_t)EALL_*4);
  float* y     = (float*)alloc((size_t)N_*EH_*4);
  float* g     = (float*)alloc((size_t)N_*EH_*4);
  float* xhxt  = (float*)alloc((size_t)N_*200*4);
  float* pht   = (float*)alloc((size_t)N_*8*4);
  float* s1p   = (float*)alloc((size_t)E_*4);
  float* s2p   = (float*)alloc((size_t)E_*4);
  float* xr    = (float*)alloc((size_t)R_*RH_*4);
  float* xr_part=(float*)alloc((size_t)NC_*R_*RH_*4);
  float* st16  = (float*)alloc((size_t)N_*16*4);
  float* sr8   = (float*)alloc((size_t)R_*8*4);
  float* shp   = (float*)alloc((size_t)E_*4);
  float* stp   = (float*)alloc((size_t)E_*4);
  float* gg16  = (float*)alloc((size_t)N_*16*4);
  float* agp   = (float*)alloc((size_t)EALL_*4);
  unsigned short* xb  = (unsigned short*)alloc((size_t)N_*XBS_*2);
  unsigned short* xeb = (unsigned short*)alloc((size_t)N_*XEBS_*2);
  unsigned short* w1b = (unsigned short*)alloc((size_t)EH_*KP_*2);
  unsigned short* w2b = (unsigned short*)alloc((size_t)EH_*KP_*2);
  unsigned short* wcb = (unsigned short*)alloc((size_t)200*KP_*2);

  hipMemsetAsync(base + z0, 0, z1 - z0, stream);

  const int TB = 256;
  const int TOT = EALL_ + 2*E_;
  int gTOT  = (TOT + TB - 1)/TB;
  int gN    = (N_ + TB - 1)/TB;
  int gPKX  = (N_*80 + TB - 1)/TB;
  const int WTOT = 2*EH_*KP_ + 200*KP_;

  // weight packs (single launch)
  k_pack_weights<<<(WTOT + TB - 1)/TB, TB, 0, stream>>>(hw1_w, hw2_w, e2r_wh, e2r_wt,
                                                        w1b, w2b, wcb);

  // CSR build: rel via block counting sort
  k_relhist<<<NBR_, 256, 0, stream>>>(rel, Hrel);
  k_relscan<<<1, 256, 0, stream>>>(Hrel, off_rel);
  k_relscatter<<<NBR_, 256, 0, stream>>>(rel, hi, ti, Hrel, hr, tr);

  // CSR build: dest/h/t (hierarchical scan)
  k_count3<<<gTOT, TB, 0, stream>>>(ia, hi, ti, cnt_dest, cnt_h, cnt_t);
  k_scanA<<<3*NSB_, 256, 0, stream>>>(cnt_dest, cnt_h, cnt_t, bsum);
  k_scanB<<<1, 64, 0, stream>>>(bsum, off_dest, off_h, off_t);
  k_scanC<<<3*NSB_, 256, 0, stream>>>(cnt_dest, cnt_h, cnt_t, bsum,
                                      off_dest, off_h, off_t, dis);
  k_scatter3<<<gTOT, TB, 0, stream>>>(ja, ia, rel, hi, ti,
                                      off_dest, off_h, off_t,
                                      cur_dest, cur_h, cur_t,
                                      dis, j_dest, wj, relh, relt);

  // GCN + highway block 1
  k_pack_x<<<gPKX, TB, 0, stream>>>((const float4*)x_e, EH4, xb);
  gemm_mfma(xb, w1b, g, EH_, N_, EH_, stream);
  k_gcn4<<<N_, 64, 0, stream>>>(off_dest, j_dest, wj, dis, xb, (float4*)y);
  k_highway3<<<(N_*EH4 + TB - 1)/TB, TB, 0, stream>>>((const float4*)x_e, EH4, (const float4*)y,
                                                      (const float4*)g, hw1_b, (float4*)out, xb);
  // block 2
  gemm_mfma(xb, w2b, g, EH_, N_, EH_, stream);
  k_gcn4<<<N_, 64, 0, stream>>>(off_dest, j_dest, wj, dis, xb, (float4*)y);
  k_highway3<<<(N_*EH4 + TB - 1)/TB, TB, 0, stream>>>((const float4*)out, LD4, (const float4*)y,
                                                      (const float4*)g, hw2_b, (float4*)out, xb);

  // E2R
  gemm_mfma(xb, wcb, xhxt, 200, N_, 200, stream);
  k_pproj<<<gN, TB, 0, stream>>>(xhxt, e2r_ah, e2r_at, (float4*)pht);
  k_fold_rel2<<<R_, 256, 0, stream>>>(off_rel, hr, tr, (const float4*)pht, s1p, s2p);
  k_e2r_agg3<<<dim3(R_, NC_), 64, 0, stream>>>(off_rel, hr, tr, s1p, s2p,
                                               (const float4*)xhxt, (float4*)xr_part);
  k_e2r_red2<<<R_, 64, 0, stream>>>((const float4*)xr_part, (float4*)xr, r2e_ar, sr8);

  // R2E
  k_dots16<<<(N_+15)/16, 256, 0, stream>>>(out, OUTD_, EH_, r2e_ah, r2e_at, st16, N_);
  k_fold_ht2<<<(N_+1)/2, 256, 0, stream>>>(off_h, off_t, relh, relt, st16, sr8, shp, stp);
  k_r2e_agg2b<<<N_, 128, 0, stream>>>(off_h, off_t, relh, relt, shp, stp,
                                      (const float4*)xr, (float4*)out, xeb);

  // GAT
  k_dots16<<<(N_+15)/16, 256, 0, stream>>>(out, OUTD_, X2D_, gat_ai, gat_aj, gg16, N_);
  k_fold_gat2<<<(N_+3)/4, 256, 0, stream>>>(off_dest, j_dest, gg16, agp);
  k_gat_agg4<<<N_, 128, 0, stream>>>(off_dest, j_dest, agp, xb, xeb, (float4*)out);
}

// Round 9
// 624.940 us; speedup vs baseline: 3.7510x; 1.0429x over previous
//
#include <hip/hip_runtime.h>
#include <math.h>

constexpr int N_    = 30000;
constexpr int E_    = 200000;
constexpr int EALL_ = 400000;
constexpr int R_    = 500;
constexpr int EH_   = 300;
constexpr int RH_   = 100;
constexpr int OUTD_ = 1000;
constexpr int LD4   = OUTD_/4;  // 250
constexpr int EH4   = EH_/4;    // 75
constexpr int RH4   = RH_/4;    // 25
constexpr int NC_   = 16;       // chunks per relation for e2r agg
constexpr int XBS_  = 320;      // bf16 row stride for x tables (zero-padded K for MFMA)
constexpr int XEBS_ = 200;      // bf16 row stride for xe table
constexpr int KP_   = 320;      // padded K for MFMA weights
constexpr int NBR_  = 64;       // blocks for rel counting sort
constexpr int PERB_ = (E_ + NBR_ - 1)/NBR_;  // 3125 edges per block
constexpr int SCB_  = 2048;     // elements per scan block
constexpr int NSB_  = (N_ + SCB_ - 1)/SCB_;  // 15 scan blocks per array
constexpr int SCNP_ = NSB_*SCB_;             // 30720 padded length

typedef __attribute__((ext_vector_type(4))) float f32x4;
typedef __attribute__((ext_vector_type(8))) short s16x8;

__device__ __forceinline__ float lrelu_(float v){ return v > 0.f ? v : 0.01f*v; }
__device__ __forceinline__ float sig_(float z){ return 1.f/(1.f + expf(-z)); }
__device__ __forceinline__ unsigned short f2bf_(float f){
  unsigned int u = __float_as_uint(f);
  unsigned int r = (u + 0x7FFFu + ((u >> 16) & 1u)) >> 16;
  return (unsigned short)r;
}
__device__ __forceinline__ float bf2f_(unsigned short h){
  return __uint_as_float(((unsigned int)h) << 16);
}

// ---------------- CSR build: dest/h/t via atomics ----------------
__global__ void k_count3(const int* __restrict__ ia,
                         const int* __restrict__ hi, const int* __restrict__ ti,
                         int* cd, int* ch, int* ct){
  int idx = blockIdx.x*blockDim.x + threadIdx.x;
  if (idx < EALL_) { atomicAdd(&cd[ia[idx]], 1); return; }
  idx -= EALL_;
  if (idx < E_) { atomicAdd(&ch[hi[idx]], 1); return; }
  idx -= E_;
  if (idx < E_) { atomicAdd(&ct[ti[idx]], 1); return; }
}

// ---------------- hierarchical exclusive scan ----------------
__global__ void k_scanA(const int* __restrict__ c0, const int* __restrict__ c1,
                        const int* __restrict__ c2, int* __restrict__ bsum){
  int arr = blockIdx.x / NSB_, b = blockIdx.x - arr*NSB_;
  const int* c = arr == 0 ? c0 : (arr == 1 ? c1 : c2);
  int t = threadIdx.x;
  const int4* c4 = reinterpret_cast<const int4*>(c + b*SCB_ + t*8);
  int4 u0 = c4[0], u1 = c4[1];
  int acc = u0.x+u0.y+u0.z+u0.w + u1.x+u1.y+u1.z+u1.w;
  __shared__ int red[256];
  red[t] = acc;
  __syncthreads();
  for (int o = 128; o > 0; o >>= 1){
    if (t < o) red[t] += red[t+o];
    __syncthreads();
  }
  if (t == 0) bsum[arr*NSB_ + b] = red[0];
}

__global__ void k_scanB(int* __restrict__ bsum, int* o0, int* o1, int* o2){
  int t = threadIdx.x;
  if (t < 3){
    int run = 0;
    for (int b = 0; b < NSB_; ++b){ int v = bsum[t*NSB_ + b]; bsum[t*NSB_ + b] = run; run += v; }
    int* o = t == 0 ? o0 : (t == 1 ? o1 : o2);
    o[N_] = run;
  }
}

__global__ void k_scanC(const int* __restrict__ c0, const int* __restrict__ c1,
                        const int* __restrict__ c2, const int* __restrict__ bsum,
                        int* o0, int* o1, int* o2, float* __restrict__ dis){
  int arr = blockIdx.x / NSB_, b = blockIdx.x - arr*NSB_;
  const int* c = arr == 0 ? c0 : (arr == 1 ? c1 : c2);
  int* o = arr == 0 ? o0 : (arr == 1 ? o1 : o2);
  int t = threadIdx.x;
  int base = b*SCB_ + t*8;
  const int4* c4 = reinterpret_cast<const int4*>(c + base);
  int4 u0 = c4[0], u1 = c4[1];
  int v[8] = {u0.x,u0.y,u0.z,u0.w,u1.x,u1.y,u1.z,u1.w};
  int tot = v[0]+v[1]+v[2]+v[3]+v[4]+v[5]+v[6]+v[7];
  __shared__ int sc[256];
  sc[t] = tot;
  __syncthreads();
  for (int off = 1; off < 256; off <<= 1){
    int add = (t >= off) ? sc[t-off] : 0;
    __syncthreads();
    sc[t] += add;
    __syncthreads();
  }
  int run = bsum[arr*NSB_ + b] + (t ? sc[t-1] : 0);
  #pragma unroll
  for (int i = 0; i < 8; ++i){
    int idx = base + i;
    o[idx] = run;
    if (arr == 0) dis[idx] = v[i] > 0 ? rsqrtf((float)v[i]) : 0.f;
    run += v[i];
  }
}

__global__ void k_scatter3(const int* __restrict__ ja, const int* __restrict__ ia,
                           const int* __restrict__ rel, const int* __restrict__ hi,
                           const int* __restrict__ ti,
                           const int* od, const int* oh, const int* ot,
                           int* curd, int* curh, int* curt,
                           const float* __restrict__ dis,
                           int* j_dest, float* wj,
                           int* relh, int* relt){
  int idx = blockIdx.x*blockDim.x + threadIdx.x;
  if (idx < EALL_){
    int e = idx, s = ia[e];
    int p = od[s] + atomicAdd(&curd[s], 1);
    int j = ja[e];
    j_dest[p] = j; wj[p] = dis[j]; return;
  }
  idx -= EALL_;
  if (idx < E_){
    int e = idx, s = hi[e];
    int p = oh[s] + atomicAdd(&curh[s], 1);
    relh[p] = rel[e]; return;
  }
  idx -= E_;
  if (idx < E_){
    int e = idx, s = ti[e];
    int p = ot[s] + atomicAdd(&curt[s], 1);
    relt[p] = rel[e]; return;
  }
}

// ---------------- rel CSR: block counting sort ----------------
__global__ void k_relhist(const int* __restrict__ rel, int* __restrict__ H){
  __shared__ int h[R_];
  int b = blockIdx.x, tid = threadIdx.x;
  for (int i = tid; i < R_; i += 256) h[i] = 0;
  __syncthreads();
  int s = b*PERB_, e = min(s + PERB_, E_);
  for (int i = s + tid; i < e; i += 256) atomicAdd(&h[rel[i]], 1);
  __syncthreads();
  for (int i = tid; i < R_; i += 256) H[b*R_ + i] = h[i];
}

__global__ void k_relscan(int* __restrict__ H, int* __restrict__ off_rel){
  __shared__ int tot[R_];
  __shared__ int sc[256];
  int tid = threadIdx.x;
  for (int r = tid; r < R_; r += 256){
    int acc = 0;
    for (int b = 0; b < NBR_; ++b){ int v = H[b*R_ + r]; H[b*R_ + r] = acc; acc += v; }
    tot[r] = acc;
  }
  __syncthreads();
  int r0 = tid*2;
  int a0 = (r0 < R_) ? tot[r0] : 0;
  int a1 = (r0+1 < R_) ? tot[r0+1] : 0;
  sc[tid] = a0 + a1;
  __syncthreads();
  for (int off = 1; off < 256; off <<= 1){
    int add = (tid >= off) ? sc[tid-off] : 0;
    __syncthreads();
    sc[tid] += add;
    __syncthreads();
  }
  int run = tid ? sc[tid-1] : 0;
  if (r0 < R_)   off_rel[r0]   = run;
  if (r0+1 < R_) off_rel[r0+1] = run + a0;
  if (tid == 255) off_rel[R_] = sc[255];
  __syncthreads();
  for (int r = tid; r < R_; r += 256){
    int o = off_rel[r];
    for (int b = 0; b < NBR_; ++b) H[b*R_ + r] += o;
  }
}

__global__ void k_relscatter(const int* __restrict__ rel, const int* __restrict__ hi,
                             const int* __restrict__ ti, const int* __restrict__ H,
                             int* __restrict__ hr, int* __restrict__ tr){
  __shared__ int cur[R_];
  int b = blockIdx.x, tid = threadIdx.x;
  for (int i = tid; i < R_; i += 256) cur[i] = H[b*R_ + i];
  __syncthreads();
  int s = b*PERB_, e = min(s + PERB_, E_);
  for (int i = s + tid; i < e; i += 256){
    int r = rel[i];
    int p = atomicAdd(&cur[r], 1);
    hr[p] = hi[i]; tr[p] = ti[i];
  }
}

// ---------------- bf16 pack ----------------
__global__ void k_pack_x(const float4* __restrict__ X, int ldx4,
                         unsigned short* __restrict__ xb){
  int idx = blockIdx.x*blockDim.x + threadIdx.x;   // N_*80
  if (idx >= N_*80) return;
  int n = idx / 80, c = idx - n*80;
  ushort4 o = make_ushort4(0,0,0,0);
  if (c < EH4){
    float4 v = X[(size_t)n*ldx4 + c];
    o.x = f2bf_(v.x); o.y = f2bf_(v.y); o.z = f2bf_(v.z); o.w = f2bf_(v.w);
  }
  *reinterpret_cast<ushort4*>(&xb[(size_t)n*XBS_ + c*4]) = o;
}

__global__ void k_pack_weights(const float* __restrict__ w1, const float* __restrict__ w2,
                               const float* __restrict__ wh, const float* __restrict__ wt,
                               unsigned short* w1b, unsigned short* w2b,
                               unsigned short* wcb){
  int idx = blockIdx.x*blockDim.x + threadIdx.x;
  if (idx < EH_*KP_){
    int n = idx/KP_, k = idx - n*KP_;
    w1b[idx] = (k < EH_) ? f2bf_(w1[(size_t)n*EH_ + k]) : (unsigned short)0;
    return;
  }
  idx -= EH_*KP_;
  if (idx < EH_*KP_){
    int n = idx/KP_, k = idx - n*KP_;
    w2b[idx] = (k < EH_) ? f2bf_(w2[(size_t)n*EH_ + k]) : (unsigned short)0;
    return;
  }
  idx -= EH_*KP_;
  if (idx < 200*KP_){
    int n = idx/KP_, k = idx - n*KP_;
    wcb[idx] = (k < EH_) ? f2bf_((n < 100) ? wh[(size_t)n*EH_ + k] : wt[(size_t)(n-100)*EH_ + k])
                         : (unsigned short)0;
  }
}

// ---------------- MFMA GEMM ----------------
__global__ __launch_bounds__(256) void k_gemm_mfma(
    const unsigned short* __restrict__ Ab,
    const unsigned short* __restrict__ Wb,
    float* __restrict__ C, int ldc, int M, int Nn){
  constexpr int WS = 328;
  constexpr int AS = 40;
  __shared__ unsigned short Ws[64*WS];
  __shared__ unsigned short As[128*AS];
  int tid = threadIdx.x;
  int lane = tid & 63, wave = tid >> 6;
  int wm = wave & 1, wn = wave >> 1;
  int m0 = blockIdx.x*128, n0 = blockIdx.y*64;

  for (int c = tid; c < 64*(KP_/8); c += 256){
    int n = c / (KP_/8), k8 = (c % (KP_/8))*8;
    s16x8 v = {0,0,0,0,0,0,0,0};
    if (n0 + n < Nn)
      v = *reinterpret_cast<const s16x8*>(&Wb[(size_t)(n0+n)*KP_ + k8]);
    *reinterpret_cast<s16x8*>(&Ws[n*WS + k8]) = v;
  }

  f32x4 acc[4][2] = {};
  int kf = (lane >> 4)*8;
  int rA = lane & 15;
  for (int k0 = 0; k0 < KP_; k0 += 32){
    __syncthreads();
    for (int c = tid; c < 128*4; c += 256){
      int r = c >> 2, k8 = (c & 3)*8;
      s16x8 v = {0,0,0,0,0,0,0,0};
      if (m0 + r < M)
        v = *reinterpret_cast<const s16x8*>(&Ab[(size_t)(m0+r)*XBS_ + k0 + k8]);
      *reinterpret_cast<s16x8*>(&As[r*AS + k8]) = v;
    }
    __syncthreads();
    s16x8 afr[4], bfr[2];
    #pragma unroll
    for (int mf = 0; mf < 4; ++mf)
      afr[mf] = *reinterpret_cast<const s16x8*>(&As[(wm*64 + mf*16 + rA)*AS + kf]);
    #pragma unroll
    for (int nf = 0; nf < 2; ++nf)
      bfr[nf] = *reinterpret_cast<const s16x8*>(&Ws[(wn*32 + nf*16 + rA)*WS + k0 + kf]);
    #pragma unroll
    for (int mf = 0; mf < 4; ++mf)
      #pragma unroll
      for (int nf = 0; nf < 2; ++nf)
        acc[mf][nf] = __builtin_amdgcn_mfma_f32_16x16x32_bf16(afr[mf], bfr[nf], acc[mf][nf], 0, 0, 0);
  }
  int col0 = n0 + wn*32 + (lane & 15);
  int rbase = m0 + wm*64 + (lane >> 4)*4;
  #pragma unroll
  for (int mf = 0; mf < 4; ++mf){
    #pragma unroll
    for (int nf = 0; nf < 2; ++nf){
      int col = col0 + nf*16;
      if (col < Nn){
        #pragma unroll
        for (int r = 0; r < 4; ++r){
          int row = rbase + mf*16 + r;
          if (row < M) C[(size_t)row*ldc + col] = acc[mf][nf][r];
        }
      }
    }
  }
}

// ---------------- fused GCN gather + highway + bf16 repack ----------------
// 1 wave per node. gathers from xsrc, highway vs Xold, writes Xn (f32) + xdst (bf16)
__global__ void k_gcn5(const int* __restrict__ off, const int* __restrict__ jd,
                       const float* __restrict__ wj, const float* __restrict__ dis,
                       const unsigned short* __restrict__ xsrc,
                       const float4* __restrict__ Xold, int ldo4,
                       const float4* __restrict__ G, const float* __restrict__ b,
                       float4* __restrict__ Xn, unsigned short* __restrict__ xdst){
  __shared__ int js[64];
  __shared__ float ws[64];
  int n = blockIdx.x, lane = threadIdx.x;   // 64
  int s = off[n], t = off[n+1];
  bool two = lane < (EH4 - 64);             // lanes 0..10 own chunk 64+lane
  float4 a0 = make_float4(0.f,0.f,0.f,0.f);
  float4 a1 = make_float4(0.f,0.f,0.f,0.f);
  for (int base = s; base < t; base += 64){
    int m = min(64, t - base);
    __syncthreads();
    if (lane < m){ js[lane] = jd[base+lane]; ws[lane] = wj[base+lane]; }
    __syncthreads();
    int q = 0;
    for (; q + 3 < m; q += 4){
      size_t r0 = (size_t)js[q]*XBS_,   r1 = (size_t)js[q+1]*XBS_;
      size_t r2 = (size_t)js[q+2]*XBS_, r3 = (size_t)js[q+3]*XBS_;
      float w0 = ws[q], w1 = ws[q+1], w2 = ws[q+2], w3 = ws[q+3];
      ushort4 u0 = *reinterpret_cast<const ushort4*>(&xsrc[r0 + lane*4]);
      ushort4 u1 = *reinterpret_cast<const ushort4*>(&xsrc[r1 + lane*4]);
      ushort4 u2 = *reinterpret_cast<const ushort4*>(&xsrc[r2 + lane*4]);
      ushort4 u3 = *reinterpret_cast<const ushort4*>(&xsrc[r3 + lane*4]);
      a0.x += w0*bf2f_(u0.x)+w1*bf2f_(u1.x)+w2*bf2f_(u2.x)+w3*bf2f_(u3.x);
      a0.y += w0*bf2f_(u0.y)+w1*bf2f_(u1.y)+w2*bf2f_(u2.y)+w3*bf2f_(u3.y);
      a0.z += w0*bf2f_(u0.z)+w1*bf2f_(u1.z)+w2*bf2f_(u2.z)+w3*bf2f_(u3.z);
      a0.w += w0*bf2f_(u0.w)+w1*bf2f_(u1.w)+w2*bf2f_(u2.w)+w3*bf2f_(u3.w);
      if (two){
        ushort4 v0 = *reinterpret_cast<const ushort4*>(&xsrc[r0 + 256 + lane*4]);
        ushort4 v1 = *reinterpret_cast<const ushort4*>(&xsrc[r1 + 256 + lane*4]);
        ushort4 v2 = *reinterpret_cast<const ushort4*>(&xsrc[r2 + 256 + lane*4]);
        ushort4 v3 = *reinterpret_cast<const ushort4*>(&xsrc[r3 + 256 + lane*4]);
        a1.x += w0*bf2f_(v0.x)+w1*bf2f_(v1.x)+w2*bf2f_(v2.x)+w3*bf2f_(v3.x);
        a1.y += w0*bf2f_(v0.y)+w1*bf2f_(v1.y)+w2*bf2f_(v2.y)+w3*bf2f_(v3.y);
        a1.z += w0*bf2f_(v0.z)+w1*bf2f_(v1.z)+w2*bf2f_(v2.z)+w3*bf2f_(v3.z);
        a1.w += w0*bf2f_(v0.w)+w1*bf2f_(v1.w)+w2*bf2f_(v2.w)+w3*bf2f_(v3.w);
      }
    }
    for (; q < m; ++q){
      size_t r0 = (size_t)js[q]*XBS_;
      float w0 = ws[q];
      ushort4 u0 = *reinterpret_cast<const ushort4*>(&xsrc[r0 + lane*4]);
      a0.x += w0*bf2f_(u0.x); a0.y += w0*bf2f_(u0.y);
      a0.z += w0*bf2f_(u0.z); a0.w += w0*bf2f_(u0.w);
      if (two){
        ushort4 v0 = *reinterpret_cast<const ushort4*>(&xsrc[r0 + 256 + lane*4]);
        a1.x += w0*bf2f_(v0.x); a1.y += w0*bf2f_(v0.y);
        a1.z += w0*bf2f_(v0.z); a1.w += w0*bf2f_(v0.w);
      }
    }
  }
  float dn = dis[n];
  // epilogue: highway on chunk lane (and 64+lane)
  {
    int c = lane;
    float4 yv;
    yv.x = fmaxf(dn*a0.x, 0.f); yv.y = fmaxf(dn*a0.y, 0.f);
    yv.z = fmaxf(dn*a0.z, 0.f); yv.w = fmaxf(dn*a0.w, 0.f);
    float4 g4 = G[(size_t)n*EH4 + c];
    float4 b4 = reinterpret_cast<const float4*>(b)[c];
    float4 xo = Xold[(size_t)n*ldo4 + c];
    float gx; float4 r;
    gx = sig_(g4.x + b4.x); r.x = gx*yv.x + (1.f-gx)*xo.x;
    gx = sig_(g4.y + b4.y); r.y = gx*yv.y + (1.f-gx)*xo.y;
    gx = sig_(g4.z + b4.z); r.z = gx*yv.z + (1.f-gx)*xo.z;
    gx = sig_(g4.w + b4.w); r.w = gx*yv.w + (1.f-gx)*xo.w;
    Xn[(size_t)n*LD4 + c] = r;
    ushort4 o;
    o.x = f2bf_(r.x); o.y = f2bf_(r.y); o.z = f2bf_(r.z); o.w = f2bf_(r.w);
    *reinterpret_cast<ushort4*>(&xdst[(size_t)n*XBS_ + c*4]) = o;
  }
  if (two){
    int c = 64 + lane;
    float4 yv;
    yv.x = fmaxf(dn*a1.x, 0.f); yv.y = fmaxf(dn*a1.y, 0.f);
    yv.z = fmaxf(dn*a1.z, 0.f); yv.w = fmaxf(dn*a1.w, 0.f);
    float4 g4 = G[(size_t)n*EH4 + c];
    float4 b4 = reinterpret_cast<const float4*>(b)[c];
    float4 xo = Xold[(size_t)n*ldo4 + c];
    float gx; float4 r;
    gx = sig_(g4.x + b4.x); r.x = gx*yv.x + (1.f-gx)*xo.x;
    gx = sig_(g4.y + b4.y); r.y = gx*yv.y + (1.f-gx)*xo.y;
    gx = sig_(g4.z + b4.z); r.z = gx*yv.z + (1.f-gx)*xo.z;
    gx = sig_(g4.w + b4.w); r.w = gx*yv.w + (1.f-gx)*xo.w;
    Xn[(size_t)n*LD4 + c] = r;
    ushort4 o;
    o.x = f2bf_(r.x); o.y = f2bf_(r.y); o.z = f2bf_(r.z); o.w = f2bf_(r.w);
    *reinterpret_cast<ushort4*>(&xdst[(size_t)n*XBS_ + c*4]) = o;
  } else if (lane < 16){
    // lanes 11..15 zero the K-pad chunks 75..79
    ushort4 z = make_ushort4(0,0,0,0);
    *reinterpret_cast<ushort4*>(&xdst[(size_t)n*XBS_ + (64+lane)*4]) = z;
  }
}

// ---------------- E2R projections -> pht[N][8] ----------------
__global__ void k_pproj(const float* __restrict__ xhxt,
                        const float* __restrict__ ah, const float* __restrict__ at,
                        float4* __restrict__ pht){
  int n = blockIdx.x*blockDim.x + threadIdx.x;
  if (n >= N_) return;
  float a0=0,a1=0,b0=0,b1=0,c0=0,c1=0,d0=0,d1=0;
  const float* xh = xhxt + (size_t)n*200;
  const float* xt = xh + 100;
  for (int f = 0; f < RH_; ++f) {
    float vh = xh[f], vt = xt[f];
    float w0 = ah[f], w1 = ah[RH_+f], u0 = at[f], u1 = at[RH_+f];
    a0 += vh*w0; a1 += vh*w1;
    b0 += vt*u0; b1 += vt*u1;
    c0 += vt*w0; c1 += vt*w1;
    d0 += vh*u0; d1 += vh*u1;
  }
  pht[(size_t)n*2]     = make_float4(a0, a1, c0, c1);  // h-side: p1 | p3
  pht[(size_t)n*2 + 1] = make_float4(b0, b1, d0, d1);  // t-side: p2 | p4
}

// ---------------- E2R fold ----------------
__global__ void k_fold_rel2(const int* __restrict__ off,
                            const int* __restrict__ hr, const int* __restrict__ tr,
                            const float4* __restrict__ pht,
                            float* __restrict__ s1p, float* __restrict__ s2p){
  __shared__ float4 redm[4];
  __shared__ float4 reds[4];
  int r = blockIdx.x;
  int tid = threadIdx.x, lane = tid & 63, w = tid >> 6;
  int s = off[r], e = off[r+1];
  float4 mx = make_float4(-1e30f,-1e30f,-1e30f,-1e30f);
  for (int p = s + tid; p < e; p += 256){
    float4 ph = pht[(size_t)hr[p]*2];
    float4 pt = pht[(size_t)tr[p]*2 + 1];
    mx.x = fmaxf(mx.x, lrelu_(ph.x + pt.x));
    mx.y = fmaxf(mx.y, lrelu_(ph.y + pt.y));
    mx.z = fmaxf(mx.z, lrelu_(ph.z + pt.z));
    mx.w = fmaxf(mx.w, lrelu_(ph.w + pt.w));
  }
  #pragma unroll
  for (int o = 1; o < 64; o <<= 1){
    mx.x = fmaxf(mx.x, __shfl_xor(mx.x, o));
    mx.y = fmaxf(mx.y, __shfl_xor(mx.y, o));
    mx.z = fmaxf(mx.z, __shfl_xor(mx.z, o));
    mx.w = fmaxf(mx.w, __shfl_xor(mx.w, o));
  }
  if (lane == 0) redm[w] = mx;
  __syncthreads();
  float4 m;
  m.x = fmaxf(fmaxf(redm[0].x, redm[1].x), fmaxf(redm[2].x, redm[3].x));
  m.y = fmaxf(fmaxf(redm[0].y, redm[1].y), fmaxf(redm[2].y, redm[3].y));
  m.z = fmaxf(fmaxf(redm[0].z, redm[1].z), fmaxf(redm[2].z, redm[3].z));
  m.w = fmaxf(fmaxf(redm[0].w, redm[1].w), fmaxf(redm[2].w, redm[3].w));
  float4 sm = make_float4(0.f,0.f,0.f,0.f);
  for (int p = s + tid; p < e; p += 256){
    float4 ph = pht[(size_t)hr[p]*2];
    float4 pt = pht[(size_t)tr[p]*2 + 1];
    sm.x += expf(lrelu_(ph.x + pt.x) - m.x);
    sm.y += expf(lrelu_(ph.y + pt.y) - m.y);
    sm.z += expf(lrelu_(ph.z + pt.z) - m.z);
    sm.w += expf(lrelu_(ph.w + pt.w) - m.w);
  }
  #pragma unroll
  for (int o = 1; o < 64; o <<= 1){
    sm.x += __shfl_xor(sm.x, o);
    sm.y += __shfl_xor(sm.y, o);
    sm.z += __shfl_xor(sm.z, o);
    sm.w += __shfl_xor(sm.w, o);
  }
  if (lane == 0) reds[w] = sm;
  __syncthreads();
  float4 sv;
  sv.x = reds[0].x + reds[1].x + reds[2].x + reds[3].x;
  sv.y = reds[0].y + reds[1].y + reds[2].y + reds[3].y;
  sv.z = reds[0].z + reds[1].z + reds[2].z + reds[3].z;
  sv.w = reds[0].w + reds[1].w + reds[2].w + reds[3].w;
  float4 inv;
  inv.x = 1.f/(sv.x + 1e-16f); inv.y = 1.f/(sv.y + 1e-16f);
  inv.z = 1.f/(sv.z + 1e-16f); inv.w = 1.f/(sv.w + 1e-16f);
  for (int p = s + tid; p < e; p += 256){
    float4 ph = pht[(size_t)hr[p]*2];
    float4 pt = pht[(size_t)tr[p]*2 + 1];
    s1p[p] = expf(lrelu_(ph.x + pt.x) - m.x)*inv.x + expf(lrelu_(ph.y + pt.y) - m.y)*inv.y;
    s2p[p] = expf(lrelu_(ph.z + pt.z) - m.z)*inv.z + expf(lrelu_(ph.w + pt.w) - m.w)*inv.w;
  }
}

// ---------------- R2E fold ----------------
__global__ void k_fold_ht2(const int* __restrict__ offh, const int* __restrict__ offt,
                           const int* __restrict__ relh, const int* __restrict__ relt,
                           const float* __restrict__ st16, const float* __restrict__ sr8,
                           float* __restrict__ shp, float* __restrict__ stp){
  int w = threadIdx.x >> 6, lane = threadIdx.x & 63;
  int n = blockIdx.x*2 + (w >> 1);
  if (n >= N_) return;
  int side = w & 1;
  const int* off = side ? offt : offh;
  const int* rl  = side ? relt : relh;
  float* op = side ? stp : shp;
  int k = lane & 7, g = lane >> 3;
  float cst = st16[(size_t)n*16 + side*8 + k];
  int s = off[n], e = off[n+1];
  float m = -1e30f;
  for (int p = s + g; p < e; p += 8)
    m = fmaxf(m, lrelu_(cst + sr8[(size_t)rl[p]*8 + k]));
  #pragma unroll
  for (int o = 8; o < 64; o <<= 1) m = fmaxf(m, __shfl_xor(m, o));
  float sum = 0.f;
  for (int p = s + g; p < e; p += 8)
    sum += expf(lrelu_(cst + sr8[(size_t)rl[p]*8 + k]) - m);
  #pragma unroll
  for (int o = 8; o < 64; o <<= 1) sum += __shfl_xor(sum, o);
  float inv = 1.f / (sum + 1e-16f);
  for (int p = s + g; p < e; p += 8){
    float t = expf(lrelu_(cst + sr8[(size_t)rl[p]*8 + k]) - m) * inv;
    #pragma unroll
    for (int o = 1; o < 8; o <<= 1) t += __shfl_xor(t, o);
    if (k == 0) op[p] = t;
  }
}

// ---------------- GAT fold ----------------
__global__ void k_fold_gat2(const int* __restrict__ off, const int* __restrict__ jd,
                            const float* __restrict__ gg16, float* __restrict__ agp){
  int w = threadIdx.x >> 6, lane = threadIdx.x & 63;
  int n = blockIdx.x*4 + w;
  if (n >= N_) return;
  int k = lane & 7, g = lane >> 3;
  float cst = gg16[(size_t)n*16 + k];
  int s = off[n], e = off[n+1];
  float m = -1e30f;
  for (int p = s + g; p < e; p += 8)
    m = fmaxf(m, lrelu_(cst + gg16[(size_t)jd[p]*16 + 8 + k]));
  #pragma unroll
  for (int o = 8; o < 64; o <<= 1) m = fmaxf(m, __shfl_xor(m, o));
  float sum = 0.f;
  for (int p = s + g; p < e; p += 8)
    sum += expf(lrelu_(cst + gg16[(size_t)jd[p]*16 + 8 + k]) - m);
  #pragma unroll
  for (int o = 8; o < 64; o <<= 1) sum += __shfl_xor(sum, o);
  float inv = 1.f / (sum + 1e-16f);
  for (int p = s + g; p < e; p += 8){
    float t = expf(lrelu_(cst + gg16[(size_t)jd[p]*16 + 8 + k]) - m) * inv;
    #pragma unroll
    for (int o = 1; o < 8; o <<= 1) t += __shfl_xor(t, o);
    if (k == 0) agp[p] = t;
  }
}

// ---------------- E2R aggregate ----------------
__global__ void k_e2r_agg3(const int* __restrict__ off,
                           const int* __restrict__ hr, const int* __restrict__ tr,
                           const float* __restrict__ s1p, const float* __restrict__ s2p,
                           const float4* __restrict__ xhxt4, float4* __restrict__ xr_part){
  int r = blockIdx.x, c = blockIdx.y;
  int lane = threadIdx.x;           // 64
  int side = lane >> 5, fl = lane & 31;
  int s = off[r], e = off[r+1];
  int len = e - s;
  int per = (len + NC_ - 1)/NC_;
  int cs = s + c*per, ce = min(cs + per, e);
  float4 acc = make_float4(0.f,0.f,0.f,0.f);
  if (fl < RH4){
    const int* idx = side ? tr : hr;
    const float* wv = side ? s2p : s1p;
    int fofs = side ? 25 + fl : fl;
    int p = cs;
    for (; p + 1 < ce; p += 2){
      float a0 = wv[p], a1 = wv[p+1];
      float4 v0 = xhxt4[(size_t)idx[p]*50 + fofs];
      float4 v1 = xhxt4[(size_t)idx[p+1]*50 + fofs];
      acc.x += a0*v0.x + a1*v1.x; acc.y += a0*v0.y + a1*v1.y;
      acc.z += a0*v0.z + a1*v1.z; acc.w += a0*v0.w + a1*v1.w;
    }
    if (p < ce){
      float a0 = wv[p];
      float4 v0 = xhxt4[(size_t)idx[p]*50 + fofs];
      acc.x += a0*v0.x; acc.y += a0*v0.y; acc.z += a0*v0.z; acc.w += a0*v0.w;
    }
  }
  float4 oth;
  oth.x = __shfl_xor(acc.x, 32); oth.y = __shfl_xor(acc.y, 32);
  oth.z = __shfl_xor(acc.z, 32); oth.w = __shfl_xor(acc.w, 32);
  if (side == 0 && fl < RH4){
    float4 o = make_float4(acc.x+oth.x, acc.y+oth.y, acc.z+oth.z, acc.w+oth.w);
    xr_part[((size_t)c*R_ + r)*RH4 + fl] = o;
  }
}

// reduce xr_part -> xr AND compute sr8
__global__ void k_e2r_red2(const float4* __restrict__ xr_part, float4* __restrict__ xr4,
                           const float* __restrict__ ar, float* __restrict__ sr8){
  __shared__ float row[RH_];
  int r = blockIdx.x, lane = threadIdx.x;   // 64
  if (lane < RH4){
    float4 a = make_float4(0.f,0.f,0.f,0.f);
    #pragma unroll
    for (int c = 0; c < NC_; ++c){
      float4 v = xr_part[((size_t)c*R_ + r)*RH4 + lane];
      a.x += v.x; a.y += v.y; a.z += v.z; a.w += v.w;
    }
    a.x *= 0.25f; a.y *= 0.25f; a.z *= 0.25f; a.w *= 0.25f;
    xr4[(size_t)r*RH4 + lane] = a;
    row[lane*4]   = a.x; row[lane*4+1] = a.y;
    row[lane*4+2] = a.z; row[lane*4+3] = a.w;
  }
  __syncthreads();
  int h = lane & 7, gk = lane >> 3;
  float acc = 0.f;
  for (int k = gk; k < RH_; k += 8) acc += row[k]*ar[(size_t)h*RH_ + k];
  #pragma unroll
  for (int o = 8; o < 64; o <<= 1) acc += __shfl_xor(acc, o);
  if (lane < 8) sr8[(size_t)r*8 + lane] = acc;
}

// ---------------- 16-head row dots from bf16 table ----------------
// out16[r][tx] (+)= sum_k X[r][c0..]*w[tx][colofs + c0..]; wA rows 0..7, wB rows 8..15
__global__ void k_dots16b(const unsigned short* __restrict__ X, int ldx, int K, int colofs, int Kw,
                          const float* __restrict__ wA, const float* __restrict__ wB,
                          float* __restrict__ out16, int M, int accum){
  __shared__ float xs[16][65];
  __shared__ float ws[16][65];
  int tid = threadIdx.x;
  int tx = tid & 15, ty = tid >> 4;
  int r0 = blockIdx.x*16;
  int lr = tid >> 4;          // staging row 0..15
  int lc = (tid & 15)*4;      // staging col base
  float acc = 0.f;
  for (int c0 = 0; c0 < K; c0 += 64){
    int cl = min(64, K - c0);
    float4 xv = make_float4(0.f,0.f,0.f,0.f);
    if (r0 + lr < M && lc < cl){
      ushort4 u = *reinterpret_cast<const ushort4*>(&X[(size_t)(r0+lr)*ldx + c0 + lc]);
      xv.x = bf2f_(u.x); xv.y = bf2f_(u.y); xv.z = bf2f_(u.z); xv.w = bf2f_(u.w);
    }
    float4 wv = make_float4(0.f,0.f,0.f,0.f);
    if (lc < cl){
      const float* wsrc = (lr < 8) ? &wA[(size_t)lr*Kw + colofs + c0 + lc]
                                   : &wB[(size_t)(lr-8)*Kw + colofs + c0 + lc];
      wv = *reinterpret_cast<const float4*>(wsrc);
    }
    xs[lr][lc] = xv.x; xs[lr][lc+1] = xv.y; xs[lr][lc+2] = xv.z; xs[lr][lc+3] = xv.w;
    ws[lr][lc] = wv.x; ws[lr][lc+1] = wv.y; ws[lr][lc+2] = wv.z; ws[lr][lc+3] = wv.w;
    __syncthreads();
    #pragma unroll
    for (int k = 0; k < 64; ++k) acc += xs[ty][k]*ws[tx][k];
    __syncthreads();
  }
  if (r0 + ty < M){
    size_t o = (size_t)(r0+ty)*16 + tx;
    out16[o] = accum ? out16[o] + acc : acc;
  }
}

// ---------------- R2E aggregate (f32 out + bf16 xeb) ----------------
__global__ void k_r2e_agg2b(const int* __restrict__ offh, const int* __restrict__ offt,
                            const int* __restrict__ relh, const int* __restrict__ relt,
                            const float* __restrict__ shp, const float* __restrict__ stp,
                            const float4* __restrict__ xr4, float4* __restrict__ out,
                            unsigned short* __restrict__ xeb){
  int n = blockIdx.x;
  int side = threadIdx.x >> 6, lane = threadIdx.x & 63;
  const int* off = side ? offt : offh;
  const int* rr  = side ? relt : relh;
  const float* sp = side ? stp : shp;
  int s = off[n], e = off[n+1];
  if (lane >= RH4) return;
  float4 acc = make_float4(0.f,0.f,0.f,0.f);
  int p = s;
  for (; p + 1 < e; p += 2){
    float a0 = sp[p], a1 = sp[p+1];
    float4 v0 = xr4[(size_t)rr[p]*RH4 + lane];
    float4 v1 = xr4[(size_t)rr[p+1]*RH4 + lane];
    acc.x += a0*v0.x + a1*v1.x; acc.y += a0*v0.y + a1*v1.y;
    acc.z += a0*v0.z + a1*v1.z; acc.w += a0*v0.w + a1*v1.w;
  }
  if (p < e){
    float a0 = sp[p];
    float4 v0 = xr4[(size_t)rr[p]*RH4 + lane];
    acc.x += a0*v0.x; acc.y += a0*v0.y; acc.z += a0*v0.z; acc.w += a0*v0.w;
  }
  float4 o = make_float4(acc.x*0.125f, acc.y*0.125f, acc.z*0.125f, acc.w*0.125f);
  out[(size_t)n*LD4 + (side ? 100 : 75) + lane] = o;
  ushort4 ob;
  ob.x = f2bf_(o.x); ob.y = f2bf_(o.y); ob.z = f2bf_(o.z); ob.w = f2bf_(o.w);
  *reinterpret_cast<ushort4*>(&xeb[(size_t)n*XEBS_ + (side ? 100 : 0) + lane*4]) = ob;
}

// ---------------- GAT aggregate (split bf16 tables, unroll-4) ----------------
__global__ void k_gat_agg4(const int* __restrict__ off, const int* __restrict__ jd,
                           const float* __restrict__ agp,
                           const unsigned short* __restrict__ xb,
                           const unsigned short* __restrict__ xeb,
                           float4* __restrict__ out){
  __shared__ int js[128];
  __shared__ float as_[128];
  int n = blockIdx.x, tid = threadIdx.x;
  int s = off[n], t = off[n+1];
  const unsigned short* tbl;
  size_t stride; int cofs;
  if (tid < 75){ tbl = xb;  stride = XBS_;  cofs = tid*4; }
  else         { tbl = xeb; stride = XEBS_; cofs = (tid-75)*4; }
  float4 acc = make_float4(0.f,0.f,0.f,0.f);
  for (int base = s; base < t; base += 128){
    int m = min(128, t - base);
    __syncthreads();
    if (tid < m){ js[tid] = jd[base+tid]; as_[tid] = agp[base+tid]; }
    __syncthreads();
    if (tid < 125){
      int q = 0;
      for (; q + 3 < m; q += 4){
        float a0 = as_[q], a1 = as_[q+1], a2 = as_[q+2], a3 = as_[q+3];
        ushort4 u0 = *reinterpret_cast<const ushort4*>(&tbl[(size_t)js[q]*stride + cofs]);
        ushort4 u1 = *reinterpret_cast<const ushort4*>(&tbl[(size_t)js[q+1]*stride + cofs]);
        ushort4 u2 = *reinterpret_cast<const ushort4*>(&tbl[(size_t)js[q+2]*stride + cofs]);
        ushort4 u3 = *reinterpret_cast<const ushort4*>(&tbl[(size_t)js[q+3]*stride + cofs]);
        acc.x += a0*bf2f_(u0.x)+a1*bf2f_(u1.x)+a2*bf2f_(u2.x)+a3*bf2f_(u3.x);
        acc.y += a0*bf2f_(u0.y)+a1*bf2f_(u1.y)+a2*bf2f_(u2.y)+a3*bf2f_(u3.y);
        acc.z += a0*bf2f_(u0.z)+a1*bf2f_(u1.z)+a2*bf2f_(u2.z)+a3*bf2f_(u3.z);
        acc.w += a0*bf2f_(u0.w)+a1*bf2f_(u1.w)+a2*bf2f_(u2.w)+a3*bf2f_(u3.w);
      }
      for (; q < m; ++q){
        float a0 = as_[q];
        ushort4 u0 = *reinterpret_cast<const ushort4*>(&tbl[(size_t)js[q]*stride + cofs]);
        acc.x += a0*bf2f_(u0.x); acc.y += a0*bf2f_(u0.y);
        acc.z += a0*bf2f_(u0.z); acc.w += a0*bf2f_(u0.w);
      }
    }
  }
  if (tid < 125){
    float4 r = make_float4(acc.x*0.125f, acc.y*0.125f, acc.z*0.125f, acc.w*0.125f);
    out[(size_t)n*LD4 + 125 + tid] = r;
  }
}

// ---------------- host ----------------
static inline void gemm_mfma(const unsigned short* Ab, const unsigned short* Wb,
                             float* C, int ldc, int M, int Nn, hipStream_t st){
  dim3 g((M + 127)/128, (Nn + 63)/64);
  k_gemm_mfma<<<g, 256, 0, st>>>(Ab, Wb, C, ldc, M, Nn);
}

extern "C" void kernel_launch(void* const* d_in, const int* in_sizes, int n_in,
                              void* d_out, int out_size, void* d_ws, size_t ws_size,
                              hipStream_t stream) {
  const float* x_e   = (const float*)d_in[0];
  const int*   ei    = (const int*)d_in[1];
  const int*   rel   = (const int*)d_in[2];
  const int*   eia   = (const int*)d_in[3];
  const float* hw1_w = (const float*)d_in[5];
  const float* hw1_b = (const float*)d_in[6];
  const float* hw2_w = (const float*)d_in[7];
  const float* hw2_b = (const float*)d_in[8];
  const float* e2r_wh= (const float*)d_in[9];
  const float* e2r_wt= (const float*)d_in[10];
  const float* e2r_ah= (const float*)d_in[11];
  const float* e2r_at= (const float*)d_in[12];
  const float* r2e_ah= (const float*)d_in[13];
  const float* r2e_at= (const float*)d_in[14];
  const float* r2e_ar= (const float*)d_in[15];
  const float* gat_ai= (const float*)d_in[16];
  const float* gat_aj= (const float*)d_in[17];
  float* out = (float*)d_out;

  const int* hi = ei;
  const int* ti = ei + E_;
  const int* ja = eia;
  const int* ia = eia + EALL_;

  char* base = (char*)d_ws;
  size_t off = 0;
  auto alloc = [&](size_t bytes)->void*{
    void* p = base + off;
    off = (off + bytes + 255) & ~(size_t)255;
    return p;
  };

  // zeroed region: padded counts + cursors
  size_t z0 = off;
  int* cnt_dest = (int*)alloc(SCNP_*4);
  int* cnt_h    = (int*)alloc(SCNP_*4);
  int* cnt_t    = (int*)alloc(SCNP_*4);
  int* cur_dest = (int*)alloc(N_*4);
  int* cur_h    = (int*)alloc(N_*4);
  int* cur_t    = (int*)alloc(N_*4);
  size_t z1 = off;

  int* off_dest = (int*)alloc(SCNP_*4);
  int* off_h    = (int*)alloc(SCNP_*4);
  int* off_t    = (int*)alloc(SCNP_*4);
  int* off_rel  = (int*)alloc((R_+1)*4);
  int* bsum     = (int*)alloc(3*NSB_*4);
  int* Hrel     = (int*)alloc((size_t)NBR_*R_*4);
  int* j_dest   = (int*)alloc((size_t)EALL_*4);
  int* hr       = (int*)alloc((size_t)E_*4);
  int* tr       = (int*)alloc((size_t)E_*4);
  int* relh     = (int*)alloc((size_t)E_*4);
  int* relt     = (int*)alloc((size_t)E_*4);

  float* dis   = (float*)alloc(SCNP_*4);
  float* wj    = (float*)alloc((size_t)EALL_*4);
  float* g     = (float*)alloc((size_t)N_*EH_*4);
  float* xhxt  = (float*)alloc((size_t)N_*200*4);
  float* pht   = (float*)alloc((size_t)N_*8*4);
  float* s1p   = (float*)alloc((size_t)E_*4);
  float* s2p   = (float*)alloc((size_t)E_*4);
  float* xr    = (float*)alloc((size_t)R_*RH_*4);
  float* xr_part=(float*)alloc((size_t)NC_*R_*RH_*4);
  float* st16  = (float*)alloc((size_t)N_*16*4);
  float* sr8   = (float*)alloc((size_t)R_*8*4);
  float* shp   = (float*)alloc((size_t)E_*4);
  float* stp   = (float*)alloc((size_t)E_*4);
  float* gg16  = (float*)alloc((size_t)N_*16*4);
  float* agp   = (float*)alloc((size_t)EALL_*4);
  unsigned short* xbA = (unsigned short*)alloc((size_t)N_*XBS_*2);   // 19.2 MB
  unsigned short* xbB = (unsigned short*)alloc((size_t)N_*XBS_*2);   // 19.2 MB
  unsigned short* xeb = (unsigned short*)alloc((size_t)N_*XEBS_*2);  // 12 MB
  unsigned short* w1b = (unsigned short*)alloc((size_t)EH_*KP_*2);
  unsigned short* w2b = (unsigned short*)alloc((size_t)EH_*KP_*2);
  unsigned short* wcb = (unsigned short*)alloc((size_t)200*KP_*2);

  hipMemsetAsync(base + z0, 0, z1 - z0, stream);

  const int TB = 256;
  const int TOT = EALL_ + 2*E_;
  int gTOT  = (TOT + TB - 1)/TB;
  int gN    = (N_ + TB - 1)/TB;
  int gPKX  = (N_*80 + TB - 1)/TB;
  const int WTOT = 2*EH_*KP_ + 200*KP_;

  // weight packs
  k_pack_weights<<<(WTOT + TB - 1)/TB, TB, 0, stream>>>(hw1_w, hw2_w, e2r_wh, e2r_wt,
                                                        w1b, w2b, wcb);

  // CSR build: rel via block counting sort
  k_relhist<<<NBR_, 256, 0, stream>>>(rel, Hrel);
  k_relscan<<<1, 256, 0, stream>>>(Hrel, off_rel);
  k_relscatter<<<NBR_, 256, 0, stream>>>(rel, hi, ti, Hrel, hr, tr);

  // CSR build: dest/h/t (hierarchical scan)
  k_count3<<<gTOT, TB, 0, stream>>>(ia, hi, ti, cnt_dest, cnt_h, cnt_t);
  k_scanA<<<3*NSB_, 256, 0, stream>>>(cnt_dest, cnt_h, cnt_t, bsum);
  k_scanB<<<1, 64, 0, stream>>>(bsum, off_dest, off_h, off_t);
  k_scanC<<<3*NSB_, 256, 0, stream>>>(cnt_dest, cnt_h, cnt_t, bsum,
                                      off_dest, off_h, off_t, dis);
  k_scatter3<<<gTOT, TB, 0, stream>>>(ja, ia, rel, hi, ti,
                                      off_dest, off_h, off_t,
                                      cur_dest, cur_h, cur_t,
                                      dis, j_dest, wj, relh, relt);

  // GCN + highway block 1 (fused): gather xbA -> out cols 0..299 + xbB
  k_pack_x<<<gPKX, TB, 0, stream>>>((const float4*)x_e, EH4, xbA);
  gemm_mfma(xbA, w1b, g, EH_, N_, EH_, stream);
  k_gcn5<<<N_, 64, 0, stream>>>(off_dest, j_dest, wj, dis, xbA,
                                (const float4*)x_e, EH4, (const float4*)g, hw1_b,
                                (float4*)out, xbB);
  // block 2: gather xbB -> out + xbA
  gemm_mfma(xbB, w2b, g, EH_, N_, EH_, stream);
  k_gcn5<<<N_, 64, 0, stream>>>(off_dest, j_dest, wj, dis, xbB,
                                (const float4*)out, LD4, (const float4*)g, hw2_b,
                                (float4*)out, xbA);

  // E2R (A-operand = xbA, the packed final x)
  gemm_mfma(xbA, wcb, xhxt, 200, N_, 200, stream);
  k_pproj<<<gN, TB, 0, stream>>>(xhxt, e2r_ah, e2r_at, (float4*)pht);
  k_fold_rel2<<<R_, 256, 0, stream>>>(off_rel, hr, tr, (const float4*)pht, s1p, s2p);
  k_e2r_agg3<<<dim3(R_, NC_), 64, 0, stream>>>(off_rel, hr, tr, s1p, s2p,
                                               (const float4*)xhxt, (float4*)xr_part);
  k_e2r_red2<<<R_, 64, 0, stream>>>((const float4*)xr_part, (float4*)xr, r2e_ar, sr8);

  // R2E (head dots from bf16 xbA)
  k_dots16b<<<(N_+15)/16, 256, 0, stream>>>(xbA, XBS_, EH_, 0, EH_, r2e_ah, r2e_at, st16, N_, 0);
  k_fold_ht2<<<(N_+1)/2, 256, 0, stream>>>(off_h, off_t, relh, relt, st16, sr8, shp, stp);
  k_r2e_agg2b<<<N_, 128, 0, stream>>>(off_h, off_t, relh, relt, shp, stp,
                                      (const float4*)xr, (float4*)out, xeb);

  // GAT (head dots: pass1 over x cols 0..299 from xbA, pass2 over xe cols 300..499 from xeb)
  k_dots16b<<<(N_+15)/16, 256, 0, stream>>>(xbA, XBS_, EH_, 0, 500, gat_ai, gat_aj, gg16, N_, 0);
  k_dots16b<<<(N_+15)/16, 256, 0, stream>>>(xeb, XEBS_, 200, EH_, 500, gat_ai, gat_aj, gg16, N_, 1);
  k_fold_gat2<<<(N_+3)/4, 256, 0, stream>>>(off_dest, j_dest, gg16, agp);
  k_gat_agg4<<<N_, 128, 0, stream>>>(off_dest, j_dest, agp, xbA, xeb, (float4*)out);
}

// Round 10
// 578.721 us; speedup vs baseline: 4.0505x; 1.0799x over previous
//
#include <hip/hip_runtime.h>
#include <math.h>

constexpr int N_    = 30000;
constexpr int E_    = 200000;
constexpr int EALL_ = 400000;
constexpr int R_    = 500;
constexpr int EH_   = 300;
constexpr int RH_   = 100;
constexpr int OUTD_ = 1000;
constexpr int LD4   = OUTD_/4;  // 250
constexpr int EH4   = EH_/4;    // 75
constexpr int RH4   = RH_/4;    // 25
constexpr int NC_   = 16;
constexpr int XBS_  = 320;      // bf16 row stride, zero-padded K for MFMA
constexpr int XEBS_ = 200;
constexpr int KP_   = 320;
constexpr int NBR_  = 64;
constexpr int PERB_ = (E_ + NBR_ - 1)/NBR_;
constexpr int SCB_  = 2048;
constexpr int NSB_  = (N_ + SCB_ - 1)/SCB_;
constexpr int SCNP_ = NSB_*SCB_;

typedef __attribute__((ext_vector_type(4))) float f32x4;
typedef __attribute__((ext_vector_type(8))) short s16x8;

__device__ __forceinline__ float lrelu_(float v){ return v > 0.f ? v : 0.01f*v; }
__device__ __forceinline__ float sig_(float z){ return 1.f/(1.f + expf(-z)); }
__device__ __forceinline__ unsigned short f2bf_(float f){
  unsigned int u = __float_as_uint(f);
  unsigned int r = (u + 0x7FFFu + ((u >> 16) & 1u)) >> 16;
  return (unsigned short)r;
}
__device__ __forceinline__ float bf2f_(unsigned short h){
  return __uint_as_float(((unsigned int)h) << 16);
}

// ---------------- merged pack: weights + x_e ----------------
__global__ void k_pack_all(const float* __restrict__ w1, const float* __restrict__ w2,
                           const float* __restrict__ wh, const float* __restrict__ wt,
                           const float4* __restrict__ Xe,
                           unsigned short* w1b, unsigned short* w2b,
                           unsigned short* wcb, unsigned short* xb){
  int idx = blockIdx.x*blockDim.x + threadIdx.x;
  if (idx < EH_*KP_){
    int n = idx/KP_, k = idx - n*KP_;
    w1b[idx] = (k < EH_) ? f2bf_(w1[(size_t)n*EH_ + k]) : (unsigned short)0;
    return;
  }
  idx -= EH_*KP_;
  if (idx < EH_*KP_){
    int n = idx/KP_, k = idx - n*KP_;
    w2b[idx] = (k < EH_) ? f2bf_(w2[(size_t)n*EH_ + k]) : (unsigned short)0;
    return;
  }
  idx -= EH_*KP_;
  if (idx < 200*KP_){
    int n = idx/KP_, k = idx - n*KP_;
    wcb[idx] = (k < EH_) ? f2bf_((n < 100) ? wh[(size_t)n*EH_ + k] : wt[(size_t)(n-100)*EH_ + k])
                         : (unsigned short)0;
    return;
  }
  idx -= 200*KP_;
  if (idx < N_*80){
    int n = idx/80, c = idx - n*80;
    ushort4 o = make_ushort4(0,0,0,0);
    if (c < EH4){
      float4 v = Xe[(size_t)n*EH4 + c];
      o.x = f2bf_(v.x); o.y = f2bf_(v.y); o.z = f2bf_(v.z); o.w = f2bf_(v.w);
    }
    *reinterpret_cast<ushort4*>(&xb[(size_t)n*XBS_ + c*4]) = o;
  }
}

// ---------------- merged: rel hist + dest/h/t counts ----------------
__global__ void k_build1(const int* __restrict__ rel, const int* __restrict__ ia,
                         const int* __restrict__ hi, const int* __restrict__ ti,
                         int* __restrict__ H, int* cd, int* ch, int* ct){
  __shared__ int h[R_];
  int tid = threadIdx.x;
  if ((int)blockIdx.x < NBR_){
    int b = blockIdx.x;
    for (int i = tid; i < R_; i += 256) h[i] = 0;
    __syncthreads();
    int s = b*PERB_, e = min(s + PERB_, E_);
    for (int i = s + tid; i < e; i += 256) atomicAdd(&h[rel[i]], 1);
    __syncthreads();
    for (int i = tid; i < R_; i += 256) H[b*R_ + i] = h[i];
    return;
  }
  int idx = (blockIdx.x - NBR_)*256 + tid;
  if (idx < EALL_) { atomicAdd(&cd[ia[idx]], 1); return; }
  idx -= EALL_;
  if (idx < E_) { atomicAdd(&ch[hi[idx]], 1); return; }
  idx -= E_;
  if (idx < E_) { atomicAdd(&ct[ti[idx]], 1); return; }
}

// ---------------- scanA ----------------
__global__ void k_scanA(const int* __restrict__ c0, const int* __restrict__ c1,
                        const int* __restrict__ c2, int* __restrict__ bsum){
  int arr = blockIdx.x / NSB_, b = blockIdx.x - arr*NSB_;
  const int* c = arr == 0 ? c0 : (arr == 1 ? c1 : c2);
  int t = threadIdx.x;
  const int4* c4 = reinterpret_cast<const int4*>(c + b*SCB_ + t*8);
  int4 u0 = c4[0], u1 = c4[1];
  int acc = u0.x+u0.y+u0.z+u0.w + u1.x+u1.y+u1.z+u1.w;
  __shared__ int red[256];
  red[t] = acc;
  __syncthreads();
  for (int o = 128; o > 0; o >>= 1){
    if (t < o) red[t] += red[t+o];
    __syncthreads();
  }
  if (t == 0) bsum[arr*NSB_ + b] = red[0];
}

// ---------------- merged: relscan + scanB ----------------
__global__ void k_mid(int* __restrict__ H, int* __restrict__ off_rel,
                      int* __restrict__ bsum, int* o0, int* o1, int* o2){
  __shared__ int tot[R_];
  __shared__ int sc[256];
  int tid = threadIdx.x;
  if (blockIdx.x == 1){
    if (tid < 3){
      int run = 0;
      for (int b = 0; b < NSB_; ++b){ int v = bsum[tid*NSB_ + b]; bsum[tid*NSB_ + b] = run; run += v; }
      int* o = tid == 0 ? o0 : (tid == 1 ? o1 : o2);
      o[N_] = run;
    }
    return;
  }
  for (int r = tid; r < R_; r += 256){
    int acc = 0;
    for (int b = 0; b < NBR_; ++b){ int v = H[b*R_ + r]; H[b*R_ + r] = acc; acc += v; }
    tot[r] = acc;
  }
  __syncthreads();
  int r0 = tid*2;
  int a0 = (r0 < R_) ? tot[r0] : 0;
  int a1 = (r0+1 < R_) ? tot[r0+1] : 0;
  sc[tid] = a0 + a1;
  __syncthreads();
  for (int off = 1; off < 256; off <<= 1){
    int add = (tid >= off) ? sc[tid-off] : 0;
    __syncthreads();
    sc[tid] += add;
    __syncthreads();
  }
  int run = tid ? sc[tid-1] : 0;
  if (r0 < R_)   off_rel[r0]   = run;
  if (r0+1 < R_) off_rel[r0+1] = run + a0;
  if (tid == 255) off_rel[R_] = sc[255];
  __syncthreads();
  for (int r = tid; r < R_; r += 256){
    int o = off_rel[r];
    for (int b = 0; b < NBR_; ++b) H[b*R_ + r] += o;
  }
}

// ---------------- scanC (+dis) ----------------
__global__ void k_scanC(const int* __restrict__ c0, const int* __restrict__ c1,
                        const int* __restrict__ c2, const int* __restrict__ bsum,
                        int* o0, int* o1, int* o2, float* __restrict__ dis){
  int arr = blockIdx.x / NSB_, b = blockIdx.x - arr*NSB_;
  const int* c = arr == 0 ? c0 : (arr == 1 ? c1 : c2);
  int* o = arr == 0 ? o0 : (arr == 1 ? o1 : o2);
  int t = threadIdx.x;
  int base = b*SCB_ + t*8;
  const int4* c4 = reinterpret_cast<const int4*>(c + base);
  int4 u0 = c4[0], u1 = c4[1];
  int v[8] = {u0.x,u0.y,u0.z,u0.w,u1.x,u1.y,u1.z,u1.w};
  int tot = v[0]+v[1]+v[2]+v[3]+v[4]+v[5]+v[6]+v[7];
  __shared__ int sc[256];
  sc[t] = tot;
  __syncthreads();
  for (int off = 1; off < 256; off <<= 1){
    int add = (t >= off) ? sc[t-off] : 0;
    __syncthreads();
    sc[t] += add;
    __syncthreads();
  }
  int run = bsum[arr*NSB_ + b] + (t ? sc[t-1] : 0);
  #pragma unroll
  for (int i = 0; i < 8; ++i){
    int idx = base + i;
    o[idx] = run;
    if (arr == 0) dis[idx] = v[i] > 0 ? rsqrtf((float)v[i]) : 0.f;
    run += v[i];
  }
}

// ---------------- merged: relscatter + dest/h/t scatter ----------------
__global__ void k_build2(const int* __restrict__ rel, const int* __restrict__ hi,
                         const int* __restrict__ ti, const int* __restrict__ H,
                         int* __restrict__ hr, int* __restrict__ tr,
                         const int* __restrict__ ja, const int* __restrict__ ia,
                         const int* od, const int* oh, const int* ot,
                         int* curd, int* curh, int* curt,
                         const float* __restrict__ dis,
                         int* j_dest, float* wj, int* relh, int* relt){
  __shared__ int cur[R_];
  int tid = threadIdx.x;
  if ((int)blockIdx.x < NBR_){
    int b = blockIdx.x;
    for (int i = tid; i < R_; i += 256) cur[i] = H[b*R_ + i];
    __syncthreads();
    int s = b*PERB_, e = min(s + PERB_, E_);
    for (int i = s + tid; i < e; i += 256){
      int r = rel[i];
      int p = atomicAdd(&cur[r], 1);
      hr[p] = hi[i]; tr[p] = ti[i];
    }
    return;
  }
  int idx = (blockIdx.x - NBR_)*256 + tid;
  if (idx < EALL_){
    int e = idx, s = ia[e];
    int p = od[s] + atomicAdd(&curd[s], 1);
    int j = ja[e];
    j_dest[p] = j; wj[p] = dis[j]; return;
  }
  idx -= EALL_;
  if (idx < E_){
    int e = idx, s = hi[e];
    int p = oh[s] + atomicAdd(&curh[s], 1);
    relh[p] = rel[e]; return;
  }
  idx -= E_;
  if (idx < E_){
    int e = idx, s = ti[e];
    int p = ot[s] + atomicAdd(&curt[s], 1);
    relt[p] = rel[e]; return;
  }
}

// ---------------- MFMA GEMM ----------------
__global__ __launch_bounds__(256) void k_gemm_mfma(
    const unsigned short* __restrict__ Ab,
    const unsigned short* __restrict__ Wb,
    float* __restrict__ C, int ldc, int M, int Nn){
  constexpr int WS = 328;
  constexpr int AS = 40;
  __shared__ unsigned short Ws[64*WS];
  __shared__ unsigned short As[128*AS];
  int tid = threadIdx.x;
  int lane = tid & 63, wave = tid >> 6;
  int wm = wave & 1, wn = wave >> 1;
  int m0 = blockIdx.x*128, n0 = blockIdx.y*64;

  for (int c = tid; c < 64*(KP_/8); c += 256){
    int n = c / (KP_/8), k8 = (c % (KP_/8))*8;
    s16x8 v = {0,0,0,0,0,0,0,0};
    if (n0 + n < Nn)
      v = *reinterpret_cast<const s16x8*>(&Wb[(size_t)(n0+n)*KP_ + k8]);
    *reinterpret_cast<s16x8*>(&Ws[n*WS + k8]) = v;
  }

  f32x4 acc[4][2] = {};
  int kf = (lane >> 4)*8;
  int rA = lane & 15;
  for (int k0 = 0; k0 < KP_; k0 += 32){
    __syncthreads();
    for (int c = tid; c < 128*4; c += 256){
      int r = c >> 2, k8 = (c & 3)*8;
      s16x8 v = {0,0,0,0,0,0,0,0};
      if (m0 + r < M)
        v = *reinterpret_cast<const s16x8*>(&Ab[(size_t)(m0+r)*XBS_ + k0 + k8]);
      *reinterpret_cast<s16x8*>(&As[r*AS + k8]) = v;
    }
    __syncthreads();
    s16x8 afr[4], bfr[2];
    #pragma unroll
    for (int mf = 0; mf < 4; ++mf)
      afr[mf] = *reinterpret_cast<const s16x8*>(&As[(wm*64 + mf*16 + rA)*AS + kf]);
    #pragma unroll
    for (int nf = 0; nf < 2; ++nf)
      bfr[nf] = *reinterpret_cast<const s16x8*>(&Ws[(wn*32 + nf*16 + rA)*WS + k0 + kf]);
    #pragma unroll
    for (int mf = 0; mf < 4; ++mf)
      #pragma unroll
      for (int nf = 0; nf < 2; ++nf)
        acc[mf][nf] = __builtin_amdgcn_mfma_f32_16x16x32_bf16(afr[mf], bfr[nf], acc[mf][nf], 0, 0, 0);
  }
  int col0 = n0 + wn*32 + (lane & 15);
  int rbase = m0 + wm*64 + (lane >> 4)*4;
  #pragma unroll
  for (int mf = 0; mf < 4; ++mf){
    #pragma unroll
    for (int nf = 0; nf < 2; ++nf){
      int col = col0 + nf*16;
      if (col < Nn){
        #pragma unroll
        for (int r = 0; r < 4; ++r){
          int row = rbase + mf*16 + r;
          if (row < M) C[(size_t)row*ldc + col] = acc[mf][nf][r];
        }
      }
    }
  }
}

// ---------------- fused GCN gather + highway + bf16 repack (bf16 residual) ----------------
__global__ void k_gcn5(const int* __restrict__ off, const int* __restrict__ jd,
                       const float* __restrict__ wj, const float* __restrict__ dis,
                       const unsigned short* __restrict__ xsrc,
                       const float4* __restrict__ G, const float* __restrict__ b,
                       float4* __restrict__ Xn, unsigned short* __restrict__ xdst){
  __shared__ int js[64];
  __shared__ float ws[64];
  int n = blockIdx.x, lane = threadIdx.x;   // 64
  int s = off[n], t = off[n+1];
  bool two = lane < (EH4 - 64);
  float4 a0 = make_float4(0.f,0.f,0.f,0.f);
  float4 a1 = make_float4(0.f,0.f,0.f,0.f);
  for (int base = s; base < t; base += 64){
    int m = min(64, t - base);
    __syncthreads();
    if (lane < m){ js[lane] = jd[base+lane]; ws[lane] = wj[base+lane]; }
    __syncthreads();
    int q = 0;
    for (; q + 3 < m; q += 4){
      size_t r0 = (size_t)js[q]*XBS_,   r1 = (size_t)js[q+1]*XBS_;
      size_t r2 = (size_t)js[q+2]*XBS_, r3 = (size_t)js[q+3]*XBS_;
      float w0 = ws[q], w1 = ws[q+1], w2 = ws[q+2], w3 = ws[q+3];
      ushort4 u0 = *reinterpret_cast<const ushort4*>(&xsrc[r0 + lane*4]);
      ushort4 u1 = *reinterpret_cast<const ushort4*>(&xsrc[r1 + lane*4]);
      ushort4 u2 = *reinterpret_cast<const ushort4*>(&xsrc[r2 + lane*4]);
      ushort4 u3 = *reinterpret_cast<const ushort4*>(&xsrc[r3 + lane*4]);
      a0.x += w0*bf2f_(u0.x)+w1*bf2f_(u1.x)+w2*bf2f_(u2.x)+w3*bf2f_(u3.x);
      a0.y += w0*bf2f_(u0.y)+w1*bf2f_(u1.y)+w2*bf2f_(u2.y)+w3*bf2f_(u3.y);
      a0.z += w0*bf2f_(u0.z)+w1*bf2f_(u1.z)+w2*bf2f_(u2.z)+w3*bf2f_(u3.z);
      a0.w += w0*bf2f_(u0.w)+w1*bf2f_(u1.w)+w2*bf2f_(u2.w)+w3*bf2f_(u3.w);
      if (two){
        ushort4 v0 = *reinterpret_cast<const ushort4*>(&xsrc[r0 + 256 + lane*4]);
        ushort4 v1 = *reinterpret_cast<const ushort4*>(&xsrc[r1 + 256 + lane*4]);
        ushort4 v2 = *reinterpret_cast<const ushort4*>(&xsrc[r2 + 256 + lane*4]);
        ushort4 v3 = *reinterpret_cast<const ushort4*>(&xsrc[r3 + 256 + lane*4]);
        a1.x += w0*bf2f_(v0.x)+w1*bf2f_(v1.x)+w2*bf2f_(v2.x)+w3*bf2f_(v3.x);
        a1.y += w0*bf2f_(v0.y)+w1*bf2f_(v1.y)+w2*bf2f_(v2.y)+w3*bf2f_(v3.y);
        a1.z += w0*bf2f_(v0.z)+w1*bf2f_(v1.z)+w2*bf2f_(v2.z)+w3*bf2f_(v3.z);
        a1.w += w0*bf2f_(v0.w)+w1*bf2f_(v1.w)+w2*bf2f_(v2.w)+w3*bf2f_(v3.w);
      }
    }
    for (; q < m; ++q){
      size_t r0 = (size_t)js[q]*XBS_;
      float w0 = ws[q];
      ushort4 u0 = *reinterpret_cast<const ushort4*>(&xsrc[r0 + lane*4]);
      a0.x += w0*bf2f_(u0.x); a0.y += w0*bf2f_(u0.y);
      a0.z += w0*bf2f_(u0.z); a0.w += w0*bf2f_(u0.w);
      if (two){
        ushort4 v0 = *reinterpret_cast<const ushort4*>(&xsrc[r0 + 256 + lane*4]);
        a1.x += w0*bf2f_(v0.x); a1.y += w0*bf2f_(v0.y);
        a1.z += w0*bf2f_(v0.z); a1.w += w0*bf2f_(v0.w);
      }
    }
  }
  float dn = dis[n];
  {
    int c = lane;
    float4 yv;
    yv.x = fmaxf(dn*a0.x, 0.f); yv.y = fmaxf(dn*a0.y, 0.f);
    yv.z = fmaxf(dn*a0.z, 0.f); yv.w = fmaxf(dn*a0.w, 0.f);
    float4 g4 = G[(size_t)n*EH4 + c];
    float4 b4 = reinterpret_cast<const float4*>(b)[c];
    ushort4 uo = *reinterpret_cast<const ushort4*>(&xsrc[(size_t)n*XBS_ + c*4]);
    float4 xo = make_float4(bf2f_(uo.x), bf2f_(uo.y), bf2f_(uo.z), bf2f_(uo.w));
    float gx; float4 r;
    gx = sig_(g4.x + b4.x); r.x = gx*yv.x + (1.f-gx)*xo.x;
    gx = sig_(g4.y + b4.y); r.y = gx*yv.y + (1.f-gx)*xo.y;
    gx = sig_(g4.z + b4.z); r.z = gx*yv.z + (1.f-gx)*xo.z;
    gx = sig_(g4.w + b4.w); r.w = gx*yv.w + (1.f-gx)*xo.w;
    Xn[(size_t)n*LD4 + c] = r;
    ushort4 o;
    o.x = f2bf_(r.x); o.y = f2bf_(r.y); o.z = f2bf_(r.z); o.w = f2bf_(r.w);
    *reinterpret_cast<ushort4*>(&xdst[(size_t)n*XBS_ + c*4]) = o;
  }
  if (two){
    int c = 64 + lane;
    float4 yv;
    yv.x = fmaxf(dn*a1.x, 0.f); yv.y = fmaxf(dn*a1.y, 0.f);
    yv.z = fmaxf(dn*a1.z, 0.f); yv.w = fmaxf(dn*a1.w, 0.f);
    float4 g4 = G[(size_t)n*EH4 + c];
    float4 b4 = reinterpret_cast<const float4*>(b)[c];
    ushort4 uo = *reinterpret_cast<const ushort4*>(&xsrc[(size_t)n*XBS_ + c*4]);
    float4 xo = make_float4(bf2f_(uo.x), bf2f_(uo.y), bf2f_(uo.z), bf2f_(uo.w));
    float gx; float4 r;
    gx = sig_(g4.x + b4.x); r.x = gx*yv.x + (1.f-gx)*xo.x;
    gx = sig_(g4.y + b4.y); r.y = gx*yv.y + (1.f-gx)*xo.y;
    gx = sig_(g4.z + b4.z); r.z = gx*yv.z + (1.f-gx)*xo.z;
    gx = sig_(g4.w + b4.w); r.w = gx*yv.w + (1.f-gx)*xo.w;
    Xn[(size_t)n*LD4 + c] = r;
    ushort4 o;
    o.x = f2bf_(r.x); o.y = f2bf_(r.y); o.z = f2bf_(r.z); o.w = f2bf_(r.w);
    *reinterpret_cast<ushort4*>(&xdst[(size_t)n*XBS_ + c*4]) = o;
  } else if (lane < 16){
    ushort4 z = make_ushort4(0,0,0,0);
    *reinterpret_cast<ushort4*>(&xdst[(size_t)n*XBS_ + (64+lane)*4]) = z;
  }
}

// ---------------- E2R projections -> pht[N][8] ----------------
__global__ void k_pproj(const float* __restrict__ xhxt,
                        const float* __restrict__ ah, const float* __restrict__ at,
                        float4* __restrict__ pht){
  int n = blockIdx.x*blockDim.x + threadIdx.x;
  if (n >= N_) return;
  float a0=0,a1=0,b0=0,b1=0,c0=0,c1=0,d0=0,d1=0;
  const float* xh = xhxt + (size_t)n*200;
  const float* xt = xh + 100;
  for (int f = 0; f < RH_; ++f) {
    float vh = xh[f], vt = xt[f];
    float w0 = ah[f], w1 = ah[RH_+f], u0 = at[f], u1 = at[RH_+f];
    a0 += vh*w0; a1 += vh*w1;
    b0 += vt*u0; b1 += vt*u1;
    c0 += vt*w0; c1 += vt*w1;
    d0 += vh*u0; d1 += vh*u1;
  }
  pht[(size_t)n*2]     = make_float4(a0, a1, c0, c1);
  pht[(size_t)n*2 + 1] = make_float4(b0, b1, d0, d1);
}

// ---------------- E2R fold ----------------
__global__ void k_fold_rel2(const int* __restrict__ off,
                            const int* __restrict__ hr, const int* __restrict__ tr,
                            const float4* __restrict__ pht,
                            float* __restrict__ s1p, float* __restrict__ s2p){
  __shared__ float4 redm[4];
  __shared__ float4 reds[4];
  int r = blockIdx.x;
  int tid = threadIdx.x, lane = tid & 63, w = tid >> 6;
  int s = off[r], e = off[r+1];
  float4 mx = make_float4(-1e30f,-1e30f,-1e30f,-1e30f);
  for (int p = s + tid; p < e; p += 256){
    float4 ph = pht[(size_t)hr[p]*2];
    float4 pt = pht[(size_t)tr[p]*2 + 1];
    mx.x = fmaxf(mx.x, lrelu_(ph.x + pt.x));
    mx.y = fmaxf(mx.y, lrelu_(ph.y + pt.y));
    mx.z = fmaxf(mx.z, lrelu_(ph.z + pt.z));
    mx.w = fmaxf(mx.w, lrelu_(ph.w + pt.w));
  }
  #pragma unroll
  for (int o = 1; o < 64; o <<= 1){
    mx.x = fmaxf(mx.x, __shfl_xor(mx.x, o));
    mx.y = fmaxf(mx.y, __shfl_xor(mx.y, o));
    mx.z = fmaxf(mx.z, __shfl_xor(mx.z, o));
    mx.w = fmaxf(mx.w, __shfl_xor(mx.w, o));
  }
  if (lane == 0) redm[w] = mx;
  __syncthreads();
  float4 m;
  m.x = fmaxf(fmaxf(redm[0].x, redm[1].x), fmaxf(redm[2].x, redm[3].x));
  m.y = fmaxf(fmaxf(redm[0].y, redm[1].y), fmaxf(redm[2].y, redm[3].y));
  m.z = fmaxf(fmaxf(redm[0].z, redm[1].z), fmaxf(redm[2].z, redm[3].z));
  m.w = fmaxf(fmaxf(redm[0].w, redm[1].w), fmaxf(redm[2].w, redm[3].w));
  float4 sm = make_float4(0.f,0.f,0.f,0.f);
  for (int p = s + tid; p < e; p += 256){
    float4 ph = pht[(size_t)hr[p]*2];
    float4 pt = pht[(size_t)tr[p]*2 + 1];
    sm.x += expf(lrelu_(ph.x + pt.x) - m.x);
    sm.y += expf(lrelu_(ph.y + pt.y) - m.y);
    sm.z += expf(lrelu_(ph.z + pt.z) - m.z);
    sm.w += expf(lrelu_(ph.w + pt.w) - m.w);
  }
  #pragma unroll
  for (int o = 1; o < 64; o <<= 1){
    sm.x += __shfl_xor(sm.x, o);
    sm.y += __shfl_xor(sm.y, o);
    sm.z += __shfl_xor(sm.z, o);
    sm.w += __shfl_xor(sm.w, o);
  }
  if (lane == 0) reds[w] = sm;
  __syncthreads();
  float4 sv;
  sv.x = reds[0].x + reds[1].x + reds[2].x + reds[3].x;
  sv.y = reds[0].y + reds[1].y + reds[2].y + reds[3].y;
  sv.z = reds[0].z + reds[1].z + reds[2].z + reds[3].z;
  sv.w = reds[0].w + reds[1].w + reds[2].w + reds[3].w;
  float4 inv;
  inv.x = 1.f/(sv.x + 1e-16f); inv.y = 1.f/(sv.y + 1e-16f);
  inv.z = 1.f/(sv.z + 1e-16f); inv.w = 1.f/(sv.w + 1e-16f);
  for (int p = s + tid; p < e; p += 256){
    float4 ph = pht[(size_t)hr[p]*2];
    float4 pt = pht[(size_t)tr[p]*2 + 1];
    s1p[p] = expf(lrelu_(ph.x + pt.x) - m.x)*inv.x + expf(lrelu_(ph.y + pt.y) - m.y)*inv.y;
    s2p[p] = expf(lrelu_(ph.z + pt.z) - m.z)*inv.z + expf(lrelu_(ph.w + pt.w) - m.w)*inv.w;
  }
}

// ---------------- E2R aggregate ----------------
__global__ void k_e2r_agg3(const int* __restrict__ off,
                           const int* __restrict__ hr, const int* __restrict__ tr,
                           const float* __restrict__ s1p, const float* __restrict__ s2p,
                           const float4* __restrict__ xhxt4, float4* __restrict__ xr_part){
  int r = blockIdx.x, c = blockIdx.y;
  int lane = threadIdx.x;
  int side = lane >> 5, fl = lane & 31;
  int s = off[r], e = off[r+1];
  int len = e - s;
  int per = (len + NC_ - 1)/NC_;
  int cs = s + c*per, ce = min(cs + per, e);
  float4 acc = make_float4(0.f,0.f,0.f,0.f);
  if (fl < RH4){
    const int* idx = side ? tr : hr;
    const float* wv = side ? s2p : s1p;
    int fofs = side ? 25 + fl : fl;
    int p = cs;
    for (; p + 1 < ce; p += 2){
      float a0 = wv[p], a1 = wv[p+1];
      float4 v0 = xhxt4[(size_t)idx[p]*50 + fofs];
      float4 v1 = xhxt4[(size_t)idx[p+1]*50 + fofs];
      acc.x += a0*v0.x + a1*v1.x; acc.y += a0*v0.y + a1*v1.y;
      acc.z += a0*v0.z + a1*v1.z; acc.w += a0*v0.w + a1*v1.w;
    }
    if (p < ce){
      float a0 = wv[p];
      float4 v0 = xhxt4[(size_t)idx[p]*50 + fofs];
      acc.x += a0*v0.x; acc.y += a0*v0.y; acc.z += a0*v0.z; acc.w += a0*v0.w;
    }
  }
  float4 oth;
  oth.x = __shfl_xor(acc.x, 32); oth.y = __shfl_xor(acc.y, 32);
  oth.z = __shfl_xor(acc.z, 32); oth.w = __shfl_xor(acc.w, 32);
  if (side == 0 && fl < RH4){
    float4 o = make_float4(acc.x+oth.x, acc.y+oth.y, acc.z+oth.z, acc.w+oth.w);
    xr_part[((size_t)c*R_ + r)*RH4 + fl] = o;
  }
}

// reduce xr_part -> xr AND compute sr8
__global__ void k_e2r_red2(const float4* __restrict__ xr_part, float4* __restrict__ xr4,
                           const float* __restrict__ ar, float* __restrict__ sr8){
  __shared__ float row[RH_];
  int r = blockIdx.x, lane = threadIdx.x;
  if (lane < RH4){
    float4 a = make_float4(0.f,0.f,0.f,0.f);
    #pragma unroll
    for (int c = 0; c < NC_; ++c){
      float4 v = xr_part[((size_t)c*R_ + r)*RH4 + lane];
      a.x += v.x; a.y += v.y; a.z += v.z; a.w += v.w;
    }
    a.x *= 0.25f; a.y *= 0.25f; a.z *= 0.25f; a.w *= 0.25f;
    xr4[(size_t)r*RH4 + lane] = a;
    row[lane*4]   = a.x; row[lane*4+1] = a.y;
    row[lane*4+2] = a.z; row[lane*4+3] = a.w;
  }
  __syncthreads();
  int h = lane & 7, gk = lane >> 3;
  float acc = 0.f;
  for (int k = gk; k < RH_; k += 8) acc += row[k]*ar[(size_t)h*RH_ + k];
  #pragma unroll
  for (int o = 8; o < 64; o <<= 1) acc += __shfl_xor(acc, o);
  if (lane < 8) sr8[(size_t)r*8 + lane] = acc;
}

// ---------------- 16-head dots from one bf16 table (R2E) ----------------
__global__ void k_dots16b(const unsigned short* __restrict__ X, int ldx, int K, int Kw,
                          const float* __restrict__ wA, const float* __restrict__ wB,
                          float* __restrict__ out16, int M){
  __shared__ float xs[16][65];
  __shared__ float ws[16][65];
  int tid = threadIdx.x;
  int tx = tid & 15, ty = tid >> 4;
  int r0 = blockIdx.x*16;
  int lr = tid >> 4;
  int lc = (tid & 15)*4;
  float acc = 0.f;
  for (int c0 = 0; c0 < K; c0 += 64){
    int cl = min(64, K - c0);
    float4 xv = make_float4(0.f,0.f,0.f,0.f);
    if (r0 + lr < M && lc < cl){
      ushort4 u = *reinterpret_cast<const ushort4*>(&X[(size_t)(r0+lr)*ldx + c0 + lc]);
      xv.x = bf2f_(u.x); xv.y = bf2f_(u.y); xv.z = bf2f_(u.z); xv.w = bf2f_(u.w);
    }
    float4 wv = make_float4(0.f,0.f,0.f,0.f);
    if (lc < cl){
      const float* wsrc = (lr < 8) ? &wA[(size_t)lr*Kw + c0 + lc]
                                   : &wB[(size_t)(lr-8)*Kw + c0 + lc];
      wv = *reinterpret_cast<const float4*>(wsrc);
    }
    xs[lr][lc] = xv.x; xs[lr][lc+1] = xv.y; xs[lr][lc+2] = xv.z; xs[lr][lc+3] = xv.w;
    ws[lr][lc] = wv.x; ws[lr][lc+1] = wv.y; ws[lr][lc+2] = wv.z; ws[lr][lc+3] = wv.w;
    __syncthreads();
    #pragma unroll
    for (int k = 0; k < 64; ++k) acc += xs[ty][k]*ws[tx][k];
    __syncthreads();
  }
  if (r0 + ty < M) out16[(size_t)(r0+ty)*16 + tx] = acc;
}

// ---------------- GAT head dots: both tables in one launch ----------------
__global__ void k_dots16g(const unsigned short* __restrict__ xb,
                          const unsigned short* __restrict__ xeb,
                          const float* __restrict__ wA, const float* __restrict__ wB,
                          float* __restrict__ out16, int M){
  __shared__ float xs[16][65];
  __shared__ float ws[16][65];
  int tid = threadIdx.x;
  int tx = tid & 15, ty = tid >> 4;
  int r0 = blockIdx.x*16;
  int lr = tid >> 4;
  int lc = (tid & 15)*4;
  float acc = 0.f;
  for (int c0 = 0; c0 < 500; c0 += 64){
    int cl = min(64, 500 - c0);
    int col = c0 + lc;
    float4 xv = make_float4(0.f,0.f,0.f,0.f);
    if (r0 + lr < M && lc < cl){
      ushort4 u = (col < 300)
        ? *reinterpret_cast<const ushort4*>(&xb[(size_t)(r0+lr)*XBS_ + col])
        : *reinterpret_cast<const ushort4*>(&xeb[(size_t)(r0+lr)*XEBS_ + col - 300]);
      xv.x = bf2f_(u.x); xv.y = bf2f_(u.y); xv.z = bf2f_(u.z); xv.w = bf2f_(u.w);
    }
    float4 wv = make_float4(0.f,0.f,0.f,0.f);
    if (lc < cl){
      const float* wsrc = (lr < 8) ? &wA[(size_t)lr*500 + col]
                                   : &wB[(size_t)(lr-8)*500 + col];
      wv = *reinterpret_cast<const float4*>(wsrc);
    }
    xs[lr][lc] = xv.x; xs[lr][lc+1] = xv.y; xs[lr][lc+2] = xv.z; xs[lr][lc+3] = xv.w;
    ws[lr][lc] = wv.x; ws[lr][lc+1] = wv.y; ws[lr][lc+2] = wv.z; ws[lr][lc+3] = wv.w;
    __syncthreads();
    #pragma unroll
    for (int k = 0; k < 64; ++k) acc += xs[ty][k]*ws[tx][k];
    __syncthreads();
  }
  if (r0 + ty < M) out16[(size_t)(r0+ty)*16 + tx] = acc;
}

// ---------------- fused R2E: softmax + aggregate (no barriers; 1 wave/side) ----------------
__global__ void k_r2e_fused(const int* __restrict__ offh, const int* __restrict__ offt,
                            const int* __restrict__ relh, const int* __restrict__ relt,
                            const float* __restrict__ st16, const float* __restrict__ sr8,
                            const float4* __restrict__ xr4, float4* __restrict__ out,
                            unsigned short* __restrict__ xeb){
  int n = blockIdx.x;
  int side = threadIdx.x >> 6, lane = threadIdx.x & 63;
  const int* off = side ? offt : offh;
  const int* rl  = side ? relt : relh;
  int s = off[n], e = off[n+1];
  int k = lane & 7, g = lane >> 3;
  float cst = st16[(size_t)n*16 + side*8 + k];
  float m = -1e30f;
  for (int p = s + g; p < e; p += 8)
    m = fmaxf(m, lrelu_(cst + sr8[(size_t)rl[p]*8 + k]));
  #pragma unroll
  for (int o = 8; o < 64; o <<= 1) m = fmaxf(m, __shfl_xor(m, o));
  float sum = 0.f;
  for (int p = s + g; p < e; p += 8)
    sum += expf(lrelu_(cst + sr8[(size_t)rl[p]*8 + k]) - m);
  #pragma unroll
  for (int o = 8; o < 64; o <<= 1) sum += __shfl_xor(sum, o);
  float inv = 1.f / (sum + 1e-16f);
  // broadcast per-head constants to all lanes
  float mks[8], invs[8], csts[8];
  int gb = lane & 56;
  #pragma unroll
  for (int kk = 0; kk < 8; ++kk){
    mks[kk]  = __shfl(m,   gb + kk);
    invs[kk] = __shfl(inv, gb + kk);
    csts[kk] = __shfl(cst, gb + kk);
  }
  float4 acc = make_float4(0.f,0.f,0.f,0.f);
  for (int base = s; base < e; base += 64){
    int mm = min(64, e - base);
    int rlv = 0; float alpha = 0.f;
    if (lane < mm){
      rlv = rl[base + lane];
      const float4* sr4 = reinterpret_cast<const float4*>(&sr8[(size_t)rlv*8]);
      float4 s0 = sr4[0], s1 = sr4[1];
      float sv[8] = {s0.x,s0.y,s0.z,s0.w,s1.x,s1.y,s1.z,s1.w};
      #pragma unroll
      for (int kk = 0; kk < 8; ++kk)
        alpha += expf(lrelu_(csts[kk] + sv[kk]) - mks[kk]) * invs[kk];
    }
    for (int q = 0; q < mm; ++q){
      float a = __shfl(alpha, q);
      int rr = __shfl(rlv, q);
      if (lane < RH4){
        float4 v = xr4[(size_t)rr*RH4 + lane];
        acc.x += a*v.x; acc.y += a*v.y; acc.z += a*v.z; acc.w += a*v.w;
      }
    }
  }
  if (lane < RH4){
    float4 o = make_float4(acc.x*0.125f, acc.y*0.125f, acc.z*0.125f, acc.w*0.125f);
    out[(size_t)n*LD4 + (side ? 100 : 75) + lane] = o;
    ushort4 ob;
    ob.x = f2bf_(o.x); ob.y = f2bf_(o.y); ob.z = f2bf_(o.z); ob.w = f2bf_(o.w);
    *reinterpret_cast<ushort4*>(&xeb[(size_t)n*XEBS_ + (side ? 100 : 0) + lane*4]) = ob;
  }
}

// ---------------- fused GAT: softmax + aggregate ----------------
__global__ void k_gat_fused(const int* __restrict__ off, const int* __restrict__ jd,
                            const float* __restrict__ gg16,
                            const unsigned short* __restrict__ xb,
                            const unsigned short* __restrict__ xeb,
                            float4* __restrict__ out){
  __shared__ int js[128];
  __shared__ float as_[128];
  __shared__ float wred[2][8];
  __shared__ float mkS[8], invS[8], cstS[8];
  int n = blockIdx.x, tid = threadIdx.x;
  int wv = tid >> 6, lane = tid & 63;
  int s = off[n], t = off[n+1];
  int k = tid & 7, g = tid >> 3;     // 16 groups x 8 heads
  float cst = gg16[(size_t)n*16 + k];
  // stats: max
  float m = -1e30f;
  for (int p = s + g; p < t; p += 16){
    int j = jd[p];
    m = fmaxf(m, lrelu_(cst + gg16[(size_t)j*16 + 8 + k]));
  }
  #pragma unroll
  for (int o = 8; o < 64; o <<= 1) m = fmaxf(m, __shfl_xor(m, o));
  if (lane < 8) wred[wv][lane] = m;
  __syncthreads();
  if (tid < 8) mkS[tid] = fmaxf(wred[0][tid], wred[1][tid]);
  __syncthreads();
  float mk = mkS[k];
  // stats: sum
  float sum = 0.f;
  for (int p = s + g; p < t; p += 16){
    int j = jd[p];
    sum += expf(lrelu_(cst + gg16[(size_t)j*16 + 8 + k]) - mk);
  }
  #pragma unroll
  for (int o = 8; o < 64; o <<= 1) sum += __shfl_xor(sum, o);
  if (lane < 8) wred[wv][lane] = sum;
  __syncthreads();
  if (tid < 8){
    invS[tid] = 1.f / (wred[0][tid] + wred[1][tid] + 1e-16f);
    cstS[tid] = gg16[(size_t)n*16 + tid];
  }
  __syncthreads();
  // aggregate
  const unsigned short* tbl;
  size_t stride; int cofs;
  if (tid < 75){ tbl = xb;  stride = XBS_;  cofs = tid*4; }
  else         { tbl = xeb; stride = XEBS_; cofs = (tid-75)*4; }
  float4 acc = make_float4(0.f,0.f,0.f,0.f);
  for (int base = s; base < t; base += 128){
    int mm = min(128, t - base);
    __syncthreads();
    if (tid < mm) js[tid] = jd[base+tid];
    __syncthreads();
    if (tid < mm){
      int j = js[tid];
      const float4* gj = reinterpret_cast<const float4*>(&gg16[(size_t)j*16 + 8]);
      float4 l0 = gj[0], l1 = gj[1];
      float a = 0.f;
      a += expf(lrelu_(cstS[0] + l0.x) - mkS[0]) * invS[0];
      a += expf(lrelu_(cstS[1] + l0.y) - mkS[1]) * invS[1];
      a += expf(lrelu_(cstS[2] + l0.z) - mkS[2]) * invS[2];
      a += expf(lrelu_(cstS[3] + l0.w) - mkS[3]) * invS[3];
      a += expf(lrelu_(cstS[4] + l1.x) - mkS[4]) * invS[4];
      a += expf(lrelu_(cstS[5] + l1.y) - mkS[5]) * invS[5];
      a += expf(lrelu_(cstS[6] + l1.z) - mkS[6]) * invS[6];
      a += expf(lrelu_(cstS[7] + l1.w) - mkS[7]) * invS[7];
      as_[tid] = a;
    }
    __syncthreads();
    if (tid < 125){
      int q = 0;
      for (; q + 3 < mm; q += 4){
        float a0 = as_[q], a1 = as_[q+1], a2 = as_[q+2], a3 = as_[q+3];
        ushort4 u0 = *reinterpret_cast<const ushort4*>(&tbl[(size_t)js[q]*stride + cofs]);
        ushort4 u1 = *reinterpret_cast<const ushort4*>(&tbl[(size_t)js[q+1]*stride + cofs]);
        ushort4 u2 = *reinterpret_cast<const ushort4*>(&tbl[(size_t)js[q+2]*stride + cofs]);
        ushort4 u3 = *reinterpret_cast<const ushort4*>(&tbl[(size_t)js[q+3]*stride + cofs]);
        acc.x += a0*bf2f_(u0.x)+a1*bf2f_(u1.x)+a2*bf2f_(u2.x)+a3*bf2f_(u3.x);
        acc.y += a0*bf2f_(u0.y)+a1*bf2f_(u1.y)+a2*bf2f_(u2.y)+a3*bf2f_(u3.y);
        acc.z += a0*bf2f_(u0.z)+a1*bf2f_(u1.z)+a2*bf2f_(u2.z)+a3*bf2f_(u3.z);
        acc.w += a0*bf2f_(u0.w)+a1*bf2f_(u1.w)+a2*bf2f_(u2.w)+a3*bf2f_(u3.w);
      }
      for (; q < mm; ++q){
        float a0 = as_[q];
        ushort4 u0 = *reinterpret_cast<const ushort4*>(&tbl[(size_t)js[q]*stride + cofs]);
        acc.x += a0*bf2f_(u0.x); acc.y += a0*bf2f_(u0.y);
        acc.z += a0*bf2f_(u0.z); acc.w += a0*bf2f_(u0.w);
      }
    }
  }
  if (tid < 125){
    float4 r = make_float4(acc.x*0.125f, acc.y*0.125f, acc.z*0.125f, acc.w*0.125f);
    out[(size_t)n*LD4 + 125 + tid] = r;
  }
}

// ---------------- host ----------------
static inline void gemm_mfma(const unsigned short* Ab, const unsigned short* Wb,
                             float* C, int ldc, int M, int Nn, hipStream_t st){
  dim3 g((M + 127)/128, (Nn + 63)/64);
  k_gemm_mfma<<<g, 256, 0, st>>>(Ab, Wb, C, ldc, M, Nn);
}

extern "C" void kernel_launch(void* const* d_in, const int* in_sizes, int n_in,
                              void* d_out, int out_size, void* d_ws, size_t ws_size,
                              hipStream_t stream) {
  const float* x_e   = (const float*)d_in[0];
  const int*   ei    = (const int*)d_in[1];
  const int*   rel   = (const int*)d_in[2];
  const int*   eia   = (const int*)d_in[3];
  const float* hw1_w = (const float*)d_in[5];
  const float* hw1_b = (const float*)d_in[6];
  const float* hw2_w = (const float*)d_in[7];
  const float* hw2_b = (const float*)d_in[8];
  const float* e2r_wh= (const float*)d_in[9];
  const float* e2r_wt= (const float*)d_in[10];
  const float* e2r_ah= (const float*)d_in[11];
  const float* e2r_at= (const float*)d_in[12];
  const float* r2e_ah= (const float*)d_in[13];
  const float* r2e_at= (const float*)d_in[14];
  const float* r2e_ar= (const float*)d_in[15];
  const float* gat_ai= (const float*)d_in[16];
  const float* gat_aj= (const float*)d_in[17];
  float* out = (float*)d_out;

  const int* hi = ei;
  const int* ti = ei + E_;
  const int* ja = eia;
  const int* ia = eia + EALL_;

  char* base = (char*)d_ws;
  size_t off = 0;
  auto alloc = [&](size_t bytes)->void*{
    void* p = base + off;
    off = (off + bytes + 255) & ~(size_t)255;
    return p;
  };

  size_t z0 = off;
  int* cnt_dest = (int*)alloc(SCNP_*4);
  int* cnt_h    = (int*)alloc(SCNP_*4);
  int* cnt_t    = (int*)alloc(SCNP_*4);
  int* cur_dest = (int*)alloc(N_*4);
  int* cur_h    = (int*)alloc(N_*4);
  int* cur_t    = (int*)alloc(N_*4);
  size_t z1 = off;

  int* off_dest = (int*)alloc(SCNP_*4);
  int* off_h    = (int*)alloc(SCNP_*4);
  int* off_t    = (int*)alloc(SCNP_*4);
  int* off_rel  = (int*)alloc((R_+1)*4);
  int* bsum     = (int*)alloc(3*NSB_*4);
  int* Hrel     = (int*)alloc((size_t)NBR_*R_*4);
  int* j_dest   = (int*)alloc((size_t)EALL_*4);
  int* hr       = (int*)alloc((size_t)E_*4);
  int* tr       = (int*)alloc((size_t)E_*4);
  int* relh     = (int*)alloc((size_t)E_*4);
  int* relt     = (int*)alloc((size_t)E_*4);

  float* dis   = (float*)alloc(SCNP_*4);
  float* wj    = (float*)alloc((size_t)EALL_*4);
  float* g     = (float*)alloc((size_t)N_*EH_*4);
  float* xhxt  = (float*)alloc((size_t)N_*200*4);
  float* pht   = (float*)alloc((size_t)N_*8*4);
  float* s1p   = (float*)alloc((size_t)E_*4);
  float* s2p   = (float*)alloc((size_t)E_*4);
  float* xr    = (float*)alloc((size_t)R_*RH_*4);
  float* xr_part=(float*)alloc((size_t)NC_*R_*RH_*4);
  float* st16  = (float*)alloc((size_t)N_*16*4);
  float* sr8   = (float*)alloc((size_t)R_*8*4);
  float* gg16  = (float*)alloc((size_t)N_*16*4);
  unsigned short* xbA = (unsigned short*)alloc((size_t)N_*XBS_*2);
  unsigned short* xbB = (unsigned short*)alloc((size_t)N_*XBS_*2);
  unsigned short* xeb = (unsigned short*)alloc((size_t)N_*XEBS_*2);
  unsigned short* w1b = (unsigned short*)alloc((size_t)EH_*KP_*2);
  unsigned short* w2b = (unsigned short*)alloc((size_t)EH_*KP_*2);
  unsigned short* wcb = (unsigned short*)alloc((size_t)200*KP_*2);

  hipMemsetAsync(base + z0, 0, z1 - z0, stream);

  const int TB = 256;
  const int TOT = EALL_ + 2*E_;
  int gTOT  = (TOT + TB - 1)/TB;
  int gN    = (N_ + TB - 1)/TB;
  const int PTOT = 2*EH_*KP_ + 200*KP_ + N_*80;

  // packs (weights + x_e) in one launch
  k_pack_all<<<(PTOT + TB - 1)/TB, TB, 0, stream>>>(hw1_w, hw2_w, e2r_wh, e2r_wt,
                                                    (const float4*)x_e,
                                                    w1b, w2b, wcb, xbA);

  // CSR build
  k_build1<<<NBR_ + gTOT, TB, 0, stream>>>(rel, ia, hi, ti, Hrel, cnt_dest, cnt_h, cnt_t);
  k_scanA<<<3*NSB_, 256, 0, stream>>>(cnt_dest, cnt_h, cnt_t, bsum);
  k_mid<<<2, 256, 0, stream>>>(Hrel, off_rel, bsum, off_dest, off_h, off_t);
  k_scanC<<<3*NSB_, 256, 0, stream>>>(cnt_dest, cnt_h, cnt_t, bsum,
                                      off_dest, off_h, off_t, dis);
  k_build2<<<NBR_ + gTOT, TB, 0, stream>>>(rel, hi, ti, Hrel, hr, tr,
                                           ja, ia, off_dest, off_h, off_t,
                                           cur_dest, cur_h, cur_t,
                                           dis, j_dest, wj, relh, relt);

  // GCN + highway block 1: gather xbA -> out cols 0..299 + xbB
  gemm_mfma(xbA, w1b, g, EH_, N_, EH_, stream);
  k_gcn5<<<N_, 64, 0, stream>>>(off_dest, j_dest, wj, dis, xbA,
                                (const float4*)g, hw1_b, (float4*)out, xbB);
  // block 2
  gemm_mfma(xbB, w2b, g, EH_, N_, EH_, stream);
  k_gcn5<<<N_, 64, 0, stream>>>(off_dest, j_dest, wj, dis, xbB,
                                (const float4*)g, hw2_b, (float4*)out, xbA);

  // E2R
  gemm_mfma(xbA, wcb, xhxt, 200, N_, 200, stream);
  k_pproj<<<gN, TB, 0, stream>>>(xhxt, e2r_ah, e2r_at, (float4*)pht);
  k_fold_rel2<<<R_, 256, 0, stream>>>(off_rel, hr, tr, (const float4*)pht, s1p, s2p);
  k_e2r_agg3<<<dim3(R_, NC_), 64, 0, stream>>>(off_rel, hr, tr, s1p, s2p,
                                               (const float4*)xhxt, (float4*)xr_part);
  k_e2r_red2<<<R_, 64, 0, stream>>>((const float4*)xr_part, (float4*)xr, r2e_ar, sr8);

  // R2E (fused softmax + aggregate)
  k_dots16b<<<(N_+15)/16, 256, 0, stream>>>(xbA, XBS_, EH_, EH_, r2e_ah, r2e_at, st16, N_);
  k_r2e_fused<<<N_, 128, 0, stream>>>(off_h, off_t, relh, relt, st16, sr8,
                                      (const float4*)xr, (float4*)out, xeb);

  // GAT (single dots launch + fused softmax/aggregate)
  k_dots16g<<<(N_+15)/16, 256, 0, stream>>>(xbA, xeb, gat_ai, gat_aj, gg16, N_);
  k_gat_fused<<<N_, 128, 0, stream>>>(off_dest, j_dest, gg16, xbA, xeb, (float4*)out);
}

// Round 11
// 575.878 us; speedup vs baseline: 4.0705x; 1.0049x over previous
//
#include <hip/hip_runtime.h>
#include <math.h>

constexpr int N_    = 30000;
constexpr int E_    = 200000;
constexpr int EALL_ = 400000;
constexpr int R_    = 500;
constexpr int EH_   = 300;
constexpr int RH_   = 100;
constexpr int OUTD_ = 1000;
constexpr int LD4   = OUTD_/4;  // 250
constexpr int EH4   = EH_/4;    // 75
constexpr int RH4   = RH_/4;    // 25
constexpr int NC_   = 16;
constexpr int XBS_  = 320;      // bf16 row stride, zero-padded K for MFMA
constexpr int XEBS_ = 200;
constexpr int KP_   = 320;
constexpr int NBR_  = 64;
constexpr int PERB_ = (E_ + NBR_ - 1)/NBR_;
constexpr int SCB_  = 2048;
constexpr int NSB_  = (N_ + SCB_ - 1)/SCB_;
constexpr int SCNP_ = NSB_*SCB_;

typedef __attribute__((ext_vector_type(4))) float f32x4;
typedef __attribute__((ext_vector_type(8))) short s16x8;

__device__ __forceinline__ float lrelu_(float v){ return v > 0.f ? v : 0.01f*v; }
__device__ __forceinline__ float sig_(float z){ return 1.f/(1.f + expf(-z)); }
__device__ __forceinline__ unsigned short f2bf_(float f){
  unsigned int u = __float_as_uint(f);
  unsigned int r = (u + 0x7FFFu + ((u >> 16) & 1u)) >> 16;
  return (unsigned short)r;
}
__device__ __forceinline__ float bf2f_(unsigned short h){
  return __uint_as_float(((unsigned int)h) << 16);
}
// online softmax accumulate: (m,s) += logit l
__device__ __forceinline__ void onl_add_(float& m, float& s, float l){
  if (l <= m) s += expf(l - m);
  else { s = s*expf(m - l) + 1.f; m = l; }
}
// combine two online states
__device__ __forceinline__ void onl_cmb_(float& m, float& s, float om, float os){
  float nm = fmaxf(m, om);
  s = s*expf(m - nm) + os*expf(om - nm);
  m = nm;
}

// ---------------- merged pack: weights + x_e ----------------
__global__ void k_pack_all(const float* __restrict__ w1, const float* __restrict__ w2,
                           const float* __restrict__ wh, const float* __restrict__ wt,
                           const float4* __restrict__ Xe,
                           unsigned short* w1b, unsigned short* w2b,
                           unsigned short* wcb, unsigned short* xb){
  int idx = blockIdx.x*blockDim.x + threadIdx.x;
  if (idx < EH_*KP_){
    int n = idx/KP_, k = idx - n*KP_;
    w1b[idx] = (k < EH_) ? f2bf_(w1[(size_t)n*EH_ + k]) : (unsigned short)0;
    return;
  }
  idx -= EH_*KP_;
  if (idx < EH_*KP_){
    int n = idx/KP_, k = idx - n*KP_;
    w2b[idx] = (k < EH_) ? f2bf_(w2[(size_t)n*EH_ + k]) : (unsigned short)0;
    return;
  }
  idx -= EH_*KP_;
  if (idx < 200*KP_){
    int n = idx/KP_, k = idx - n*KP_;
    wcb[idx] = (k < EH_) ? f2bf_((n < 100) ? wh[(size_t)n*EH_ + k] : wt[(size_t)(n-100)*EH_ + k])
                         : (unsigned short)0;
    return;
  }
  idx -= 200*KP_;
  if (idx < N_*80){
    int n = idx/80, c = idx - n*80;
    ushort4 o = make_ushort4(0,0,0,0);
    if (c < EH4){
      float4 v = Xe[(size_t)n*EH4 + c];
      o.x = f2bf_(v.x); o.y = f2bf_(v.y); o.z = f2bf_(v.z); o.w = f2bf_(v.w);
    }
    *reinterpret_cast<ushort4*>(&xb[(size_t)n*XBS_ + c*4]) = o;
  }
}

// ---------------- merged: rel hist + dest/h/t counts ----------------
__global__ void k_build1(const int* __restrict__ rel, const int* __restrict__ ia,
                         const int* __restrict__ hi, const int* __restrict__ ti,
                         int* __restrict__ H, int* cd, int* ch, int* ct){
  __shared__ int h[R_];
  int tid = threadIdx.x;
  if ((int)blockIdx.x < NBR_){
    int b = blockIdx.x;
    for (int i = tid; i < R_; i += 256) h[i] = 0;
    __syncthreads();
    int s = b*PERB_, e = min(s + PERB_, E_);
    for (int i = s + tid; i < e; i += 256) atomicAdd(&h[rel[i]], 1);
    __syncthreads();
    for (int i = tid; i < R_; i += 256) H[b*R_ + i] = h[i];
    return;
  }
  int idx = (blockIdx.x - NBR_)*256 + tid;
  if (idx < EALL_) { atomicAdd(&cd[ia[idx]], 1); return; }
  idx -= EALL_;
  if (idx < E_) { atomicAdd(&ch[hi[idx]], 1); return; }
  idx -= E_;
  if (idx < E_) { atomicAdd(&ct[ti[idx]], 1); return; }
}

// ---------------- scanA ----------------
__global__ void k_scanA(const int* __restrict__ c0, const int* __restrict__ c1,
                        const int* __restrict__ c2, int* __restrict__ bsum){
  int arr = blockIdx.x / NSB_, b = blockIdx.x - arr*NSB_;
  const int* c = arr == 0 ? c0 : (arr == 1 ? c1 : c2);
  int t = threadIdx.x;
  const int4* c4 = reinterpret_cast<const int4*>(c + b*SCB_ + t*8);
  int4 u0 = c4[0], u1 = c4[1];
  int acc = u0.x+u0.y+u0.z+u0.w + u1.x+u1.y+u1.z+u1.w;
  __shared__ int red[256];
  red[t] = acc;
  __syncthreads();
  for (int o = 128; o > 0; o >>= 1){
    if (t < o) red[t] += red[t+o];
    __syncthreads();
  }
  if (t == 0) bsum[arr*NSB_ + b] = red[0];
}

// ---------------- merged: relscan + scanB ----------------
__global__ void k_mid(int* __restrict__ H, int* __restrict__ off_rel,
                      int* __restrict__ bsum, int* o0, int* o1, int* o2){
  __shared__ int tot[R_];
  __shared__ int sc[256];
  int tid = threadIdx.x;
  if (blockIdx.x == 1){
    if (tid < 3){
      int run = 0;
      for (int b = 0; b < NSB_; ++b){ int v = bsum[tid*NSB_ + b]; bsum[tid*NSB_ + b] = run; run += v; }
      int* o = tid == 0 ? o0 : (tid == 1 ? o1 : o2);
      o[N_] = run;
    }
    return;
  }
  for (int r = tid; r < R_; r += 256){
    int acc = 0;
    for (int b = 0; b < NBR_; ++b){ int v = H[b*R_ + r]; H[b*R_ + r] = acc; acc += v; }
    tot[r] = acc;
  }
  __syncthreads();
  int r0 = tid*2;
  int a0 = (r0 < R_) ? tot[r0] : 0;
  int a1 = (r0+1 < R_) ? tot[r0+1] : 0;
  sc[tid] = a0 + a1;
  __syncthreads();
  for (int off = 1; off < 256; off <<= 1){
    int add = (tid >= off) ? sc[tid-off] : 0;
    __syncthreads();
    sc[tid] += add;
    __syncthreads();
  }
  int run = tid ? sc[tid-1] : 0;
  if (r0 < R_)   off_rel[r0]   = run;
  if (r0+1 < R_) off_rel[r0+1] = run + a0;
  if (tid == 255) off_rel[R_] = sc[255];
  __syncthreads();
  for (int r = tid; r < R_; r += 256){
    int o = off_rel[r];
    for (int b = 0; b < NBR_; ++b) H[b*R_ + r] += o;
  }
}

// ---------------- scanC (+dis) ----------------
__global__ void k_scanC(const int* __restrict__ c0, const int* __restrict__ c1,
                        const int* __restrict__ c2, const int* __restrict__ bsum,
                        int* o0, int* o1, int* o2, float* __restrict__ dis){
  int arr = blockIdx.x / NSB_, b = blockIdx.x - arr*NSB_;
  const int* c = arr == 0 ? c0 : (arr == 1 ? c1 : c2);
  int* o = arr == 0 ? o0 : (arr == 1 ? o1 : o2);
  int t = threadIdx.x;
  int base = b*SCB_ + t*8;
  const int4* c4 = reinterpret_cast<const int4*>(c + base);
  int4 u0 = c4[0], u1 = c4[1];
  int v[8] = {u0.x,u0.y,u0.z,u0.w,u1.x,u1.y,u1.z,u1.w};
  int tot = v[0]+v[1]+v[2]+v[3]+v[4]+v[5]+v[6]+v[7];
  __shared__ int sc[256];
  sc[t] = tot;
  __syncthreads();
  for (int off = 1; off < 256; off <<= 1){
    int add = (t >= off) ? sc[t-off] : 0;
    __syncthreads();
    sc[t] += add;
    __syncthreads();
  }
  int run = bsum[arr*NSB_ + b] + (t ? sc[t-1] : 0);
  #pragma unroll
  for (int i = 0; i < 8; ++i){
    int idx = base + i;
    o[idx] = run;
    if (arr == 0) dis[idx] = v[i] > 0 ? rsqrtf((float)v[i]) : 0.f;
    run += v[i];
  }
}

// ---------------- merged: relscatter + dest/h/t scatter ----------------
__global__ void k_build2(const int* __restrict__ rel, const int* __restrict__ hi,
                         const int* __restrict__ ti, const int* __restrict__ H,
                         int* __restrict__ hr, int* __restrict__ tr,
                         const int* __restrict__ ja, const int* __restrict__ ia,
                         const int* od, const int* oh, const int* ot,
                         int* curd, int* curh, int* curt,
                         const float* __restrict__ dis,
                         int* j_dest, float* wj, int* relh, int* relt){
  __shared__ int cur[R_];
  int tid = threadIdx.x;
  if ((int)blockIdx.x < NBR_){
    int b = blockIdx.x;
    for (int i = tid; i < R_; i += 256) cur[i] = H[b*R_ + i];
    __syncthreads();
    int s = b*PERB_, e = min(s + PERB_, E_);
    for (int i = s + tid; i < e; i += 256){
      int r = rel[i];
      int p = atomicAdd(&cur[r], 1);
      hr[p] = hi[i]; tr[p] = ti[i];
    }
    return;
  }
  int idx = (blockIdx.x - NBR_)*256 + tid;
  if (idx < EALL_){
    int e = idx, s = ia[e];
    int p = od[s] + atomicAdd(&curd[s], 1);
    int j = ja[e];
    j_dest[p] = j; wj[p] = dis[j]; return;
  }
  idx -= EALL_;
  if (idx < E_){
    int e = idx, s = hi[e];
    int p = oh[s] + atomicAdd(&curh[s], 1);
    relh[p] = rel[e]; return;
  }
  idx -= E_;
  if (idx < E_){
    int e = idx, s = ti[e];
    int p = ot[s] + atomicAdd(&curt[s], 1);
    relt[p] = rel[e]; return;
  }
}

// ---------------- MFMA GEMM ----------------
__global__ __launch_bounds__(256) void k_gemm_mfma(
    const unsigned short* __restrict__ Ab,
    const unsigned short* __restrict__ Wb,
    float* __restrict__ C, int ldc, int M, int Nn){
  constexpr int WS = 328;
  constexpr int AS = 40;
  __shared__ unsigned short Ws[64*WS];
  __shared__ unsigned short As[128*AS];
  int tid = threadIdx.x;
  int lane = tid & 63, wave = tid >> 6;
  int wm = wave & 1, wn = wave >> 1;
  int m0 = blockIdx.x*128, n0 = blockIdx.y*64;

  for (int c = tid; c < 64*(KP_/8); c += 256){
    int n = c / (KP_/8), k8 = (c % (KP_/8))*8;
    s16x8 v = {0,0,0,0,0,0,0,0};
    if (n0 + n < Nn)
      v = *reinterpret_cast<const s16x8*>(&Wb[(size_t)(n0+n)*KP_ + k8]);
    *reinterpret_cast<s16x8*>(&Ws[n*WS + k8]) = v;
  }

  f32x4 acc[4][2] = {};
  int kf = (lane >> 4)*8;
  int rA = lane & 15;
  for (int k0 = 0; k0 < KP_; k0 += 32){
    __syncthreads();
    for (int c = tid; c < 128*4; c += 256){
      int r = c >> 2, k8 = (c & 3)*8;
      s16x8 v = {0,0,0,0,0,0,0,0};
      if (m0 + r < M)
        v = *reinterpret_cast<const s16x8*>(&Ab[(size_t)(m0+r)*XBS_ + k0 + k8]);
      *reinterpret_cast<s16x8*>(&As[r*AS + k8]) = v;
    }
    __syncthreads();
    s16x8 afr[4], bfr[2];
    #pragma unroll
    for (int mf = 0; mf < 4; ++mf)
      afr[mf] = *reinterpret_cast<const s16x8*>(&As[(wm*64 + mf*16 + rA)*AS + kf]);
    #pragma unroll
    for (int nf = 0; nf < 2; ++nf)
      bfr[nf] = *reinterpret_cast<const s16x8*>(&Ws[(wn*32 + nf*16 + rA)*WS + k0 + kf]);
    #pragma unroll
    for (int mf = 0; mf < 4; ++mf)
      #pragma unroll
      for (int nf = 0; nf < 2; ++nf)
        acc[mf][nf] = __builtin_amdgcn_mfma_f32_16x16x32_bf16(afr[mf], bfr[nf], acc[mf][nf], 0, 0, 0);
  }
  int col0 = n0 + wn*32 + (lane & 15);
  int rbase = m0 + wm*64 + (lane >> 4)*4;
  #pragma unroll
  for (int mf = 0; mf < 4; ++mf){
    #pragma unroll
    for (int nf = 0; nf < 2; ++nf){
      int col = col0 + nf*16;
      if (col < Nn){
        #pragma unroll
        for (int r = 0; r < 4; ++r){
          int row = rbase + mf*16 + r;
          if (row < M) C[(size_t)row*ldc + col] = acc[mf][nf][r];
        }
      }
    }
  }
}

// ---------------- fused GCN gather + highway + bf16 repack ----------------
__global__ void k_gcn5(const int* __restrict__ off, const int* __restrict__ jd,
                       const float* __restrict__ wj, const float* __restrict__ dis,
                       const unsigned short* __restrict__ xsrc,
                       const float4* __restrict__ G, const float* __restrict__ b,
                       float4* __restrict__ Xn, unsigned short* __restrict__ xdst){
  __shared__ int js[64];
  __shared__ float ws[64];
  int n = blockIdx.x, lane = threadIdx.x;   // 64
  int s = off[n], t = off[n+1];
  bool two = lane < (EH4 - 64);
  float4 a0 = make_float4(0.f,0.f,0.f,0.f);
  float4 a1 = make_float4(0.f,0.f,0.f,0.f);
  for (int base = s; base < t; base += 64){
    int m = min(64, t - base);
    __syncthreads();
    if (lane < m){ js[lane] = jd[base+lane]; ws[lane] = wj[base+lane]; }
    __syncthreads();
    int q = 0;
    for (; q + 3 < m; q += 4){
      size_t r0 = (size_t)js[q]*XBS_,   r1 = (size_t)js[q+1]*XBS_;
      size_t r2 = (size_t)js[q+2]*XBS_, r3 = (size_t)js[q+3]*XBS_;
      float w0 = ws[q], w1 = ws[q+1], w2 = ws[q+2], w3 = ws[q+3];
      ushort4 u0 = *reinterpret_cast<const ushort4*>(&xsrc[r0 + lane*4]);
      ushort4 u1 = *reinterpret_cast<const ushort4*>(&xsrc[r1 + lane*4]);
      ushort4 u2 = *reinterpret_cast<const ushort4*>(&xsrc[r2 + lane*4]);
      ushort4 u3 = *reinterpret_cast<const ushort4*>(&xsrc[r3 + lane*4]);
      a0.x += w0*bf2f_(u0.x)+w1*bf2f_(u1.x)+w2*bf2f_(u2.x)+w3*bf2f_(u3.x);
      a0.y += w0*bf2f_(u0.y)+w1*bf2f_(u1.y)+w2*bf2f_(u2.y)+w3*bf2f_(u3.y);
      a0.z += w0*bf2f_(u0.z)+w1*bf2f_(u1.z)+w2*bf2f_(u2.z)+w3*bf2f_(u3.z);
      a0.w += w0*bf2f_(u0.w)+w1*bf2f_(u1.w)+w2*bf2f_(u2.w)+w3*bf2f_(u3.w);
      if (two){
        ushort4 v0 = *reinterpret_cast<const ushort4*>(&xsrc[r0 + 256 + lane*4]);
        ushort4 v1 = *reinterpret_cast<const ushort4*>(&xsrc[r1 + 256 + lane*4]);
        ushort4 v2 = *reinterpret_cast<const ushort4*>(&xsrc[r2 + 256 + lane*4]);
        ushort4 v3 = *reinterpret_cast<const ushort4*>(&xsrc[r3 + 256 + lane*4]);
        a1.x += w0*bf2f_(v0.x)+w1*bf2f_(v1.x)+w2*bf2f_(v2.x)+w3*bf2f_(v3.x);
        a1.y += w0*bf2f_(v0.y)+w1*bf2f_(v1.y)+w2*bf2f_(v2.y)+w3*bf2f_(v3.y);
        a1.z += w0*bf2f_(v0.z)+w1*bf2f_(v1.z)+w2*bf2f_(v2.z)+w3*bf2f_(v3.z);
        a1.w += w0*bf2f_(v0.w)+w1*bf2f_(v1.w)+w2*bf2f_(v2.w)+w3*bf2f_(v3.w);
      }
    }
    for (; q < m; ++q){
      size_t r0 = (size_t)js[q]*XBS_;
      float w0 = ws[q];
      ushort4 u0 = *reinterpret_cast<const ushort4*>(&xsrc[r0 + lane*4]);
      a0.x += w0*bf2f_(u0.x); a0.y += w0*bf2f_(u0.y);
      a0.z += w0*bf2f_(u0.z); a0.w += w0*bf2f_(u0.w);
      if (two){
        ushort4 v0 = *reinterpret_cast<const ushort4*>(&xsrc[r0 + 256 + lane*4]);
        a1.x += w0*bf2f_(v0.x); a1.y += w0*bf2f_(v0.y);
        a1.z += w0*bf2f_(v0.z); a1.w += w0*bf2f_(v0.w);
      }
    }
  }
  float dn = dis[n];
  {
    int c = lane;
    float4 yv;
    yv.x = fmaxf(dn*a0.x, 0.f); yv.y = fmaxf(dn*a0.y, 0.f);
    yv.z = fmaxf(dn*a0.z, 0.f); yv.w = fmaxf(dn*a0.w, 0.f);
    float4 g4 = G[(size_t)n*EH4 + c];
    float4 b4 = reinterpret_cast<const float4*>(b)[c];
    ushort4 uo = *reinterpret_cast<const ushort4*>(&xsrc[(size_t)n*XBS_ + c*4]);
    float4 xo = make_float4(bf2f_(uo.x), bf2f_(uo.y), bf2f_(uo.z), bf2f_(uo.w));
    float gx; float4 r;
    gx = sig_(g4.x + b4.x); r.x = gx*yv.x + (1.f-gx)*xo.x;
    gx = sig_(g4.y + b4.y); r.y = gx*yv.y + (1.f-gx)*xo.y;
    gx = sig_(g4.z + b4.z); r.z = gx*yv.z + (1.f-gx)*xo.z;
    gx = sig_(g4.w + b4.w); r.w = gx*yv.w + (1.f-gx)*xo.w;
    Xn[(size_t)n*LD4 + c] = r;
    ushort4 o;
    o.x = f2bf_(r.x); o.y = f2bf_(r.y); o.z = f2bf_(r.z); o.w = f2bf_(r.w);
    *reinterpret_cast<ushort4*>(&xdst[(size_t)n*XBS_ + c*4]) = o;
  }
  if (two){
    int c = 64 + lane;
    float4 yv;
    yv.x = fmaxf(dn*a1.x, 0.f); yv.y = fmaxf(dn*a1.y, 0.f);
    yv.z = fmaxf(dn*a1.z, 0.f); yv.w = fmaxf(dn*a1.w, 0.f);
    float4 g4 = G[(size_t)n*EH4 + c];
    float4 b4 = reinterpret_cast<const float4*>(b)[c];
    ushort4 uo = *reinterpret_cast<const ushort4*>(&xsrc[(size_t)n*XBS_ + c*4]);
    float4 xo = make_float4(bf2f_(uo.x), bf2f_(uo.y), bf2f_(uo.z), bf2f_(uo.w));
    float gx; float4 r;
    gx = sig_(g4.x + b4.x); r.x = gx*yv.x + (1.f-gx)*xo.x;
    gx = sig_(g4.y + b4.y); r.y = gx*yv.y + (1.f-gx)*xo.y;
    gx = sig_(g4.z + b4.z); r.z = gx*yv.z + (1.f-gx)*xo.z;
    gx = sig_(g4.w + b4.w); r.w = gx*yv.w + (1.f-gx)*xo.w;
    Xn[(size_t)n*LD4 + c] = r;
    ushort4 o;
    o.x = f2bf_(r.x); o.y = f2bf_(r.y); o.z = f2bf_(r.z); o.w = f2bf_(r.w);
    *reinterpret_cast<ushort4*>(&xdst[(size_t)n*XBS_ + c*4]) = o;
  } else if (lane < 16){
    ushort4 z = make_ushort4(0,0,0,0);
    *reinterpret_cast<ushort4*>(&xdst[(size_t)n*XBS_ + (64+lane)*4]) = z;
  }
}

// ---------------- E2R projections -> pht[N][8] ----------------
__global__ void k_pproj(const float* __restrict__ xhxt,
                        const float* __restrict__ ah, const float* __restrict__ at,
                        float4* __restrict__ pht){
  int n = blockIdx.x*blockDim.x + threadIdx.x;
  if (n >= N_) return;
  float a0=0,a1=0,b0=0,b1=0,c0=0,c1=0,d0=0,d1=0;
  const float* xh = xhxt + (size_t)n*200;
  const float* xt = xh + 100;
  for (int f = 0; f < RH_; ++f) {
    float vh = xh[f], vt = xt[f];
    float w0 = ah[f], w1 = ah[RH_+f], u0 = at[f], u1 = at[RH_+f];
    a0 += vh*w0; a1 += vh*w1;
    b0 += vt*u0; b1 += vt*u1;
    c0 += vt*w0; c1 += vt*w1;
    d0 += vh*u0; d1 += vh*u1;
  }
  pht[(size_t)n*2]     = make_float4(a0, a1, c0, c1);
  pht[(size_t)n*2 + 1] = make_float4(b0, b1, d0, d1);
}

// ---------------- E2R fold ----------------
__global__ void k_fold_rel2(const int* __restrict__ off,
                            const int* __restrict__ hr, const int* __restrict__ tr,
                            const float4* __restrict__ pht,
                            float* __restrict__ s1p, float* __restrict__ s2p){
  __shared__ float4 redm[4];
  __shared__ float4 reds[4];
  int r = blockIdx.x;
  int tid = threadIdx.x, lane = tid & 63, w = tid >> 6;
  int s = off[r], e = off[r+1];
  float4 mx = make_float4(-1e30f,-1e30f,-1e30f,-1e30f);
  for (int p = s + tid; p < e; p += 256){
    float4 ph = pht[(size_t)hr[p]*2];
    float4 pt = pht[(size_t)tr[p]*2 + 1];
    mx.x = fmaxf(mx.x, lrelu_(ph.x + pt.x));
    mx.y = fmaxf(mx.y, lrelu_(ph.y + pt.y));
    mx.z = fmaxf(mx.z, lrelu_(ph.z + pt.z));
    mx.w = fmaxf(mx.w, lrelu_(ph.w + pt.w));
  }
  #pragma unroll
  for (int o = 1; o < 64; o <<= 1){
    mx.x = fmaxf(mx.x, __shfl_xor(mx.x, o));
    mx.y = fmaxf(mx.y, __shfl_xor(mx.y, o));
    mx.z = fmaxf(mx.z, __shfl_xor(mx.z, o));
    mx.w = fmaxf(mx.w, __shfl_xor(mx.w, o));
  }
  if (lane == 0) redm[w] = mx;
  __syncthreads();
  float4 m;
  m.x = fmaxf(fmaxf(redm[0].x, redm[1].x), fmaxf(redm[2].x, redm[3].x));
  m.y = fmaxf(fmaxf(redm[0].y, redm[1].y), fmaxf(redm[2].y, redm[3].y));
  m.z = fmaxf(fmaxf(redm[0].z, redm[1].z), fmaxf(redm[2].z, redm[3].z));
  m.w = fmaxf(fmaxf(redm[0].w, redm[1].w), fmaxf(redm[2].w, redm[3].w));
  float4 sm = make_float4(0.f,0.f,0.f,0.f);
  for (int p = s + tid; p < e; p += 256){
    float4 ph = pht[(size_t)hr[p]*2];
    float4 pt = pht[(size_t)tr[p]*2 + 1];
    sm.x += expf(lrelu_(ph.x + pt.x) - m.x);
    sm.y += expf(lrelu_(ph.y + pt.y) - m.y);
    sm.z += expf(lrelu_(ph.z + pt.z) - m.z);
    sm.w += expf(lrelu_(ph.w + pt.w) - m.w);
  }
  #pragma unroll
  for (int o = 1; o < 64; o <<= 1){
    sm.x += __shfl_xor(sm.x, o);
    sm.y += __shfl_xor(sm.y, o);
    sm.z += __shfl_xor(sm.z, o);
    sm.w += __shfl_xor(sm.w, o);
  }
  if (lane == 0) reds[w] = sm;
  __syncthreads();
  float4 sv;
  sv.x = reds[0].x + reds[1].x + reds[2].x + reds[3].x;
  sv.y = reds[0].y + reds[1].y + reds[2].y + reds[3].y;
  sv.z = reds[0].z + reds[1].z + reds[2].z + reds[3].z;
  sv.w = reds[0].w + reds[1].w + reds[2].w + reds[3].w;
  float4 inv;
  inv.x = 1.f/(sv.x + 1e-16f); inv.y = 1.f/(sv.y + 1e-16f);
  inv.z = 1.f/(sv.z + 1e-16f); inv.w = 1.f/(sv.w + 1e-16f);
  for (int p = s + tid; p < e; p += 256){
    float4 ph = pht[(size_t)hr[p]*2];
    float4 pt = pht[(size_t)tr[p]*2 + 1];
    s1p[p] = expf(lrelu_(ph.x + pt.x) - m.x)*inv.x + expf(lrelu_(ph.y + pt.y) - m.y)*inv.y;
    s2p[p] = expf(lrelu_(ph.z + pt.z) - m.z)*inv.z + expf(lrelu_(ph.w + pt.w) - m.w)*inv.w;
  }
}

// ---------------- E2R aggregate ----------------
__global__ void k_e2r_agg3(const int* __restrict__ off,
                           const int* __restrict__ hr, const int* __restrict__ tr,
                           const float* __restrict__ s1p, const float* __restrict__ s2p,
                           const float4* __restrict__ xhxt4, float4* __restrict__ xr_part){
  int r = blockIdx.x, c = blockIdx.y;
  int lane = threadIdx.x;
  int side = lane >> 5, fl = lane & 31;
  int s = off[r], e = off[r+1];
  int len = e - s;
  int per = (len + NC_ - 1)/NC_;
  int cs = s + c*per, ce = min(cs + per, e);
  float4 acc = make_float4(0.f,0.f,0.f,0.f);
  if (fl < RH4){
    const int* idx = side ? tr : hr;
    const float* wv = side ? s2p : s1p;
    int fofs = side ? 25 + fl : fl;
    int p = cs;
    for (; p + 1 < ce; p += 2){
      float a0 = wv[p], a1 = wv[p+1];
      float4 v0 = xhxt4[(size_t)idx[p]*50 + fofs];
      float4 v1 = xhxt4[(size_t)idx[p+1]*50 + fofs];
      acc.x += a0*v0.x + a1*v1.x; acc.y += a0*v0.y + a1*v1.y;
      acc.z += a0*v0.z + a1*v1.z; acc.w += a0*v0.w + a1*v1.w;
    }
    if (p < ce){
      float a0 = wv[p];
      float4 v0 = xhxt4[(size_t)idx[p]*50 + fofs];
      acc.x += a0*v0.x; acc.y += a0*v0.y; acc.z += a0*v0.z; acc.w += a0*v0.w;
    }
  }
  float4 oth;
  oth.x = __shfl_xor(acc.x, 32); oth.y = __shfl_xor(acc.y, 32);
  oth.z = __shfl_xor(acc.z, 32); oth.w = __shfl_xor(acc.w, 32);
  if (side == 0 && fl < RH4){
    float4 o = make_float4(acc.x+oth.x, acc.y+oth.y, acc.z+oth.z, acc.w+oth.w);
    xr_part[((size_t)c*R_ + r)*RH4 + fl] = o;
  }
}

// reduce xr_part -> xr AND compute sr8
__global__ void k_e2r_red2(const float4* __restrict__ xr_part, float4* __restrict__ xr4,
                           const float* __restrict__ ar, float* __restrict__ sr8){
  __shared__ float row[RH_];
  int r = blockIdx.x, lane = threadIdx.x;
  if (lane < RH4){
    float4 a = make_float4(0.f,0.f,0.f,0.f);
    #pragma unroll
    for (int c = 0; c < NC_; ++c){
      float4 v = xr_part[((size_t)c*R_ + r)*RH4 + lane];
      a.x += v.x; a.y += v.y; a.z += v.z; a.w += v.w;
    }
    a.x *= 0.25f; a.y *= 0.25f; a.z *= 0.25f; a.w *= 0.25f;
    xr4[(size_t)r*RH4 + lane] = a;
    row[lane*4]   = a.x; row[lane*4+1] = a.y;
    row[lane*4+2] = a.z; row[lane*4+3] = a.w;
  }
  __syncthreads();
  int h = lane & 7, gk = lane >> 3;
  float acc = 0.f;
  for (int k = gk; k < RH_; k += 8) acc += row[k]*ar[(size_t)h*RH_ + k];
  #pragma unroll
  for (int o = 8; o < 64; o <<= 1) acc += __shfl_xor(acc, o);
  if (lane < 8) sr8[(size_t)r*8 + lane] = acc;
}

// ---------------- 16-head dots from one bf16 table (R2E) ----------------
__global__ void k_dots16b(const unsigned short* __restrict__ X, int ldx, int K, int Kw,
                          const float* __restrict__ wA, const float* __restrict__ wB,
                          float* __restrict__ out16, int M){
  __shared__ float xs[16][65];
  __shared__ float ws[16][65];
  int tid = threadIdx.x;
  int tx = tid & 15, ty = tid >> 4;
  int r0 = blockIdx.x*16;
  int lr = tid >> 4;
  int lc = (tid & 15)*4;
  float acc = 0.f;
  for (int c0 = 0; c0 < K; c0 += 64){
    int cl = min(64, K - c0);
    float4 xv = make_float4(0.f,0.f,0.f,0.f);
    if (r0 + lr < M && lc < cl){
      ushort4 u = *reinterpret_cast<const ushort4*>(&X[(size_t)(r0+lr)*ldx + c0 + lc]);
      xv.x = bf2f_(u.x); xv.y = bf2f_(u.y); xv.z = bf2f_(u.z); xv.w = bf2f_(u.w);
    }
    float4 wv = make_float4(0.f,0.f,0.f,0.f);
    if (lc < cl){
      const float* wsrc = (lr < 8) ? &wA[(size_t)lr*Kw + c0 + lc]
                                   : &wB[(size_t)(lr-8)*Kw + c0 + lc];
      wv = *reinterpret_cast<const float4*>(wsrc);
    }
    xs[lr][lc] = xv.x; xs[lr][lc+1] = xv.y; xs[lr][lc+2] = xv.z; xs[lr][lc+3] = xv.w;
    ws[lr][lc] = wv.x; ws[lr][lc+1] = wv.y; ws[lr][lc+2] = wv.z; ws[lr][lc+3] = wv.w;
    __syncthreads();
    #pragma unroll
    for (int k = 0; k < 64; ++k) acc += xs[ty][k]*ws[tx][k];
    __syncthreads();
  }
  if (r0 + ty < M) out16[(size_t)(r0+ty)*16 + tx] = acc;
}

// ---------------- GAT head dots: both tables in one launch ----------------
__global__ void k_dots16g(const unsigned short* __restrict__ xb,
                          const unsigned short* __restrict__ xeb,
                          const float* __restrict__ wA, const float* __restrict__ wB,
                          float* __restrict__ out16, int M){
  __shared__ float xs[16][65];
  __shared__ float ws[16][65];
  int tid = threadIdx.x;
  int tx = tid & 15, ty = tid >> 4;
  int r0 = blockIdx.x*16;
  int lr = tid >> 4;
  int lc = (tid & 15)*4;
  float acc = 0.f;
  for (int c0 = 0; c0 < 500; c0 += 64){
    int cl = min(64, 500 - c0);
    int col = c0 + lc;
    float4 xv = make_float4(0.f,0.f,0.f,0.f);
    if (r0 + lr < M && lc < cl){
      ushort4 u = (col < 300)
        ? *reinterpret_cast<const ushort4*>(&xb[(size_t)(r0+lr)*XBS_ + col])
        : *reinterpret_cast<const ushort4*>(&xeb[(size_t)(r0+lr)*XEBS_ + col - 300]);
      xv.x = bf2f_(u.x); xv.y = bf2f_(u.y); xv.z = bf2f_(u.z); xv.w = bf2f_(u.w);
    }
    float4 wv = make_float4(0.f,0.f,0.f,0.f);
    if (lc < cl){
      const float* wsrc = (lr < 8) ? &wA[(size_t)lr*500 + col]
                                   : &wB[(size_t)(lr-8)*500 + col];
      wv = *reinterpret_cast<const float4*>(wsrc);
    }
    xs[lr][lc] = xv.x; xs[lr][lc+1] = xv.y; xs[lr][lc+2] = xv.z; xs[lr][lc+3] = xv.w;
    ws[lr][lc] = wv.x; ws[lr][lc+1] = wv.y; ws[lr][lc+2] = wv.z; ws[lr][lc+3] = wv.w;
    __syncthreads();
    #pragma unroll
    for (int k = 0; k < 64; ++k) acc += xs[ty][k]*ws[tx][k];
    __syncthreads();
  }
  if (r0 + ty < M) out16[(size_t)(r0+ty)*16 + tx] = acc;
}

// ---------------- fused R2E: online softmax + aggregate ----------------
__global__ void k_r2e_fused(const int* __restrict__ offh, const int* __restrict__ offt,
                            const int* __restrict__ relh, const int* __restrict__ relt,
                            const float* __restrict__ st16, const float* __restrict__ sr8,
                            const float4* __restrict__ xr4, float4* __restrict__ out,
                            unsigned short* __restrict__ xeb){
  int n = blockIdx.x;
  int side = threadIdx.x >> 6, lane = threadIdx.x & 63;
  const int* off = side ? offt : offh;
  const int* rl  = side ? relt : relh;
  int s = off[n], e = off[n+1];
  int k = lane & 7, g = lane >> 3;
  float cst = st16[(size_t)n*16 + side*8 + k];
  // online (m,s) over strided edges
  float m = -1e30f, sum = 0.f;
  for (int p = s + g; p < e; p += 8)
    onl_add_(m, sum, lrelu_(cst + sr8[(size_t)rl[p]*8 + k]));
  #pragma unroll
  for (int o = 8; o < 64; o <<= 1){
    float om = __shfl_xor(m, o), os = __shfl_xor(sum, o);
    onl_cmb_(m, sum, om, os);
  }
  float inv = 1.f / (sum + 1e-16f);
  float mks[8], invs[8], csts[8];
  int gb = lane & 56;
  #pragma unroll
  for (int kk = 0; kk < 8; ++kk){
    mks[kk]  = __shfl(m,   gb + kk);
    invs[kk] = __shfl(inv, gb + kk);
    csts[kk] = __shfl(cst, gb + kk);
  }
  float4 acc = make_float4(0.f,0.f,0.f,0.f);
  for (int base = s; base < e; base += 64){
    int mm = min(64, e - base);
    int rlv = 0; float alpha = 0.f;
    if (lane < mm){
      rlv = rl[base + lane];
      const float4* sr4 = reinterpret_cast<const float4*>(&sr8[(size_t)rlv*8]);
      float4 s0 = sr4[0], s1 = sr4[1];
      float sv[8] = {s0.x,s0.y,s0.z,s0.w,s1.x,s1.y,s1.z,s1.w};
      #pragma unroll
      for (int kk = 0; kk < 8; ++kk)
        alpha += expf(lrelu_(csts[kk] + sv[kk]) - mks[kk]) * invs[kk];
    }
    for (int q = 0; q < mm; ++q){
      float a = __shfl(alpha, q);
      int rr = __shfl(rlv, q);
      if (lane < RH4){
        float4 v = xr4[(size_t)rr*RH4 + lane];
        acc.x += a*v.x; acc.y += a*v.y; acc.z += a*v.z; acc.w += a*v.w;
      }
    }
  }
  if (lane < RH4){
    float4 o = make_float4(acc.x*0.125f, acc.y*0.125f, acc.z*0.125f, acc.w*0.125f);
    out[(size_t)n*LD4 + (side ? 100 : 75) + lane] = o;
    ushort4 ob;
    ob.x = f2bf_(o.x); ob.y = f2bf_(o.y); ob.z = f2bf_(o.z); ob.w = f2bf_(o.w);
    *reinterpret_cast<ushort4*>(&xeb[(size_t)n*XEBS_ + (side ? 100 : 0) + lane*4]) = ob;
  }
}

// ---------------- fused GAT: online softmax + aggregate ----------------
__global__ void k_gat_fused(const int* __restrict__ off, const int* __restrict__ jd,
                            const float* __restrict__ gg16,
                            const unsigned short* __restrict__ xb,
                            const unsigned short* __restrict__ xeb,
                            float4* __restrict__ out){
  __shared__ int js[128];
  __shared__ float as_[128];
  __shared__ float wm_[2][8], ws_[2][8];
  __shared__ float mkS[8], invS[8], cstS[8];
  int n = blockIdx.x, tid = threadIdx.x;
  int wv = tid >> 6, lane = tid & 63;
  int s = off[n], t = off[n+1];
  int k = tid & 7, g = tid >> 3;     // 16 groups x 8 heads
  float cst = gg16[(size_t)n*16 + k];
  // single online stats pass
  float m = -1e30f, sum = 0.f;
  for (int p = s + g; p < t; p += 16){
    int j = jd[p];
    onl_add_(m, sum, lrelu_(cst + gg16[(size_t)j*16 + 8 + k]));
  }
  #pragma unroll
  for (int o = 8; o < 64; o <<= 1){
    float om = __shfl_xor(m, o), os = __shfl_xor(sum, o);
    onl_cmb_(m, sum, om, os);
  }
  if (lane < 8){ wm_[wv][lane] = m; ws_[wv][lane] = sum; }
  __syncthreads();
  if (tid < 8){
    float m0 = wm_[0][tid], s0 = ws_[0][tid];
    float m1 = wm_[1][tid], s1 = ws_[1][tid];
    float nm = fmaxf(m0, m1);
    float ns = s0*expf(m0 - nm) + s1*expf(m1 - nm);
    mkS[tid] = nm;
    invS[tid] = 1.f / (ns + 1e-16f);
    cstS[tid] = gg16[(size_t)n*16 + tid];
  }
  __syncthreads();
  // aggregate
  const unsigned short* tbl;
  size_t stride; int cofs;
  if (tid < 75){ tbl = xb;  stride = XBS_;  cofs = tid*4; }
  else         { tbl = xeb; stride = XEBS_; cofs = (tid-75)*4; }
  float4 acc = make_float4(0.f,0.f,0.f,0.f);
  for (int base = s; base < t; base += 128){
    int mm = min(128, t - base);
    __syncthreads();
    if (tid < mm) js[tid] = jd[base+tid];
    __syncthreads();
    if (tid < mm){
      int j = js[tid];
      const float4* gj = reinterpret_cast<const float4*>(&gg16[(size_t)j*16 + 8]);
      float4 l0 = gj[0], l1 = gj[1];
      float a = 0.f;
      a += expf(lrelu_(cstS[0] + l0.x) - mkS[0]) * invS[0];
      a += expf(lrelu_(cstS[1] + l0.y) - mkS[1]) * invS[1];
      a += expf(lrelu_(cstS[2] + l0.z) - mkS[2]) * invS[2];
      a += expf(lrelu_(cstS[3] + l0.w) - mkS[3]) * invS[3];
      a += expf(lrelu_(cstS[4] + l1.x) - mkS[4]) * invS[4];
      a += expf(lrelu_(cstS[5] + l1.y) - mkS[5]) * invS[5];
      a += expf(lrelu_(cstS[6] + l1.z) - mkS[6]) * invS[6];
      a += expf(lrelu_(cstS[7] + l1.w) - mkS[7]) * invS[7];
      as_[tid] = a;
    }
    __syncthreads();
    if (tid < 125){
      int q = 0;
      for (; q + 3 < mm; q += 4){
        float a0 = as_[q], a1 = as_[q+1], a2 = as_[q+2], a3 = as_[q+3];
        ushort4 u0 = *reinterpret_cast<const ushort4*>(&tbl[(size_t)js[q]*stride + cofs]);
        ushort4 u1 = *reinterpret_cast<const ushort4*>(&tbl[(size_t)js[q+1]*stride + cofs]);
        ushort4 u2 = *reinterpret_cast<const ushort4*>(&tbl[(size_t)js[q+2]*stride + cofs]);
        ushort4 u3 = *reinterpret_cast<const ushort4*>(&tbl[(size_t)js[q+3]*stride + cofs]);
        acc.x += a0*bf2f_(u0.x)+a1*bf2f_(u1.x)+a2*bf2f_(u2.x)+a3*bf2f_(u3.x);
        acc.y += a0*bf2f_(u0.y)+a1*bf2f_(u1.y)+a2*bf2f_(u2.y)+a3*bf2f_(u3.y);
        acc.z += a0*bf2f_(u0.z)+a1*bf2f_(u1.z)+a2*bf2f_(u2.z)+a3*bf2f_(u3.z);
        acc.w += a0*bf2f_(u0.w)+a1*bf2f_(u1.w)+a2*bf2f_(u2.w)+a3*bf2f_(u3.w);
      }
      for (; q < mm; ++q){
        float a0 = as_[q];
        ushort4 u0 = *reinterpret_cast<const ushort4*>(&tbl[(size_t)js[q]*stride + cofs]);
        acc.x += a0*bf2f_(u0.x); acc.y += a0*bf2f_(u0.y);
        acc.z += a0*bf2f_(u0.z); acc.w += a0*bf2f_(u0.w);
      }
    }
  }
  if (tid < 125){
    float4 r = make_float4(acc.x*0.125f, acc.y*0.125f, acc.z*0.125f, acc.w*0.125f);
    out[(size_t)n*LD4 + 125 + tid] = r;
  }
}

// ---------------- host ----------------
static inline void gemm_mfma(const unsigned short* Ab, const unsigned short* Wb,
                             float* C, int ldc, int M, int Nn, hipStream_t st){
  dim3 g((M + 127)/128, (Nn + 63)/64);
  k_gemm_mfma<<<g, 256, 0, st>>>(Ab, Wb, C, ldc, M, Nn);
}

extern "C" void kernel_launch(void* const* d_in, const int* in_sizes, int n_in,
                              void* d_out, int out_size, void* d_ws, size_t ws_size,
                              hipStream_t stream) {
  const float* x_e   = (const float*)d_in[0];
  const int*   ei    = (const int*)d_in[1];
  const int*   rel   = (const int*)d_in[2];
  const int*   eia   = (const int*)d_in[3];
  const float* hw1_w = (const float*)d_in[5];
  const float* hw1_b = (const float*)d_in[6];
  const float* hw2_w = (const float*)d_in[7];
  const float* hw2_b = (const float*)d_in[8];
  const float* e2r_wh= (const float*)d_in[9];
  const float* e2r_wt= (const float*)d_in[10];
  const float* e2r_ah= (const float*)d_in[11];
  const float* e2r_at= (const float*)d_in[12];
  const float* r2e_ah= (const float*)d_in[13];
  const float* r2e_at= (const float*)d_in[14];
  const float* r2e_ar= (const float*)d_in[15];
  const float* gat_ai= (const float*)d_in[16];
  const float* gat_aj= (const float*)d_in[17];
  float* out = (float*)d_out;

  const int* hi = ei;
  const int* ti = ei + E_;
  const int* ja = eia;
  const int* ia = eia + EALL_;

  char* base = (char*)d_ws;
  size_t off = 0;
  auto alloc = [&](size_t bytes)->void*{
    void* p = base + off;
    off = (off + bytes + 255) & ~(size_t)255;
    return p;
  };

  size_t z0 = off;
  int* cnt_dest = (int*)alloc(SCNP_*4);
  int* cnt_h    = (int*)alloc(SCNP_*4);
  int* cnt_t    = (int*)alloc(SCNP_*4);
  int* cur_dest = (int*)alloc(N_*4);
  int* cur_h    = (int*)alloc(N_*4);
  int* cur_t    = (int*)alloc(N_*4);
  size_t z1 = off;

  int* off_dest = (int*)alloc(SCNP_*4);
  int* off_h    = (int*)alloc(SCNP_*4);
  int* off_t    = (int*)alloc(SCNP_*4);
  int* off_rel  = (int*)alloc((R_+1)*4);
  int* bsum     = (int*)alloc(3*NSB_*4);
  int* Hrel     = (int*)alloc((size_t)NBR_*R_*4);
  int* j_dest   = (int*)alloc((size_t)EALL_*4);
  int* hr       = (int*)alloc((size_t)E_*4);
  int* tr       = (int*)alloc((size_t)E_*4);
  int* relh     = (int*)alloc((size_t)E_*4);
  int* relt     = (int*)alloc((size_t)E_*4);

  float* dis   = (float*)alloc(SCNP_*4);
  float* wj    = (float*)alloc((size_t)EALL_*4);
  float* g     = (float*)alloc((size_t)N_*EH_*4);
  float* xhxt  = (float*)alloc((size_t)N_*200*4);
  float* pht   = (float*)alloc((size_t)N_*8*4);
  float* s1p   = (float*)alloc((size_t)E_*4);
  float* s2p   = (float*)alloc((size_t)E_*4);
  float* xr    = (float*)alloc((size_t)R_*RH_*4);
  float* xr_part=(float*)alloc((size_t)NC_*R_*RH_*4);
  float* st16  = (float*)alloc((size_t)N_*16*4);
  float* sr8   = (float*)alloc((size_t)R_*8*4);
  float* gg16  = (float*)alloc((size_t)N_*16*4);
  unsigned short* xbA = (unsigned short*)alloc((size_t)N_*XBS_*2);
  unsigned short* xbB = (unsigned short*)alloc((size_t)N_*XBS_*2);
  unsigned short* xeb = (unsigned short*)alloc((size_t)N_*XEBS_*2);
  unsigned short* w1b = (unsigned short*)alloc((size_t)EH_*KP_*2);
  unsigned short* w2b = (unsigned short*)alloc((size_t)EH_*KP_*2);
  unsigned short* wcb = (unsigned short*)alloc((size_t)200*KP_*2);

  hipMemsetAsync(base + z0, 0, z1 - z0, stream);

  const int TB = 256;
  const int TOT = EALL_ + 2*E_;
  int gTOT  = (TOT + TB - 1)/TB;
  int gN    = (N_ + TB - 1)/TB;
  const int PTOT = 2*EH_*KP_ + 200*KP_ + N_*80;

  k_pack_all<<<(PTOT + TB - 1)/TB, TB, 0, stream>>>(hw1_w, hw2_w, e2r_wh, e2r_wt,
                                                    (const float4*)x_e,
                                                    w1b, w2b, wcb, xbA);

  k_build1<<<NBR_ + gTOT, TB, 0, stream>>>(rel, ia, hi, ti, Hrel, cnt_dest, cnt_h, cnt_t);
  k_scanA<<<3*NSB_, 256, 0, stream>>>(cnt_dest, cnt_h, cnt_t, bsum);
  k_mid<<<2, 256, 0, stream>>>(Hrel, off_rel, bsum, off_dest, off_h, off_t);
  k_scanC<<<3*NSB_, 256, 0, stream>>>(cnt_dest, cnt_h, cnt_t, bsum,
                                      off_dest, off_h, off_t, dis);
  k_build2<<<NBR_ + gTOT, TB, 0, stream>>>(rel, hi, ti, Hrel, hr, tr,
                                           ja, ia, off_dest, off_h, off_t,
                                           cur_dest, cur_h, cur_t,
                                           dis, j_dest, wj, relh, relt);

  gemm_mfma(xbA, w1b, g, EH_, N_, EH_, stream);
  k_gcn5<<<N_, 64, 0, stream>>>(off_dest, j_dest, wj, dis, xbA,
                                (const float4*)g, hw1_b, (float4*)out, xbB);
  gemm_mfma(xbB, w2b, g, EH_, N_, EH_, stream);
  k_gcn5<<<N_, 64, 0, stream>>>(off_dest, j_dest, wj, dis, xbB,
                                (const float4*)g, hw2_b, (float4*)out, xbA);

  gemm_mfma(xbA, wcb, xhxt, 200, N_, 200, stream);
  k_pproj<<<gN, TB, 0, stream>>>(xhxt, e2r_ah, e2r_at, (float4*)pht);
  k_fold_rel2<<<R_, 256, 0, stream>>>(off_rel, hr, tr, (const float4*)pht, s1p, s2p);
  k_e2r_agg3<<<dim3(R_, NC_), 64, 0, stream>>>(off_rel, hr, tr, s1p, s2p,
                                               (const float4*)xhxt, (float4*)xr_part);
  k_e2r_red2<<<R_, 64, 0, stream>>>((const float4*)xr_part, (float4*)xr, r2e_ar, sr8);

  k_dots16b<<<(N_+15)/16, 256, 0, stream>>>(xbA, XBS_, EH_, EH_, r2e_ah, r2e_at, st16, N_);
  k_r2e_fused<<<N_, 128, 0, stream>>>(off_h, off_t, relh, relt, st16, sr8,
                                      (const float4*)xr, (float4*)out, xeb);

  k_dots16g<<<(N_+15)/16, 256, 0, stream>>>(xbA, xeb, gat_ai, gat_aj, gg16, N_);
  k_gat_fused<<<N_, 128, 0, stream>>>(off_dest, j_dest, gg16, xbA, xeb, (float4*)out);
}